// Round 6
// baseline (1944.716 us; speedup 1.0000x reference)
//
#include <hip/hip_runtime.h>
#include <math.h>
#include <stdint.h>

#define LL 2
#define HH 4
#define DHH 64
#define DD 256
#define BB 8
#define NI 8192
#define ND 4096
#define NROW 12288
#define KPOOL 768
#define EC 65536
#define EI 32768
#define EO 32768
#define EK 8192
#define EHGT (EC+EI+EO+EK)

typedef unsigned short u16;
typedef short bf16x8 __attribute__((ext_vector_type(8)));
typedef float f32x4 __attribute__((ext_vector_type(4)));
typedef unsigned short u16x4 __attribute__((ext_vector_type(4)));

__device__ inline float gelu_f(float x){ return 0.5f*x*(1.f+erff(x*0.70710678118654752f)); }
__device__ inline u16 f2b(float x){ uint32_t u=__float_as_uint(x); return (u16)((u + 0x7fffu + ((u>>16)&1u))>>16); }
__device__ inline float b2f(u16 h){ return __uint_as_float(((uint32_t)h)<<16); }

// ---------------- generic fill ----------------
__global__ void fill_u32(uint32_t* p, uint32_t v, int n){
    int i = blockIdx.x*256 + threadIdx.x;
    if(i<n) p[i]=v;
}

// ---------------- activation split-convert ----------------
__global__ void cvt_split(const float* __restrict__ A, int nA, const float* __restrict__ B, int nB,
                          u16* __restrict__ oh, u16* __restrict__ ol){
    int i = (blockIdx.x*256 + threadIdx.x)*4;
    int tot = nA + nB;
    if(i >= tot) return;
    float4 v = (i < nA) ? *(const float4*)(A + i) : *(const float4*)(B + (i - nA));
    float vv[4] = {v.x, v.y, v.z, v.w};
    u16x4 h4, l4;
    #pragma unroll
    for(int j=0;j<4;j++){
        float x = vv[j];
        u16 h = f2b(x);
        h4[j] = h;
        l4[j] = f2b(x - b2f(h));
    }
    *(u16x4*)(oh + i) = h4;
    *(u16x4*)(ol + i) = l4;
}

// ---------------- weight transpose + split ----------------
struct WCArgs { const float* in[8]; u16* oh[8]; u16* ol[8]; int cnt[8]; int nr; };
__global__ void wcvt_split(WCArgs a){
    int mat = blockIdx.y, ri = 0;
    while(ri < a.nr-1 && mat >= a.cnt[ri]){ mat -= a.cnt[ri]; ri++; }
    const float* in = a.in[ri] + (size_t)mat*65536;
    u16* oh = a.oh[ri] + (size_t)mat*65536;
    u16* ol = a.ol[ri] + (size_t)mat*65536;
    int n = blockIdx.x, k = threadIdx.x;
    float x = in[(size_t)k*DD + n];
    u16 h = f2b(x);
    oh[n*DD + k] = h;
    ol[n*DD + k] = f2b(x - b2f(h));
}

// ---------------- MFMA batched GEMM with fused epilogues ----------------
// mode 0: C=f32   mode 1: Oh/Ol=split bf16
// mode 2: Xacc = 0.5*(g*acc + (1-g)*X)
// mode 3: v=relu(Xacc + 0.5*(g*acc+(1-g)*X)); C=v; Oh/Ol=split(v)
struct GDesc { const u16* Ah; const u16* Al; const u16* Bh; const u16* Bl;
               float* C; u16* Oh; u16* Ol;
               const float* X; float* Xacc; const float* skipp;
               int mblks; int mode; };
struct GArgs { GDesc d[10]; int nd; };

__global__ __launch_bounds__(256) void gemm_mfma(GArgs ga){
    __shared__ u16 Ah[128][40], Al[128][40], Bh[128][40], Bl[128][40];
    int mb = blockIdx.x, di = 0;
    while(di < ga.nd-1 && mb >= ga.d[di].mblks){ mb -= ga.d[di].mblks; di++; }
    GDesc g = ga.d[di];
    const int m0 = mb*128, n0 = blockIdx.y*128;
    const int tid = threadIdx.x;
    const int lane = tid & 63, wid = tid >> 6;
    const int wm = (wid>>1)*64, wn = (wid&1)*64;
    const int l15 = lane & 15, l4 = lane >> 4;
    const int srow = tid >> 1, scol = (tid & 1)*16;
    const size_t aoff = (size_t)(m0 + srow)*DD + scol;
    const size_t boff = (size_t)(n0 + srow)*DD + scol;
    f32x4 acc[4][4] = {};
    for(int k0=0;k0<DD;k0+=32){
        bf16x8 ah0 = *(const bf16x8*)(g.Ah + aoff + k0);
        bf16x8 ah1 = *(const bf16x8*)(g.Ah + aoff + k0 + 8);
        bf16x8 al0 = *(const bf16x8*)(g.Al + aoff + k0);
        bf16x8 al1 = *(const bf16x8*)(g.Al + aoff + k0 + 8);
        bf16x8 bh0 = *(const bf16x8*)(g.Bh + boff + k0);
        bf16x8 bh1 = *(const bf16x8*)(g.Bh + boff + k0 + 8);
        bf16x8 bl0 = *(const bf16x8*)(g.Bl + boff + k0);
        bf16x8 bl1 = *(const bf16x8*)(g.Bl + boff + k0 + 8);
        __syncthreads();
        *(bf16x8*)&Ah[srow][scol] = ah0; *(bf16x8*)&Ah[srow][scol+8] = ah1;
        *(bf16x8*)&Al[srow][scol] = al0; *(bf16x8*)&Al[srow][scol+8] = al1;
        *(bf16x8*)&Bh[srow][scol] = bh0; *(bf16x8*)&Bh[srow][scol+8] = bh1;
        *(bf16x8*)&Bl[srow][scol] = bl0; *(bf16x8*)&Bl[srow][scol+8] = bl1;
        __syncthreads();
        bf16x8 afh[4], afl[4], bfh[4], bfl[4];
        #pragma unroll
        for(int i=0;i<4;i++){
            afh[i] = *(const bf16x8*)&Ah[wm + i*16 + l15][l4*8];
            afl[i] = *(const bf16x8*)&Al[wm + i*16 + l15][l4*8];
            bfh[i] = *(const bf16x8*)&Bh[wn + i*16 + l15][l4*8];
            bfl[i] = *(const bf16x8*)&Bl[wn + i*16 + l15][l4*8];
        }
        #pragma unroll
        for(int i=0;i<4;i++)
            #pragma unroll
            for(int j=0;j<4;j++){
                acc[i][j] = __builtin_amdgcn_mfma_f32_16x16x32_bf16(afh[i], bfh[j], acc[i][j], 0,0,0);
                acc[i][j] = __builtin_amdgcn_mfma_f32_16x16x32_bf16(afh[i], bfl[j], acc[i][j], 0,0,0);
                acc[i][j] = __builtin_amdgcn_mfma_f32_16x16x32_bf16(afl[i], bfh[j], acc[i][j], 0,0,0);
            }
    }
    const int mode = g.mode;
    float gg = 0.f;
    if(mode >= 2) gg = 1.f/(1.f + expf(-*g.skipp));
    #pragma unroll
    for(int i=0;i<4;i++){
        #pragma unroll
        for(int j=0;j<4;j++){
            int ccol = n0 + wn + j*16 + l15;
            #pragma unroll
            for(int r=0;r<4;r++){
                int row = m0 + wm + i*16 + l4*4 + r;
                size_t o = (size_t)row*DD + ccol;
                float val = acc[i][j][r];
                if(mode==0){
                    g.C[o] = val;
                } else if(mode==1){
                    u16 hh = f2b(val); g.Oh[o]=hh; g.Ol[o]=f2b(val-b2f(hh));
                } else {
                    float v2 = gg*val + (1.f-gg)*g.X[o];
                    if(mode==2){
                        g.Xacc[o] = 0.5f*v2;
                    } else {
                        float v3 = g.Xacc[o] + 0.5f*v2;
                        v3 = v3 > 0.f ? v3 : 0.f;
                        g.C[o] = v3;
                        u16 hh = f2b(v3); g.Oh[o]=hh; g.Ol[o]=f2b(v3-b2f(hh));
                    }
                }
            }
        }
    }
}

// ---------- combine ----------
__global__ void combine_all(const float* __restrict__ Wk, const float* __restrict__ Wv,
                            const float* __restrict__ Ra, const float* __restrict__ Rm,
                            float* __restrict__ wtk, float* __restrict__ wtv){
    const int st_tab[2][4] = {{0,1,0,0},{0,0,1,0}};
    int combo = blockIdx.y;
    int idx = combo >> 1, kv = combo & 1;
    int r = idx & 3, wb = idx >> 2, dir = wb & 1;
    int st = st_tab[dir][r];
    const float* W = (kv ? Wv : Wk) + (size_t)(wb*2 + st)*65536;
    const float* R = (kv ? Rm : Ra) + (size_t)idx*16384;
    float* o = (kv ? wtv : wtk) + (size_t)idx*65536;
    int d = blockIdx.x, c = threadIdx.x;
    int h = c >> 6, f = c & 63;
    const float* Wrow = W + d*DD + h*64;
    const float* Rh = R + h*4096 + f;
    float s = 0.f;
    #pragma unroll 8
    for(int k=0;k<64;k++) s += Wrow[k]*Rh[k*64];
    o[d*DD + c] = s;
}

// ---------------- CSR build (both directions in one pass) ----------------
__device__ inline void edge_decode(int e, int& r, int& el){
    if(e < EC){ r=0; el=e; }
    else if(e < EC+EI){ r=1; el=e-EC; }
    else if(e < EC+EI+EO){ r=2; el=e-(EC+EI); }
    else { r=3; el=e-(EC+EI+EO); }
}

struct CB2 {
    const int* row[8]; const int* col[8];
    int dt[8];
    uint32_t* cnt; uint32_t* rowptr; uint32_t* einfo; uint32_t* slot;
};

__global__ void csr_hist2(CB2 a){
    int ge = blockIdx.x*256 + threadIdx.x;
    if(ge >= 2*EHGT) return;
    int dir = ge >= EHGT;
    int e = ge - dir*EHGT;
    int r, el; edge_decode(e, r, el);
    int idx = dir*4 + r;
    int c = a.col[idx][el];
    int dst = dir*NROW + (a.dt[idx] ? (NI + c) : c);
    atomicAdd(&a.cnt[dst], 1u);
}

__global__ __launch_bounds__(1024) void scan_rowptr2(uint32_t* cnt, uint32_t* rowptr){
    __shared__ uint32_t part[1024];
    int t = threadIdx.x;
    int base = t*24;
    uint32_t lpre[24];
    uint32_t sum = 0;
    #pragma unroll
    for(int i=0;i<24;i++){
        uint32_t c = cnt[base+i];
        lpre[i] = sum; sum += c;
        cnt[base+i] = 0;
    }
    part[t] = sum;
    __syncthreads();
    for(int offs=1; offs<1024; offs<<=1){
        uint32_t v = (t>=offs) ? part[t-offs] : 0u;
        __syncthreads();
        part[t] += v;
        __syncthreads();
    }
    uint32_t pre = (t==0) ? 0u : part[t-1];
    #pragma unroll
    for(int i=0;i<24;i++) rowptr[base+i] = pre + lpre[i];
    if(t==1023) rowptr[2*NROW] = part[1023];
}

__global__ void csr_scatter2(CB2 a){
    int ge = blockIdx.x*256 + threadIdx.x;
    if(ge >= 2*EHGT) return;
    int dir = ge >= EHGT;
    int e = ge - dir*EHGT;
    int r, el; edge_decode(e, r, el);
    int idx = dir*4 + r;
    int c = a.col[idx][el];
    int dst = dir*NROW + (a.dt[idx] ? (NI + c) : c);
    int src = a.row[idx][el];
    uint32_t p = a.rowptr[dst] + atomicAdd(&a.cnt[dst], 1u);
    a.einfo[p] = (uint32_t)src | ((uint32_t)r << 16);
    a.slot[ge] = p;
}

// ---------------- HGT edge scores: wave per edge ----------------
struct P1Args {
    const int* row[4]; const int* col[4];
    const float* Q[2];
    const float* ka;
    const float* prel;
    const uint32_t* slot;
    float* sc;
    int dt[4];
};

__global__ __launch_bounds__(256) void hgt_pass1(P1Args a){
    int w = blockIdx.x*4 + (threadIdx.x >> 6);
    int lane = threadIdx.x & 63;
    if(w >= EHGT) return;
    int r, el; edge_decode(w, r, el);
    int dt = a.dt[r];
    int rn = a.row[r][el], cn = a.col[r][el];
    float4 qv = *(const float4*)(a.Q[dt] + (size_t)cn*DD + lane*4);
    float4 kv = *(const float4*)(a.ka + (size_t)r*NI*DD + (size_t)rn*DD + lane*4);
    float d = qv.x*kv.x + qv.y*kv.y + qv.z*kv.z + qv.w*kv.w;
    d += __shfl_xor(d, 1); d += __shfl_xor(d, 2);
    d += __shfl_xor(d, 4); d += __shfl_xor(d, 8);
    if((lane & 15) == 0){
        int h = lane >> 4;
        a.sc[(size_t)a.slot[w]*HH + h] = d * a.prel[r*HH + h] * 0.125f;
    }
}

// one wave per (dst,h): segment softmax + gather + gelu + split-bf16 out
__global__ __launch_bounds__(256) void hgt_rowpass(const uint32_t* __restrict__ rowptr,
                                                   const uint32_t* __restrict__ einfo,
                                                   const float* __restrict__ sc,
                                                   const float* __restrict__ vmb,
                                                   u16* __restrict__ bagg_h,
                                                   u16* __restrict__ bagg_l){
    int w = blockIdx.x*4 + (threadIdx.x >> 6);
    int lane = threadIdx.x & 63;
    int rowi = w >> 2, h = w & 3;
    uint32_t p0 = rowptr[rowi], p1 = rowptr[rowi+1];
    size_t obase = (size_t)rowi*DD + h*64 + lane;
    float o = 0.f;
    if(p0 != p1){
        float m = -INFINITY;
        for(uint32_t p = p0+lane; p < p1; p += 64) m = fmaxf(m, sc[(size_t)p*HH + h]);
        #pragma unroll
        for(int s=32;s;s>>=1) m = fmaxf(m, __shfl_xor(m, s));
        float den = 0.f;
        for(uint32_t p = p0+lane; p < p1; p += 64) den += expf(sc[(size_t)p*HH + h] - m);
        #pragma unroll
        for(int s=32;s;s>>=1) den += __shfl_xor(den, s);
        float inv = 1.f/(den + 1e-16f);
        for(uint32_t p = p0; p < p1; p++){
            uint32_t ei = einfo[p];
            int src = ei & 0xffff, r = ei >> 16;
            float alpha = expf(sc[(size_t)p*HH + h] - m) * inv;
            o += alpha * vmb[((size_t)r*NI + src)*DD + h*64 + lane];
        }
    }
    float g = gelu_f(o);
    u16 hh = f2b(g);
    bagg_h[obase] = hh;
    bagg_l[obase] = f2b(g - b2f(hh));
}

// ---------------- pooling ----------------
__global__ void pool_h2(const float* __restrict__ xi, const float* __restrict__ xd,
                        const float* __restrict__ w, float* __restrict__ h){
    int node = blockIdx.x*4 + (threadIdx.x>>6);
    int lane = threadIdx.x & 63;
    const float* xr = (node < NI) ? (xi + (size_t)node*DD) : (xd + (size_t)(node-NI)*DD);
    float s = 0.f;
    for(int j=lane;j<DD;j+=64) s += xr[j]*w[j];
    for(int m=32;m;m>>=1) s += __shfl_xor(s, m);
    if(lane==0) h[node] = s;
}

// GAT-style pooling score via fwd CSR + implicit self-loop; wave per dst node
__global__ __launch_bounds__(256) void pool_csr(const uint32_t* __restrict__ rowptr,
                                                const uint32_t* __restrict__ einfo,
                                                const float* __restrict__ h,
                                                const float* __restrict__ att,
                                                float* __restrict__ score){
    int w = blockIdx.x*4 + (threadIdx.x >> 6);
    int lane = threadIdx.x & 63;
    if(w >= NROW) return;
    uint32_t p0 = rowptr[w], p1 = rowptr[w+1];
    float a0 = att[0], a1 = att[1];
    float hn = h[w];
    float es = a0*hn + a1*hn;
    es = es >= 0.f ? es : 0.2f*es;
    float m = -INFINITY;
    for(uint32_t p = p0+lane; p < p1; p += 64){
        uint32_t ei = einfo[p];
        int src = ei & 0xffff, r = ei >> 16;
        float hs = h[r==1 ? NI+src : src];
        float e = a0*hs + a1*hn;
        e = e >= 0.f ? e : 0.2f*e;
        m = fmaxf(m, e);
    }
    #pragma unroll
    for(int s=32;s;s>>=1) m = fmaxf(m, __shfl_xor(m, s));
    m = fmaxf(m, es);
    float lden = 0.f, lnum = 0.f;
    for(uint32_t p = p0+lane; p < p1; p += 64){
        uint32_t ei = einfo[p];
        int src = ei & 0xffff, r = ei >> 16;
        float hs = h[r==1 ? NI+src : src];
        float e = a0*hs + a1*hn;
        e = e >= 0.f ? e : 0.2f*e;
        float a = expf(e - m);
        lden += a; lnum += a*hs;
    }
    #pragma unroll
    for(int s=32;s;s>>=1){ lden += __shfl_xor(lden, s); lnum += __shfl_xor(lnum, s); }
    float aself = expf(es - m);
    lden += aself; lnum += aself*hn;
    if(lane==0) score[w] = lnum/(lden + 1e-16f);
}

// top-768 of 1536 per graph via bitonic sort
__global__ __launch_bounds__(512) void topk_kernel(const float* __restrict__ score,
                                                   const float* __restrict__ bias,
                                                   int* __restrict__ sel_node,
                                                   float* __restrict__ sel_scale){
    __shared__ float skey[2048];
    __shared__ int   sval[2048];
    int b = blockIdx.x;
    float bv = bias[0];
    for(int p=threadIdx.x;p<2048;p+=512){
        if(p<1536){
            int node = (p<1024) ? (b*1024 + p) : (NI + b*512 + (p-1024));
            skey[p] = score[node] + bv;
            sval[p] = node;
        } else {
            skey[p] = -INFINITY;
            sval[p] = -1;
        }
    }
    for(int k=2;k<=2048;k<<=1){
        for(int j=k>>1;j>0;j>>=1){
            __syncthreads();
            for(int i=threadIdx.x;i<2048;i+=512){
                int ixj = i^j;
                if(ixj > i){
                    bool up = ((i & k) == 0);
                    float ki = skey[i], kj = skey[ixj];
                    if((ki < kj) == up){
                        skey[i]=kj; skey[ixj]=ki;
                        int t=sval[i]; sval[i]=sval[ixj]; sval[ixj]=t;
                    }
                }
            }
        }
    }
    __syncthreads();
    for(int j=threadIdx.x;j<KPOOL;j+=512){
        sel_node[b*KPOOL + j] = sval[j];
        sel_scale[b*KPOOL + j] = tanhf(skey[j]);
    }
}

__global__ void gather_xp(const int* __restrict__ sel, const float* __restrict__ scale,
                          const float* __restrict__ xi, const float* __restrict__ xd,
                          float* __restrict__ xp, u16* __restrict__ bh, u16* __restrict__ bl){
    int i = blockIdx.x*256 + threadIdx.x;
    int rowp = i >> 8, c = i & 255;
    int node = sel[rowp];
    float s = scale[rowp];
    float v = (node < NI) ? xi[(size_t)node*DD + c] : xd[(size_t)(node-NI)*DD + c];
    float x = v*s;
    xp[i] = x;
    u16 hh = f2b(x);
    bh[i] = hh;
    bl[i] = f2b(x - b2f(hh));
}

// ---------------- MFMA flash attention: block per (b,h,64 q rows), pre-split inputs ----------------
__global__ __launch_bounds__(256) void attn_mfma(const u16* __restrict__ Qh, const u16* __restrict__ Ql,
                                                 const u16* __restrict__ Kh, const u16* __restrict__ Kl,
                                                 const u16* __restrict__ Vh,
                                                 u16* __restrict__ aoh, u16* __restrict__ aol){
    __shared__ u16 KhS[64*64], KlS[64*64], VtS[64*64];
    char* KhB = (char*)KhS; char* KlB = (char*)KlS; char* VtB = (char*)VtS;
    int bh = blockIdx.y;
    int b = bh >> 2, h = bh & 3;
    int q0 = blockIdx.x * 64;
    int tid = threadIdx.x;
    int lane = tid & 63;
    int w = tid >> 6;
    int l15 = lane & 15, l4 = lane >> 4;
    size_t qrow = (size_t)(b*KPOOL + q0 + w*16 + l15);
    bf16x8 qh[2], ql[2];
    #pragma unroll
    for(int c=0;c<2;c++){
        qh[c] = *(const bf16x8*)(Qh + qrow*DD + h*64 + c*32 + l4*8);
        ql[c] = *(const bf16x8*)(Ql + qrow*DD + h*64 + c*32 + l4*8);
    }
    float mreg = -INFINITY, lreg = 0.f;
    f32x4 O[4] = {};
    for(int k0=0;k0<KPOOL;k0+=64){
        __syncthreads();
        {   // stage K hi/lo + V^T from pre-split bf16
            int row = tid >> 2, q4 = tid & 3;
            size_t gbase = ((size_t)(b*KPOOL + k0 + row))*DD + h*64 + q4*16;
            bf16x8 k0v = *(const bf16x8*)(Kh + gbase);
            bf16x8 k1v = *(const bf16x8*)(Kh + gbase + 8);
            bf16x8 kl0 = *(const bf16x8*)(Kl + gbase);
            bf16x8 kl1 = *(const bf16x8*)(Kl + gbase + 8);
            bf16x8 v0v = *(const bf16x8*)(Vh + gbase);
            bf16x8 v1v = *(const bf16x8*)(Vh + gbase + 8);
            int sw = (row&7)<<4;
            int colb = q4*32;
            *(bf16x8*)(KhB + row*128 + (colb ^ sw))        = k0v;
            *(bf16x8*)(KhB + row*128 + ((colb+16) ^ sw))   = k1v;
            *(bf16x8*)(KlB + row*128 + (colb ^ sw))        = kl0;
            *(bf16x8*)(KlB + row*128 + ((colb+16) ^ sw))   = kl1;
            #pragma unroll
            for(int j=0;j<8;j++){
                int dh0 = q4*16 + j;
                int dh1 = q4*16 + 8 + j;
                *(u16*)(VtB + dh0*128 + ((row*2) ^ ((dh0&7)<<4))) = (u16)(short)v0v[j];
                *(u16*)(VtB + dh1*128 + ((row*2) ^ ((dh1&7)<<4))) = (u16)(short)v1v[j];
            }
        }
        __syncthreads();
        // S^T tiles: mfma(A=K, B=Q)
        f32x4 s[4] = {};
        #pragma unroll
        for(int t=0;t<4;t++){
            int arow = t*16 + l15;
            int sw = (arow&7)<<4;
            const char* bh_ = KhB + arow*128;
            const char* bl_ = KlB + arow*128;
            bf16x8 kh0 = *(const bf16x8*)(bh_ + ((l4*16) ^ sw));
            bf16x8 kh1 = *(const bf16x8*)(bh_ + ((l4*16 + 64) ^ sw));
            bf16x8 kl0 = *(const bf16x8*)(bl_ + ((l4*16) ^ sw));
            bf16x8 kl1 = *(const bf16x8*)(bl_ + ((l4*16 + 64) ^ sw));
            s[t] = __builtin_amdgcn_mfma_f32_16x16x32_bf16(kh0, qh[0], s[t], 0,0,0);
            s[t] = __builtin_amdgcn_mfma_f32_16x16x32_bf16(kh1, qh[1], s[t], 0,0,0);
            s[t] = __builtin_amdgcn_mfma_f32_16x16x32_bf16(kh0, ql[0], s[t], 0,0,0);
            s[t] = __builtin_amdgcn_mfma_f32_16x16x32_bf16(kh1, ql[1], s[t], 0,0,0);
            s[t] = __builtin_amdgcn_mfma_f32_16x16x32_bf16(kl0, qh[0], s[t], 0,0,0);
            s[t] = __builtin_amdgcn_mfma_f32_16x16x32_bf16(kl1, qh[1], s[t], 0,0,0);
        }
        // online softmax
        float cm = -INFINITY;
        #pragma unroll
        for(int t=0;t<4;t++)
            #pragma unroll
            for(int r=0;r<4;r++){ s[t][r] *= 0.125f; cm = fmaxf(cm, s[t][r]); }
        cm = fmaxf(cm, __shfl_xor(cm,16));
        cm = fmaxf(cm, __shfl_xor(cm,32));
        float nm = fmaxf(mreg, cm);
        float es = expf(mreg - nm);
        float ps = 0.f;
        #pragma unroll
        for(int t=0;t<4;t++)
            #pragma unroll
            for(int r=0;r<4;r++){ float pv = expf(s[t][r] - nm); s[t][r] = pv; ps += pv; }
        ps += __shfl_xor(ps,16);
        ps += __shfl_xor(ps,32);
        lreg = lreg*es + ps;
        mreg = nm;
        #pragma unroll
        for(int d=0;d<4;d++){ O[d][0]*=es; O[d][1]*=es; O[d][2]*=es; O[d][3]*=es; }
        // O^T += mfma(A=V^T, B=P^T)
        #pragma unroll
        for(int c32=0;c32<2;c32++){
            bf16x8 pb;
            #pragma unroll
            for(int j=0;j<8;j++){
                int srcl = ((((lane>>4)*2 + (j>>2)) & 3) << 4) | l15;
                float v0 = __shfl(s[c32*2+0][j&3], srcl, 64);
                float v1 = __shfl(s[c32*2+1][j&3], srcl, 64);
                float v = (lane < 32) ? v0 : v1;
                pb[j] = (short)f2b(v);
            }
            #pragma unroll
            for(int dhb=0; dhb<4; dhb++){
                int vrow = dhb*16 + l15;
                bf16x8 va = *(const bf16x8*)(VtB + vrow*128 + ((c32*64 + l4*16) ^ ((vrow&7)<<4)));
                O[dhb] = __builtin_amdgcn_mfma_f32_16x16x32_bf16(va, pb, O[dhb], 0,0,0);
            }
        }
    }
    float inv = 1.f/lreg;
    #pragma unroll
    for(int dhb=0;dhb<4;dhb++)
        #pragma unroll
        for(int r=0;r<4;r++){
            float val = O[dhb][r]*inv;
            size_t o = qrow*DD + h*64 + dhb*16 + l4*4 + r;
            u16 hh = f2b(val);
            aoh[o] = hh;
            aol[o] = f2b(val - b2f(hh));
        }
}

// layernorm row kernel
__global__ __launch_bounds__(256) void ln_kernel(const float* __restrict__ xp, const float* __restrict__ o2,
                                                 const float* __restrict__ lg, const float* __restrict__ lb,
                                                 float* __restrict__ gatt){
    __shared__ float red[256];
    int r = blockIdx.x, c = threadIdx.x;
    float y = xp[(size_t)r*DD + c] + o2[(size_t)r*DD + c];
    red[c] = y; __syncthreads();
    for(int s=128;s;s>>=1){ if(c<s) red[c] += red[c+s]; __syncthreads(); }
    float mu = red[0]*(1.f/DD);
    __syncthreads();
    float d = y - mu;
    red[c] = d*d; __syncthreads();
    for(int s=128;s;s>>=1){ if(c<s) red[c] += red[c+s]; __syncthreads(); }
    float var = red[0]*(1.f/DD);
    gatt[(size_t)r*DD + c] = lg[c]*d/sqrtf(var+1e-5f) + lb[c];
}

__global__ void feat_reduce2(const float* __restrict__ xp, const float* __restrict__ gatt,
                             float* __restrict__ out){
    int b = blockIdx.x, c = threadIdx.x;
    int j0 = blockIdx.y*64;
    float s1=0.f, s2=0.f;
    for(int j=j0;j<j0+64;j++){
        size_t base = ((size_t)(b*KPOOL + j))*DD + c;
        s1 += xp[base];
        s2 += gatt[base];
    }
    atomicAdd(&out[b*512 + c], s1);
    atomicAdd(&out[b*512 + 256 + c], s2);
}

__global__ void cosine_kernel(const float* __restrict__ u, const float* __restrict__ v,
                              float* __restrict__ out){
    int b = blockIdx.x, t = threadIdx.x;
    float du=0.f, nu=0.f, nv=0.f;
    for(int j=t;j<512;j+=64){
        float a = u[b*512+j], bb = v[b*512+j];
        du += a*bb; nu += a*a; nv += bb*bb;
    }
    for(int m=32;m;m>>=1){
        du += __shfl_xor(du,m); nu += __shfl_xor(nu,m); nv += __shfl_xor(nv,m);
    }
    if(t==0) out[b] = du / (fmaxf(sqrtf(nu),1e-8f)*fmaxf(sqrtf(nv),1e-8f));
}

// =======================================================================
extern "C" void kernel_launch(void* const* d_in, const int* in_sizes, int n_in,
                              void* d_out, int out_size, void* d_ws, size_t ws_size,
                              hipStream_t stream){
    (void)in_sizes; (void)n_in; (void)out_size; (void)ws_size;
    const float* hgt_Wk   = (const float*)d_in[12];
    const float* hgt_Wq   = (const float*)d_in[13];
    const float* hgt_Wv   = (const float*)d_in[14];
    const float* hgt_Wo   = (const float*)d_in[15];
    const float* hgt_arel = (const float*)d_in[16];
    const float* hgt_mrel = (const float*)d_in[17];
    const float* hgt_prel = (const float*)d_in[18];
    const float* hgt_skip = (const float*)d_in[19];
    const float* pool_W   = (const float*)d_in[20];
    const float* pool_att = (const float*)d_in[21];
    const float* pool_bias= (const float*)d_in[22];
    const float* t_wq     = (const float*)d_in[23];
    const float* t_wk     = (const float*)d_in[24];
    const float* t_wv     = (const float*)d_in[25];
    const float* t_wo     = (const float*)d_in[26];
    const float* ln_g     = (const float*)d_in[27];
    const float* ln_b     = (const float*)d_in[28];
    float* out = (float*)d_out;

    char* base = (char*)d_ws;
    size_t off = 0;
    auto allocb = [&](size_t nbytes)->void*{
        void* p = (void*)(base + off);
        off += ((nbytes + 255) & ~(size_t)255);
        return p;
    };
    const size_t MAT = 65536;
    // ---- persistent ----
    u16* bwtk_h = (u16*)allocb(16*MAT*2); u16* bwtk_l = (u16*)allocb(16*MAT*2);
    u16* bwtv_h = (u16*)allocb(16*MAT*2); u16* bwtv_l = (u16*)allocb(16*MAT*2);
    u16* bwq_h  = (u16*)allocb(8*MAT*2);  u16* bwq_l  = (u16*)allocb(8*MAT*2);
    u16* bwo_h  = (u16*)allocb(8*MAT*2);  u16* bwo_l  = (u16*)allocb(8*MAT*2);
    u16* btw_h  = (u16*)allocb(4*MAT*2);  u16* btw_l  = (u16*)allocb(4*MAT*2);
    float* ubuf = (float*)allocb(BB*512*4);
    float* vbuf = (float*)allocb(BB*512*4);
    float* xa_i = (float*)allocb((size_t)NI*DD*4);
    float* xa_d = (float*)allocb((size_t)ND*DD*4);
    float* xb_i = (float*)allocb((size_t)NI*DD*4);
    float* xb_d = (float*)allocb((size_t)ND*DD*4);
    // ---- per-branch CSR (lives across conv + pooling) ----
    uint32_t* ccnt   = (uint32_t*)allocb((size_t)2*NROW*4);
    uint32_t* rowptr = (uint32_t*)allocb((size_t)(2*NROW+1)*4);
    uint32_t* einfo  = (uint32_t*)allocb((size_t)2*EHGT*4);
    uint32_t* slot   = (uint32_t*)allocb((size_t)2*EHGT*4);
    size_t region = off;
    // ---- conv scratch ----
    float* q_i  = (float*)allocb((size_t)NI*DD*4);
    float* q_d  = (float*)allocb((size_t)ND*DD*4);
    float* ka4  = (float*)allocb((size_t)4*NI*DD*4);
    float* vmb  = (float*)allocb((size_t)4*NI*DD*4);
    float* scb  = (float*)allocb((size_t)2*EHGT*HH*4);
    float* xacc_i= (float*)allocb((size_t)NI*DD*4);
    float* xacc_d= (float*)allocb((size_t)ND*DD*4);
    u16* bcur_h = (u16*)allocb((size_t)NROW*DD*2);
    u16* bcur_l = (u16*)allocb((size_t)NROW*DD*2);
    u16* bagg_h = (u16*)allocb((size_t)NROW*DD*2);
    u16* bagg_l = (u16*)allocb((size_t)NROW*DD*2);
    // ---- pooling/transformer overlay ----
    off = region;
    float* hvec = (float*)allocb(NROW*4);
    float* pscore = (float*)allocb(NROW*4);
    int* seln   = (int*)allocb(BB*KPOOL*4);
    float* sels = (float*)allocb(BB*KPOOL*4);
    float* xp   = (float*)allocb((size_t)BB*KPOOL*DD*4);
    float* o2   = (float*)allocb((size_t)BB*KPOOL*DD*4);
    float* gatt = (float*)allocb((size_t)BB*KPOOL*DD*4);
    u16* bxp_h = (u16*)allocb((size_t)BB*KPOOL*DD*2);
    u16* bxp_l = (u16*)allocb((size_t)BB*KPOOL*DD*2);
    u16* qbh = (u16*)allocb((size_t)BB*KPOOL*DD*2);
    u16* qbl = (u16*)allocb((size_t)BB*KPOOL*DD*2);
    u16* kbh = (u16*)allocb((size_t)BB*KPOOL*DD*2);
    u16* kbl = (u16*)allocb((size_t)BB*KPOOL*DD*2);
    u16* vbh = (u16*)allocb((size_t)BB*KPOOL*DD*2);
    u16* vbl = (u16*)allocb((size_t)BB*KPOOL*DD*2);
    u16* bao_h = (u16*)allocb((size_t)BB*KPOOL*DD*2);
    u16* bao_l = (u16*)allocb((size_t)BB*KPOOL*DD*2);

    const int st_tab[2][4] = {{0,1,0,0},{0,0,1,0}};
    const int dt_tab[2][4] = {{0,0,1,0},{0,1,0,0}};
    const int MR = BB*KPOOL;

    fill_u32<<<(2*BB*512+255)/256,256,0,stream>>>((uint32_t*)ubuf, 0u, 2*BB*512);
    float* wtkF = ka4;
    float* wtvF = ka4 + 16*MAT;
    combine_all<<<dim3(256,32),256,0,stream>>>(hgt_Wk, hgt_Wv, hgt_arel, hgt_mrel, wtkF, wtvF);
    WCArgs wc;
    wc.in[0]=wtkF;   wc.oh[0]=bwtk_h; wc.ol[0]=bwtk_l; wc.cnt[0]=16;
    wc.in[1]=wtvF;   wc.oh[1]=bwtv_h; wc.ol[1]=bwtv_l; wc.cnt[1]=16;
    wc.in[2]=hgt_Wq; wc.oh[2]=bwq_h;  wc.ol[2]=bwq_l;  wc.cnt[2]=8;
    wc.in[3]=hgt_Wo; wc.oh[3]=bwo_h;  wc.ol[3]=bwo_l;  wc.cnt[3]=8;
    wc.in[4]=t_wq;   wc.oh[4]=btw_h;          wc.ol[4]=btw_l;          wc.cnt[4]=1;
    wc.in[5]=t_wk;   wc.oh[5]=btw_h+1*MAT;    wc.ol[5]=btw_l+1*MAT;    wc.cnt[5]=1;
    wc.in[6]=t_wv;   wc.oh[6]=btw_h+2*MAT;    wc.ol[6]=btw_l+2*MAT;    wc.cnt[6]=1;
    wc.in[7]=t_wo;   wc.oh[7]=btw_h+3*MAT;    wc.ol[7]=btw_l+3*MAT;    wc.cnt[7]=1;
    wc.nr = 8;
    wcvt_split<<<dim3(256,52),256,0,stream>>>(wc);

    for(int bi=0;bi<2;bi++){
        int ib = bi*6;
        const float* x_inst = (const float*)d_in[ib+0];
        const float* x_data = (const float*)d_in[ib+1];
        const int* ecp = (const int*)d_in[ib+2];
        const int* eip = (const int*)d_in[ib+3];
        const int* eop = (const int*)d_in[ib+4];
        const int* ekp = (const int*)d_in[ib+5];
        const int* rows_f[4] = {ecp, eip, eop, ekp};
        const int* cols_f[4] = {ecp+EC, eip+EI, eop+EO, ekp+EK};

        // ---- CSR build (both dirs, one pass) ----
        CB2 cb;
        for(int r=0;r<4;r++){
            cb.row[r]   = rows_f[r]; cb.col[r]   = cols_f[r]; cb.dt[r]   = dt_tab[0][r];
            cb.row[4+r] = cols_f[r]; cb.col[4+r] = rows_f[r]; cb.dt[4+r] = dt_tab[1][r];
        }
        cb.cnt = ccnt; cb.rowptr = rowptr; cb.einfo = einfo; cb.slot = slot;
        fill_u32<<<(2*NROW+255)/256,256,0,stream>>>(ccnt, 0u, 2*NROW);
        csr_hist2<<<(2*EHGT+255)/256,256,0,stream>>>(cb);
        scan_rowptr2<<<1,1024,0,stream>>>(ccnt, rowptr);
        csr_scatter2<<<(2*EHGT+255)/256,256,0,stream>>>(cb);

        const float* cur_i = x_inst;
        const float* cur_d = x_data;
        cvt_split<<<((NROW*DD/4)+255)/256,256,0,stream>>>(cur_i, NI*DD, cur_d, ND*DD, bcur_h, bcur_l);
        for(int l=0;l<LL;l++){
            float* nxt_i = (l==0) ? xa_i : xb_i;
            float* nxt_d = (l==0) ? xa_d : xb_d;
            for(int dir=0;dir<2;dir++){
                int wb = l*2 + dir;
                const int* rows[4]; const int* cols[4];
                for(int r=0;r<4;r++){
                    rows[r] = dir ? cols_f[r] : rows_f[r];
                    cols[r] = dir ? rows_f[r] : cols_f[r];
                }

                // --- mega GEMM: Q(2) + KA(4) + VM(4) in one launch ---
                GArgs g1; int nb1 = 0, ndx = 0;
                auto addg = [&](int srctype, const u16* Bh, const u16* Bl, float* Cm, int M){
                    GDesc& d = g1.d[ndx];
                    size_t ao = srctype ? (size_t)NI*DD : 0;
                    d.Ah = bcur_h + ao; d.Al = bcur_l + ao;
                    d.Bh = Bh; d.Bl = Bl; d.C = Cm;
                    d.Oh = nullptr; d.Ol = nullptr; d.X = nullptr; d.Xacc = nullptr; d.skipp = nullptr;
                    d.mblks = M/128; d.mode = 0;
                    nb1 += M/128; ndx++;
                };
                addg(0, bwq_h + (size_t)(wb*2+0)*MAT, bwq_l + (size_t)(wb*2+0)*MAT, q_i, NI);
                addg(1, bwq_h + (size_t)(wb*2+1)*MAT, bwq_l + (size_t)(wb*2+1)*MAT, q_d, ND);
                for(int r=0;r<4;r++){
                    int st = st_tab[dir][r];
                    addg(st, bwtk_h + (size_t)(wb*4+r)*MAT, bwtk_l + (size_t)(wb*4+r)*MAT,
                         ka4 + (size_t)r*NI*DD, st ? ND : NI);
                }
                for(int r=0;r<4;r++){
                    int st = st_tab[dir][r];
                    addg(st, bwtv_h + (size_t)(wb*4+r)*MAT, bwtv_l + (size_t)(wb*4+r)*MAT,
                         vmb + (size_t)r*NI*DD, st ? ND : NI);
                }
                g1.nd = ndx;
                gemm_mfma<<<dim3(nb1,2),256,0,stream>>>(g1);

                // --- edge scores ---
                P1Args pa;
                for(int r=0;r<4;r++){
                    pa.row[r] = rows[r]; pa.col[r] = cols[r];
                    pa.dt[r] = dt_tab[dir][r];
                }
                pa.Q[0]=q_i; pa.Q[1]=q_d;
                pa.ka = ka4;
                pa.prel = hgt_prel + (size_t)wb*4*HH;
                pa.slot = slot + (size_t)dir*EHGT;
                pa.sc = scb;
                hgt_pass1<<<EHGT/4,256,0,stream>>>(pa);

                // --- per-(dst,h) softmax + gather + gelu + split ---
                hgt_rowpass<<<NROW,256,0,stream>>>(rowptr + (size_t)dir*NROW, einfo, scb, vmb, bagg_h, bagg_l);

                // --- Wo GEMMs with fused skip/relu epilogue ---
                GArgs g3; g3.nd = 2;
                for(int t=0;t<2;t++){
                    GDesc& d = g3.d[t];
                    size_t ao = t ? (size_t)NI*DD : 0;
                    d.Ah = bagg_h + ao; d.Al = bagg_l + ao;
                    d.Bh = bwo_h + (size_t)(wb*2+t)*MAT; d.Bl = bwo_l + (size_t)(wb*2+t)*MAT;
                    d.C = t ? nxt_d : nxt_i;
                    d.Oh = bcur_h + ao; d.Ol = bcur_l + ao;
                    d.X = t ? cur_d : cur_i;
                    d.Xacc = t ? xacc_d : xacc_i;
                    d.skipp = hgt_skip + wb*2 + t;
                    d.mblks = (t ? ND : NI)/128;
                    d.mode = dir ? 3 : 2;
                }
                gemm_mfma<<<dim3(NI/128 + ND/128,2),256,0,stream>>>(g3);
            }
            cur_i = nxt_i;
            cur_d = nxt_d;
        }

        // -------- SAGPooling (CSR-based, no atomics) --------
        pool_h2<<<NROW/4,256,0,stream>>>(cur_i, cur_d, pool_W, hvec);
        pool_csr<<<NROW/4,256,0,stream>>>(rowptr, einfo, hvec, pool_att, pscore);
        topk_kernel<<<BB,512,0,stream>>>(pscore, pool_bias, seln, sels);
        gather_xp<<<BB*KPOOL,256,0,stream>>>(seln, sels, cur_i, cur_d, xp, bxp_h, bxp_l);

        // -------- transformer --------
        GArgs g4; g4.nd = 3;
        for(int t=0;t<3;t++){
            GDesc& d = g4.d[t];
            d.Ah=bxp_h; d.Al=bxp_l;
            d.Bh=btw_h + (size_t)t*MAT; d.Bl=btw_l + (size_t)t*MAT;
            d.C = nullptr;
            d.Oh = (t==0)? qbh : (t==1)? kbh : vbh;
            d.Ol = (t==0)? qbl : (t==1)? kbl : vbl;
            d.X = nullptr; d.Xacc = nullptr; d.skipp = nullptr;
            d.mblks = MR/128; d.mode = 1;
        }
        gemm_mfma<<<dim3(3*(MR/128),2),256,0,stream>>>(g4);
        attn_mfma<<<dim3(KPOOL/64, BB*HH),256,0,stream>>>(qbh, qbl, kbh, kbl, vbh, bao_h, bao_l);
        GArgs g5; g5.nd = 1;
        {
            GDesc& d = g5.d[0];
            d.Ah=bao_h; d.Al=bao_l;
            d.Bh=btw_h + (size_t)3*MAT; d.Bl=btw_l + (size_t)3*MAT;
            d.C=o2; d.Oh=nullptr; d.Ol=nullptr; d.X=nullptr; d.Xacc=nullptr; d.skipp=nullptr;
            d.mblks=MR/128; d.mode=0;
        }
        gemm_mfma<<<dim3(MR/128,2),256,0,stream>>>(g5);
        ln_kernel<<<MR,256,0,stream>>>(xp, o2, ln_g, ln_b, gatt);
        feat_reduce2<<<dim3(BB,12),256,0,stream>>>(xp, gatt, bi ? vbuf : ubuf);
    }

    cosine_kernel<<<BB,64,0,stream>>>(ubuf, vbuf, out);
}

// Round 9
// 1933.175 us; speedup vs baseline: 1.0060x; 1.0060x over previous
//
#include <hip/hip_runtime.h>
#include <math.h>
#include <stdint.h>

#define LL 2
#define HH 4
#define DHH 64
#define DD 256
#define BB 8
#define NI 8192
#define ND 4096
#define NROW 12288
#define KPOOL 768
#define EC 65536
#define EI 32768
#define EO 32768
#define EK 8192
#define EHGT (EC+EI+EO+EK)

typedef unsigned short u16;
typedef short bf16x8 __attribute__((ext_vector_type(8)));
typedef float f32x4 __attribute__((ext_vector_type(4)));
typedef unsigned short u16x4 __attribute__((ext_vector_type(4)));

__device__ inline float gelu_f(float x){ return 0.5f*x*(1.f+erff(x*0.70710678118654752f)); }
__device__ inline u16 f2b(float x){ uint32_t u=__float_as_uint(x); return (u16)((u + 0x7fffu + ((u>>16)&1u))>>16); }
__device__ inline float b2f(u16 h){ return __uint_as_float(((uint32_t)h)<<16); }

// ---------------- generic fill ----------------
__global__ void fill_u32(uint32_t* p, uint32_t v, int n){
    int i = blockIdx.x*256 + threadIdx.x;
    if(i<n) p[i]=v;
}

// ---------------- activation split-convert ----------------
__global__ void cvt_split(const float* __restrict__ A, int nA, const float* __restrict__ B, int nB,
                          u16* __restrict__ oh, u16* __restrict__ ol){
    int i = (blockIdx.x*256 + threadIdx.x)*4;
    int tot = nA + nB;
    if(i >= tot) return;
    float4 v = (i < nA) ? *(const float4*)(A + i) : *(const float4*)(B + (i - nA));
    float vv[4] = {v.x, v.y, v.z, v.w};
    u16x4 h4, l4;
    #pragma unroll
    for(int j=0;j<4;j++){
        float x = vv[j];
        u16 h = f2b(x);
        h4[j] = h;
        l4[j] = f2b(x - b2f(h));
    }
    *(u16x4*)(oh + i) = h4;
    *(u16x4*)(ol + i) = l4;
}

// ---------------- weight transpose + split ----------------
struct WCArgs { const float* in[8]; u16* oh[8]; u16* ol[8]; int cnt[8]; int nr; };
__global__ void wcvt_split(WCArgs a){
    int mat = blockIdx.y, ri = 0;
    while(ri < a.nr-1 && mat >= a.cnt[ri]){ mat -= a.cnt[ri]; ri++; }
    const float* in = a.in[ri] + (size_t)mat*65536;
    u16* oh = a.oh[ri] + (size_t)mat*65536;
    u16* ol = a.ol[ri] + (size_t)mat*65536;
    int n = blockIdx.x, k = threadIdx.x;
    float x = in[(size_t)k*DD + n];
    u16 h = f2b(x);
    oh[n*DD + k] = h;
    ol[n*DD + k] = f2b(x - b2f(h));
}

// ---------------- MFMA batched GEMM with fused epilogues ----------------
// LDS: paired hi/lo buffers, [128 rows][128 bytes] (cols 0-63 = hi, 64-127 = lo),
// XOR-swizzled byte ^= (row&7)<<4 (bijective within the 128-byte row).
// mode 0: C=f32   mode 1: Oh/Ol=split bf16
// mode 2: Xacc = 0.5*(g*acc + (1-g)*X)
// mode 3: v=relu(Xacc + 0.5*(g*acc+(1-g)*X)); C=v; Oh/Ol=split(v)
struct GDesc { const u16* Ah; const u16* Al; const u16* Bh; const u16* Bl;
               float* C; u16* Oh; u16* Ol;
               const float* X; float* Xacc; const float* skipp;
               int mblks; int mode; };
struct GArgs { GDesc d[10]; int nd; };

__global__ __launch_bounds__(256) void gemm_mfma(GArgs ga){
    __shared__ u16 AS[128*64], BS[128*64];
    char* Abuf = (char*)AS; char* Bbuf = (char*)BS;
    int mb = blockIdx.x, di = 0;
    while(di < ga.nd-1 && mb >= ga.d[di].mblks){ mb -= ga.d[di].mblks; di++; }
    GDesc g = ga.d[di];
    const int m0 = mb*128, n0 = blockIdx.y*128;
    const int tid = threadIdx.x;
    const int lane = tid & 63, wid = tid >> 6;
    const int wm = (wid>>1)*64, wn = (wid&1)*64;
    const int l15 = lane & 15, l4 = lane >> 4;
    const int srow = tid >> 1, hf = tid & 1;
    const int ssw = (srow&7)<<4;
    const int c0 = (hf*32) ^ ssw;
    const int c1 = (hf*32+16) ^ ssw;
    const int c2 = (64+hf*32) ^ ssw;
    const int c3 = (64+hf*32+16) ^ ssw;
    const int rb = srow*128;
    const size_t aoff = (size_t)(m0 + srow)*DD + hf*16;
    const size_t boff = (size_t)(n0 + srow)*DD + hf*16;
    f32x4 acc[4][4] = {};
    for(int k0=0;k0<DD;k0+=32){
        bf16x8 ah0 = *(const bf16x8*)(g.Ah + aoff + k0);
        bf16x8 ah1 = *(const bf16x8*)(g.Ah + aoff + k0 + 8);
        bf16x8 al0 = *(const bf16x8*)(g.Al + aoff + k0);
        bf16x8 al1 = *(const bf16x8*)(g.Al + aoff + k0 + 8);
        bf16x8 bh0 = *(const bf16x8*)(g.Bh + boff + k0);
        bf16x8 bh1 = *(const bf16x8*)(g.Bh + boff + k0 + 8);
        bf16x8 bl0 = *(const bf16x8*)(g.Bl + boff + k0);
        bf16x8 bl1 = *(const bf16x8*)(g.Bl + boff + k0 + 8);
        __syncthreads();
        *(bf16x8*)(Abuf + rb + c0) = ah0; *(bf16x8*)(Abuf + rb + c1) = ah1;
        *(bf16x8*)(Abuf + rb + c2) = al0; *(bf16x8*)(Abuf + rb + c3) = al1;
        *(bf16x8*)(Bbuf + rb + c0) = bh0; *(bf16x8*)(Bbuf + rb + c1) = bh1;
        *(bf16x8*)(Bbuf + rb + c2) = bl0; *(bf16x8*)(Bbuf + rb + c3) = bl1;
        __syncthreads();
        bf16x8 afh[4], afl[4], bfh[4], bfl[4];
        #pragma unroll
        for(int i=0;i<4;i++){
            int ar = wm + i*16 + l15;
            int swa = (ar&7)<<4;
            int abase = ar*128;
            afh[i] = *(const bf16x8*)(Abuf + abase + ((l4*16) ^ swa));
            afl[i] = *(const bf16x8*)(Abuf + abase + ((64 + l4*16) ^ swa));
            int br = wn + i*16 + l15;
            int swb = (br&7)<<4;
            int bbase = br*128;
            bfh[i] = *(const bf16x8*)(Bbuf + bbase + ((l4*16) ^ swb));
            bfl[i] = *(const bf16x8*)(Bbuf + bbase + ((64 + l4*16) ^ swb));
        }
        #pragma unroll
        for(int i=0;i<4;i++)
            #pragma unroll
            for(int j=0;j<4;j++){
                acc[i][j] = __builtin_amdgcn_mfma_f32_16x16x32_bf16(afh[i], bfh[j], acc[i][j], 0,0,0);
                acc[i][j] = __builtin_amdgcn_mfma_f32_16x16x32_bf16(afh[i], bfl[j], acc[i][j], 0,0,0);
                acc[i][j] = __builtin_amdgcn_mfma_f32_16x16x32_bf16(afl[i], bfh[j], acc[i][j], 0,0,0);
            }
    }
    const int mode = g.mode;
    float gg = 0.f;
    if(mode >= 2) gg = 1.f/(1.f + expf(-*g.skipp));
    #pragma unroll
    for(int i=0;i<4;i++){
        #pragma unroll
        for(int j=0;j<4;j++){
            int ccol = n0 + wn + j*16 + l15;
            #pragma unroll
            for(int r=0;r<4;r++){
                int row = m0 + wm + i*16 + l4*4 + r;
                size_t o = (size_t)row*DD + ccol;
                float val = acc[i][j][r];
                if(mode==0){
                    g.C[o] = val;
                } else if(mode==1){
                    u16 hh = f2b(val); g.Oh[o]=hh; g.Ol[o]=f2b(val-b2f(hh));
                } else {
                    float v2 = gg*val + (1.f-gg)*g.X[o];
                    if(mode==2){
                        g.Xacc[o] = 0.5f*v2;
                    } else {
                        float v3 = g.Xacc[o] + 0.5f*v2;
                        v3 = v3 > 0.f ? v3 : 0.f;
                        g.C[o] = v3;
                        u16 hh = f2b(v3); g.Oh[o]=hh; g.Ol[o]=f2b(v3-b2f(hh));
                    }
                }
            }
        }
    }
}

// ---------- combine ----------
__global__ void combine_all(const float* __restrict__ Wk, const float* __restrict__ Wv,
                            const float* __restrict__ Ra, const float* __restrict__ Rm,
                            float* __restrict__ wtk, float* __restrict__ wtv){
    const int st_tab[2][4] = {{0,1,0,0},{0,0,1,0}};
    int combo = blockIdx.y;
    int idx = combo >> 1, kv = combo & 1;
    int r = idx & 3, wb = idx >> 2, dir = wb & 1;
    int st = st_tab[dir][r];
    const float* W = (kv ? Wv : Wk) + (size_t)(wb*2 + st)*65536;
    const float* R = (kv ? Rm : Ra) + (size_t)idx*16384;
    float* o = (kv ? wtv : wtk) + (size_t)idx*65536;
    int d = blockIdx.x, c = threadIdx.x;
    int h = c >> 6, f = c & 63;
    const float* Wrow = W + d*DD + h*64;
    const float* Rh = R + h*4096 + f;
    float s = 0.f;
    #pragma unroll 8
    for(int k=0;k<64;k++) s += Wrow[k]*Rh[k*64];
    o[d*DD + c] = s;
}

// ---------------- CSR build (both directions in one pass) ----------------
__device__ inline void edge_decode(int e, int& r, int& el){
    if(e < EC){ r=0; el=e; }
    else if(e < EC+EI){ r=1; el=e-EC; }
    else if(e < EC+EI+EO){ r=2; el=e-(EC+EI); }
    else { r=3; el=e-(EC+EI+EO); }
}

struct CB2 {
    const int* row[8]; const int* col[8];
    int dt[8];
    uint32_t* cnt; uint32_t* rowptr; uint32_t* einfo; uint32_t* slot;
};

__global__ void csr_hist2(CB2 a){
    int ge = blockIdx.x*256 + threadIdx.x;
    if(ge >= 2*EHGT) return;
    int dir = ge >= EHGT;
    int e = ge - dir*EHGT;
    int r, el; edge_decode(e, r, el);
    int idx = dir*4 + r;
    int c = a.col[idx][el];
    int dst = dir*NROW + (a.dt[idx] ? (NI + c) : c);
    atomicAdd(&a.cnt[dst], 1u);
}

__global__ __launch_bounds__(1024) void scan_rowptr2(uint32_t* cnt, uint32_t* rowptr){
    __shared__ uint32_t part[1024];
    int t = threadIdx.x;
    int base = t*24;
    uint32_t lpre[24];
    uint32_t sum = 0;
    #pragma unroll
    for(int i=0;i<24;i++){
        uint32_t c = cnt[base+i];
        lpre[i] = sum; sum += c;
        cnt[base+i] = 0;
    }
    part[t] = sum;
    __syncthreads();
    for(int offs=1; offs<1024; offs<<=1){
        uint32_t v = (t>=offs) ? part[t-offs] : 0u;
        __syncthreads();
        part[t] += v;
        __syncthreads();
    }
    uint32_t pre = (t==0) ? 0u : part[t-1];
    #pragma unroll
    for(int i=0;i<24;i++) rowptr[base+i] = pre + lpre[i];
    if(t==1023) rowptr[2*NROW] = part[1023];
}

__global__ void csr_scatter2(CB2 a){
    int ge = blockIdx.x*256 + threadIdx.x;
    if(ge >= 2*EHGT) return;
    int dir = ge >= EHGT;
    int e = ge - dir*EHGT;
    int r, el; edge_decode(e, r, el);
    int idx = dir*4 + r;
    int c = a.col[idx][el];
    int dst = dir*NROW + (a.dt[idx] ? (NI + c) : c);
    int src = a.row[idx][el];
    uint32_t p = a.rowptr[dst] + atomicAdd(&a.cnt[dst], 1u);
    a.einfo[p] = (uint32_t)src | ((uint32_t)r << 16);
    a.slot[ge] = p;
}

// ---------------- HGT edge scores: wave per edge ----------------
struct P1Args {
    const int* row[4]; const int* col[4];
    const float* Q[2];
    const float* ka;
    const float* prel;
    const uint32_t* slot;
    float* sc;
    int dt[4];
};

__global__ __launch_bounds__(256) void hgt_pass1(P1Args a){
    int w = blockIdx.x*4 + (threadIdx.x >> 6);
    int lane = threadIdx.x & 63;
    if(w >= EHGT) return;
    int r, el; edge_decode(w, r, el);
    int dt = a.dt[r];
    int rn = a.row[r][el], cn = a.col[r][el];
    float4 qv = *(const float4*)(a.Q[dt] + (size_t)cn*DD + lane*4);
    float4 kv = *(const float4*)(a.ka + (size_t)r*NI*DD + (size_t)rn*DD + lane*4);
    float d = qv.x*kv.x + qv.y*kv.y + qv.z*kv.z + qv.w*kv.w;
    d += __shfl_xor(d, 1); d += __shfl_xor(d, 2);
    d += __shfl_xor(d, 4); d += __shfl_xor(d, 8);
    if((lane & 15) == 0){
        int h = lane >> 4;
        a.sc[(size_t)a.slot[w]*HH + h] = d * a.prel[r*HH + h] * 0.125f;
    }
}

// one wave per (dst,h): segment softmax + gather + gelu + split-bf16 out
__global__ __launch_bounds__(256) void hgt_rowpass(const uint32_t* __restrict__ rowptr,
                                                   const uint32_t* __restrict__ einfo,
                                                   const float* __restrict__ sc,
                                                   const float* __restrict__ vmb,
                                                   u16* __restrict__ bagg_h,
                                                   u16* __restrict__ bagg_l){
    int w = blockIdx.x*4 + (threadIdx.x >> 6);
    int lane = threadIdx.x & 63;
    int rowi = w >> 2, h = w & 3;
    uint32_t p0 = rowptr[rowi], p1 = rowptr[rowi+1];
    size_t obase = (size_t)rowi*DD + h*64 + lane;
    float o = 0.f;
    if(p0 != p1){
        float m = -INFINITY;
        for(uint32_t p = p0+lane; p < p1; p += 64) m = fmaxf(m, sc[(size_t)p*HH + h]);
        #pragma unroll
        for(int s=32;s;s>>=1) m = fmaxf(m, __shfl_xor(m, s));
        float den = 0.f;
        for(uint32_t p = p0+lane; p < p1; p += 64) den += expf(sc[(size_t)p*HH + h] - m);
        #pragma unroll
        for(int s=32;s;s>>=1) den += __shfl_xor(den, s);
        float inv = 1.f/(den + 1e-16f);
        for(uint32_t p = p0; p < p1; p++){
            uint32_t ei = einfo[p];
            int src = ei & 0xffff, r = ei >> 16;
            float alpha = expf(sc[(size_t)p*HH + h] - m) * inv;
            o += alpha * vmb[((size_t)r*NI + src)*DD + h*64 + lane];
        }
    }
    float g = gelu_f(o);
    u16 hh = f2b(g);
    bagg_h[obase] = hh;
    bagg_l[obase] = f2b(g - b2f(hh));
}

// ---------------- pooling ----------------
__global__ void pool_h2(const float* __restrict__ xi, const float* __restrict__ xd,
                        const float* __restrict__ w, float* __restrict__ h){
    int node = blockIdx.x*4 + (threadIdx.x>>6);
    int lane = threadIdx.x & 63;
    const float* xr = (node < NI) ? (xi + (size_t)node*DD) : (xd + (size_t)(node-NI)*DD);
    float s = 0.f;
    for(int j=lane;j<DD;j+=64) s += xr[j]*w[j];
    for(int m=32;m;m>>=1) s += __shfl_xor(s, m);
    if(lane==0) h[node] = s;
}

// GAT-style pooling score via fwd CSR + implicit self-loop; wave per dst node
__global__ __launch_bounds__(256) void pool_csr(const uint32_t* __restrict__ rowptr,
                                                const uint32_t* __restrict__ einfo,
                                                const float* __restrict__ h,
                                                const float* __restrict__ att,
                                                float* __restrict__ score){
    int w = blockIdx.x*4 + (threadIdx.x >> 6);
    int lane = threadIdx.x & 63;
    if(w >= NROW) return;
    uint32_t p0 = rowptr[w], p1 = rowptr[w+1];
    float a0 = att[0], a1 = att[1];
    float hn = h[w];
    float es = a0*hn + a1*hn;
    es = es >= 0.f ? es : 0.2f*es;
    float m = -INFINITY;
    for(uint32_t p = p0+lane; p < p1; p += 64){
        uint32_t ei = einfo[p];
        int src = ei & 0xffff, r = ei >> 16;
        float hs = h[r==1 ? NI+src : src];
        float e = a0*hs + a1*hn;
        e = e >= 0.f ? e : 0.2f*e;
        m = fmaxf(m, e);
    }
    #pragma unroll
    for(int s=32;s;s>>=1) m = fmaxf(m, __shfl_xor(m, s));
    m = fmaxf(m, es);
    float lden = 0.f, lnum = 0.f;
    for(uint32_t p = p0+lane; p < p1; p += 64){
        uint32_t ei = einfo[p];
        int src = ei & 0xffff, r = ei >> 16;
        float hs = h[r==1 ? NI+src : src];
        float e = a0*hs + a1*hn;
        e = e >= 0.f ? e : 0.2f*e;
        float a = expf(e - m);
        lden += a; lnum += a*hs;
    }
    #pragma unroll
    for(int s=32;s;s>>=1){ lden += __shfl_xor(lden, s); lnum += __shfl_xor(lnum, s); }
    float aself = expf(es - m);
    lden += aself; lnum += aself*hn;
    if(lane==0) score[w] = lnum/(lden + 1e-16f);
}

// top-768 of 1536 per graph via bitonic sort
__global__ __launch_bounds__(512) void topk_kernel(const float* __restrict__ score,
                                                   const float* __restrict__ bias,
                                                   int* __restrict__ sel_node,
                                                   float* __restrict__ sel_scale){
    __shared__ float skey[2048];
    __shared__ int   sval[2048];
    int b = blockIdx.x;
    float bv = bias[0];
    for(int p=threadIdx.x;p<2048;p+=512){
        if(p<1536){
            int node = (p<1024) ? (b*1024 + p) : (NI + b*512 + (p-1024));
            skey[p] = score[node] + bv;
            sval[p] = node;
        } else {
            skey[p] = -INFINITY;
            sval[p] = -1;
        }
    }
    for(int k=2;k<=2048;k<<=1){
        for(int j=k>>1;j>0;j>>=1){
            __syncthreads();
            for(int i=threadIdx.x;i<2048;i+=512){
                int ixj = i^j;
                if(ixj > i){
                    bool up = ((i & k) == 0);
                    float ki = skey[i], kj = skey[ixj];
                    if((ki < kj) == up){
                        skey[i]=kj; skey[ixj]=ki;
                        int t=sval[i]; sval[i]=sval[ixj]; sval[ixj]=t;
                    }
                }
            }
        }
    }
    __syncthreads();
    for(int j=threadIdx.x;j<KPOOL;j+=512){
        sel_node[b*KPOOL + j] = sval[j];
        sel_scale[b*KPOOL + j] = tanhf(skey[j]);
    }
}

__global__ void gather_xp(const int* __restrict__ sel, const float* __restrict__ scale,
                          const float* __restrict__ xi, const float* __restrict__ xd,
                          float* __restrict__ xp, u16* __restrict__ bh, u16* __restrict__ bl){
    int i = blockIdx.x*256 + threadIdx.x;
    int rowp = i >> 8, c = i & 255;
    int node = sel[rowp];
    float s = scale[rowp];
    float v = (node < NI) ? xi[(size_t)node*DD + c] : xd[(size_t)(node-NI)*DD + c];
    float x = v*s;
    xp[i] = x;
    u16 hh = f2b(x);
    bh[i] = hh;
    bl[i] = f2b(x - b2f(hh));
}

// ---------------- MFMA flash attention: block per (b,h,64 q rows), pre-split inputs ----------------
__global__ __launch_bounds__(256) void attn_mfma(const u16* __restrict__ Qh, const u16* __restrict__ Ql,
                                                 const u16* __restrict__ Kh, const u16* __restrict__ Kl,
                                                 const u16* __restrict__ Vh,
                                                 u16* __restrict__ aoh, u16* __restrict__ aol){
    __shared__ u16 KhS[64*64], KlS[64*64], VtS[64*64];
    char* KhB = (char*)KhS; char* KlB = (char*)KlS; char* VtB = (char*)VtS;
    int bh = blockIdx.y;
    int b = bh >> 2, h = bh & 3;
    int q0 = blockIdx.x * 64;
    int tid = threadIdx.x;
    int lane = tid & 63;
    int w = tid >> 6;
    int l15 = lane & 15, l4 = lane >> 4;
    size_t qrow = (size_t)(b*KPOOL + q0 + w*16 + l15);
    bf16x8 qh[2], ql[2];
    #pragma unroll
    for(int c=0;c<2;c++){
        qh[c] = *(const bf16x8*)(Qh + qrow*DD + h*64 + c*32 + l4*8);
        ql[c] = *(const bf16x8*)(Ql + qrow*DD + h*64 + c*32 + l4*8);
    }
    float mreg = -INFINITY, lreg = 0.f;
    f32x4 O[4] = {};
    for(int k0=0;k0<KPOOL;k0+=64){
        __syncthreads();
        {   // stage K hi/lo + V^T from pre-split bf16
            int row = tid >> 2, q4 = tid & 3;
            size_t gbase = ((size_t)(b*KPOOL + k0 + row))*DD + h*64 + q4*16;
            bf16x8 k0v = *(const bf16x8*)(Kh + gbase);
            bf16x8 k1v = *(const bf16x8*)(Kh + gbase + 8);
            bf16x8 kl0 = *(const bf16x8*)(Kl + gbase);
            bf16x8 kl1 = *(const bf16x8*)(Kl + gbase + 8);
            bf16x8 v0v = *(const bf16x8*)(Vh + gbase);
            bf16x8 v1v = *(const bf16x8*)(Vh + gbase + 8);
            int sw = (row&7)<<4;
            int colb = q4*32;
            *(bf16x8*)(KhB + row*128 + (colb ^ sw))        = k0v;
            *(bf16x8*)(KhB + row*128 + ((colb+16) ^ sw))   = k1v;
            *(bf16x8*)(KlB + row*128 + (colb ^ sw))        = kl0;
            *(bf16x8*)(KlB + row*128 + ((colb+16) ^ sw))   = kl1;
            #pragma unroll
            for(int j=0;j<8;j++){
                int dh0 = q4*16 + j;
                int dh1 = q4*16 + 8 + j;
                *(u16*)(VtB + dh0*128 + ((row*2) ^ ((dh0&7)<<4))) = (u16)(short)v0v[j];
                *(u16*)(VtB + dh1*128 + ((row*2) ^ ((dh1&7)<<4))) = (u16)(short)v1v[j];
            }
        }
        __syncthreads();
        // S^T tiles: mfma(A=K, B=Q)
        f32x4 s[4] = {};
        #pragma unroll
        for(int t=0;t<4;t++){
            int arow = t*16 + l15;
            int sw = (arow&7)<<4;
            const char* bh_ = KhB + arow*128;
            const char* bl_ = KlB + arow*128;
            bf16x8 kh0 = *(const bf16x8*)(bh_ + ((l4*16) ^ sw));
            bf16x8 kh1 = *(const bf16x8*)(bh_ + ((l4*16 + 64) ^ sw));
            bf16x8 kl0 = *(const bf16x8*)(bl_ + ((l4*16) ^ sw));
            bf16x8 kl1 = *(const bf16x8*)(bl_ + ((l4*16 + 64) ^ sw));
            s[t] = __builtin_amdgcn_mfma_f32_16x16x32_bf16(kh0, qh[0], s[t], 0,0,0);
            s[t] = __builtin_amdgcn_mfma_f32_16x16x32_bf16(kh1, qh[1], s[t], 0,0,0);
            s[t] = __builtin_amdgcn_mfma_f32_16x16x32_bf16(kh0, ql[0], s[t], 0,0,0);
            s[t] = __builtin_amdgcn_mfma_f32_16x16x32_bf16(kh1, ql[1], s[t], 0,0,0);
            s[t] = __builtin_amdgcn_mfma_f32_16x16x32_bf16(kl0, qh[0], s[t], 0,0,0);
            s[t] = __builtin_amdgcn_mfma_f32_16x16x32_bf16(kl1, qh[1], s[t], 0,0,0);
        }
        // online softmax
        float cm = -INFINITY;
        #pragma unroll
        for(int t=0;t<4;t++)
            #pragma unroll
            for(int r=0;r<4;r++){ s[t][r] *= 0.125f; cm = fmaxf(cm, s[t][r]); }
        cm = fmaxf(cm, __shfl_xor(cm,16));
        cm = fmaxf(cm, __shfl_xor(cm,32));
        float nm = fmaxf(mreg, cm);
        float es = expf(mreg - nm);
        float ps = 0.f;
        #pragma unroll
        for(int t=0;t<4;t++)
            #pragma unroll
            for(int r=0;r<4;r++){ float pv = expf(s[t][r] - nm); s[t][r] = pv; ps += pv; }
        ps += __shfl_xor(ps,16);
        ps += __shfl_xor(ps,32);
        lreg = lreg*es + ps;
        mreg = nm;
        #pragma unroll
        for(int d=0;d<4;d++){ O[d][0]*=es; O[d][1]*=es; O[d][2]*=es; O[d][3]*=es; }
        // O^T += mfma(A=V^T, B=P^T)
        #pragma unroll
        for(int c32=0;c32<2;c32++){
            bf16x8 pb;
            #pragma unroll
            for(int j=0;j<8;j++){
                int srcl = ((((lane>>4)*2 + (j>>2)) & 3) << 4) | l15;
                float v0 = __shfl(s[c32*2+0][j&3], srcl, 64);
                float v1 = __shfl(s[c32*2+1][j&3], srcl, 64);
                float v = (lane < 32) ? v0 : v1;
                pb[j] = (short)f2b(v);
            }
            #pragma unroll
            for(int dhb=0; dhb<4; dhb++){
                int vrow = dhb*16 + l15;
                bf16x8 va = *(const bf16x8*)(VtB + vrow*128 + ((c32*64 + l4*16) ^ ((vrow&7)<<4)));
                O[dhb] = __builtin_amdgcn_mfma_f32_16x16x32_bf16(va, pb, O[dhb], 0,0,0);
            }
        }
    }
    float inv = 1.f/lreg;
    #pragma unroll
    for(int dhb=0;dhb<4;dhb++)
        #pragma unroll
        for(int r=0;r<4;r++){
            float val = O[dhb][r]*inv;
            size_t o = qrow*DD + h*64 + dhb*16 + l4*4 + r;
            u16 hh = f2b(val);
            aoh[o] = hh;
            aol[o] = f2b(val - b2f(hh));
        }
}

// layernorm row kernel
__global__ __launch_bounds__(256) void ln_kernel(const float* __restrict__ xp, const float* __restrict__ o2,
                                                 const float* __restrict__ lg, const float* __restrict__ lb,
                                                 float* __restrict__ gatt){
    __shared__ float red[256];
    int r = blockIdx.x, c = threadIdx.x;
    float y = xp[(size_t)r*DD + c] + o2[(size_t)r*DD + c];
    red[c] = y; __syncthreads();
    for(int s=128;s;s>>=1){ if(c<s) red[c] += red[c+s]; __syncthreads(); }
    float mu = red[0]*(1.f/DD);
    __syncthreads();
    float d = y - mu;
    red[c] = d*d; __syncthreads();
    for(int s=128;s;s>>=1){ if(c<s) red[c] += red[c+s]; __syncthreads(); }
    float var = red[0]*(1.f/DD);
    gatt[(size_t)r*DD + c] = lg[c]*d/sqrtf(var+1e-5f) + lb[c];
}

__global__ void feat_reduce2(const float* __restrict__ xp, const float* __restrict__ gatt,
                             float* __restrict__ out){
    int b = blockIdx.x, c = threadIdx.x;
    int j0 = blockIdx.y*64;
    float s1=0.f, s2=0.f;
    for(int j=j0;j<j0+64;j++){
        size_t base = ((size_t)(b*KPOOL + j))*DD + c;
        s1 += xp[base];
        s2 += gatt[base];
    }
    atomicAdd(&out[b*512 + c], s1);
    atomicAdd(&out[b*512 + 256 + c], s2);
}

__global__ void cosine_kernel(const float* __restrict__ u, const float* __restrict__ v,
                              float* __restrict__ out){
    int b = blockIdx.x, t = threadIdx.x;
    float du=0.f, nu=0.f, nv=0.f;
    for(int j=t;j<512;j+=64){
        float a = u[b*512+j], bb = v[b*512+j];
        du += a*bb; nu += a*a; nv += bb*bb;
    }
    for(int m=32;m;m>>=1){
        du += __shfl_xor(du,m); nu += __shfl_xor(nu,m); nv += __shfl_xor(nv,m);
    }
    if(t==0) out[b] = du / (fmaxf(sqrtf(nu),1e-8f)*fmaxf(sqrtf(nv),1e-8f));
}

// =======================================================================
extern "C" void kernel_launch(void* const* d_in, const int* in_sizes, int n_in,
                              void* d_out, int out_size, void* d_ws, size_t ws_size,
                              hipStream_t stream){
    (void)in_sizes; (void)n_in; (void)out_size; (void)ws_size;
    const float* hgt_Wk   = (const float*)d_in[12];
    const float* hgt_Wq   = (const float*)d_in[13];
    const float* hgt_Wv   = (const float*)d_in[14];
    const float* hgt_Wo   = (const float*)d_in[15];
    const float* hgt_arel = (const float*)d_in[16];
    const float* hgt_mrel = (const float*)d_in[17];
    const float* hgt_prel = (const float*)d_in[18];
    const float* hgt_skip = (const float*)d_in[19];
    const float* pool_W   = (const float*)d_in[20];
    const float* pool_att = (const float*)d_in[21];
    const float* pool_bias= (const float*)d_in[22];
    const float* t_wq     = (const float*)d_in[23];
    const float* t_wk     = (const float*)d_in[24];
    const float* t_wv     = (const float*)d_in[25];
    const float* t_wo     = (const float*)d_in[26];
    const float* ln_g     = (const float*)d_in[27];
    const float* ln_b     = (const float*)d_in[28];
    float* out = (float*)d_out;

    char* base = (char*)d_ws;
    size_t off = 0;
    auto allocb = [&](size_t nbytes)->void*{
        void* p = (void*)(base + off);
        off += ((nbytes + 255) & ~(size_t)255);
        return p;
    };
    const size_t MAT = 65536;
    // ---- persistent ----
    u16* bwtk_h = (u16*)allocb(16*MAT*2); u16* bwtk_l = (u16*)allocb(16*MAT*2);
    u16* bwtv_h = (u16*)allocb(16*MAT*2); u16* bwtv_l = (u16*)allocb(16*MAT*2);
    u16* bwq_h  = (u16*)allocb(8*MAT*2);  u16* bwq_l  = (u16*)allocb(8*MAT*2);
    u16* bwo_h  = (u16*)allocb(8*MAT*2);  u16* bwo_l  = (u16*)allocb(8*MAT*2);
    u16* btw_h  = (u16*)allocb(4*MAT*2);  u16* btw_l  = (u16*)allocb(4*MAT*2);
    float* ubuf = (float*)allocb(BB*512*4);
    float* vbuf = (float*)allocb(BB*512*4);
    float* xa_i = (float*)allocb((size_t)NI*DD*4);
    float* xa_d = (float*)allocb((size_t)ND*DD*4);
    float* xb_i = (float*)allocb((size_t)NI*DD*4);
    float* xb_d = (float*)allocb((size_t)ND*DD*4);
    // ---- per-branch CSR (lives across conv + pooling) ----
    uint32_t* ccnt   = (uint32_t*)allocb((size_t)2*NROW*4);
    uint32_t* rowptr = (uint32_t*)allocb((size_t)(2*NROW+1)*4);
    uint32_t* einfo  = (uint32_t*)allocb((size_t)2*EHGT*4);
    uint32_t* slot   = (uint32_t*)allocb((size_t)2*EHGT*4);
    size_t region = off;
    // ---- conv scratch ----
    float* q_i  = (float*)allocb((size_t)NI*DD*4);
    float* q_d  = (float*)allocb((size_t)ND*DD*4);
    float* ka4  = (float*)allocb((size_t)4*NI*DD*4);
    float* vmb  = (float*)allocb((size_t)4*NI*DD*4);
    float* scb  = (float*)allocb((size_t)2*EHGT*HH*4);
    float* xacc_i= (float*)allocb((size_t)NI*DD*4);
    float* xacc_d= (float*)allocb((size_t)ND*DD*4);
    u16* bcur_h = (u16*)allocb((size_t)NROW*DD*2);
    u16* bcur_l = (u16*)allocb((size_t)NROW*DD*2);
    u16* bagg_h = (u16*)allocb((size_t)NROW*DD*2);
    u16* bagg_l = (u16*)allocb((size_t)NROW*DD*2);
    // ---- pooling/transformer overlay ----
    off = region;
    float* hvec = (float*)allocb(NROW*4);
    float* pscore = (float*)allocb(NROW*4);
    int* seln   = (int*)allocb(BB*KPOOL*4);
    float* sels = (float*)allocb(BB*KPOOL*4);
    float* xp   = (float*)allocb((size_t)BB*KPOOL*DD*4);
    float* o2   = (float*)allocb((size_t)BB*KPOOL*DD*4);
    float* gatt = (float*)allocb((size_t)BB*KPOOL*DD*4);
    u16* bxp_h = (u16*)allocb((size_t)BB*KPOOL*DD*2);
    u16* bxp_l = (u16*)allocb((size_t)BB*KPOOL*DD*2);
    u16* qbh = (u16*)allocb((size_t)BB*KPOOL*DD*2);
    u16* qbl = (u16*)allocb((size_t)BB*KPOOL*DD*2);
    u16* kbh = (u16*)allocb((size_t)BB*KPOOL*DD*2);
    u16* kbl = (u16*)allocb((size_t)BB*KPOOL*DD*2);
    u16* vbh = (u16*)allocb((size_t)BB*KPOOL*DD*2);
    u16* vbl = (u16*)allocb((size_t)BB*KPOOL*DD*2);
    u16* bao_h = (u16*)allocb((size_t)BB*KPOOL*DD*2);
    u16* bao_l = (u16*)allocb((size_t)BB*KPOOL*DD*2);

    const int st_tab[2][4] = {{0,1,0,0},{0,0,1,0}};
    const int dt_tab[2][4] = {{0,0,1,0},{0,1,0,0}};
    const int MR = BB*KPOOL;

    fill_u32<<<(2*BB*512+255)/256,256,0,stream>>>((uint32_t*)ubuf, 0u, 2*BB*512);
    float* wtkF = ka4;
    float* wtvF = ka4 + 16*MAT;
    combine_all<<<dim3(256,32),256,0,stream>>>(hgt_Wk, hgt_Wv, hgt_arel, hgt_mrel, wtkF, wtvF);
    WCArgs wc;
    wc.in[0]=wtkF;   wc.oh[0]=bwtk_h; wc.ol[0]=bwtk_l; wc.cnt[0]=16;
    wc.in[1]=wtvF;   wc.oh[1]=bwtv_h; wc.ol[1]=bwtv_l; wc.cnt[1]=16;
    wc.in[2]=hgt_Wq; wc.oh[2]=bwq_h;  wc.ol[2]=bwq_l;  wc.cnt[2]=8;
    wc.in[3]=hgt_Wo; wc.oh[3]=bwo_h;  wc.ol[3]=bwo_l;  wc.cnt[3]=8;
    wc.in[4]=t_wq;   wc.oh[4]=btw_h;          wc.ol[4]=btw_l;          wc.cnt[4]=1;
    wc.in[5]=t_wk;   wc.oh[5]=btw_h+1*MAT;    wc.ol[5]=btw_l+1*MAT;    wc.cnt[5]=1;
    wc.in[6]=t_wv;   wc.oh[6]=btw_h+2*MAT;    wc.ol[6]=btw_l+2*MAT;    wc.cnt[6]=1;
    wc.in[7]=t_wo;   wc.oh[7]=btw_h+3*MAT;    wc.ol[7]=btw_l+3*MAT;    wc.cnt[7]=1;
    wc.nr = 8;
    wcvt_split<<<dim3(256,52),256,0,stream>>>(wc);

    for(int bi=0;bi<2;bi++){
        int ib = bi*6;
        const float* x_inst = (const float*)d_in[ib+0];
        const float* x_data = (const float*)d_in[ib+1];
        const int* ecp = (const int*)d_in[ib+2];
        const int* eip = (const int*)d_in[ib+3];
        const int* eop = (const int*)d_in[ib+4];
        const int* ekp = (const int*)d_in[ib+5];
        const int* rows_f[4] = {ecp, eip, eop, ekp};
        const int* cols_f[4] = {ecp+EC, eip+EI, eop+EO, ekp+EK};

        // ---- CSR build (both dirs, one pass) ----
        CB2 cb;
        for(int r=0;r<4;r++){
            cb.row[r]   = rows_f[r]; cb.col[r]   = cols_f[r]; cb.dt[r]   = dt_tab[0][r];
            cb.row[4+r] = cols_f[r]; cb.col[4+r] = rows_f[r]; cb.dt[4+r] = dt_tab[1][r];
        }
        cb.cnt = ccnt; cb.rowptr = rowptr; cb.einfo = einfo; cb.slot = slot;
        fill_u32<<<(2*NROW+255)/256,256,0,stream>>>(ccnt, 0u, 2*NROW);
        csr_hist2<<<(2*EHGT+255)/256,256,0,stream>>>(cb);
        scan_rowptr2<<<1,1024,0,stream>>>(ccnt, rowptr);
        csr_scatter2<<<(2*EHGT+255)/256,256,0,stream>>>(cb);

        const float* cur_i = x_inst;
        const float* cur_d = x_data;
        cvt_split<<<((NROW*DD/4)+255)/256,256,0,stream>>>(cur_i, NI*DD, cur_d, ND*DD, bcur_h, bcur_l);
        for(int l=0;l<LL;l++){
            float* nxt_i = (l==0) ? xa_i : xb_i;
            float* nxt_d = (l==0) ? xa_d : xb_d;
            for(int dir=0;dir<2;dir++){
                int wb = l*2 + dir;
                const int* rows[4]; const int* cols[4];
                for(int r=0;r<4;r++){
                    rows[r] = dir ? cols_f[r] : rows_f[r];
                    cols[r] = dir ? rows_f[r] : cols_f[r];
                }

                // --- mega GEMM: Q(2) + KA(4) + VM(4) in one launch ---
                GArgs g1; int nb1 = 0, ndx = 0;
                auto addg = [&](int srctype, const u16* Bh, const u16* Bl, float* Cm, int M){
                    GDesc& d = g1.d[ndx];
                    size_t ao = srctype ? (size_t)NI*DD : 0;
                    d.Ah = bcur_h + ao; d.Al = bcur_l + ao;
                    d.Bh = Bh; d.Bl = Bl; d.C = Cm;
                    d.Oh = nullptr; d.Ol = nullptr; d.X = nullptr; d.Xacc = nullptr; d.skipp = nullptr;
                    d.mblks = M/128; d.mode = 0;
                    nb1 += M/128; ndx++;
                };
                addg(0, bwq_h + (size_t)(wb*2+0)*MAT, bwq_l + (size_t)(wb*2+0)*MAT, q_i, NI);
                addg(1, bwq_h + (size_t)(wb*2+1)*MAT, bwq_l + (size_t)(wb*2+1)*MAT, q_d, ND);
                for(int r=0;r<4;r++){
                    int st = st_tab[dir][r];
                    addg(st, bwtk_h + (size_t)(wb*4+r)*MAT, bwtk_l + (size_t)(wb*4+r)*MAT,
                         ka4 + (size_t)r*NI*DD, st ? ND : NI);
                }
                for(int r=0;r<4;r++){
                    int st = st_tab[dir][r];
                    addg(st, bwtv_h + (size_t)(wb*4+r)*MAT, bwtv_l + (size_t)(wb*4+r)*MAT,
                         vmb + (size_t)r*NI*DD, st ? ND : NI);
                }
                g1.nd = ndx;
                gemm_mfma<<<dim3(nb1,2),256,0,stream>>>(g1);

                // --- edge scores ---
                P1Args pa;
                for(int r=0;r<4;r++){
                    pa.row[r] = rows[r]; pa.col[r] = cols[r];
                    pa.dt[r] = dt_tab[dir][r];
                }
                pa.Q[0]=q_i; pa.Q[1]=q_d;
                pa.ka = ka4;
                pa.prel = hgt_prel + (size_t)wb*4*HH;
                pa.slot = slot + (size_t)dir*EHGT;
                pa.sc = scb;
                hgt_pass1<<<EHGT/4,256,0,stream>>>(pa);

                // --- per-(dst,h) softmax + gather + gelu + split ---
                hgt_rowpass<<<NROW,256,0,stream>>>(rowptr + (size_t)dir*NROW, einfo, scb, vmb, bagg_h, bagg_l);

                // --- Wo GEMMs with fused skip/relu epilogue ---
                GArgs g3; g3.nd = 2;
                for(int t=0;t<2;t++){
                    GDesc& d = g3.d[t];
                    size_t ao = t ? (size_t)NI*DD : 0;
                    d.Ah = bagg_h + ao; d.Al = bagg_l + ao;
                    d.Bh = bwo_h + (size_t)(wb*2+t)*MAT; d.Bl = bwo_l + (size_t)(wb*2+t)*MAT;
                    d.C = t ? nxt_d : nxt_i;
                    d.Oh = bcur_h + ao; d.Ol = bcur_l + ao;
                    d.X = t ? cur_d : cur_i;
                    d.Xacc = t ? xacc_d : xacc_i;
                    d.skipp = hgt_skip + wb*2 + t;
                    d.mblks = (t ? ND : NI)/128;
                    d.mode = dir ? 3 : 2;
                }
                gemm_mfma<<<dim3(NI/128 + ND/128,2),256,0,stream>>>(g3);
            }
            cur_i = nxt_i;
            cur_d = nxt_d;
        }

        // -------- SAGPooling (CSR-based, no atomics) --------
        pool_h2<<<NROW/4,256,0,stream>>>(cur_i, cur_d, pool_W, hvec);
        pool_csr<<<NROW/4,256,0,stream>>>(rowptr, einfo, hvec, pool_att, pscore);
        topk_kernel<<<BB,512,0,stream>>>(pscore, pool_bias, seln, sels);
        gather_xp<<<BB*KPOOL,256,0,stream>>>(seln, sels, cur_i, cur_d, xp, bxp_h, bxp_l);

        // -------- transformer --------
        GArgs g4; g4.nd = 3;
        for(int t=0;t<3;t++){
            GDesc& d = g4.d[t];
            d.Ah=bxp_h; d.Al=bxp_l;
            d.Bh=btw_h + (size_t)t*MAT; d.Bl=btw_l + (size_t)t*MAT;
            d.C = nullptr;
            d.Oh = (t==0)? qbh : (t==1)? kbh : vbh;
            d.Ol = (t==0)? qbl : (t==1)? kbl : vbl;
            d.X = nullptr; d.Xacc = nullptr; d.skipp = nullptr;
            d.mblks = MR/128; d.mode = 1;
        }
        gemm_mfma<<<dim3(3*(MR/128),2),256,0,stream>>>(g4);
        attn_mfma<<<dim3(KPOOL/64, BB*HH),256,0,stream>>>(qbh, qbl, kbh, kbl, vbh, bao_h, bao_l);
        GArgs g5; g5.nd = 1;
        {
            GDesc& d = g5.d[0];
            d.Ah=bao_h; d.Al=bao_l;
            d.Bh=btw_h + (size_t)3*MAT; d.Bl=btw_l + (size_t)3*MAT;
            d.C=o2; d.Oh=nullptr; d.Ol=nullptr; d.X=nullptr; d.Xacc=nullptr; d.skipp=nullptr;
            d.mblks=MR/128; d.mode=0;
        }
        gemm_mfma<<<dim3(MR/128,2),256,0,stream>>>(g5);
        ln_kernel<<<MR,256,0,stream>>>(xp, o2, ln_g, ln_b, gatt);
        feat_reduce2<<<dim3(BB,12),256,0,stream>>>(xp, gatt, bi ? vbuf : ubuf);
    }

    cosine_kernel<<<BB,64,0,stream>>>(ubuf, vbuf, out);
}

// Round 10
// 1800.980 us; speedup vs baseline: 1.0798x; 1.0734x over previous
//
#include <hip/hip_runtime.h>
#include <math.h>
#include <stdint.h>

#define LL 2
#define HH 4
#define DHH 64
#define DD 256
#define BB 8
#define NI 8192
#define ND 4096
#define NROW 12288
#define KPOOL 768
#define EC 65536
#define EI 32768
#define EO 32768
#define EK 8192
#define EHGT (EC+EI+EO+EK)

typedef unsigned short u16;
typedef short bf16x8 __attribute__((ext_vector_type(8)));
typedef float f32x4 __attribute__((ext_vector_type(4)));
typedef unsigned short u16x4 __attribute__((ext_vector_type(4)));

__device__ inline float gelu_f(float x){ return 0.5f*x*(1.f+erff(x*0.70710678118654752f)); }
__device__ inline u16 f2b(float x){ uint32_t u=__float_as_uint(x); return (u16)((u + 0x7fffu + ((u>>16)&1u))>>16); }
__device__ inline float b2f(u16 h){ return __uint_as_float(((uint32_t)h)<<16); }

// ---------------- generic fill ----------------
__global__ void fill_u32(uint32_t* p, uint32_t v, int n){
    int i = blockIdx.x*256 + threadIdx.x;
    if(i<n) p[i]=v;
}

// ---------------- activation split-convert ----------------
__global__ void cvt_split(const float* __restrict__ A, int nA, const float* __restrict__ B, int nB,
                          u16* __restrict__ oh, u16* __restrict__ ol){
    int i = (blockIdx.x*256 + threadIdx.x)*4;
    int tot = nA + nB;
    if(i >= tot) return;
    float4 v = (i < nA) ? *(const float4*)(A + i) : *(const float4*)(B + (i - nA));
    float vv[4] = {v.x, v.y, v.z, v.w};
    u16x4 h4, l4;
    #pragma unroll
    for(int j=0;j<4;j++){
        float x = vv[j];
        u16 h = f2b(x);
        h4[j] = h;
        l4[j] = f2b(x - b2f(h));
    }
    *(u16x4*)(oh + i) = h4;
    *(u16x4*)(ol + i) = l4;
}

// ---------------- weight transpose + split ----------------
struct WCArgs { const float* in[8]; u16* oh[8]; u16* ol[8]; int cnt[8]; int nr; };
__global__ void wcvt_split(WCArgs a){
    int mat = blockIdx.y, ri = 0;
    while(ri < a.nr-1 && mat >= a.cnt[ri]){ mat -= a.cnt[ri]; ri++; }
    const float* in = a.in[ri] + (size_t)mat*65536;
    u16* oh = a.oh[ri] + (size_t)mat*65536;
    u16* ol = a.ol[ri] + (size_t)mat*65536;
    int n = blockIdx.x, k = threadIdx.x;
    float x = in[(size_t)k*DD + n];
    u16 h = f2b(x);
    oh[n*DD + k] = h;
    ol[n*DD + k] = f2b(x - b2f(h));
}

// ---------------- MFMA batched GEMM with fused epilogues ----------------
// LDS: paired hi/lo buffers, [128 rows][128 bytes], XOR-swizzle byte ^= (row&7)<<4.
// Register prefetch pipeline: next K-tile's loads issue before the MFMA block.
// mode 0: C=f32   mode 1: Oh/Ol=split bf16
// mode 2: Xacc = 0.5*(g*acc + (1-g)*X)
// mode 3: v=relu(Xacc + 0.5*(g*acc+(1-g)*X)); C=v; Oh/Ol=split(v)
struct GDesc { const u16* Ah; const u16* Al; const u16* Bh; const u16* Bl;
               float* C; u16* Oh; u16* Ol;
               const float* X; float* Xacc; const float* skipp;
               int mblks; int mode; };
struct GArgs { GDesc d[10]; int nd; };

__global__ __launch_bounds__(256) void gemm_mfma(GArgs ga){
    __shared__ u16 AS[128*64], BS[128*64];
    char* Abuf = (char*)AS; char* Bbuf = (char*)BS;
    int mb = blockIdx.x, di = 0;
    while(di < ga.nd-1 && mb >= ga.d[di].mblks){ mb -= ga.d[di].mblks; di++; }
    GDesc g = ga.d[di];
    const int m0 = mb*128, n0 = blockIdx.y*128;
    const int tid = threadIdx.x;
    const int lane = tid & 63, wid = tid >> 6;
    const int wm = (wid>>1)*64, wn = (wid&1)*64;
    const int l15 = lane & 15, l4 = lane >> 4;
    const int srow = tid >> 1, hf = tid & 1;
    const int ssw = (srow&7)<<4;
    const int c0 = (hf*32) ^ ssw;
    const int c1 = (hf*32+16) ^ ssw;
    const int c2 = (64+hf*32) ^ ssw;
    const int c3 = (64+hf*32+16) ^ ssw;
    const int rbyte = srow*128;
    const u16* __restrict__ Aph = g.Ah + (size_t)(m0 + srow)*DD + hf*16;
    const u16* __restrict__ Apl = g.Al + (size_t)(m0 + srow)*DD + hf*16;
    const u16* __restrict__ Bph = g.Bh + (size_t)(n0 + srow)*DD + hf*16;
    const u16* __restrict__ Bpl = g.Bl + (size_t)(n0 + srow)*DD + hf*16;
    f32x4 acc[4][4] = {};
    bf16x8 r0 = *(const bf16x8*)(Aph);
    bf16x8 r1 = *(const bf16x8*)(Aph + 8);
    bf16x8 r2 = *(const bf16x8*)(Apl);
    bf16x8 r3 = *(const bf16x8*)(Apl + 8);
    bf16x8 r4 = *(const bf16x8*)(Bph);
    bf16x8 r5 = *(const bf16x8*)(Bph + 8);
    bf16x8 r6 = *(const bf16x8*)(Bpl);
    bf16x8 r7 = *(const bf16x8*)(Bpl + 8);
    #pragma unroll
    for(int k0=0;k0<DD;k0+=32){
        __syncthreads();
        *(bf16x8*)(Abuf + rbyte + c0) = r0; *(bf16x8*)(Abuf + rbyte + c1) = r1;
        *(bf16x8*)(Abuf + rbyte + c2) = r2; *(bf16x8*)(Abuf + rbyte + c3) = r3;
        *(bf16x8*)(Bbuf + rbyte + c0) = r4; *(bf16x8*)(Bbuf + rbyte + c1) = r5;
        *(bf16x8*)(Bbuf + rbyte + c2) = r6; *(bf16x8*)(Bbuf + rbyte + c3) = r7;
        __syncthreads();
        if(k0 + 32 < DD){
            int kn = k0 + 32;
            r0 = *(const bf16x8*)(Aph + kn);     r1 = *(const bf16x8*)(Aph + kn + 8);
            r2 = *(const bf16x8*)(Apl + kn);     r3 = *(const bf16x8*)(Apl + kn + 8);
            r4 = *(const bf16x8*)(Bph + kn);     r5 = *(const bf16x8*)(Bph + kn + 8);
            r6 = *(const bf16x8*)(Bpl + kn);     r7 = *(const bf16x8*)(Bpl + kn + 8);
        }
        bf16x8 afh[4], afl[4], bfh[4], bfl[4];
        #pragma unroll
        for(int i=0;i<4;i++){
            int ar = wm + i*16 + l15;
            int swa = (ar&7)<<4;
            int abase = ar*128;
            afh[i] = *(const bf16x8*)(Abuf + abase + ((l4*16) ^ swa));
            afl[i] = *(const bf16x8*)(Abuf + abase + ((64 + l4*16) ^ swa));
            int br = wn + i*16 + l15;
            int swb = (br&7)<<4;
            int bbase = br*128;
            bfh[i] = *(const bf16x8*)(Bbuf + bbase + ((l4*16) ^ swb));
            bfl[i] = *(const bf16x8*)(Bbuf + bbase + ((64 + l4*16) ^ swb));
        }
        #pragma unroll
        for(int i=0;i<4;i++)
            #pragma unroll
            for(int j=0;j<4;j++){
                acc[i][j] = __builtin_amdgcn_mfma_f32_16x16x32_bf16(afh[i], bfh[j], acc[i][j], 0,0,0);
                acc[i][j] = __builtin_amdgcn_mfma_f32_16x16x32_bf16(afh[i], bfl[j], acc[i][j], 0,0,0);
                acc[i][j] = __builtin_amdgcn_mfma_f32_16x16x32_bf16(afl[i], bfh[j], acc[i][j], 0,0,0);
            }
    }
    const int mode = g.mode;
    float gg = 0.f;
    if(mode >= 2) gg = 1.f/(1.f + expf(-*g.skipp));
    #pragma unroll
    for(int i=0;i<4;i++){
        #pragma unroll
        for(int j=0;j<4;j++){
            int ccol = n0 + wn + j*16 + l15;
            #pragma unroll
            for(int r=0;r<4;r++){
                int row = m0 + wm + i*16 + l4*4 + r;
                size_t o = (size_t)row*DD + ccol;
                float val = acc[i][j][r];
                if(mode==0){
                    g.C[o] = val;
                } else if(mode==1){
                    u16 hh = f2b(val); g.Oh[o]=hh; g.Ol[o]=f2b(val-b2f(hh));
                } else {
                    float v2 = gg*val + (1.f-gg)*g.X[o];
                    if(mode==2){
                        g.Xacc[o] = 0.5f*v2;
                    } else {
                        float v3 = g.Xacc[o] + 0.5f*v2;
                        v3 = v3 > 0.f ? v3 : 0.f;
                        g.C[o] = v3;
                        u16 hh = f2b(v3); g.Oh[o]=hh; g.Ol[o]=f2b(v3-b2f(hh));
                    }
                }
            }
        }
    }
}

// ---------- combine ----------
__global__ void combine_all(const float* __restrict__ Wk, const float* __restrict__ Wv,
                            const float* __restrict__ Ra, const float* __restrict__ Rm,
                            float* __restrict__ wtk, float* __restrict__ wtv){
    const int st_tab[2][4] = {{0,1,0,0},{0,0,1,0}};
    int combo = blockIdx.y;
    int idx = combo >> 1, kv = combo & 1;
    int r = idx & 3, wb = idx >> 2, dir = wb & 1;
    int st = st_tab[dir][r];
    const float* W = (kv ? Wv : Wk) + (size_t)(wb*2 + st)*65536;
    const float* R = (kv ? Rm : Ra) + (size_t)idx*16384;
    float* o = (kv ? wtv : wtk) + (size_t)idx*65536;
    int d = blockIdx.x, c = threadIdx.x;
    int h = c >> 6, f = c & 63;
    const float* Wrow = W + d*DD + h*64;
    const float* Rh = R + h*4096 + f;
    float s = 0.f;
    #pragma unroll 8
    for(int k=0;k<64;k++) s += Wrow[k]*Rh[k*64];
    o[d*DD + c] = s;
}

// ---------------- CSR build (both directions in one pass) ----------------
__device__ inline void edge_decode(int e, int& r, int& el){
    if(e < EC){ r=0; el=e; }
    else if(e < EC+EI){ r=1; el=e-EC; }
    else if(e < EC+EI+EO){ r=2; el=e-(EC+EI); }
    else { r=3; el=e-(EC+EI+EO); }
}

struct CB2 {
    const int* row[8]; const int* col[8];
    int dt[8];
    uint32_t* cnt; uint32_t* rowptr; uint32_t* einfo; uint32_t* slot;
};

__global__ void csr_hist2(CB2 a){
    int ge = blockIdx.x*256 + threadIdx.x;
    if(ge >= 2*EHGT) return;
    int dir = ge >= EHGT;
    int e = ge - dir*EHGT;
    int r, el; edge_decode(e, r, el);
    int idx = dir*4 + r;
    int c = a.col[idx][el];
    int dst = dir*NROW + (a.dt[idx] ? (NI + c) : c);
    atomicAdd(&a.cnt[dst], 1u);
}

__global__ __launch_bounds__(1024) void scan_rowptr2(uint32_t* cnt, uint32_t* rowptr){
    __shared__ uint32_t part[1024];
    int t = threadIdx.x;
    int base = t*24;
    uint32_t lpre[24];
    uint32_t sum = 0;
    #pragma unroll
    for(int i=0;i<24;i++){
        uint32_t c = cnt[base+i];
        lpre[i] = sum; sum += c;
        cnt[base+i] = 0;
    }
    part[t] = sum;
    __syncthreads();
    for(int offs=1; offs<1024; offs<<=1){
        uint32_t v = (t>=offs) ? part[t-offs] : 0u;
        __syncthreads();
        part[t] += v;
        __syncthreads();
    }
    uint32_t pre = (t==0) ? 0u : part[t-1];
    #pragma unroll
    for(int i=0;i<24;i++) rowptr[base+i] = pre + lpre[i];
    if(t==1023) rowptr[2*NROW] = part[1023];
}

__global__ void csr_scatter2(CB2 a){
    int ge = blockIdx.x*256 + threadIdx.x;
    if(ge >= 2*EHGT) return;
    int dir = ge >= EHGT;
    int e = ge - dir*EHGT;
    int r, el; edge_decode(e, r, el);
    int idx = dir*4 + r;
    int c = a.col[idx][el];
    int dst = dir*NROW + (a.dt[idx] ? (NI + c) : c);
    int src = a.row[idx][el];
    uint32_t p = a.rowptr[dst] + atomicAdd(&a.cnt[dst], 1u);
    a.einfo[p] = (uint32_t)src | ((uint32_t)r << 16);
    a.slot[ge] = p;
}

// ---------------- HGT edge scores: wave per edge ----------------
struct P1Args {
    const int* row[4]; const int* col[4];
    const float* Q[2];
    const float* ka;
    const float* prel;
    const uint32_t* slot;
    float* sc;
    int dt[4];
};

__global__ __launch_bounds__(256) void hgt_pass1(P1Args a){
    int w = blockIdx.x*4 + (threadIdx.x >> 6);
    int lane = threadIdx.x & 63;
    if(w >= EHGT) return;
    int r, el; edge_decode(w, r, el);
    int dt = a.dt[r];
    int rn = a.row[r][el], cn = a.col[r][el];
    float4 qv = *(const float4*)(a.Q[dt] + (size_t)cn*DD + lane*4);
    float4 kv = *(const float4*)(a.ka + (size_t)r*NI*DD + (size_t)rn*DD + lane*4);
    float d = qv.x*kv.x + qv.y*kv.y + qv.z*kv.z + qv.w*kv.w;
    d += __shfl_xor(d, 1); d += __shfl_xor(d, 2);
    d += __shfl_xor(d, 4); d += __shfl_xor(d, 8);
    if((lane & 15) == 0){
        int h = lane >> 4;
        a.sc[(size_t)a.slot[w]*HH + h] = d * a.prel[r*HH + h] * 0.125f;
    }
}

// one wave per (dst,h): ONLINE segment softmax + gather + gelu + split-bf16 out
__global__ __launch_bounds__(256) void hgt_rowpass(const uint32_t* __restrict__ rowptr,
                                                   const uint32_t* __restrict__ einfo,
                                                   const float* __restrict__ sc,
                                                   const float* __restrict__ vmb,
                                                   u16* __restrict__ bagg_h,
                                                   u16* __restrict__ bagg_l){
    int w = blockIdx.x*4 + (threadIdx.x >> 6);
    int lane = threadIdx.x & 63;
    int rowi = w >> 2, h = w & 3;
    uint32_t p0 = rowptr[rowi], p1 = rowptr[rowi+1];
    size_t obase = (size_t)rowi*DD + h*64 + lane;
    float o = 0.f;
    if(p0 != p1){
        float m = -INFINITY, den = 0.f;
        for(uint32_t p = p0; p < p1; p++){
            float s = sc[(size_t)p*HH + h];
            uint32_t ei = einfo[p];
            int src = ei & 0xffff, r = ei >> 16;
            float vmv = vmb[((size_t)r*NI + src)*DD + h*64 + lane];
            float nm = fmaxf(m, s);
            float scale = expf(m - nm);
            float pe = expf(s - nm);
            den = den*scale + pe;
            o = o*scale + pe*vmv;
            m = nm;
        }
        o /= (den + 1e-16f);
    }
    float g = gelu_f(o);
    u16 hh = f2b(g);
    bagg_h[obase] = hh;
    bagg_l[obase] = f2b(g - b2f(hh));
}

// ---------------- pooling ----------------
__global__ void pool_h2(const float* __restrict__ xi, const float* __restrict__ xd,
                        const float* __restrict__ w, float* __restrict__ h){
    int node = blockIdx.x*4 + (threadIdx.x>>6);
    int lane = threadIdx.x & 63;
    const float* xr = (node < NI) ? (xi + (size_t)node*DD) : (xd + (size_t)(node-NI)*DD);
    float s = 0.f;
    for(int j=lane;j<DD;j+=64) s += xr[j]*w[j];
    for(int m=32;m;m>>=1) s += __shfl_xor(s, m);
    if(lane==0) h[node] = s;
}

// GAT-style pooling score via fwd CSR + implicit self-loop; wave per dst node
__global__ __launch_bounds__(256) void pool_csr(const uint32_t* __restrict__ rowptr,
                                                const uint32_t* __restrict__ einfo,
                                                const float* __restrict__ h,
                                                const float* __restrict__ att,
                                                float* __restrict__ score){
    int w = blockIdx.x*4 + (threadIdx.x >> 6);
    int lane = threadIdx.x & 63;
    if(w >= NROW) return;
    uint32_t p0 = rowptr[w], p1 = rowptr[w+1];
    float a0 = att[0], a1 = att[1];
    float hn = h[w];
    float es = a0*hn + a1*hn;
    es = es >= 0.f ? es : 0.2f*es;
    float m = -INFINITY;
    for(uint32_t p = p0+lane; p < p1; p += 64){
        uint32_t ei = einfo[p];
        int src = ei & 0xffff, r = ei >> 16;
        float hs = h[r==1 ? NI+src : src];
        float e = a0*hs + a1*hn;
        e = e >= 0.f ? e : 0.2f*e;
        m = fmaxf(m, e);
    }
    #pragma unroll
    for(int s=32;s;s>>=1) m = fmaxf(m, __shfl_xor(m, s));
    m = fmaxf(m, es);
    float lden = 0.f, lnum = 0.f;
    for(uint32_t p = p0+lane; p < p1; p += 64){
        uint32_t ei = einfo[p];
        int src = ei & 0xffff, r = ei >> 16;
        float hs = h[r==1 ? NI+src : src];
        float e = a0*hs + a1*hn;
        e = e >= 0.f ? e : 0.2f*e;
        float a = expf(e - m);
        lden += a; lnum += a*hs;
    }
    #pragma unroll
    for(int s=32;s;s>>=1){ lden += __shfl_xor(lden, s); lnum += __shfl_xor(lnum, s); }
    float aself = expf(es - m);
    lden += aself; lnum += aself*hn;
    if(lane==0) score[w] = lnum/(lden + 1e-16f);
}

// top-768 of 1536 per graph via bitonic sort
__global__ __launch_bounds__(512) void topk_kernel(const float* __restrict__ score,
                                                   const float* __restrict__ bias,
                                                   int* __restrict__ sel_node,
                                                   float* __restrict__ sel_scale){
    __shared__ float skey[2048];
    __shared__ int   sval[2048];
    int b = blockIdx.x;
    float bv = bias[0];
    for(int p=threadIdx.x;p<2048;p+=512){
        if(p<1536){
            int node = (p<1024) ? (b*1024 + p) : (NI + b*512 + (p-1024));
            skey[p] = score[node] + bv;
            sval[p] = node;
        } else {
            skey[p] = -INFINITY;
            sval[p] = -1;
        }
    }
    for(int k=2;k<=2048;k<<=1){
        for(int j=k>>1;j>0;j>>=1){
            __syncthreads();
            for(int i=threadIdx.x;i<2048;i+=512){
                int ixj = i^j;
                if(ixj > i){
                    bool up = ((i & k) == 0);
                    float ki = skey[i], kj = skey[ixj];
                    if((ki < kj) == up){
                        skey[i]=kj; skey[ixj]=ki;
                        int t=sval[i]; sval[i]=sval[ixj]; sval[ixj]=t;
                    }
                }
            }
        }
    }
    __syncthreads();
    for(int j=threadIdx.x;j<KPOOL;j+=512){
        sel_node[b*KPOOL + j] = sval[j];
        sel_scale[b*KPOOL + j] = tanhf(skey[j]);
    }
}

__global__ void gather_xp(const int* __restrict__ sel, const float* __restrict__ scale,
                          const float* __restrict__ xi, const float* __restrict__ xd,
                          float* __restrict__ xp, u16* __restrict__ bh, u16* __restrict__ bl){
    int i = blockIdx.x*256 + threadIdx.x;
    int rowp = i >> 8, c = i & 255;
    int node = sel[rowp];
    float s = scale[rowp];
    float v = (node < NI) ? xi[(size_t)node*DD + c] : xd[(size_t)(node-NI)*DD + c];
    float x = v*s;
    xp[i] = x;
    u16 hh = f2b(x);
    bh[i] = hh;
    bl[i] = f2b(x - b2f(hh));
}

// ---------------- MFMA flash attention: block per (b,h,64 q rows), pre-split inputs ----------------
__global__ __launch_bounds__(256) void attn_mfma(const u16* __restrict__ Qh, const u16* __restrict__ Ql,
                                                 const u16* __restrict__ Kh, const u16* __restrict__ Kl,
                                                 const u16* __restrict__ Vh,
                                                 u16* __restrict__ aoh, u16* __restrict__ aol){
    __shared__ u16 KhS[64*64], KlS[64*64], VtS[64*64];
    char* KhB = (char*)KhS; char* KlB = (char*)KlS; char* VtB = (char*)VtS;
    int bh = blockIdx.y;
    int b = bh >> 2, h = bh & 3;
    int q0 = blockIdx.x * 64;
    int tid = threadIdx.x;
    int lane = tid & 63;
    int w = tid >> 6;
    int l15 = lane & 15, l4 = lane >> 4;
    size_t qrow = (size_t)(b*KPOOL + q0 + w*16 + l15);
    bf16x8 qh[2], ql[2];
    #pragma unroll
    for(int c=0;c<2;c++){
        qh[c] = *(const bf16x8*)(Qh + qrow*DD + h*64 + c*32 + l4*8);
        ql[c] = *(const bf16x8*)(Ql + qrow*DD + h*64 + c*32 + l4*8);
    }
    float mreg = -INFINITY, lreg = 0.f;
    f32x4 O[4] = {};
    for(int k0=0;k0<KPOOL;k0+=64){
        __syncthreads();
        {   // stage K hi/lo + V^T from pre-split bf16
            int row = tid >> 2, q4 = tid & 3;
            size_t gbase = ((size_t)(b*KPOOL + k0 + row))*DD + h*64 + q4*16;
            bf16x8 k0v = *(const bf16x8*)(Kh + gbase);
            bf16x8 k1v = *(const bf16x8*)(Kh + gbase + 8);
            bf16x8 kl0 = *(const bf16x8*)(Kl + gbase);
            bf16x8 kl1 = *(const bf16x8*)(Kl + gbase + 8);
            bf16x8 v0v = *(const bf16x8*)(Vh + gbase);
            bf16x8 v1v = *(const bf16x8*)(Vh + gbase + 8);
            int sw = (row&7)<<4;
            int colb = q4*32;
            *(bf16x8*)(KhB + row*128 + (colb ^ sw))        = k0v;
            *(bf16x8*)(KhB + row*128 + ((colb+16) ^ sw))   = k1v;
            *(bf16x8*)(KlB + row*128 + (colb ^ sw))        = kl0;
            *(bf16x8*)(KlB + row*128 + ((colb+16) ^ sw))   = kl1;
            #pragma unroll
            for(int j=0;j<8;j++){
                int dh0 = q4*16 + j;
                int dh1 = q4*16 + 8 + j;
                *(u16*)(VtB + dh0*128 + ((row*2) ^ ((dh0&7)<<4))) = (u16)(short)v0v[j];
                *(u16*)(VtB + dh1*128 + ((row*2) ^ ((dh1&7)<<4))) = (u16)(short)v1v[j];
            }
        }
        __syncthreads();
        // S^T tiles: mfma(A=K, B=Q)
        f32x4 s[4] = {};
        #pragma unroll
        for(int t=0;t<4;t++){
            int arow = t*16 + l15;
            int sw = (arow&7)<<4;
            const char* bh_ = KhB + arow*128;
            const char* bl_ = KlB + arow*128;
            bf16x8 kh0 = *(const bf16x8*)(bh_ + ((l4*16) ^ sw));
            bf16x8 kh1 = *(const bf16x8*)(bh_ + ((l4*16 + 64) ^ sw));
            bf16x8 kl0 = *(const bf16x8*)(bl_ + ((l4*16) ^ sw));
            bf16x8 kl1 = *(const bf16x8*)(bl_ + ((l4*16 + 64) ^ sw));
            s[t] = __builtin_amdgcn_mfma_f32_16x16x32_bf16(kh0, qh[0], s[t], 0,0,0);
            s[t] = __builtin_amdgcn_mfma_f32_16x16x32_bf16(kh1, qh[1], s[t], 0,0,0);
            s[t] = __builtin_amdgcn_mfma_f32_16x16x32_bf16(kh0, ql[0], s[t], 0,0,0);
            s[t] = __builtin_amdgcn_mfma_f32_16x16x32_bf16(kh1, ql[1], s[t], 0,0,0);
            s[t] = __builtin_amdgcn_mfma_f32_16x16x32_bf16(kl0, qh[0], s[t], 0,0,0);
            s[t] = __builtin_amdgcn_mfma_f32_16x16x32_bf16(kl1, qh[1], s[t], 0,0,0);
        }
        // online softmax
        float cm = -INFINITY;
        #pragma unroll
        for(int t=0;t<4;t++)
            #pragma unroll
            for(int r=0;r<4;r++){ s[t][r] *= 0.125f; cm = fmaxf(cm, s[t][r]); }
        cm = fmaxf(cm, __shfl_xor(cm,16));
        cm = fmaxf(cm, __shfl_xor(cm,32));
        float nm = fmaxf(mreg, cm);
        float es = expf(mreg - nm);
        float ps = 0.f;
        #pragma unroll
        for(int t=0;t<4;t++)
            #pragma unroll
            for(int r=0;r<4;r++){ float pv = expf(s[t][r] - nm); s[t][r] = pv; ps += pv; }
        ps += __shfl_xor(ps,16);
        ps += __shfl_xor(ps,32);
        lreg = lreg*es + ps;
        mreg = nm;
        #pragma unroll
        for(int d=0;d<4;d++){ O[d][0]*=es; O[d][1]*=es; O[d][2]*=es; O[d][3]*=es; }
        // O^T += mfma(A=V^T, B=P^T)
        #pragma unroll
        for(int c32=0;c32<2;c32++){
            bf16x8 pb;
            #pragma unroll
            for(int j=0;j<8;j++){
                int srcl = ((((lane>>4)*2 + (j>>2)) & 3) << 4) | l15;
                float v0 = __shfl(s[c32*2+0][j&3], srcl, 64);
                float v1 = __shfl(s[c32*2+1][j&3], srcl, 64);
                float v = (lane < 32) ? v0 : v1;
                pb[j] = (short)f2b(v);
            }
            #pragma unroll
            for(int dhb=0; dhb<4; dhb++){
                int vrow = dhb*16 + l15;
                bf16x8 va = *(const bf16x8*)(VtB + vrow*128 + ((c32*64 + l4*16) ^ ((vrow&7)<<4)));
                O[dhb] = __builtin_amdgcn_mfma_f32_16x16x32_bf16(va, pb, O[dhb], 0,0,0);
            }
        }
    }
    float inv = 1.f/lreg;
    #pragma unroll
    for(int dhb=0;dhb<4;dhb++)
        #pragma unroll
        for(int r=0;r<4;r++){
            float val = O[dhb][r]*inv;
            size_t o = qrow*DD + h*64 + dhb*16 + l4*4 + r;
            u16 hh = f2b(val);
            aoh[o] = hh;
            aol[o] = f2b(val - b2f(hh));
        }
}

// layernorm row kernel
__global__ __launch_bounds__(256) void ln_kernel(const float* __restrict__ xp, const float* __restrict__ o2,
                                                 const float* __restrict__ lg, const float* __restrict__ lb,
                                                 float* __restrict__ gatt){
    __shared__ float red[256];
    int r = blockIdx.x, c = threadIdx.x;
    float y = xp[(size_t)r*DD + c] + o2[(size_t)r*DD + c];
    red[c] = y; __syncthreads();
    for(int s=128;s;s>>=1){ if(c<s) red[c] += red[c+s]; __syncthreads(); }
    float mu = red[0]*(1.f/DD);
    __syncthreads();
    float d = y - mu;
    red[c] = d*d; __syncthreads();
    for(int s=128;s;s>>=1){ if(c<s) red[c] += red[c+s]; __syncthreads(); }
    float var = red[0]*(1.f/DD);
    gatt[(size_t)r*DD + c] = lg[c]*d/sqrtf(var+1e-5f) + lb[c];
}

__global__ void feat_reduce2(const float* __restrict__ xp, const float* __restrict__ gatt,
                             float* __restrict__ out){
    int b = blockIdx.x, c = threadIdx.x;
    int j0 = blockIdx.y*64;
    float s1=0.f, s2=0.f;
    for(int j=j0;j<j0+64;j++){
        size_t base = ((size_t)(b*KPOOL + j))*DD + c;
        s1 += xp[base];
        s2 += gatt[base];
    }
    atomicAdd(&out[b*512 + c], s1);
    atomicAdd(&out[b*512 + 256 + c], s2);
}

__global__ void cosine_kernel(const float* __restrict__ u, const float* __restrict__ v,
                              float* __restrict__ out){
    int b = blockIdx.x, t = threadIdx.x;
    float du=0.f, nu=0.f, nv=0.f;
    for(int j=t;j<512;j+=64){
        float a = u[b*512+j], bb = v[b*512+j];
        du += a*bb; nu += a*a; nv += bb*bb;
    }
    for(int m=32;m;m>>=1){
        du += __shfl_xor(du,m); nu += __shfl_xor(nu,m); nv += __shfl_xor(nv,m);
    }
    if(t==0) out[b] = du / (fmaxf(sqrtf(nu),1e-8f)*fmaxf(sqrtf(nv),1e-8f));
}

// =======================================================================
extern "C" void kernel_launch(void* const* d_in, const int* in_sizes, int n_in,
                              void* d_out, int out_size, void* d_ws, size_t ws_size,
                              hipStream_t stream){
    (void)in_sizes; (void)n_in; (void)out_size; (void)ws_size;
    const float* hgt_Wk   = (const float*)d_in[12];
    const float* hgt_Wq   = (const float*)d_in[13];
    const float* hgt_Wv   = (const float*)d_in[14];
    const float* hgt_Wo   = (const float*)d_in[15];
    const float* hgt_arel = (const float*)d_in[16];
    const float* hgt_mrel = (const float*)d_in[17];
    const float* hgt_prel = (const float*)d_in[18];
    const float* hgt_skip = (const float*)d_in[19];
    const float* pool_W   = (const float*)d_in[20];
    const float* pool_att = (const float*)d_in[21];
    const float* pool_bias= (const float*)d_in[22];
    const float* t_wq     = (const float*)d_in[23];
    const float* t_wk     = (const float*)d_in[24];
    const float* t_wv     = (const float*)d_in[25];
    const float* t_wo     = (const float*)d_in[26];
    const float* ln_g     = (const float*)d_in[27];
    const float* ln_b     = (const float*)d_in[28];
    float* out = (float*)d_out;

    char* base = (char*)d_ws;
    size_t off = 0;
    auto allocb = [&](size_t nbytes)->void*{
        void* p = (void*)(base + off);
        off += ((nbytes + 255) & ~(size_t)255);
        return p;
    };
    const size_t MAT = 65536;
    // ---- persistent ----
    u16* bwtk_h = (u16*)allocb(16*MAT*2); u16* bwtk_l = (u16*)allocb(16*MAT*2);
    u16* bwtv_h = (u16*)allocb(16*MAT*2); u16* bwtv_l = (u16*)allocb(16*MAT*2);
    u16* bwq_h  = (u16*)allocb(8*MAT*2);  u16* bwq_l  = (u16*)allocb(8*MAT*2);
    u16* bwo_h  = (u16*)allocb(8*MAT*2);  u16* bwo_l  = (u16*)allocb(8*MAT*2);
    u16* btw_h  = (u16*)allocb(4*MAT*2);  u16* btw_l  = (u16*)allocb(4*MAT*2);
    float* ubuf = (float*)allocb(BB*512*4);
    float* vbuf = (float*)allocb(BB*512*4);
    float* xa_i = (float*)allocb((size_t)NI*DD*4);
    float* xa_d = (float*)allocb((size_t)ND*DD*4);
    float* xb_i = (float*)allocb((size_t)NI*DD*4);
    float* xb_d = (float*)allocb((size_t)ND*DD*4);
    // ---- per-branch CSR (lives across conv + pooling) ----
    uint32_t* ccnt   = (uint32_t*)allocb((size_t)2*NROW*4);
    uint32_t* rowptr = (uint32_t*)allocb((size_t)(2*NROW+1)*4);
    uint32_t* einfo  = (uint32_t*)allocb((size_t)2*EHGT*4);
    uint32_t* slot   = (uint32_t*)allocb((size_t)2*EHGT*4);
    size_t region = off;
    // ---- conv scratch ----
    float* q_i  = (float*)allocb((size_t)NI*DD*4);
    float* q_d  = (float*)allocb((size_t)ND*DD*4);
    float* ka4  = (float*)allocb((size_t)4*NI*DD*4);
    float* vmb  = (float*)allocb((size_t)4*NI*DD*4);
    float* scb  = (float*)allocb((size_t)2*EHGT*HH*4);
    float* xacc_i= (float*)allocb((size_t)NI*DD*4);
    float* xacc_d= (float*)allocb((size_t)ND*DD*4);
    u16* bcur_h = (u16*)allocb((size_t)NROW*DD*2);
    u16* bcur_l = (u16*)allocb((size_t)NROW*DD*2);
    u16* bagg_h = (u16*)allocb((size_t)NROW*DD*2);
    u16* bagg_l = (u16*)allocb((size_t)NROW*DD*2);
    // ---- pooling/transformer overlay ----
    off = region;
    float* hvec = (float*)allocb(NROW*4);
    float* pscore = (float*)allocb(NROW*4);
    int* seln   = (int*)allocb(BB*KPOOL*4);
    float* sels = (float*)allocb(BB*KPOOL*4);
    float* xp   = (float*)allocb((size_t)BB*KPOOL*DD*4);
    float* o2   = (float*)allocb((size_t)BB*KPOOL*DD*4);
    float* gatt = (float*)allocb((size_t)BB*KPOOL*DD*4);
    u16* bxp_h = (u16*)allocb((size_t)BB*KPOOL*DD*2);
    u16* bxp_l = (u16*)allocb((size_t)BB*KPOOL*DD*2);
    u16* qbh = (u16*)allocb((size_t)BB*KPOOL*DD*2);
    u16* qbl = (u16*)allocb((size_t)BB*KPOOL*DD*2);
    u16* kbh = (u16*)allocb((size_t)BB*KPOOL*DD*2);
    u16* kbl = (u16*)allocb((size_t)BB*KPOOL*DD*2);
    u16* vbh = (u16*)allocb((size_t)BB*KPOOL*DD*2);
    u16* vbl = (u16*)allocb((size_t)BB*KPOOL*DD*2);
    u16* bao_h = (u16*)allocb((size_t)BB*KPOOL*DD*2);
    u16* bao_l = (u16*)allocb((size_t)BB*KPOOL*DD*2);

    const int st_tab[2][4] = {{0,1,0,0},{0,0,1,0}};
    const int dt_tab[2][4] = {{0,0,1,0},{0,1,0,0}};
    const int MR = BB*KPOOL;

    fill_u32<<<(2*BB*512+255)/256,256,0,stream>>>((uint32_t*)ubuf, 0u, 2*BB*512);
    float* wtkF = ka4;
    float* wtvF = ka4 + 16*MAT;
    combine_all<<<dim3(256,32),256,0,stream>>>(hgt_Wk, hgt_Wv, hgt_arel, hgt_mrel, wtkF, wtvF);
    WCArgs wc;
    wc.in[0]=wtkF;   wc.oh[0]=bwtk_h; wc.ol[0]=bwtk_l; wc.cnt[0]=16;
    wc.in[1]=wtvF;   wc.oh[1]=bwtv_h; wc.ol[1]=bwtv_l; wc.cnt[1]=16;
    wc.in[2]=hgt_Wq; wc.oh[2]=bwq_h;  wc.ol[2]=bwq_l;  wc.cnt[2]=8;
    wc.in[3]=hgt_Wo; wc.oh[3]=bwo_h;  wc.ol[3]=bwo_l;  wc.cnt[3]=8;
    wc.in[4]=t_wq;   wc.oh[4]=btw_h;          wc.ol[4]=btw_l;          wc.cnt[4]=1;
    wc.in[5]=t_wk;   wc.oh[5]=btw_h+1*MAT;    wc.ol[5]=btw_l+1*MAT;    wc.cnt[5]=1;
    wc.in[6]=t_wv;   wc.oh[6]=btw_h+2*MAT;    wc.ol[6]=btw_l+2*MAT;    wc.cnt[6]=1;
    wc.in[7]=t_wo;   wc.oh[7]=btw_h+3*MAT;    wc.ol[7]=btw_l+3*MAT;    wc.cnt[7]=1;
    wc.nr = 8;
    wcvt_split<<<dim3(256,52),256,0,stream>>>(wc);

    for(int bi=0;bi<2;bi++){
        int ib = bi*6;
        const float* x_inst = (const float*)d_in[ib+0];
        const float* x_data = (const float*)d_in[ib+1];
        const int* ecp = (const int*)d_in[ib+2];
        const int* eip = (const int*)d_in[ib+3];
        const int* eop = (const int*)d_in[ib+4];
        const int* ekp = (const int*)d_in[ib+5];
        const int* rows_f[4] = {ecp, eip, eop, ekp};
        const int* cols_f[4] = {ecp+EC, eip+EI, eop+EO, ekp+EK};

        // ---- CSR build (both dirs, one pass) ----
        CB2 cb;
        for(int r=0;r<4;r++){
            cb.row[r]   = rows_f[r]; cb.col[r]   = cols_f[r]; cb.dt[r]   = dt_tab[0][r];
            cb.row[4+r] = cols_f[r]; cb.col[4+r] = rows_f[r]; cb.dt[4+r] = dt_tab[1][r];
        }
        cb.cnt = ccnt; cb.rowptr = rowptr; cb.einfo = einfo; cb.slot = slot;
        fill_u32<<<(2*NROW+255)/256,256,0,stream>>>(ccnt, 0u, 2*NROW);
        csr_hist2<<<(2*EHGT+255)/256,256,0,stream>>>(cb);
        scan_rowptr2<<<1,1024,0,stream>>>(ccnt, rowptr);
        csr_scatter2<<<(2*EHGT+255)/256,256,0,stream>>>(cb);

        const float* cur_i = x_inst;
        const float* cur_d = x_data;
        cvt_split<<<((NROW*DD/4)+255)/256,256,0,stream>>>(cur_i, NI*DD, cur_d, ND*DD, bcur_h, bcur_l);
        for(int l=0;l<LL;l++){
            float* nxt_i = (l==0) ? xa_i : xb_i;
            float* nxt_d = (l==0) ? xa_d : xb_d;
            for(int dir=0;dir<2;dir++){
                int wb = l*2 + dir;
                const int* rows[4]; const int* cols[4];
                for(int r=0;r<4;r++){
                    rows[r] = dir ? cols_f[r] : rows_f[r];
                    cols[r] = dir ? rows_f[r] : cols_f[r];
                }

                // --- mega GEMM: Q(2) + KA(4) + VM(4) in one launch ---
                GArgs g1; int nb1 = 0, ndx = 0;
                auto addg = [&](int srctype, const u16* Bh, const u16* Bl, float* Cm, int M){
                    GDesc& d = g1.d[ndx];
                    size_t ao = srctype ? (size_t)NI*DD : 0;
                    d.Ah = bcur_h + ao; d.Al = bcur_l + ao;
                    d.Bh = Bh; d.Bl = Bl; d.C = Cm;
                    d.Oh = nullptr; d.Ol = nullptr; d.X = nullptr; d.Xacc = nullptr; d.skipp = nullptr;
                    d.mblks = M/128; d.mode = 0;
                    nb1 += M/128; ndx++;
                };
                addg(0, bwq_h + (size_t)(wb*2+0)*MAT, bwq_l + (size_t)(wb*2+0)*MAT, q_i, NI);
                addg(1, bwq_h + (size_t)(wb*2+1)*MAT, bwq_l + (size_t)(wb*2+1)*MAT, q_d, ND);
                for(int r=0;r<4;r++){
                    int st = st_tab[dir][r];
                    addg(st, bwtk_h + (size_t)(wb*4+r)*MAT, bwtk_l + (size_t)(wb*4+r)*MAT,
                         ka4 + (size_t)r*NI*DD, st ? ND : NI);
                }
                for(int r=0;r<4;r++){
                    int st = st_tab[dir][r];
                    addg(st, bwtv_h + (size_t)(wb*4+r)*MAT, bwtv_l + (size_t)(wb*4+r)*MAT,
                         vmb + (size_t)r*NI*DD, st ? ND : NI);
                }
                g1.nd = ndx;
                gemm_mfma<<<dim3(nb1,2),256,0,stream>>>(g1);

                // --- edge scores ---
                P1Args pa;
                for(int r=0;r<4;r++){
                    pa.row[r] = rows[r]; pa.col[r] = cols[r];
                    pa.dt[r] = dt_tab[dir][r];
                }
                pa.Q[0]=q_i; pa.Q[1]=q_d;
                pa.ka = ka4;
                pa.prel = hgt_prel + (size_t)wb*4*HH;
                pa.slot = slot + (size_t)dir*EHGT;
                pa.sc = scb;
                hgt_pass1<<<EHGT/4,256,0,stream>>>(pa);

                // --- per-(dst,h) online softmax + gather + gelu + split ---
                hgt_rowpass<<<NROW,256,0,stream>>>(rowptr + (size_t)dir*NROW, einfo, scb, vmb, bagg_h, bagg_l);

                // --- Wo GEMMs with fused skip/relu epilogue ---
                GArgs g3; g3.nd = 2;
                for(int t=0;t<2;t++){
                    GDesc& d = g3.d[t];
                    size_t ao = t ? (size_t)NI*DD : 0;
                    d.Ah = bagg_h + ao; d.Al = bagg_l + ao;
                    d.Bh = bwo_h + (size_t)(wb*2+t)*MAT; d.Bl = bwo_l + (size_t)(wb*2+t)*MAT;
                    d.C = t ? nxt_d : nxt_i;
                    d.Oh = bcur_h + ao; d.Ol = bcur_l + ao;
                    d.X = t ? cur_d : cur_i;
                    d.Xacc = t ? xacc_d : xacc_i;
                    d.skipp = hgt_skip + wb*2 + t;
                    d.mblks = (t ? ND : NI)/128;
                    d.mode = dir ? 3 : 2;
                }
                gemm_mfma<<<dim3(NI/128 + ND/128,2),256,0,stream>>>(g3);
            }
            cur_i = nxt_i;
            cur_d = nxt_d;
        }

        // -------- SAGPooling (CSR-based, no atomics) --------
        pool_h2<<<NROW/4,256,0,stream>>>(cur_i, cur_d, pool_W, hvec);
        pool_csr<<<NROW/4,256,0,stream>>>(rowptr, einfo, hvec, pool_att, pscore);
        topk_kernel<<<BB,512,0,stream>>>(pscore, pool_bias, seln, sels);
        gather_xp<<<BB*KPOOL,256,0,stream>>>(seln, sels, cur_i, cur_d, xp, bxp_h, bxp_l);

        // -------- transformer --------
        GArgs g4; g4.nd = 3;
        for(int t=0;t<3;t++){
            GDesc& d = g4.d[t];
            d.Ah=bxp_h; d.Al=bxp_l;
            d.Bh=btw_h + (size_t)t*MAT; d.Bl=btw_l + (size_t)t*MAT;
            d.C = nullptr;
            d.Oh = (t==0)? qbh : (t==1)? kbh : vbh;
            d.Ol = (t==0)? qbl : (t==1)? kbl : vbl;
            d.X = nullptr; d.Xacc = nullptr; d.skipp = nullptr;
            d.mblks = MR/128; d.mode = 1;
        }
        gemm_mfma<<<dim3(3*(MR/128),2),256,0,stream>>>(g4);
        attn_mfma<<<dim3(KPOOL/64, BB*HH),256,0,stream>>>(qbh, qbl, kbh, kbl, vbh, bao_h, bao_l);
        GArgs g5; g5.nd = 1;
        {
            GDesc& d = g5.d[0];
            d.Ah=bao_h; d.Al=bao_l;
            d.Bh=btw_h + (size_t)3*MAT; d.Bl=btw_l + (size_t)3*MAT;
            d.C=o2; d.Oh=nullptr; d.Ol=nullptr; d.X=nullptr; d.Xacc=nullptr; d.skipp=nullptr;
            d.mblks=MR/128; d.mode=0;
        }
        gemm_mfma<<<dim3(MR/128,2),256,0,stream>>>(g5);
        ln_kernel<<<MR,256,0,stream>>>(xp, o2, ln_g, ln_b, gatt);
        feat_reduce2<<<dim3(BB,12),256,0,stream>>>(xp, gatt, bi ? vbuf : ubuf);
    }

    cosine_kernel<<<BB,64,0,stream>>>(ubuf, vbuf, out);
}

// Round 11
// 1713.445 us; speedup vs baseline: 1.1350x; 1.0511x over previous
//
#include <hip/hip_runtime.h>
#include <math.h>
#include <stdint.h>

#define LL 2
#define HH 4
#define DHH 64
#define DD 256
#define BB 8
#define NI 8192
#define ND 4096
#define NROW 12288
#define KPOOL 768
#define EC 65536
#define EI 32768
#define EO 32768
#define EK 8192
#define EHGT (EC+EI+EO+EK)

typedef unsigned short u16;
typedef short bf16x8 __attribute__((ext_vector_type(8)));
typedef float f32x4 __attribute__((ext_vector_type(4)));
typedef unsigned short u16x4 __attribute__((ext_vector_type(4)));

__device__ inline float gelu_f(float x){ return 0.5f*x*(1.f+erff(x*0.70710678118654752f)); }
__device__ inline u16 f2b(float x){ uint32_t u=__float_as_uint(x); return (u16)((u + 0x7fffu + ((u>>16)&1u))>>16); }
__device__ inline float b2f(u16 h){ return __uint_as_float(((uint32_t)h)<<16); }

// ---------------- generic fill ----------------
__global__ void fill_u32(uint32_t* p, uint32_t v, int n){
    int i = blockIdx.x*256 + threadIdx.x;
    if(i<n) p[i]=v;
}

// ---------------- activation split-convert ----------------
__global__ void cvt_split(const float* __restrict__ A, int nA, const float* __restrict__ B, int nB,
                          u16* __restrict__ oh, u16* __restrict__ ol){
    int i = (blockIdx.x*256 + threadIdx.x)*4;
    int tot = nA + nB;
    if(i >= tot) return;
    float4 v = (i < nA) ? *(const float4*)(A + i) : *(const float4*)(B + (i - nA));
    float vv[4] = {v.x, v.y, v.z, v.w};
    u16x4 h4, l4;
    #pragma unroll
    for(int j=0;j<4;j++){
        float x = vv[j];
        u16 h = f2b(x);
        h4[j] = h;
        l4[j] = f2b(x - b2f(h));
    }
    *(u16x4*)(oh + i) = h4;
    *(u16x4*)(ol + i) = l4;
}

// ---------------- weight transpose + split ----------------
struct WCArgs { const float* in[8]; u16* oh[8]; u16* ol[8]; int cnt[8]; int nr; };
__global__ void wcvt_split(WCArgs a){
    int mat = blockIdx.y, ri = 0;
    while(ri < a.nr-1 && mat >= a.cnt[ri]){ mat -= a.cnt[ri]; ri++; }
    const float* in = a.in[ri] + (size_t)mat*65536;
    u16* oh = a.oh[ri] + (size_t)mat*65536;
    u16* ol = a.ol[ri] + (size_t)mat*65536;
    int n = blockIdx.x, k = threadIdx.x;
    float x = in[(size_t)k*DD + n];
    u16 h = f2b(x);
    oh[n*DD + k] = h;
    ol[n*DD + k] = f2b(x - b2f(h));
}

// ---------------- MFMA batched GEMM with fused epilogues ----------------
// LDS: paired hi/lo buffers, [128 rows][128 bytes], XOR-swizzle byte ^= (row&7)<<4.
// Register prefetch pipeline: next K-tile's loads issue before the MFMA block.
// mode 0: C=f32   mode 1: Oh/Ol=split bf16
// mode 2: Xacc = 0.5*(g*acc + (1-g)*X)
// mode 3: v=relu(Xacc + 0.5*(g*acc+(1-g)*X)); C=v; Oh/Ol=split(v)
struct GDesc { const u16* Ah; const u16* Al; const u16* Bh; const u16* Bl;
               float* C; u16* Oh; u16* Ol;
               const float* X; float* Xacc; const float* skipp;
               int mblks; int mode; };
struct GArgs { GDesc d[10]; int nd; };

__global__ __launch_bounds__(256) void gemm_mfma(GArgs ga){
    __shared__ u16 AS[128*64], BS[128*64];
    char* Abuf = (char*)AS; char* Bbuf = (char*)BS;
    int mb = blockIdx.x, di = 0;
    while(di < ga.nd-1 && mb >= ga.d[di].mblks){ mb -= ga.d[di].mblks; di++; }
    GDesc g = ga.d[di];
    const int m0 = mb*128, n0 = blockIdx.y*128;
    const int tid = threadIdx.x;
    const int lane = tid & 63, wid = tid >> 6;
    const int wm = (wid>>1)*64, wn = (wid&1)*64;
    const int l15 = lane & 15, l4 = lane >> 4;
    const int srow = tid >> 1, hf = tid & 1;
    const int ssw = (srow&7)<<4;
    const int c0 = (hf*32) ^ ssw;
    const int c1 = (hf*32+16) ^ ssw;
    const int c2 = (64+hf*32) ^ ssw;
    const int c3 = (64+hf*32+16) ^ ssw;
    const int rbyte = srow*128;
    const u16* __restrict__ Aph = g.Ah + (size_t)(m0 + srow)*DD + hf*16;
    const u16* __restrict__ Apl = g.Al + (size_t)(m0 + srow)*DD + hf*16;
    const u16* __restrict__ Bph = g.Bh + (size_t)(n0 + srow)*DD + hf*16;
    const u16* __restrict__ Bpl = g.Bl + (size_t)(n0 + srow)*DD + hf*16;
    f32x4 acc[4][4] = {};
    bf16x8 r0 = *(const bf16x8*)(Aph);
    bf16x8 r1 = *(const bf16x8*)(Aph + 8);
    bf16x8 r2 = *(const bf16x8*)(Apl);
    bf16x8 r3 = *(const bf16x8*)(Apl + 8);
    bf16x8 r4 = *(const bf16x8*)(Bph);
    bf16x8 r5 = *(const bf16x8*)(Bph + 8);
    bf16x8 r6 = *(const bf16x8*)(Bpl);
    bf16x8 r7 = *(const bf16x8*)(Bpl + 8);
    #pragma unroll
    for(int k0=0;k0<DD;k0+=32){
        __syncthreads();
        *(bf16x8*)(Abuf + rbyte + c0) = r0; *(bf16x8*)(Abuf + rbyte + c1) = r1;
        *(bf16x8*)(Abuf + rbyte + c2) = r2; *(bf16x8*)(Abuf + rbyte + c3) = r3;
        *(bf16x8*)(Bbuf + rbyte + c0) = r4; *(bf16x8*)(Bbuf + rbyte + c1) = r5;
        *(bf16x8*)(Bbuf + rbyte + c2) = r6; *(bf16x8*)(Bbuf + rbyte + c3) = r7;
        __syncthreads();
        if(k0 + 32 < DD){
            int kn = k0 + 32;
            r0 = *(const bf16x8*)(Aph + kn);     r1 = *(const bf16x8*)(Aph + kn + 8);
            r2 = *(const bf16x8*)(Apl + kn);     r3 = *(const bf16x8*)(Apl + kn + 8);
            r4 = *(const bf16x8*)(Bph + kn);     r5 = *(const bf16x8*)(Bph + kn + 8);
            r6 = *(const bf16x8*)(Bpl + kn);     r7 = *(const bf16x8*)(Bpl + kn + 8);
        }
        bf16x8 afh[4], afl[4], bfh[4], bfl[4];
        #pragma unroll
        for(int i=0;i<4;i++){
            int ar = wm + i*16 + l15;
            int swa = (ar&7)<<4;
            int abase = ar*128;
            afh[i] = *(const bf16x8*)(Abuf + abase + ((l4*16) ^ swa));
            afl[i] = *(const bf16x8*)(Abuf + abase + ((64 + l4*16) ^ swa));
            int br = wn + i*16 + l15;
            int swb = (br&7)<<4;
            int bbase = br*128;
            bfh[i] = *(const bf16x8*)(Bbuf + bbase + ((l4*16) ^ swb));
            bfl[i] = *(const bf16x8*)(Bbuf + bbase + ((64 + l4*16) ^ swb));
        }
        #pragma unroll
        for(int i=0;i<4;i++)
            #pragma unroll
            for(int j=0;j<4;j++){
                acc[i][j] = __builtin_amdgcn_mfma_f32_16x16x32_bf16(afh[i], bfh[j], acc[i][j], 0,0,0);
                acc[i][j] = __builtin_amdgcn_mfma_f32_16x16x32_bf16(afh[i], bfl[j], acc[i][j], 0,0,0);
                acc[i][j] = __builtin_amdgcn_mfma_f32_16x16x32_bf16(afl[i], bfh[j], acc[i][j], 0,0,0);
            }
    }
    const int mode = g.mode;
    float gg = 0.f;
    if(mode >= 2) gg = 1.f/(1.f + expf(-*g.skipp));
    #pragma unroll
    for(int i=0;i<4;i++){
        #pragma unroll
        for(int j=0;j<4;j++){
            int ccol = n0 + wn + j*16 + l15;
            #pragma unroll
            for(int r=0;r<4;r++){
                int row = m0 + wm + i*16 + l4*4 + r;
                size_t o = (size_t)row*DD + ccol;
                float val = acc[i][j][r];
                if(mode==0){
                    g.C[o] = val;
                } else if(mode==1){
                    u16 hh = f2b(val); g.Oh[o]=hh; g.Ol[o]=f2b(val-b2f(hh));
                } else {
                    float v2 = gg*val + (1.f-gg)*g.X[o];
                    if(mode==2){
                        g.Xacc[o] = 0.5f*v2;
                    } else {
                        float v3 = g.Xacc[o] + 0.5f*v2;
                        v3 = v3 > 0.f ? v3 : 0.f;
                        g.C[o] = v3;
                        u16 hh = f2b(v3); g.Oh[o]=hh; g.Ol[o]=f2b(v3-b2f(hh));
                    }
                }
            }
        }
    }
}

// ---------- combine ----------
__global__ void combine_all(const float* __restrict__ Wk, const float* __restrict__ Wv,
                            const float* __restrict__ Ra, const float* __restrict__ Rm,
                            float* __restrict__ wtk, float* __restrict__ wtv){
    const int st_tab[2][4] = {{0,1,0,0},{0,0,1,0}};
    int combo = blockIdx.y;
    int idx = combo >> 1, kv = combo & 1;
    int r = idx & 3, wb = idx >> 2, dir = wb & 1;
    int st = st_tab[dir][r];
    const float* W = (kv ? Wv : Wk) + (size_t)(wb*2 + st)*65536;
    const float* R = (kv ? Rm : Ra) + (size_t)idx*16384;
    float* o = (kv ? wtv : wtk) + (size_t)idx*65536;
    int d = blockIdx.x, c = threadIdx.x;
    int h = c >> 6, f = c & 63;
    const float* Wrow = W + d*DD + h*64;
    const float* Rh = R + h*4096 + f;
    float s = 0.f;
    #pragma unroll 8
    for(int k=0;k<64;k++) s += Wrow[k]*Rh[k*64];
    o[d*DD + c] = s;
}

// ---------------- CSR build (both directions in one pass) ----------------
// einfo packing: low16 = r*NI+src (VM row index), high16 = homogeneous node id of src
__device__ inline void edge_decode(int e, int& r, int& el){
    if(e < EC){ r=0; el=e; }
    else if(e < EC+EI){ r=1; el=e-EC; }
    else if(e < EC+EI+EO){ r=2; el=e-(EC+EI); }
    else { r=3; el=e-(EC+EI+EO); }
}

struct CB2 {
    const int* row[8]; const int* col[8];
    int dt[8]; int st[8];
    uint32_t* cnt; uint32_t* rowptr; uint32_t* einfo; uint32_t* slot;
};

__global__ void csr_hist2(CB2 a){
    int ge = blockIdx.x*256 + threadIdx.x;
    if(ge >= 2*EHGT) return;
    int dir = ge >= EHGT;
    int e = ge - dir*EHGT;
    int r, el; edge_decode(e, r, el);
    int idx = dir*4 + r;
    int c = a.col[idx][el];
    int dst = dir*NROW + (a.dt[idx] ? (NI + c) : c);
    atomicAdd(&a.cnt[dst], 1u);
}

__global__ __launch_bounds__(1024) void scan_rowptr2(uint32_t* cnt, uint32_t* rowptr){
    __shared__ uint32_t part[1024];
    int t = threadIdx.x;
    int base = t*24;
    uint32_t lpre[24];
    uint32_t sum = 0;
    #pragma unroll
    for(int i=0;i<24;i++){
        uint32_t c = cnt[base+i];
        lpre[i] = sum; sum += c;
        cnt[base+i] = 0;
    }
    part[t] = sum;
    __syncthreads();
    for(int offs=1; offs<1024; offs<<=1){
        uint32_t v = (t>=offs) ? part[t-offs] : 0u;
        __syncthreads();
        part[t] += v;
        __syncthreads();
    }
    uint32_t pre = (t==0) ? 0u : part[t-1];
    #pragma unroll
    for(int i=0;i<24;i++) rowptr[base+i] = pre + lpre[i];
    if(t==1023) rowptr[2*NROW] = part[1023];
}

__global__ void csr_scatter2(CB2 a){
    int ge = blockIdx.x*256 + threadIdx.x;
    if(ge >= 2*EHGT) return;
    int dir = ge >= EHGT;
    int e = ge - dir*EHGT;
    int r, el; edge_decode(e, r, el);
    int idx = dir*4 + r;
    int c = a.col[idx][el];
    int dst = dir*NROW + (a.dt[idx] ? (NI + c) : c);
    int src = a.row[idx][el];
    uint32_t p = a.rowptr[dst] + atomicAdd(&a.cnt[dst], 1u);
    uint32_t vmidx = (uint32_t)(r*NI + src);
    uint32_t hom = a.st[idx] ? (uint32_t)(NI + src) : (uint32_t)src;
    a.einfo[p] = vmidx | (hom << 16);
    a.slot[ge] = p;
}

// ---------------- HGT edge scores: wave per edge ----------------
struct P1Args {
    const int* row[4]; const int* col[4];
    const float* Q[2];
    const float* ka;
    const float* prel;
    const uint32_t* slot;
    float* sc;
    int dt[4];
};

__global__ __launch_bounds__(256) void hgt_pass1(P1Args a){
    int w = blockIdx.x*4 + (threadIdx.x >> 6);
    int lane = threadIdx.x & 63;
    if(w >= EHGT) return;
    int r, el; edge_decode(w, r, el);
    int dt = a.dt[r];
    int rn = a.row[r][el], cn = a.col[r][el];
    float4 qv = *(const float4*)(a.Q[dt] + (size_t)cn*DD + lane*4);
    float4 kv = *(const float4*)(a.ka + (size_t)r*NI*DD + (size_t)rn*DD + lane*4);
    float d = qv.x*kv.x + qv.y*kv.y + qv.z*kv.z + qv.w*kv.w;
    d += __shfl_xor(d, 1); d += __shfl_xor(d, 2);
    d += __shfl_xor(d, 4); d += __shfl_xor(d, 8);
    if((lane & 15) == 0){
        int h = lane >> 4;
        a.sc[(size_t)a.slot[w]*HH + h] = d * a.prel[r*HH + h] * 0.125f;
    }
}

// one wave per (dst,h): lane-parallel softmax stats + LDS alpha + fma-only gather
__global__ __launch_bounds__(256) void hgt_rowpass(const uint32_t* __restrict__ rowptr,
                                                   const uint32_t* __restrict__ einfo,
                                                   const float* __restrict__ sc,
                                                   const float* __restrict__ vmb,
                                                   u16* __restrict__ bagg_h,
                                                   u16* __restrict__ bagg_l){
    __shared__ float alds[4][256];
    int wv = threadIdx.x >> 6, lane = threadIdx.x & 63;
    int w = blockIdx.x*4 + wv;
    int rowi = w >> 2, h = w & 3;
    uint32_t p0 = rowptr[rowi], p1 = rowptr[rowi+1];
    size_t obase = (size_t)rowi*DD + h*64 + lane;
    float o = 0.f;
    if(p0 != p1){
        float m = -INFINITY;
        for(uint32_t p = p0+lane; p < p1; p += 64) m = fmaxf(m, sc[(size_t)p*HH + h]);
        #pragma unroll
        for(int s=32;s;s>>=1) m = fmaxf(m, __shfl_xor(m, s));
        float den = 0.f;
        for(uint32_t p = p0+lane; p < p1; p += 64) den += expf(sc[(size_t)p*HH + h] - m);
        #pragma unroll
        for(int s=32;s;s>>=1) den += __shfl_xor(den, s);
        float inv = 1.f/(den + 1e-16f);
        const float* vmh = vmb + h*64 + lane;
        for(uint32_t t0 = p0; t0 < p1; t0 += 256){
            uint32_t cnt = p1 - t0; if(cnt > 256u) cnt = 256u;
            for(uint32_t j = lane; j < cnt; j += 64)
                alds[wv][j] = expf(sc[(size_t)(t0+j)*HH + h] - m) * inv;
            uint32_t j = 0;
            for(; j + 2 <= cnt; j += 2){
                uint32_t e0 = einfo[t0+j], e1 = einfo[t0+j+1];
                float a0 = alds[wv][j], a1 = alds[wv][j+1];
                float v0 = vmh[(size_t)(e0 & 0xffffu)*DD];
                float v1 = vmh[(size_t)(e1 & 0xffffu)*DD];
                o += a0*v0 + a1*v1;
            }
            if(j < cnt){
                uint32_t e0 = einfo[t0+j];
                o += alds[wv][j] * vmh[(size_t)(e0 & 0xffffu)*DD];
            }
        }
    }
    float g = gelu_f(o);
    u16 hh = f2b(g);
    bagg_h[obase] = hh;
    bagg_l[obase] = f2b(g - b2f(hh));
}

// ---------------- pooling ----------------
__global__ void pool_h2(const float* __restrict__ xi, const float* __restrict__ xd,
                        const float* __restrict__ w, float* __restrict__ h){
    int node = blockIdx.x*4 + (threadIdx.x>>6);
    int lane = threadIdx.x & 63;
    const float* xr = (node < NI) ? (xi + (size_t)node*DD) : (xd + (size_t)(node-NI)*DD);
    float s = 0.f;
    for(int j=lane;j<DD;j+=64) s += xr[j]*w[j];
    for(int m=32;m;m>>=1) s += __shfl_xor(s, m);
    if(lane==0) h[node] = s;
}

// GAT-style pooling score via fwd CSR + implicit self-loop; wave per dst node
__global__ __launch_bounds__(256) void pool_csr(const uint32_t* __restrict__ rowptr,
                                                const uint32_t* __restrict__ einfo,
                                                const float* __restrict__ h,
                                                const float* __restrict__ att,
                                                float* __restrict__ score){
    int w = blockIdx.x*4 + (threadIdx.x >> 6);
    int lane = threadIdx.x & 63;
    if(w >= NROW) return;
    uint32_t p0 = rowptr[w], p1 = rowptr[w+1];
    float a0 = att[0], a1 = att[1];
    float hn = h[w];
    float es = a0*hn + a1*hn;
    es = es >= 0.f ? es : 0.2f*es;
    float m = -INFINITY;
    for(uint32_t p = p0+lane; p < p1; p += 64){
        float hs = h[einfo[p] >> 16];
        float e = a0*hs + a1*hn;
        e = e >= 0.f ? e : 0.2f*e;
        m = fmaxf(m, e);
    }
    #pragma unroll
    for(int s=32;s;s>>=1) m = fmaxf(m, __shfl_xor(m, s));
    m = fmaxf(m, es);
    float lden = 0.f, lnum = 0.f;
    for(uint32_t p = p0+lane; p < p1; p += 64){
        float hs = h[einfo[p] >> 16];
        float e = a0*hs + a1*hn;
        e = e >= 0.f ? e : 0.2f*e;
        float a = expf(e - m);
        lden += a; lnum += a*hs;
    }
    #pragma unroll
    for(int s=32;s;s>>=1){ lden += __shfl_xor(lden, s); lnum += __shfl_xor(lnum, s); }
    float aself = expf(es - m);
    lden += aself; lnum += aself*hn;
    if(lane==0) score[w] = lnum/(lden + 1e-16f);
}

// top-768 of 1536 per graph via bitonic sort
__global__ __launch_bounds__(512) void topk_kernel(const float* __restrict__ score,
                                                   const float* __restrict__ bias,
                                                   int* __restrict__ sel_node,
                                                   float* __restrict__ sel_scale){
    __shared__ float skey[2048];
    __shared__ int   sval[2048];
    int b = blockIdx.x;
    float bv = bias[0];
    for(int p=threadIdx.x;p<2048;p+=512){
        if(p<1536){
            int node = (p<1024) ? (b*1024 + p) : (NI + b*512 + (p-1024));
            skey[p] = score[node] + bv;
            sval[p] = node;
        } else {
            skey[p] = -INFINITY;
            sval[p] = -1;
        }
    }
    for(int k=2;k<=2048;k<<=1){
        for(int j=k>>1;j>0;j>>=1){
            __syncthreads();
            for(int i=threadIdx.x;i<2048;i+=512){
                int ixj = i^j;
                if(ixj > i){
                    bool up = ((i & k) == 0);
                    float ki = skey[i], kj = skey[ixj];
                    if((ki < kj) == up){
                        skey[i]=kj; skey[ixj]=ki;
                        int t=sval[i]; sval[i]=sval[ixj]; sval[ixj]=t;
                    }
                }
            }
        }
    }
    __syncthreads();
    for(int j=threadIdx.x;j<KPOOL;j+=512){
        sel_node[b*KPOOL + j] = sval[j];
        sel_scale[b*KPOOL + j] = tanhf(skey[j]);
    }
}

__global__ void gather_xp(const int* __restrict__ sel, const float* __restrict__ scale,
                          const float* __restrict__ xi, const float* __restrict__ xd,
                          float* __restrict__ xp, u16* __restrict__ bh, u16* __restrict__ bl){
    int i = blockIdx.x*256 + threadIdx.x;
    int rowp = i >> 8, c = i & 255;
    int node = sel[rowp];
    float s = scale[rowp];
    float v = (node < NI) ? xi[(size_t)node*DD + c] : xd[(size_t)(node-NI)*DD + c];
    float x = v*s;
    xp[i] = x;
    u16 hh = f2b(x);
    bh[i] = hh;
    bl[i] = f2b(x - b2f(hh));
}

// ---------------- MFMA flash attention: block per (b,h,64 q rows), pre-split inputs ----------------
__global__ __launch_bounds__(256) void attn_mfma(const u16* __restrict__ Qh, const u16* __restrict__ Ql,
                                                 const u16* __restrict__ Kh, const u16* __restrict__ Kl,
                                                 const u16* __restrict__ Vh,
                                                 u16* __restrict__ aoh, u16* __restrict__ aol){
    __shared__ u16 KhS[64*64], KlS[64*64], VtS[64*64];
    char* KhB = (char*)KhS; char* KlB = (char*)KlS; char* VtB = (char*)VtS;
    int bh = blockIdx.y;
    int b = bh >> 2, h = bh & 3;
    int q0 = blockIdx.x * 64;
    int tid = threadIdx.x;
    int lane = tid & 63;
    int w = tid >> 6;
    int l15 = lane & 15, l4 = lane >> 4;
    size_t qrow = (size_t)(b*KPOOL + q0 + w*16 + l15);
    bf16x8 qh[2], ql[2];
    #pragma unroll
    for(int c=0;c<2;c++){
        qh[c] = *(const bf16x8*)(Qh + qrow*DD + h*64 + c*32 + l4*8);
        ql[c] = *(const bf16x8*)(Ql + qrow*DD + h*64 + c*32 + l4*8);
    }
    float mreg = -INFINITY, lreg = 0.f;
    f32x4 O[4] = {};
    for(int k0=0;k0<KPOOL;k0+=64){
        __syncthreads();
        {   // stage K hi/lo + V^T from pre-split bf16
            int row = tid >> 2, q4 = tid & 3;
            size_t gbase = ((size_t)(b*KPOOL + k0 + row))*DD + h*64 + q4*16;
            bf16x8 k0v = *(const bf16x8*)(Kh + gbase);
            bf16x8 k1v = *(const bf16x8*)(Kh + gbase + 8);
            bf16x8 kl0 = *(const bf16x8*)(Kl + gbase);
            bf16x8 kl1 = *(const bf16x8*)(Kl + gbase + 8);
            bf16x8 v0v = *(const bf16x8*)(Vh + gbase);
            bf16x8 v1v = *(const bf16x8*)(Vh + gbase + 8);
            int sw = (row&7)<<4;
            int colb = q4*32;
            *(bf16x8*)(KhB + row*128 + (colb ^ sw))        = k0v;
            *(bf16x8*)(KhB + row*128 + ((colb+16) ^ sw))   = k1v;
            *(bf16x8*)(KlB + row*128 + (colb ^ sw))        = kl0;
            *(bf16x8*)(KlB + row*128 + ((colb+16) ^ sw))   = kl1;
            #pragma unroll
            for(int j=0;j<8;j++){
                int dh0 = q4*16 + j;
                int dh1 = q4*16 + 8 + j;
                *(u16*)(VtB + dh0*128 + ((row*2) ^ ((dh0&7)<<4))) = (u16)(short)v0v[j];
                *(u16*)(VtB + dh1*128 + ((row*2) ^ ((dh1&7)<<4))) = (u16)(short)v1v[j];
            }
        }
        __syncthreads();
        // S^T tiles: mfma(A=K, B=Q)
        f32x4 s[4] = {};
        #pragma unroll
        for(int t=0;t<4;t++){
            int arow = t*16 + l15;
            int sw = (arow&7)<<4;
            const char* bh_ = KhB + arow*128;
            const char* bl_ = KlB + arow*128;
            bf16x8 kh0 = *(const bf16x8*)(bh_ + ((l4*16) ^ sw));
            bf16x8 kh1 = *(const bf16x8*)(bh_ + ((l4*16 + 64) ^ sw));
            bf16x8 kl0 = *(const bf16x8*)(bl_ + ((l4*16) ^ sw));
            bf16x8 kl1 = *(const bf16x8*)(bl_ + ((l4*16 + 64) ^ sw));
            s[t] = __builtin_amdgcn_mfma_f32_16x16x32_bf16(kh0, qh[0], s[t], 0,0,0);
            s[t] = __builtin_amdgcn_mfma_f32_16x16x32_bf16(kh1, qh[1], s[t], 0,0,0);
            s[t] = __builtin_amdgcn_mfma_f32_16x16x32_bf16(kh0, ql[0], s[t], 0,0,0);
            s[t] = __builtin_amdgcn_mfma_f32_16x16x32_bf16(kh1, ql[1], s[t], 0,0,0);
            s[t] = __builtin_amdgcn_mfma_f32_16x16x32_bf16(kl0, qh[0], s[t], 0,0,0);
            s[t] = __builtin_amdgcn_mfma_f32_16x16x32_bf16(kl1, qh[1], s[t], 0,0,0);
        }
        // online softmax
        float cm = -INFINITY;
        #pragma unroll
        for(int t=0;t<4;t++)
            #pragma unroll
            for(int r=0;r<4;r++){ s[t][r] *= 0.125f; cm = fmaxf(cm, s[t][r]); }
        cm = fmaxf(cm, __shfl_xor(cm,16));
        cm = fmaxf(cm, __shfl_xor(cm,32));
        float nm = fmaxf(mreg, cm);
        float es = expf(mreg - nm);
        float ps = 0.f;
        #pragma unroll
        for(int t=0;t<4;t++)
            #pragma unroll
            for(int r=0;r<4;r++){ float pv = expf(s[t][r] - nm); s[t][r] = pv; ps += pv; }
        ps += __shfl_xor(ps,16);
        ps += __shfl_xor(ps,32);
        lreg = lreg*es + ps;
        mreg = nm;
        #pragma unroll
        for(int d=0;d<4;d++){ O[d][0]*=es; O[d][1]*=es; O[d][2]*=es; O[d][3]*=es; }
        // O^T += mfma(A=V^T, B=P^T)
        #pragma unroll
        for(int c32=0;c32<2;c32++){
            bf16x8 pb;
            #pragma unroll
            for(int j=0;j<8;j++){
                int srcl = ((((lane>>4)*2 + (j>>2)) & 3) << 4) | l15;
                float v0 = __shfl(s[c32*2+0][j&3], srcl, 64);
                float v1 = __shfl(s[c32*2+1][j&3], srcl, 64);
                float v = (lane < 32) ? v0 : v1;
                pb[j] = (short)f2b(v);
            }
            #pragma unroll
            for(int dhb=0; dhb<4; dhb++){
                int vrow = dhb*16 + l15;
                bf16x8 va = *(const bf16x8*)(VtB + vrow*128 + ((c32*64 + l4*16) ^ ((vrow&7)<<4)));
                O[dhb] = __builtin_amdgcn_mfma_f32_16x16x32_bf16(va, pb, O[dhb], 0,0,0);
            }
        }
    }
    float inv = 1.f/lreg;
    #pragma unroll
    for(int dhb=0;dhb<4;dhb++)
        #pragma unroll
        for(int r=0;r<4;r++){
            float val = O[dhb][r]*inv;
            size_t o = qrow*DD + h*64 + dhb*16 + l4*4 + r;
            u16 hh = f2b(val);
            aoh[o] = hh;
            aol[o] = f2b(val - b2f(hh));
        }
}

// layernorm row kernel
__global__ __launch_bounds__(256) void ln_kernel(const float* __restrict__ xp, const float* __restrict__ o2,
                                                 const float* __restrict__ lg, const float* __restrict__ lb,
                                                 float* __restrict__ gatt){
    __shared__ float red[256];
    int r = blockIdx.x, c = threadIdx.x;
    float y = xp[(size_t)r*DD + c] + o2[(size_t)r*DD + c];
    red[c] = y; __syncthreads();
    for(int s=128;s;s>>=1){ if(c<s) red[c] += red[c+s]; __syncthreads(); }
    float mu = red[0]*(1.f/DD);
    __syncthreads();
    float d = y - mu;
    red[c] = d*d; __syncthreads();
    for(int s=128;s;s>>=1){ if(c<s) red[c] += red[c+s]; __syncthreads(); }
    float var = red[0]*(1.f/DD);
    gatt[(size_t)r*DD + c] = lg[c]*d/sqrtf(var+1e-5f) + lb[c];
}

__global__ void feat_reduce2(const float* __restrict__ xp, const float* __restrict__ gatt,
                             float* __restrict__ out){
    int b = blockIdx.x, c = threadIdx.x;
    int j0 = blockIdx.y*64;
    float s1=0.f, s2=0.f;
    for(int j=j0;j<j0+64;j++){
        size_t base = ((size_t)(b*KPOOL + j))*DD + c;
        s1 += xp[base];
        s2 += gatt[base];
    }
    atomicAdd(&out[b*512 + c], s1);
    atomicAdd(&out[b*512 + 256 + c], s2);
}

__global__ void cosine_kernel(const float* __restrict__ u, const float* __restrict__ v,
                              float* __restrict__ out){
    int b = blockIdx.x, t = threadIdx.x;
    float du=0.f, nu=0.f, nv=0.f;
    for(int j=t;j<512;j+=64){
        float a = u[b*512+j], bb = v[b*512+j];
        du += a*bb; nu += a*a; nv += bb*bb;
    }
    for(int m=32;m;m>>=1){
        du += __shfl_xor(du,m); nu += __shfl_xor(nu,m); nv += __shfl_xor(nv,m);
    }
    if(t==0) out[b] = du / (fmaxf(sqrtf(nu),1e-8f)*fmaxf(sqrtf(nv),1e-8f));
}

// =======================================================================
extern "C" void kernel_launch(void* const* d_in, const int* in_sizes, int n_in,
                              void* d_out, int out_size, void* d_ws, size_t ws_size,
                              hipStream_t stream){
    (void)in_sizes; (void)n_in; (void)out_size; (void)ws_size;
    const float* hgt_Wk   = (const float*)d_in[12];
    const float* hgt_Wq   = (const float*)d_in[13];
    const float* hgt_Wv   = (const float*)d_in[14];
    const float* hgt_Wo   = (const float*)d_in[15];
    const float* hgt_arel = (const float*)d_in[16];
    const float* hgt_mrel = (const float*)d_in[17];
    const float* hgt_prel = (const float*)d_in[18];
    const float* hgt_skip = (const float*)d_in[19];
    const float* pool_W   = (const float*)d_in[20];
    const float* pool_att = (const float*)d_in[21];
    const float* pool_bias= (const float*)d_in[22];
    const float* t_wq     = (const float*)d_in[23];
    const float* t_wk     = (const float*)d_in[24];
    const float* t_wv     = (const float*)d_in[25];
    const float* t_wo     = (const float*)d_in[26];
    const float* ln_g     = (const float*)d_in[27];
    const float* ln_b     = (const float*)d_in[28];
    float* out = (float*)d_out;

    char* base = (char*)d_ws;
    size_t off = 0;
    auto allocb = [&](size_t nbytes)->void*{
        void* p = (void*)(base + off);
        off += ((nbytes + 255) & ~(size_t)255);
        return p;
    };
    const size_t MAT = 65536;
    // ---- persistent ----
    u16* bwtk_h = (u16*)allocb(16*MAT*2); u16* bwtk_l = (u16*)allocb(16*MAT*2);
    u16* bwtv_h = (u16*)allocb(16*MAT*2); u16* bwtv_l = (u16*)allocb(16*MAT*2);
    u16* bwq_h  = (u16*)allocb(8*MAT*2);  u16* bwq_l  = (u16*)allocb(8*MAT*2);
    u16* bwo_h  = (u16*)allocb(8*MAT*2);  u16* bwo_l  = (u16*)allocb(8*MAT*2);
    u16* btw_h  = (u16*)allocb(4*MAT*2);  u16* btw_l  = (u16*)allocb(4*MAT*2);
    float* ubuf = (float*)allocb(BB*512*4);
    float* vbuf = (float*)allocb(BB*512*4);
    float* xa_i = (float*)allocb((size_t)NI*DD*4);
    float* xa_d = (float*)allocb((size_t)ND*DD*4);
    float* xb_i = (float*)allocb((size_t)NI*DD*4);
    float* xb_d = (float*)allocb((size_t)ND*DD*4);
    // ---- per-branch CSR (lives across conv + pooling) ----
    uint32_t* ccnt   = (uint32_t*)allocb((size_t)2*NROW*4);
    uint32_t* rowptr = (uint32_t*)allocb((size_t)(2*NROW+1)*4);
    uint32_t* einfo  = (uint32_t*)allocb((size_t)2*EHGT*4);
    uint32_t* slot   = (uint32_t*)allocb((size_t)2*EHGT*4);
    size_t region = off;
    // ---- conv scratch ----
    float* q_i  = (float*)allocb((size_t)NI*DD*4);
    float* q_d  = (float*)allocb((size_t)ND*DD*4);
    float* ka4  = (float*)allocb((size_t)4*NI*DD*4);
    float* vmb  = (float*)allocb((size_t)4*NI*DD*4);
    float* scb  = (float*)allocb((size_t)2*EHGT*HH*4);
    float* xacc_i= (float*)allocb((size_t)NI*DD*4);
    float* xacc_d= (float*)allocb((size_t)ND*DD*4);
    u16* bcur_h = (u16*)allocb((size_t)NROW*DD*2);
    u16* bcur_l = (u16*)allocb((size_t)NROW*DD*2);
    u16* bagg_h = (u16*)allocb((size_t)NROW*DD*2);
    u16* bagg_l = (u16*)allocb((size_t)NROW*DD*2);
    // ---- pooling/transformer overlay ----
    off = region;
    float* hvec = (float*)allocb(NROW*4);
    float* pscore = (float*)allocb(NROW*4);
    int* seln   = (int*)allocb(BB*KPOOL*4);
    float* sels = (float*)allocb(BB*KPOOL*4);
    float* xp   = (float*)allocb((size_t)BB*KPOOL*DD*4);
    float* o2   = (float*)allocb((size_t)BB*KPOOL*DD*4);
    float* gatt = (float*)allocb((size_t)BB*KPOOL*DD*4);
    u16* bxp_h = (u16*)allocb((size_t)BB*KPOOL*DD*2);
    u16* bxp_l = (u16*)allocb((size_t)BB*KPOOL*DD*2);
    u16* qbh = (u16*)allocb((size_t)BB*KPOOL*DD*2);
    u16* qbl = (u16*)allocb((size_t)BB*KPOOL*DD*2);
    u16* kbh = (u16*)allocb((size_t)BB*KPOOL*DD*2);
    u16* kbl = (u16*)allocb((size_t)BB*KPOOL*DD*2);
    u16* vbh = (u16*)allocb((size_t)BB*KPOOL*DD*2);
    u16* vbl = (u16*)allocb((size_t)BB*KPOOL*DD*2);
    u16* bao_h = (u16*)allocb((size_t)BB*KPOOL*DD*2);
    u16* bao_l = (u16*)allocb((size_t)BB*KPOOL*DD*2);

    const int st_tab[2][4] = {{0,1,0,0},{0,0,1,0}};
    const int dt_tab[2][4] = {{0,0,1,0},{0,1,0,0}};
    const int MR = BB*KPOOL;

    fill_u32<<<(2*BB*512+255)/256,256,0,stream>>>((uint32_t*)ubuf, 0u, 2*BB*512);
    float* wtkF = ka4;
    float* wtvF = ka4 + 16*MAT;
    combine_all<<<dim3(256,32),256,0,stream>>>(hgt_Wk, hgt_Wv, hgt_arel, hgt_mrel, wtkF, wtvF);
    WCArgs wc;
    wc.in[0]=wtkF;   wc.oh[0]=bwtk_h; wc.ol[0]=bwtk_l; wc.cnt[0]=16;
    wc.in[1]=wtvF;   wc.oh[1]=bwtv_h; wc.ol[1]=bwtv_l; wc.cnt[1]=16;
    wc.in[2]=hgt_Wq; wc.oh[2]=bwq_h;  wc.ol[2]=bwq_l;  wc.cnt[2]=8;
    wc.in[3]=hgt_Wo; wc.oh[3]=bwo_h;  wc.ol[3]=bwo_l;  wc.cnt[3]=8;
    wc.in[4]=t_wq;   wc.oh[4]=btw_h;          wc.ol[4]=btw_l;          wc.cnt[4]=1;
    wc.in[5]=t_wk;   wc.oh[5]=btw_h+1*MAT;    wc.ol[5]=btw_l+1*MAT;    wc.cnt[5]=1;
    wc.in[6]=t_wv;   wc.oh[6]=btw_h+2*MAT;    wc.ol[6]=btw_l+2*MAT;    wc.cnt[6]=1;
    wc.in[7]=t_wo;   wc.oh[7]=btw_h+3*MAT;    wc.ol[7]=btw_l+3*MAT;    wc.cnt[7]=1;
    wc.nr = 8;
    wcvt_split<<<dim3(256,52),256,0,stream>>>(wc);

    for(int bi=0;bi<2;bi++){
        int ib = bi*6;
        const float* x_inst = (const float*)d_in[ib+0];
        const float* x_data = (const float*)d_in[ib+1];
        const int* ecp = (const int*)d_in[ib+2];
        const int* eip = (const int*)d_in[ib+3];
        const int* eop = (const int*)d_in[ib+4];
        const int* ekp = (const int*)d_in[ib+5];
        const int* rows_f[4] = {ecp, eip, eop, ekp};
        const int* cols_f[4] = {ecp+EC, eip+EI, eop+EO, ekp+EK};

        // ---- CSR build (both dirs, one pass) ----
        CB2 cb;
        for(int r=0;r<4;r++){
            cb.row[r]   = rows_f[r]; cb.col[r]   = cols_f[r]; cb.dt[r]   = dt_tab[0][r]; cb.st[r]   = st_tab[0][r];
            cb.row[4+r] = cols_f[r]; cb.col[4+r] = rows_f[r]; cb.dt[4+r] = dt_tab[1][r]; cb.st[4+r] = st_tab[1][r];
        }
        cb.cnt = ccnt; cb.rowptr = rowptr; cb.einfo = einfo; cb.slot = slot;
        fill_u32<<<(2*NROW+255)/256,256,0,stream>>>(ccnt, 0u, 2*NROW);
        csr_hist2<<<(2*EHGT+255)/256,256,0,stream>>>(cb);
        scan_rowptr2<<<1,1024,0,stream>>>(ccnt, rowptr);
        csr_scatter2<<<(2*EHGT+255)/256,256,0,stream>>>(cb);

        const float* cur_i = x_inst;
        const float* cur_d = x_data;
        cvt_split<<<((NROW*DD/4)+255)/256,256,0,stream>>>(cur_i, NI*DD, cur_d, ND*DD, bcur_h, bcur_l);
        for(int l=0;l<LL;l++){
            float* nxt_i = (l==0) ? xa_i : xb_i;
            float* nxt_d = (l==0) ? xa_d : xb_d;
            for(int dir=0;dir<2;dir++){
                int wb = l*2 + dir;
                const int* rows[4]; const int* cols[4];
                for(int r=0;r<4;r++){
                    rows[r] = dir ? cols_f[r] : rows_f[r];
                    cols[r] = dir ? rows_f[r] : cols_f[r];
                }

                // --- mega GEMM: Q(2) + KA(4) + VM(4) in one launch ---
                GArgs g1; int nb1 = 0, ndx = 0;
                auto addg = [&](int srctype, const u16* Bh, const u16* Bl, float* Cm, int M){
                    GDesc& d = g1.d[ndx];
                    size_t ao = srctype ? (size_t)NI*DD : 0;
                    d.Ah = bcur_h + ao; d.Al = bcur_l + ao;
                    d.Bh = Bh; d.Bl = Bl; d.C = Cm;
                    d.Oh = nullptr; d.Ol = nullptr; d.X = nullptr; d.Xacc = nullptr; d.skipp = nullptr;
                    d.mblks = M/128; d.mode = 0;
                    nb1 += M/128; ndx++;
                };
                addg(0, bwq_h + (size_t)(wb*2+0)*MAT, bwq_l + (size_t)(wb*2+0)*MAT, q_i, NI);
                addg(1, bwq_h + (size_t)(wb*2+1)*MAT, bwq_l + (size_t)(wb*2+1)*MAT, q_d, ND);
                for(int r=0;r<4;r++){
                    int st = st_tab[dir][r];
                    addg(st, bwtk_h + (size_t)(wb*4+r)*MAT, bwtk_l + (size_t)(wb*4+r)*MAT,
                         ka4 + (size_t)r*NI*DD, st ? ND : NI);
                }
                for(int r=0;r<4;r++){
                    int st = st_tab[dir][r];
                    addg(st, bwtv_h + (size_t)(wb*4+r)*MAT, bwtv_l + (size_t)(wb*4+r)*MAT,
                         vmb + (size_t)r*NI*DD, st ? ND : NI);
                }
                g1.nd = ndx;
                gemm_mfma<<<dim3(nb1,2),256,0,stream>>>(g1);

                // --- edge scores ---
                P1Args pa;
                for(int r=0;r<4;r++){
                    pa.row[r] = rows[r]; pa.col[r] = cols[r];
                    pa.dt[r] = dt_tab[dir][r];
                }
                pa.Q[0]=q_i; pa.Q[1]=q_d;
                pa.ka = ka4;
                pa.prel = hgt_prel + (size_t)wb*4*HH;
                pa.slot = slot + (size_t)dir*EHGT;
                pa.sc = scb;
                hgt_pass1<<<EHGT/4,256,0,stream>>>(pa);

                // --- per-(dst,h) softmax (LDS alpha) + gather + gelu + split ---
                hgt_rowpass<<<NROW,256,0,stream>>>(rowptr + (size_t)dir*NROW, einfo, scb, vmb, bagg_h, bagg_l);

                // --- Wo GEMMs with fused skip/relu epilogue ---
                GArgs g3; g3.nd = 2;
                for(int t=0;t<2;t++){
                    GDesc& d = g3.d[t];
                    size_t ao = t ? (size_t)NI*DD : 0;
                    d.Ah = bagg_h + ao; d.Al = bagg_l + ao;
                    d.Bh = bwo_h + (size_t)(wb*2+t)*MAT; d.Bl = bwo_l + (size_t)(wb*2+t)*MAT;
                    d.C = t ? nxt_d : nxt_i;
                    d.Oh = bcur_h + ao; d.Ol = bcur_l + ao;
                    d.X = t ? cur_d : cur_i;
                    d.Xacc = t ? xacc_d : xacc_i;
                    d.skipp = hgt_skip + wb*2 + t;
                    d.mblks = (t ? ND : NI)/128;
                    d.mode = dir ? 3 : 2;
                }
                gemm_mfma<<<dim3(NI/128 + ND/128,2),256,0,stream>>>(g3);
            }
            cur_i = nxt_i;
            cur_d = nxt_d;
        }

        // -------- SAGPooling (CSR-based, no atomics) --------
        pool_h2<<<NROW/4,256,0,stream>>>(cur_i, cur_d, pool_W, hvec);
        pool_csr<<<NROW/4,256,0,stream>>>(rowptr, einfo, hvec, pool_att, pscore);
        topk_kernel<<<BB,512,0,stream>>>(pscore, pool_bias, seln, sels);
        gather_xp<<<BB*KPOOL,256,0,stream>>>(seln, sels, cur_i, cur_d, xp, bxp_h, bxp_l);

        // -------- transformer --------
        GArgs g4; g4.nd = 3;
        for(int t=0;t<3;t++){
            GDesc& d = g4.d[t];
            d.Ah=bxp_h; d.Al=bxp_l;
            d.Bh=btw_h + (size_t)t*MAT; d.Bl=btw_l + (size_t)t*MAT;
            d.C = nullptr;
            d.Oh = (t==0)? qbh : (t==1)? kbh : vbh;
            d.Ol = (t==0)? qbl : (t==1)? kbl : vbl;
            d.X = nullptr; d.Xacc = nullptr; d.skipp = nullptr;
            d.mblks = MR/128; d.mode = 1;
        }
        gemm_mfma<<<dim3(3*(MR/128),2),256,0,stream>>>(g4);
        attn_mfma<<<dim3(KPOOL/64, BB*HH),256,0,stream>>>(qbh, qbl, kbh, kbl, vbh, bao_h, bao_l);
        GArgs g5; g5.nd = 1;
        {
            GDesc& d = g5.d[0];
            d.Ah=bao_h; d.Al=bao_l;
            d.Bh=btw_h + (size_t)3*MAT; d.Bl=btw_l + (size_t)3*MAT;
            d.C=o2; d.Oh=nullptr; d.Ol=nullptr; d.X=nullptr; d.Xacc=nullptr; d.skipp=nullptr;
            d.mblks=MR/128; d.mode=0;
        }
        gemm_mfma<<<dim3(MR/128,2),256,0,stream>>>(g5);
        ln_kernel<<<MR,256,0,stream>>>(xp, o2, ln_g, ln_b, gatt);
        feat_reduce2<<<dim3(BB,12),256,0,stream>>>(xp, gatt, bi ? vbuf : ubuf);
    }

    cosine_kernel<<<BB,64,0,stream>>>(ubuf, vbuf, out);
}

// Round 12
// 1415.617 us; speedup vs baseline: 1.3738x; 1.2104x over previous
//
#include <hip/hip_runtime.h>
#include <math.h>
#include <stdint.h>

#define LL 2
#define HH 4
#define DHH 64
#define DD 256
#define BB 8
#define NI 8192
#define ND 4096
#define NROW 12288
#define KPOOL 768
#define EC 65536
#define EI 32768
#define EO 32768
#define EK 8192
#define EHGT (EC+EI+EO+EK)

typedef unsigned short u16;
typedef short bf16x8 __attribute__((ext_vector_type(8)));
typedef float f32x4 __attribute__((ext_vector_type(4)));
typedef unsigned short u16x4 __attribute__((ext_vector_type(4)));

__device__ inline float gelu_f(float x){ return 0.5f*x*(1.f+erff(x*0.70710678118654752f)); }
__device__ inline u16 f2b(float x){ uint32_t u=__float_as_uint(x); return (u16)((u + 0x7fffu + ((u>>16)&1u))>>16); }
__device__ inline float b2f(u16 h){ return __uint_as_float(((uint32_t)h)<<16); }

// ---------------- generic fill ----------------
__global__ void fill_u32(uint32_t* p, uint32_t v, int n){
    int i = blockIdx.x*256 + threadIdx.x;
    if(i<n) p[i]=v;
}

// ---------------- activation split-convert ----------------
__global__ void cvt_split(const float* __restrict__ A, int nA, const float* __restrict__ B, int nB,
                          u16* __restrict__ oh, u16* __restrict__ ol){
    int i = (blockIdx.x*256 + threadIdx.x)*4;
    int tot = nA + nB;
    if(i >= tot) return;
    float4 v = (i < nA) ? *(const float4*)(A + i) : *(const float4*)(B + (i - nA));
    float vv[4] = {v.x, v.y, v.z, v.w};
    u16x4 h4, l4;
    #pragma unroll
    for(int j=0;j<4;j++){
        float x = vv[j];
        u16 h = f2b(x);
        h4[j] = h;
        l4[j] = f2b(x - b2f(h));
    }
    *(u16x4*)(oh + i) = h4;
    *(u16x4*)(ol + i) = l4;
}

// ---------------- weight transpose + split ----------------
struct WCArgs { const float* in[8]; u16* oh[8]; u16* ol[8]; int cnt[8]; int nr; };
__global__ void wcvt_split(WCArgs a){
    int mat = blockIdx.y, ri = 0;
    while(ri < a.nr-1 && mat >= a.cnt[ri]){ mat -= a.cnt[ri]; ri++; }
    const float* in = a.in[ri] + (size_t)mat*65536;
    u16* oh = a.oh[ri] + (size_t)mat*65536;
    u16* ol = a.ol[ri] + (size_t)mat*65536;
    int n = blockIdx.x, k = threadIdx.x;
    float x = in[(size_t)k*DD + n];
    u16 h = f2b(x);
    oh[n*DD + k] = h;
    ol[n*DD + k] = f2b(x - b2f(h));
}

// ---------------- MFMA batched GEMM with fused epilogues ----------------
struct GDesc { const u16* Ah; const u16* Al; const u16* Bh; const u16* Bl;
               float* C; u16* Oh; u16* Ol;
               const float* X; float* Xacc; const float* skipp;
               int mblks; int mode; };
struct GArgs { GDesc d[10]; int nd; };

__global__ __launch_bounds__(256) void gemm_mfma(GArgs ga){
    __shared__ u16 AS[128*64], BS[128*64];
    char* Abuf = (char*)AS; char* Bbuf = (char*)BS;
    int mb = blockIdx.x, di = 0;
    while(di < ga.nd-1 && mb >= ga.d[di].mblks){ mb -= ga.d[di].mblks; di++; }
    GDesc g = ga.d[di];
    const int m0 = mb*128, n0 = blockIdx.y*128;
    const int tid = threadIdx.x;
    const int lane = tid & 63, wid = tid >> 6;
    const int wm = (wid>>1)*64, wn = (wid&1)*64;
    const int l15 = lane & 15, l4 = lane >> 4;
    const int srow = tid >> 1, hf = tid & 1;
    const int ssw = (srow&7)<<4;
    const int c0 = (hf*32) ^ ssw;
    const int c1 = (hf*32+16) ^ ssw;
    const int c2 = (64+hf*32) ^ ssw;
    const int c3 = (64+hf*32+16) ^ ssw;
    const int rbyte = srow*128;
    const u16* __restrict__ Aph = g.Ah + (size_t)(m0 + srow)*DD + hf*16;
    const u16* __restrict__ Apl = g.Al + (size_t)(m0 + srow)*DD + hf*16;
    const u16* __restrict__ Bph = g.Bh + (size_t)(n0 + srow)*DD + hf*16;
    const u16* __restrict__ Bpl = g.Bl + (size_t)(n0 + srow)*DD + hf*16;
    f32x4 acc[4][4] = {};
    bf16x8 r0 = *(const bf16x8*)(Aph);
    bf16x8 r1 = *(const bf16x8*)(Aph + 8);
    bf16x8 r2 = *(const bf16x8*)(Apl);
    bf16x8 r3 = *(const bf16x8*)(Apl + 8);
    bf16x8 r4 = *(const bf16x8*)(Bph);
    bf16x8 r5 = *(const bf16x8*)(Bph + 8);
    bf16x8 r6 = *(const bf16x8*)(Bpl);
    bf16x8 r7 = *(const bf16x8*)(Bpl + 8);
    #pragma unroll
    for(int k0=0;k0<DD;k0+=32){
        __syncthreads();
        *(bf16x8*)(Abuf + rbyte + c0) = r0; *(bf16x8*)(Abuf + rbyte + c1) = r1;
        *(bf16x8*)(Abuf + rbyte + c2) = r2; *(bf16x8*)(Abuf + rbyte + c3) = r3;
        *(bf16x8*)(Bbuf + rbyte + c0) = r4; *(bf16x8*)(Bbuf + rbyte + c1) = r5;
        *(bf16x8*)(Bbuf + rbyte + c2) = r6; *(bf16x8*)(Bbuf + rbyte + c3) = r7;
        __syncthreads();
        if(k0 + 32 < DD){
            int kn = k0 + 32;
            r0 = *(const bf16x8*)(Aph + kn);     r1 = *(const bf16x8*)(Aph + kn + 8);
            r2 = *(const bf16x8*)(Apl + kn);     r3 = *(const bf16x8*)(Apl + kn + 8);
            r4 = *(const bf16x8*)(Bph + kn);     r5 = *(const bf16x8*)(Bph + kn + 8);
            r6 = *(const bf16x8*)(Bpl + kn);     r7 = *(const bf16x8*)(Bpl + kn + 8);
        }
        bf16x8 afh[4], afl[4], bfh[4], bfl[4];
        #pragma unroll
        for(int i=0;i<4;i++){
            int ar = wm + i*16 + l15;
            int swa = (ar&7)<<4;
            int abase = ar*128;
            afh[i] = *(const bf16x8*)(Abuf + abase + ((l4*16) ^ swa));
            afl[i] = *(const bf16x8*)(Abuf + abase + ((64 + l4*16) ^ swa));
            int br = wn + i*16 + l15;
            int swb = (br&7)<<4;
            int bbase = br*128;
            bfh[i] = *(const bf16x8*)(Bbuf + bbase + ((l4*16) ^ swb));
            bfl[i] = *(const bf16x8*)(Bbuf + bbase + ((64 + l4*16) ^ swb));
        }
        #pragma unroll
        for(int i=0;i<4;i++)
            #pragma unroll
            for(int j=0;j<4;j++){
                acc[i][j] = __builtin_amdgcn_mfma_f32_16x16x32_bf16(afh[i], bfh[j], acc[i][j], 0,0,0);
                acc[i][j] = __builtin_amdgcn_mfma_f32_16x16x32_bf16(afh[i], bfl[j], acc[i][j], 0,0,0);
                acc[i][j] = __builtin_amdgcn_mfma_f32_16x16x32_bf16(afl[i], bfh[j], acc[i][j], 0,0,0);
            }
    }
    const int mode = g.mode;
    float gg = 0.f;
    if(mode >= 2) gg = 1.f/(1.f + expf(-*g.skipp));
    #pragma unroll
    for(int i=0;i<4;i++){
        #pragma unroll
        for(int j=0;j<4;j++){
            int ccol = n0 + wn + j*16 + l15;
            #pragma unroll
            for(int r=0;r<4;r++){
                int row = m0 + wm + i*16 + l4*4 + r;
                size_t o = (size_t)row*DD + ccol;
                float val = acc[i][j][r];
                if(mode==0){
                    g.C[o] = val;
                } else if(mode==1){
                    u16 hh = f2b(val); g.Oh[o]=hh; g.Ol[o]=f2b(val-b2f(hh));
                } else {
                    float v2 = gg*val + (1.f-gg)*g.X[o];
                    if(mode==2){
                        g.Xacc[o] = 0.5f*v2;
                    } else {
                        float v3 = g.Xacc[o] + 0.5f*v2;
                        v3 = v3 > 0.f ? v3 : 0.f;
                        g.C[o] = v3;
                        u16 hh = f2b(v3); g.Oh[o]=hh; g.Ol[o]=f2b(v3-b2f(hh));
                    }
                }
            }
        }
    }
}

// ---------- combine ----------
__global__ void combine_all(const float* __restrict__ Wk, const float* __restrict__ Wv,
                            const float* __restrict__ Ra, const float* __restrict__ Rm,
                            float* __restrict__ wtk, float* __restrict__ wtv){
    const int st_tab[2][4] = {{0,1,0,0},{0,0,1,0}};
    int combo = blockIdx.y;
    int idx = combo >> 1, kv = combo & 1;
    int r = idx & 3, wb = idx >> 2, dir = wb & 1;
    int st = st_tab[dir][r];
    const float* W = (kv ? Wv : Wk) + (size_t)(wb*2 + st)*65536;
    const float* R = (kv ? Rm : Ra) + (size_t)idx*16384;
    float* o = (kv ? wtv : wtk) + (size_t)idx*65536;
    int d = blockIdx.x, c = threadIdx.x;
    int h = c >> 6, f = c & 63;
    const float* Wrow = W + d*DD + h*64;
    const float* Rh = R + h*4096 + f;
    float s = 0.f;
    #pragma unroll 8
    for(int k=0;k<64;k++) s += Wrow[k]*Rh[k*64];
    o[d*DD + c] = s;
}

// ---------------- CSR build (both directions in one pass) ----------------
// einfo packing: low16 = r*NI+src (VM/KA row index; r = vmidx>>13), high16 = hom node id of src
__device__ inline void edge_decode(int e, int& r, int& el){
    if(e < EC){ r=0; el=e; }
    else if(e < EC+EI){ r=1; el=e-EC; }
    else if(e < EC+EI+EO){ r=2; el=e-(EC+EI); }
    else { r=3; el=e-(EC+EI+EO); }
}

struct CB2 {
    const int* row[8]; const int* col[8];
    int dt[8]; int st[8];
    uint32_t* cnt; uint32_t* rowptr; uint32_t* einfo;
};

__global__ void csr_hist2(CB2 a){
    int ge = blockIdx.x*256 + threadIdx.x;
    if(ge >= 2*EHGT) return;
    int dir = ge >= EHGT;
    int e = ge - dir*EHGT;
    int r, el; edge_decode(e, r, el);
    int idx = dir*4 + r;
    int c = a.col[idx][el];
    int dst = dir*NROW + (a.dt[idx] ? (NI + c) : c);
    atomicAdd(&a.cnt[dst], 1u);
}

__global__ __launch_bounds__(1024) void scan_rowptr2(uint32_t* cnt, uint32_t* rowptr){
    __shared__ uint32_t part[1024];
    int t = threadIdx.x;
    int base = t*24;
    uint32_t lpre[24];
    uint32_t sum = 0;
    #pragma unroll
    for(int i=0;i<24;i++){
        uint32_t c = cnt[base+i];
        lpre[i] = sum; sum += c;
        cnt[base+i] = 0;
    }
    part[t] = sum;
    __syncthreads();
    for(int offs=1; offs<1024; offs<<=1){
        uint32_t v = (t>=offs) ? part[t-offs] : 0u;
        __syncthreads();
        part[t] += v;
        __syncthreads();
    }
    uint32_t pre = (t==0) ? 0u : part[t-1];
    #pragma unroll
    for(int i=0;i<24;i++) rowptr[base+i] = pre + lpre[i];
    if(t==1023) rowptr[2*NROW] = part[1023];
}

__global__ void csr_scatter2(CB2 a){
    int ge = blockIdx.x*256 + threadIdx.x;
    if(ge >= 2*EHGT) return;
    int dir = ge >= EHGT;
    int e = ge - dir*EHGT;
    int r, el; edge_decode(e, r, el);
    int idx = dir*4 + r;
    int c = a.col[idx][el];
    int dst = dir*NROW + (a.dt[idx] ? (NI + c) : c);
    int src = a.row[idx][el];
    uint32_t p = a.rowptr[dst] + atomicAdd(&a.cnt[dst], 1u);
    uint32_t vmidx = (uint32_t)(r*NI + src);
    uint32_t hom = a.st[idx] ? (uint32_t)(NI + src) : (uint32_t)src;
    a.einfo[p] = vmidx | (hom << 16);
}

// ---------------- fused HGT edge phase: wave per dst, all 4 heads, online softmax ----------------
// lane holds elements lane*4..lane*4+3 of the 256-wide row; head h = lane>>4.
// After the 16-lane shfl reduce, each lane group holds exactly its head's score.
__global__ __launch_bounds__(256) void hgt_fused(const uint32_t* __restrict__ rowptr,
                                                 const uint32_t* __restrict__ einfo,
                                                 const float* __restrict__ q_i,
                                                 const float* __restrict__ q_d,
                                                 const float* __restrict__ ka,
                                                 const float* __restrict__ vm,
                                                 const float* __restrict__ prel,
                                                 u16* __restrict__ bagg_h,
                                                 u16* __restrict__ bagg_l){
    int wv = threadIdx.x >> 6, lane = threadIdx.x & 63;
    int rowi = blockIdx.x*4 + wv;
    uint32_t p0 = rowptr[rowi], p1 = rowptr[rowi+1];
    int h = lane >> 4;
    const float* qrow = (rowi < NI) ? (q_i + (size_t)rowi*DD) : (q_d + (size_t)(rowi-NI)*DD);
    float4 q4 = *(const float4*)(qrow + lane*4);
    float pr0 = prel[0*HH+h]*0.125f, pr1 = prel[1*HH+h]*0.125f;
    float pr2 = prel[2*HH+h]*0.125f, pr3 = prel[3*HH+h]*0.125f;
    float m = -INFINITY, den = 0.f;
    float4 o4 = {0.f,0.f,0.f,0.f};
    for(uint32_t p = p0; p < p1; p++){
        uint32_t vmidx = einfo[p] & 0xffffu;
        int r = vmidx >> 13;
        float4 k4 = *(const float4*)(ka + (size_t)vmidx*DD + lane*4);
        float4 v4 = *(const float4*)(vm + (size_t)vmidx*DD + lane*4);
        float d = q4.x*k4.x + q4.y*k4.y + q4.z*k4.z + q4.w*k4.w;
        d += __shfl_xor(d, 1); d += __shfl_xor(d, 2);
        d += __shfl_xor(d, 4); d += __shfl_xor(d, 8);
        float pf = (r==0) ? pr0 : (r==1) ? pr1 : (r==2) ? pr2 : pr3;
        float s = d * pf;
        float nm = fmaxf(m, s);
        float sc_ = expf(m - nm);
        float pe = expf(s - nm);
        den = den*sc_ + pe;
        o4.x = o4.x*sc_ + pe*v4.x;
        o4.y = o4.y*sc_ + pe*v4.y;
        o4.z = o4.z*sc_ + pe*v4.z;
        o4.w = o4.w*sc_ + pe*v4.w;
        m = nm;
    }
    float inv = 1.f/(den + 1e-16f);
    float vals[4] = {o4.x*inv, o4.y*inv, o4.z*inv, o4.w*inv};
    u16x4 h4, l4;
    #pragma unroll
    for(int j=0;j<4;j++){
        float g = gelu_f(vals[j]);
        u16 hh = f2b(g);
        h4[j] = hh;
        l4[j] = f2b(g - b2f(hh));
    }
    size_t ob = (size_t)rowi*DD + lane*4;
    *(u16x4*)(bagg_h + ob) = h4;
    *(u16x4*)(bagg_l + ob) = l4;
}

// ---------------- pooling ----------------
__global__ void pool_h2(const float* __restrict__ xi, const float* __restrict__ xd,
                        const float* __restrict__ w, float* __restrict__ h){
    int node = blockIdx.x*4 + (threadIdx.x>>6);
    int lane = threadIdx.x & 63;
    const float* xr = (node < NI) ? (xi + (size_t)node*DD) : (xd + (size_t)(node-NI)*DD);
    float s = 0.f;
    for(int j=lane;j<DD;j+=64) s += xr[j]*w[j];
    for(int m=32;m;m>>=1) s += __shfl_xor(s, m);
    if(lane==0) h[node] = s;
}

// GAT-style pooling score via fwd CSR + implicit self-loop; wave per dst node
__global__ __launch_bounds__(256) void pool_csr(const uint32_t* __restrict__ rowptr,
                                                const uint32_t* __restrict__ einfo,
                                                const float* __restrict__ h,
                                                const float* __restrict__ att,
                                                float* __restrict__ score){
    int w = blockIdx.x*4 + (threadIdx.x >> 6);
    int lane = threadIdx.x & 63;
    if(w >= NROW) return;
    uint32_t p0 = rowptr[w], p1 = rowptr[w+1];
    float a0 = att[0], a1 = att[1];
    float hn = h[w];
    float es = a0*hn + a1*hn;
    es = es >= 0.f ? es : 0.2f*es;
    float m = -INFINITY;
    for(uint32_t p = p0+lane; p < p1; p += 64){
        float hs = h[einfo[p] >> 16];
        float e = a0*hs + a1*hn;
        e = e >= 0.f ? e : 0.2f*e;
        m = fmaxf(m, e);
    }
    #pragma unroll
    for(int s=32;s;s>>=1) m = fmaxf(m, __shfl_xor(m, s));
    m = fmaxf(m, es);
    float lden = 0.f, lnum = 0.f;
    for(uint32_t p = p0+lane; p < p1; p += 64){
        float hs = h[einfo[p] >> 16];
        float e = a0*hs + a1*hn;
        e = e >= 0.f ? e : 0.2f*e;
        float a = expf(e - m);
        lden += a; lnum += a*hs;
    }
    #pragma unroll
    for(int s=32;s;s>>=1){ lden += __shfl_xor(lden, s); lnum += __shfl_xor(lnum, s); }
    float aself = expf(es - m);
    lden += aself; lnum += aself*hn;
    if(lane==0) score[w] = lnum/(lden + 1e-16f);
}

// top-768 of 1536 per graph via bitonic sort
__global__ __launch_bounds__(512) void topk_kernel(const float* __restrict__ score,
                                                   const float* __restrict__ bias,
                                                   int* __restrict__ sel_node,
                                                   float* __restrict__ sel_scale){
    __shared__ float skey[2048];
    __shared__ int   sval[2048];
    int b = blockIdx.x;
    float bv = bias[0];
    for(int p=threadIdx.x;p<2048;p+=512){
        if(p<1536){
            int node = (p<1024) ? (b*1024 + p) : (NI + b*512 + (p-1024));
            skey[p] = score[node] + bv;
            sval[p] = node;
        } else {
            skey[p] = -INFINITY;
            sval[p] = -1;
        }
    }
    for(int k=2;k<=2048;k<<=1){
        for(int j=k>>1;j>0;j>>=1){
            __syncthreads();
            for(int i=threadIdx.x;i<2048;i+=512){
                int ixj = i^j;
                if(ixj > i){
                    bool up = ((i & k) == 0);
                    float ki = skey[i], kj = skey[ixj];
                    if((ki < kj) == up){
                        skey[i]=kj; skey[ixj]=ki;
                        int t=sval[i]; sval[i]=sval[ixj]; sval[ixj]=t;
                    }
                }
            }
        }
    }
    __syncthreads();
    for(int j=threadIdx.x;j<KPOOL;j+=512){
        sel_node[b*KPOOL + j] = sval[j];
        sel_scale[b*KPOOL + j] = tanhf(skey[j]);
    }
}

__global__ void gather_xp(const int* __restrict__ sel, const float* __restrict__ scale,
                          const float* __restrict__ xi, const float* __restrict__ xd,
                          float* __restrict__ xp, u16* __restrict__ bh, u16* __restrict__ bl){
    int i = blockIdx.x*256 + threadIdx.x;
    int rowp = i >> 8, c = i & 255;
    int node = sel[rowp];
    float s = scale[rowp];
    float v = (node < NI) ? xi[(size_t)node*DD + c] : xd[(size_t)(node-NI)*DD + c];
    float x = v*s;
    xp[i] = x;
    u16 hh = f2b(x);
    bh[i] = hh;
    bl[i] = f2b(x - b2f(hh));
}

// ---------------- MFMA flash attention: block per (b,h,64 q rows), pre-split inputs ----------------
__global__ __launch_bounds__(256) void attn_mfma(const u16* __restrict__ Qh, const u16* __restrict__ Ql,
                                                 const u16* __restrict__ Kh, const u16* __restrict__ Kl,
                                                 const u16* __restrict__ Vh,
                                                 u16* __restrict__ aoh, u16* __restrict__ aol){
    __shared__ u16 KhS[64*64], KlS[64*64], VtS[64*64];
    char* KhB = (char*)KhS; char* KlB = (char*)KlS; char* VtB = (char*)VtS;
    int bh = blockIdx.y;
    int b = bh >> 2, h = bh & 3;
    int q0 = blockIdx.x * 64;
    int tid = threadIdx.x;
    int lane = tid & 63;
    int w = tid >> 6;
    int l15 = lane & 15, l4 = lane >> 4;
    size_t qrow = (size_t)(b*KPOOL + q0 + w*16 + l15);
    bf16x8 qh[2], ql[2];
    #pragma unroll
    for(int c=0;c<2;c++){
        qh[c] = *(const bf16x8*)(Qh + qrow*DD + h*64 + c*32 + l4*8);
        ql[c] = *(const bf16x8*)(Ql + qrow*DD + h*64 + c*32 + l4*8);
    }
    float mreg = -INFINITY, lreg = 0.f;
    f32x4 O[4] = {};
    for(int k0=0;k0<KPOOL;k0+=64){
        __syncthreads();
        {   // stage K hi/lo + V^T from pre-split bf16
            int row = tid >> 2, q4 = tid & 3;
            size_t gbase = ((size_t)(b*KPOOL + k0 + row))*DD + h*64 + q4*16;
            bf16x8 k0v = *(const bf16x8*)(Kh + gbase);
            bf16x8 k1v = *(const bf16x8*)(Kh + gbase + 8);
            bf16x8 kl0 = *(const bf16x8*)(Kl + gbase);
            bf16x8 kl1 = *(const bf16x8*)(Kl + gbase + 8);
            bf16x8 v0v = *(const bf16x8*)(Vh + gbase);
            bf16x8 v1v = *(const bf16x8*)(Vh + gbase + 8);
            int sw = (row&7)<<4;
            int colb = q4*32;
            *(bf16x8*)(KhB + row*128 + (colb ^ sw))        = k0v;
            *(bf16x8*)(KhB + row*128 + ((colb+16) ^ sw))   = k1v;
            *(bf16x8*)(KlB + row*128 + (colb ^ sw))        = kl0;
            *(bf16x8*)(KlB + row*128 + ((colb+16) ^ sw))   = kl1;
            #pragma unroll
            for(int j=0;j<8;j++){
                int dh0 = q4*16 + j;
                int dh1 = q4*16 + 8 + j;
                *(u16*)(VtB + dh0*128 + ((row*2) ^ ((dh0&7)<<4))) = (u16)(short)v0v[j];
                *(u16*)(VtB + dh1*128 + ((row*2) ^ ((dh1&7)<<4))) = (u16)(short)v1v[j];
            }
        }
        __syncthreads();
        // S^T tiles: mfma(A=K, B=Q)
        f32x4 s[4] = {};
        #pragma unroll
        for(int t=0;t<4;t++){
            int arow = t*16 + l15;
            int sw = (arow&7)<<4;
            const char* bh_ = KhB + arow*128;
            const char* bl_ = KlB + arow*128;
            bf16x8 kh0 = *(const bf16x8*)(bh_ + ((l4*16) ^ sw));
            bf16x8 kh1 = *(const bf16x8*)(bh_ + ((l4*16 + 64) ^ sw));
            bf16x8 kl0 = *(const bf16x8*)(bl_ + ((l4*16) ^ sw));
            bf16x8 kl1 = *(const bf16x8*)(bl_ + ((l4*16 + 64) ^ sw));
            s[t] = __builtin_amdgcn_mfma_f32_16x16x32_bf16(kh0, qh[0], s[t], 0,0,0);
            s[t] = __builtin_amdgcn_mfma_f32_16x16x32_bf16(kh1, qh[1], s[t], 0,0,0);
            s[t] = __builtin_amdgcn_mfma_f32_16x16x32_bf16(kh0, ql[0], s[t], 0,0,0);
            s[t] = __builtin_amdgcn_mfma_f32_16x16x32_bf16(kh1, ql[1], s[t], 0,0,0);
            s[t] = __builtin_amdgcn_mfma_f32_16x16x32_bf16(kl0, qh[0], s[t], 0,0,0);
            s[t] = __builtin_amdgcn_mfma_f32_16x16x32_bf16(kl1, qh[1], s[t], 0,0,0);
        }
        // online softmax
        float cm = -INFINITY;
        #pragma unroll
        for(int t=0;t<4;t++)
            #pragma unroll
            for(int r=0;r<4;r++){ s[t][r] *= 0.125f; cm = fmaxf(cm, s[t][r]); }
        cm = fmaxf(cm, __shfl_xor(cm,16));
        cm = fmaxf(cm, __shfl_xor(cm,32));
        float nm = fmaxf(mreg, cm);
        float es = expf(mreg - nm);
        float ps = 0.f;
        #pragma unroll
        for(int t=0;t<4;t++)
            #pragma unroll
            for(int r=0;r<4;r++){ float pv = expf(s[t][r] - nm); s[t][r] = pv; ps += pv; }
        ps += __shfl_xor(ps,16);
        ps += __shfl_xor(ps,32);
        lreg = lreg*es + ps;
        mreg = nm;
        #pragma unroll
        for(int d=0;d<4;d++){ O[d][0]*=es; O[d][1]*=es; O[d][2]*=es; O[d][3]*=es; }
        // O^T += mfma(A=V^T, B=P^T)
        #pragma unroll
        for(int c32=0;c32<2;c32++){
            bf16x8 pb;
            #pragma unroll
            for(int j=0;j<8;j++){
                int srcl = ((((lane>>4)*2 + (j>>2)) & 3) << 4) | l15;
                float v0 = __shfl(s[c32*2+0][j&3], srcl, 64);
                float v1 = __shfl(s[c32*2+1][j&3], srcl, 64);
                float v = (lane < 32) ? v0 : v1;
                pb[j] = (short)f2b(v);
            }
            #pragma unroll
            for(int dhb=0; dhb<4; dhb++){
                int vrow = dhb*16 + l15;
                bf16x8 va = *(const bf16x8*)(VtB + vrow*128 + ((c32*64 + l4*16) ^ ((vrow&7)<<4)));
                O[dhb] = __builtin_amdgcn_mfma_f32_16x16x32_bf16(va, pb, O[dhb], 0,0,0);
            }
        }
    }
    float inv = 1.f/lreg;
    #pragma unroll
    for(int dhb=0;dhb<4;dhb++)
        #pragma unroll
        for(int r=0;r<4;r++){
            float val = O[dhb][r]*inv;
            size_t o = qrow*DD + h*64 + dhb*16 + l4*4 + r;
            u16 hh = f2b(val);
            aoh[o] = hh;
            aol[o] = f2b(val - b2f(hh));
        }
}

// layernorm row kernel
__global__ __launch_bounds__(256) void ln_kernel(const float* __restrict__ xp, const float* __restrict__ o2,
                                                 const float* __restrict__ lg, const float* __restrict__ lb,
                                                 float* __restrict__ gatt){
    __shared__ float red[256];
    int r = blockIdx.x, c = threadIdx.x;
    float y = xp[(size_t)r*DD + c] + o2[(size_t)r*DD + c];
    red[c] = y; __syncthreads();
    for(int s=128;s;s>>=1){ if(c<s) red[c] += red[c+s]; __syncthreads(); }
    float mu = red[0]*(1.f/DD);
    __syncthreads();
    float d = y - mu;
    red[c] = d*d; __syncthreads();
    for(int s=128;s;s>>=1){ if(c<s) red[c] += red[c+s]; __syncthreads(); }
    float var = red[0]*(1.f/DD);
    gatt[(size_t)r*DD + c] = lg[c]*d/sqrtf(var+1e-5f) + lb[c];
}

__global__ void feat_reduce2(const float* __restrict__ xp, const float* __restrict__ gatt,
                             float* __restrict__ out){
    int b = blockIdx.x, c = threadIdx.x;
    int j0 = blockIdx.y*64;
    float s1=0.f, s2=0.f;
    for(int j=j0;j<j0+64;j++){
        size_t base = ((size_t)(b*KPOOL + j))*DD + c;
        s1 += xp[base];
        s2 += gatt[base];
    }
    atomicAdd(&out[b*512 + c], s1);
    atomicAdd(&out[b*512 + 256 + c], s2);
}

__global__ void cosine_kernel(const float* __restrict__ u, const float* __restrict__ v,
                              float* __restrict__ out){
    int b = blockIdx.x, t = threadIdx.x;
    float du=0.f, nu=0.f, nv=0.f;
    for(int j=t;j<512;j+=64){
        float a = u[b*512+j], bb = v[b*512+j];
        du += a*bb; nu += a*a; nv += bb*bb;
    }
    for(int m=32;m;m>>=1){
        du += __shfl_xor(du,m); nu += __shfl_xor(nu,m); nv += __shfl_xor(nv,m);
    }
    if(t==0) out[b] = du / (fmaxf(sqrtf(nu),1e-8f)*fmaxf(sqrtf(nv),1e-8f));
}

// =======================================================================
extern "C" void kernel_launch(void* const* d_in, const int* in_sizes, int n_in,
                              void* d_out, int out_size, void* d_ws, size_t ws_size,
                              hipStream_t stream){
    (void)in_sizes; (void)n_in; (void)out_size; (void)ws_size;
    const float* hgt_Wk   = (const float*)d_in[12];
    const float* hgt_Wq   = (const float*)d_in[13];
    const float* hgt_Wv   = (const float*)d_in[14];
    const float* hgt_Wo   = (const float*)d_in[15];
    const float* hgt_arel = (const float*)d_in[16];
    const float* hgt_mrel = (const float*)d_in[17];
    const float* hgt_prel = (const float*)d_in[18];
    const float* hgt_skip = (const float*)d_in[19];
    const float* pool_W   = (const float*)d_in[20];
    const float* pool_att = (const float*)d_in[21];
    const float* pool_bias= (const float*)d_in[22];
    const float* t_wq     = (const float*)d_in[23];
    const float* t_wk     = (const float*)d_in[24];
    const float* t_wv     = (const float*)d_in[25];
    const float* t_wo     = (const float*)d_in[26];
    const float* ln_g     = (const float*)d_in[27];
    const float* ln_b     = (const float*)d_in[28];
    float* out = (float*)d_out;

    char* base = (char*)d_ws;
    size_t off = 0;
    auto allocb = [&](size_t nbytes)->void*{
        void* p = (void*)(base + off);
        off += ((nbytes + 255) & ~(size_t)255);
        return p;
    };
    const size_t MAT = 65536;
    // ---- persistent ----
    u16* bwtk_h = (u16*)allocb(16*MAT*2); u16* bwtk_l = (u16*)allocb(16*MAT*2);
    u16* bwtv_h = (u16*)allocb(16*MAT*2); u16* bwtv_l = (u16*)allocb(16*MAT*2);
    u16* bwq_h  = (u16*)allocb(8*MAT*2);  u16* bwq_l  = (u16*)allocb(8*MAT*2);
    u16* bwo_h  = (u16*)allocb(8*MAT*2);  u16* bwo_l  = (u16*)allocb(8*MAT*2);
    u16* btw_h  = (u16*)allocb(4*MAT*2);  u16* btw_l  = (u16*)allocb(4*MAT*2);
    float* ubuf = (float*)allocb(BB*512*4);
    float* vbuf = (float*)allocb(BB*512*4);
    float* xa_i = (float*)allocb((size_t)NI*DD*4);
    float* xa_d = (float*)allocb((size_t)ND*DD*4);
    float* xb_i = (float*)allocb((size_t)NI*DD*4);
    float* xb_d = (float*)allocb((size_t)ND*DD*4);
    // ---- per-branch CSR ----
    uint32_t* ccnt   = (uint32_t*)allocb((size_t)2*NROW*4);
    uint32_t* rowptr = (uint32_t*)allocb((size_t)(2*NROW+1)*4);
    uint32_t* einfo  = (uint32_t*)allocb((size_t)2*EHGT*4);
    size_t region = off;
    // ---- conv scratch ----
    float* q_i  = (float*)allocb((size_t)NI*DD*4);
    float* q_d  = (float*)allocb((size_t)ND*DD*4);
    float* ka4  = (float*)allocb((size_t)4*NI*DD*4);
    float* vmb  = (float*)allocb((size_t)4*NI*DD*4);
    float* xacc_i= (float*)allocb((size_t)NI*DD*4);
    float* xacc_d= (float*)allocb((size_t)ND*DD*4);
    u16* bcur_h = (u16*)allocb((size_t)NROW*DD*2);
    u16* bcur_l = (u16*)allocb((size_t)NROW*DD*2);
    u16* bagg_h = (u16*)allocb((size_t)NROW*DD*2);
    u16* bagg_l = (u16*)allocb((size_t)NROW*DD*2);
    // ---- pooling/transformer overlay ----
    off = region;
    float* hvec = (float*)allocb(NROW*4);
    float* pscore = (float*)allocb(NROW*4);
    int* seln   = (int*)allocb(BB*KPOOL*4);
    float* sels = (float*)allocb(BB*KPOOL*4);
    float* xp   = (float*)allocb((size_t)BB*KPOOL*DD*4);
    float* o2   = (float*)allocb((size_t)BB*KPOOL*DD*4);
    float* gatt = (float*)allocb((size_t)BB*KPOOL*DD*4);
    u16* bxp_h = (u16*)allocb((size_t)BB*KPOOL*DD*2);
    u16* bxp_l = (u16*)allocb((size_t)BB*KPOOL*DD*2);
    u16* qbh = (u16*)allocb((size_t)BB*KPOOL*DD*2);
    u16* qbl = (u16*)allocb((size_t)BB*KPOOL*DD*2);
    u16* kbh = (u16*)allocb((size_t)BB*KPOOL*DD*2);
    u16* kbl = (u16*)allocb((size_t)BB*KPOOL*DD*2);
    u16* vbh = (u16*)allocb((size_t)BB*KPOOL*DD*2);
    u16* vbl = (u16*)allocb((size_t)BB*KPOOL*DD*2);
    u16* bao_h = (u16*)allocb((size_t)BB*KPOOL*DD*2);
    u16* bao_l = (u16*)allocb((size_t)BB*KPOOL*DD*2);

    const int st_tab[2][4] = {{0,1,0,0},{0,0,1,0}};
    const int dt_tab[2][4] = {{0,0,1,0},{0,1,0,0}};
    const int MR = BB*KPOOL;

    fill_u32<<<(2*BB*512+255)/256,256,0,stream>>>((uint32_t*)ubuf, 0u, 2*BB*512);
    float* wtkF = ka4;
    float* wtvF = ka4 + 16*MAT;
    combine_all<<<dim3(256,32),256,0,stream>>>(hgt_Wk, hgt_Wv, hgt_arel, hgt_mrel, wtkF, wtvF);
    WCArgs wc;
    wc.in[0]=wtkF;   wc.oh[0]=bwtk_h; wc.ol[0]=bwtk_l; wc.cnt[0]=16;
    wc.in[1]=wtvF;   wc.oh[1]=bwtv_h; wc.ol[1]=bwtv_l; wc.cnt[1]=16;
    wc.in[2]=hgt_Wq; wc.oh[2]=bwq_h;  wc.ol[2]=bwq_l;  wc.cnt[2]=8;
    wc.in[3]=hgt_Wo; wc.oh[3]=bwo_h;  wc.ol[3]=bwo_l;  wc.cnt[3]=8;
    wc.in[4]=t_wq;   wc.oh[4]=btw_h;          wc.ol[4]=btw_l;          wc.cnt[4]=1;
    wc.in[5]=t_wk;   wc.oh[5]=btw_h+1*MAT;    wc.ol[5]=btw_l+1*MAT;    wc.cnt[5]=1;
    wc.in[6]=t_wv;   wc.oh[6]=btw_h+2*MAT;    wc.ol[6]=btw_l+2*MAT;    wc.cnt[6]=1;
    wc.in[7]=t_wo;   wc.oh[7]=btw_h+3*MAT;    wc.ol[7]=btw_l+3*MAT;    wc.cnt[7]=1;
    wc.nr = 8;
    wcvt_split<<<dim3(256,52),256,0,stream>>>(wc);

    for(int bi=0;bi<2;bi++){
        int ib = bi*6;
        const float* x_inst = (const float*)d_in[ib+0];
        const float* x_data = (const float*)d_in[ib+1];
        const int* ecp = (const int*)d_in[ib+2];
        const int* eip = (const int*)d_in[ib+3];
        const int* eop = (const int*)d_in[ib+4];
        const int* ekp = (const int*)d_in[ib+5];
        const int* rows_f[4] = {ecp, eip, eop, ekp};
        const int* cols_f[4] = {ecp+EC, eip+EI, eop+EO, ekp+EK};

        // ---- CSR build (both dirs, one pass) ----
        CB2 cb;
        for(int r=0;r<4;r++){
            cb.row[r]   = rows_f[r]; cb.col[r]   = cols_f[r]; cb.dt[r]   = dt_tab[0][r]; cb.st[r]   = st_tab[0][r];
            cb.row[4+r] = cols_f[r]; cb.col[4+r] = rows_f[r]; cb.dt[4+r] = dt_tab[1][r]; cb.st[4+r] = st_tab[1][r];
        }
        cb.cnt = ccnt; cb.rowptr = rowptr; cb.einfo = einfo;
        fill_u32<<<(2*NROW+255)/256,256,0,stream>>>(ccnt, 0u, 2*NROW);
        csr_hist2<<<(2*EHGT+255)/256,256,0,stream>>>(cb);
        scan_rowptr2<<<1,1024,0,stream>>>(ccnt, rowptr);
        csr_scatter2<<<(2*EHGT+255)/256,256,0,stream>>>(cb);

        const float* cur_i = x_inst;
        const float* cur_d = x_data;
        cvt_split<<<((NROW*DD/4)+255)/256,256,0,stream>>>(cur_i, NI*DD, cur_d, ND*DD, bcur_h, bcur_l);
        for(int l=0;l<LL;l++){
            float* nxt_i = (l==0) ? xa_i : xb_i;
            float* nxt_d = (l==0) ? xa_d : xb_d;
            for(int dir=0;dir<2;dir++){
                int wb = l*2 + dir;

                // --- mega GEMM: Q(2) + KA(4) + VM(4) in one launch ---
                GArgs g1; int nb1 = 0, ndx = 0;
                auto addg = [&](int srctype, const u16* Bh, const u16* Bl, float* Cm, int M){
                    GDesc& d = g1.d[ndx];
                    size_t ao = srctype ? (size_t)NI*DD : 0;
                    d.Ah = bcur_h + ao; d.Al = bcur_l + ao;
                    d.Bh = Bh; d.Bl = Bl; d.C = Cm;
                    d.Oh = nullptr; d.Ol = nullptr; d.X = nullptr; d.Xacc = nullptr; d.skipp = nullptr;
                    d.mblks = M/128; d.mode = 0;
                    nb1 += M/128; ndx++;
                };
                addg(0, bwq_h + (size_t)(wb*2+0)*MAT, bwq_l + (size_t)(wb*2+0)*MAT, q_i, NI);
                addg(1, bwq_h + (size_t)(wb*2+1)*MAT, bwq_l + (size_t)(wb*2+1)*MAT, q_d, ND);
                for(int r=0;r<4;r++){
                    int st = st_tab[dir][r];
                    addg(st, bwtk_h + (size_t)(wb*4+r)*MAT, bwtk_l + (size_t)(wb*4+r)*MAT,
                         ka4 + (size_t)r*NI*DD, st ? ND : NI);
                }
                for(int r=0;r<4;r++){
                    int st = st_tab[dir][r];
                    addg(st, bwtv_h + (size_t)(wb*4+r)*MAT, bwtv_l + (size_t)(wb*4+r)*MAT,
                         vmb + (size_t)r*NI*DD, st ? ND : NI);
                }
                g1.nd = ndx;
                gemm_mfma<<<dim3(nb1,2),256,0,stream>>>(g1);

                // --- fused edge phase: scores + online softmax + gather + gelu + split ---
                hgt_fused<<<NROW/4,256,0,stream>>>(rowptr + (size_t)dir*NROW, einfo,
                    q_i, q_d, ka4, vmb, hgt_prel + (size_t)wb*4*HH, bagg_h, bagg_l);

                // --- Wo GEMMs with fused skip/relu epilogue ---
                GArgs g3; g3.nd = 2;
                for(int t=0;t<2;t++){
                    GDesc& d = g3.d[t];
                    size_t ao = t ? (size_t)NI*DD : 0;
                    d.Ah = bagg_h + ao; d.Al = bagg_l + ao;
                    d.Bh = bwo_h + (size_t)(wb*2+t)*MAT; d.Bl = bwo_l + (size_t)(wb*2+t)*MAT;
                    d.C = t ? nxt_d : nxt_i;
                    d.Oh = bcur_h + ao; d.Ol = bcur_l + ao;
                    d.X = t ? cur_d : cur_i;
                    d.Xacc = t ? xacc_d : xacc_i;
                    d.skipp = hgt_skip + wb*2 + t;
                    d.mblks = (t ? ND : NI)/128;
                    d.mode = dir ? 3 : 2;
                }
                gemm_mfma<<<dim3(NI/128 + ND/128,2),256,0,stream>>>(g3);
            }
            cur_i = nxt_i;
            cur_d = nxt_d;
        }

        // -------- SAGPooling (CSR-based, no atomics) --------
        pool_h2<<<NROW/4,256,0,stream>>>(cur_i, cur_d, pool_W, hvec);
        pool_csr<<<NROW/4,256,0,stream>>>(rowptr, einfo, hvec, pool_att, pscore);
        topk_kernel<<<BB,512,0,stream>>>(pscore, pool_bias, seln, sels);
        gather_xp<<<BB*KPOOL,256,0,stream>>>(seln, sels, cur_i, cur_d, xp, bxp_h, bxp_l);

        // -------- transformer --------
        GArgs g4; g4.nd = 3;
        for(int t=0;t<3;t++){
            GDesc& d = g4.d[t];
            d.Ah=bxp_h; d.Al=bxp_l;
            d.Bh=btw_h + (size_t)t*MAT; d.Bl=btw_l + (size_t)t*MAT;
            d.C = nullptr;
            d.Oh = (t==0)? qbh : (t==1)? kbh : vbh;
            d.Ol = (t==0)? qbl : (t==1)? kbl : vbl;
            d.X = nullptr; d.Xacc = nullptr; d.skipp = nullptr;
            d.mblks = MR/128; d.mode = 1;
        }
        gemm_mfma<<<dim3(3*(MR/128),2),256,0,stream>>>(g4);
        attn_mfma<<<dim3(KPOOL/64, BB*HH),256,0,stream>>>(qbh, qbl, kbh, kbl, vbh, bao_h, bao_l);
        GArgs g5; g5.nd = 1;
        {
            GDesc& d = g5.d[0];
            d.Ah=bao_h; d.Al=bao_l;
            d.Bh=btw_h + (size_t)3*MAT; d.Bl=btw_l + (size_t)3*MAT;
            d.C=o2; d.Oh=nullptr; d.Ol=nullptr; d.X=nullptr; d.Xacc=nullptr; d.skipp=nullptr;
            d.mblks=MR/128; d.mode=0;
        }
        gemm_mfma<<<dim3(MR/128,2),256,0,stream>>>(g5);
        ln_kernel<<<MR,256,0,stream>>>(xp, o2, ln_g, ln_b, gatt);
        feat_reduce2<<<dim3(BB,12),256,0,stream>>>(xp, gatt, bi ? vbuf : ubuf);
    }

    cosine_kernel<<<BB,64,0,stream>>>(ubuf, vbuf, out);
}

// Round 13
// 1280.359 us; speedup vs baseline: 1.5189x; 1.1056x over previous
//
#include <hip/hip_runtime.h>
#include <math.h>
#include <stdint.h>

#define LL 2
#define HH 4
#define DHH 64
#define DD 256
#define BB 8
#define NI 8192
#define ND 4096
#define NROW 12288
#define KPOOL 768
#define EC 65536
#define EI 32768
#define EO 32768
#define EK 8192
#define EHGT (EC+EI+EO+EK)

typedef unsigned short u16;
typedef short bf16x8 __attribute__((ext_vector_type(8)));
typedef float f32x4 __attribute__((ext_vector_type(4)));
typedef unsigned short u16x4 __attribute__((ext_vector_type(4)));

__device__ inline float gelu_f(float x){ return 0.5f*x*(1.f+erff(x*0.70710678118654752f)); }
__device__ inline u16 f2b(float x){ uint32_t u=__float_as_uint(x); return (u16)((u + 0x7fffu + ((u>>16)&1u))>>16); }
__device__ inline float b2f(u16 h){ return __uint_as_float(((uint32_t)h)<<16); }

// ---------------- generic fill ----------------
__global__ void fill_u32(uint32_t* p, uint32_t v, int n){
    int i = blockIdx.x*256 + threadIdx.x;
    if(i<n) p[i]=v;
}

// ---------------- activation split-convert ----------------
__global__ void cvt_split(const float* __restrict__ A, int nA, const float* __restrict__ B, int nB,
                          u16* __restrict__ oh, u16* __restrict__ ol){
    int i = (blockIdx.x*256 + threadIdx.x)*4;
    int tot = nA + nB;
    if(i >= tot) return;
    float4 v = (i < nA) ? *(const float4*)(A + i) : *(const float4*)(B + (i - nA));
    float vv[4] = {v.x, v.y, v.z, v.w};
    u16x4 h4, l4;
    #pragma unroll
    for(int j=0;j<4;j++){
        float x = vv[j];
        u16 h = f2b(x);
        h4[j] = h;
        l4[j] = f2b(x - b2f(h));
    }
    *(u16x4*)(oh + i) = h4;
    *(u16x4*)(ol + i) = l4;
}

// ---------------- weight transpose + split ----------------
struct WCArgs { const float* in[8]; u16* oh[8]; u16* ol[8]; int cnt[8]; int nr; };
__global__ void wcvt_split(WCArgs a){
    int mat = blockIdx.y, ri = 0;
    while(ri < a.nr-1 && mat >= a.cnt[ri]){ mat -= a.cnt[ri]; ri++; }
    const float* in = a.in[ri] + (size_t)mat*65536;
    u16* oh = a.oh[ri] + (size_t)mat*65536;
    u16* ol = a.ol[ri] + (size_t)mat*65536;
    int n = blockIdx.x, k = threadIdx.x;
    float x = in[(size_t)k*DD + n];
    u16 h = f2b(x);
    oh[n*DD + k] = h;
    ol[n*DD + k] = f2b(x - b2f(h));
}

// ---------------- MFMA batched GEMM with fused, LDS-restaged epilogues ----------------
// LDS: paired hi/lo staging [128 rows][128 bytes], XOR-swizzle (row&7)<<4; reused as
// float[64][128] for the coalesced epilogue (two half-tile passes).
// mode 0: C=f32   mode 1: Oh/Ol=split bf16
// mode 2: Xacc = 0.5*(g*acc + (1-g)*X)
// mode 3: v=relu(Xacc + 0.5*(g*acc+(1-g)*X)); C=v; Oh/Ol=split(v)
struct GDesc { const u16* Ah; const u16* Al; const u16* Bh; const u16* Bl;
               float* C; u16* Oh; u16* Ol;
               const float* X; float* Xacc; const float* skipp;
               int mblks; int mode; };
struct GArgs { GDesc d[10]; int nd; };

__global__ __launch_bounds__(256) void gemm_mfma(GArgs ga){
    __shared__ u16 SBUF[2*128*64];
    char* Abuf = (char*)SBUF;
    char* Bbuf = (char*)(SBUF + 128*64);
    int mb = blockIdx.x, di = 0;
    while(di < ga.nd-1 && mb >= ga.d[di].mblks){ mb -= ga.d[di].mblks; di++; }
    GDesc g = ga.d[di];
    const int m0 = mb*128, n0 = blockIdx.y*128;
    const int tid = threadIdx.x;
    const int lane = tid & 63, wid = tid >> 6;
    const int wm = (wid>>1)*64, wn = (wid&1)*64;
    const int l15 = lane & 15, l4 = lane >> 4;
    const int srow = tid >> 1, hf = tid & 1;
    const int ssw = (srow&7)<<4;
    const int c0 = (hf*32) ^ ssw;
    const int c1 = (hf*32+16) ^ ssw;
    const int c2 = (64+hf*32) ^ ssw;
    const int c3 = (64+hf*32+16) ^ ssw;
    const int rbyte = srow*128;
    const u16* __restrict__ Aph = g.Ah + (size_t)(m0 + srow)*DD + hf*16;
    const u16* __restrict__ Apl = g.Al + (size_t)(m0 + srow)*DD + hf*16;
    const u16* __restrict__ Bph = g.Bh + (size_t)(n0 + srow)*DD + hf*16;
    const u16* __restrict__ Bpl = g.Bl + (size_t)(n0 + srow)*DD + hf*16;
    f32x4 acc[4][4] = {};
    bf16x8 r0 = *(const bf16x8*)(Aph);
    bf16x8 r1 = *(const bf16x8*)(Aph + 8);
    bf16x8 r2 = *(const bf16x8*)(Apl);
    bf16x8 r3 = *(const bf16x8*)(Apl + 8);
    bf16x8 r4 = *(const bf16x8*)(Bph);
    bf16x8 r5 = *(const bf16x8*)(Bph + 8);
    bf16x8 r6 = *(const bf16x8*)(Bpl);
    bf16x8 r7 = *(const bf16x8*)(Bpl + 8);
    #pragma unroll
    for(int k0=0;k0<DD;k0+=32){
        __syncthreads();
        *(bf16x8*)(Abuf + rbyte + c0) = r0; *(bf16x8*)(Abuf + rbyte + c1) = r1;
        *(bf16x8*)(Abuf + rbyte + c2) = r2; *(bf16x8*)(Abuf + rbyte + c3) = r3;
        *(bf16x8*)(Bbuf + rbyte + c0) = r4; *(bf16x8*)(Bbuf + rbyte + c1) = r5;
        *(bf16x8*)(Bbuf + rbyte + c2) = r6; *(bf16x8*)(Bbuf + rbyte + c3) = r7;
        __syncthreads();
        if(k0 + 32 < DD){
            int kn = k0 + 32;
            r0 = *(const bf16x8*)(Aph + kn);     r1 = *(const bf16x8*)(Aph + kn + 8);
            r2 = *(const bf16x8*)(Apl + kn);     r3 = *(const bf16x8*)(Apl + kn + 8);
            r4 = *(const bf16x8*)(Bph + kn);     r5 = *(const bf16x8*)(Bph + kn + 8);
            r6 = *(const bf16x8*)(Bpl + kn);     r7 = *(const bf16x8*)(Bpl + kn + 8);
        }
        bf16x8 afh[4], afl[4], bfh[4], bfl[4];
        #pragma unroll
        for(int i=0;i<4;i++){
            int ar = wm + i*16 + l15;
            int swa = (ar&7)<<4;
            int abase = ar*128;
            afh[i] = *(const bf16x8*)(Abuf + abase + ((l4*16) ^ swa));
            afl[i] = *(const bf16x8*)(Abuf + abase + ((64 + l4*16) ^ swa));
            int br = wn + i*16 + l15;
            int swb = (br&7)<<4;
            int bbase = br*128;
            bfh[i] = *(const bf16x8*)(Bbuf + bbase + ((l4*16) ^ swb));
            bfl[i] = *(const bf16x8*)(Bbuf + bbase + ((64 + l4*16) ^ swb));
        }
        #pragma unroll
        for(int i=0;i<4;i++)
            #pragma unroll
            for(int j=0;j<4;j++){
                acc[i][j] = __builtin_amdgcn_mfma_f32_16x16x32_bf16(afh[i], bfh[j], acc[i][j], 0,0,0);
                acc[i][j] = __builtin_amdgcn_mfma_f32_16x16x32_bf16(afh[i], bfl[j], acc[i][j], 0,0,0);
                acc[i][j] = __builtin_amdgcn_mfma_f32_16x16x32_bf16(afl[i], bfh[j], acc[i][j], 0,0,0);
            }
    }
    // ---- coalesced epilogue via LDS restage (two 64-row passes) ----
    const int mode = g.mode;
    float gg = 0.f;
    if(mode >= 2) gg = 1.f/(1.f + expf(-*g.skipp));
    float* LDSf = (float*)SBUF;
    const int lrow = tid >> 5;
    const int cc4 = (tid & 31)*4;
    #pragma unroll
    for(int half=0; half<2; half++){
        __syncthreads();
        if((wid>>1) == half){
            #pragma unroll
            for(int i=0;i<4;i++)
                #pragma unroll
                for(int j=0;j<4;j++)
                    #pragma unroll
                    for(int r=0;r<4;r++)
                        LDSf[(i*16 + l4*4 + r)*128 + wn + j*16 + l15] = acc[i][j][r];
        }
        __syncthreads();
        #pragma unroll
        for(int k=0;k<8;k++){
            int row = lrow + k*8;
            size_t o = (size_t)(m0 + half*64 + row)*DD + n0 + cc4;
            float4 v = *(const float4*)&LDSf[row*128 + cc4];
            float vv[4] = {v.x, v.y, v.z, v.w};
            if(mode==0){
                *(float4*)(g.C + o) = v;
            } else if(mode==1){
                u16x4 h4, lo4;
                #pragma unroll
                for(int j=0;j<4;j++){
                    u16 hh = f2b(vv[j]); h4[j]=hh; lo4[j]=f2b(vv[j]-b2f(hh));
                }
                *(u16x4*)(g.Oh + o) = h4;
                *(u16x4*)(g.Ol + o) = lo4;
            } else if(mode==2){
                float4 x = *(const float4*)(g.X + o);
                float xx[4] = {x.x, x.y, x.z, x.w};
                float4 w;
                float* ww = (float*)&w;
                #pragma unroll
                for(int j=0;j<4;j++) ww[j] = 0.5f*(gg*vv[j] + (1.f-gg)*xx[j]);
                *(float4*)(g.Xacc + o) = w;
            } else {
                float4 x = *(const float4*)(g.X + o);
                float4 xa = *(const float4*)(g.Xacc + o);
                float xx[4] = {x.x, x.y, x.z, x.w};
                float aa[4] = {xa.x, xa.y, xa.z, xa.w};
                float4 cv;
                float* cvv = (float*)&cv;
                u16x4 h4, lo4;
                #pragma unroll
                for(int j=0;j<4;j++){
                    float v3 = aa[j] + 0.5f*(gg*vv[j] + (1.f-gg)*xx[j]);
                    v3 = v3 > 0.f ? v3 : 0.f;
                    cvv[j] = v3;
                    u16 hh = f2b(v3); h4[j]=hh; lo4[j]=f2b(v3-b2f(hh));
                }
                *(float4*)(g.C + o) = cv;
                *(u16x4*)(g.Oh + o) = h4;
                *(u16x4*)(g.Ol + o) = lo4;
            }
        }
    }
}

// ---------- combine ----------
__global__ void combine_all(const float* __restrict__ Wk, const float* __restrict__ Wv,
                            const float* __restrict__ Ra, const float* __restrict__ Rm,
                            float* __restrict__ wtk, float* __restrict__ wtv){
    const int st_tab[2][4] = {{0,1,0,0},{0,0,1,0}};
    int combo = blockIdx.y;
    int idx = combo >> 1, kv = combo & 1;
    int r = idx & 3, wb = idx >> 2, dir = wb & 1;
    int st = st_tab[dir][r];
    const float* W = (kv ? Wv : Wk) + (size_t)(wb*2 + st)*65536;
    const float* R = (kv ? Rm : Ra) + (size_t)idx*16384;
    float* o = (kv ? wtv : wtk) + (size_t)idx*65536;
    int d = blockIdx.x, c = threadIdx.x;
    int h = c >> 6, f = c & 63;
    const float* Wrow = W + d*DD + h*64;
    const float* Rh = R + h*4096 + f;
    float s = 0.f;
    #pragma unroll 8
    for(int k=0;k<64;k++) s += Wrow[k]*Rh[k*64];
    o[d*DD + c] = s;
}

// ---------------- CSR build (both directions in one pass) ----------------
// einfo packing: low16 = r*NI+src (VM/KA row index; r = vmidx>>13), high16 = hom node id of src
__device__ inline void edge_decode(int e, int& r, int& el){
    if(e < EC){ r=0; el=e; }
    else if(e < EC+EI){ r=1; el=e-EC; }
    else if(e < EC+EI+EO){ r=2; el=e-(EC+EI); }
    else { r=3; el=e-(EC+EI+EO); }
}

struct CB2 {
    const int* row[8]; const int* col[8];
    int dt[8]; int st[8];
    uint32_t* cnt; uint32_t* rowptr; uint32_t* einfo;
};

__global__ void csr_hist2(CB2 a){
    int ge = blockIdx.x*256 + threadIdx.x;
    if(ge >= 2*EHGT) return;
    int dir = ge >= EHGT;
    int e = ge - dir*EHGT;
    int r, el; edge_decode(e, r, el);
    int idx = dir*4 + r;
    int c = a.col[idx][el];
    int dst = dir*NROW + (a.dt[idx] ? (NI + c) : c);
    atomicAdd(&a.cnt[dst], 1u);
}

__global__ __launch_bounds__(1024) void scan_rowptr2(uint32_t* cnt, uint32_t* rowptr){
    __shared__ uint32_t part[1024];
    int t = threadIdx.x;
    int base = t*24;
    uint32_t lpre[24];
    uint32_t sum = 0;
    #pragma unroll
    for(int i=0;i<24;i++){
        uint32_t c = cnt[base+i];
        lpre[i] = sum; sum += c;
        cnt[base+i] = 0;
    }
    part[t] = sum;
    __syncthreads();
    for(int offs=1; offs<1024; offs<<=1){
        uint32_t v = (t>=offs) ? part[t-offs] : 0u;
        __syncthreads();
        part[t] += v;
        __syncthreads();
    }
    uint32_t pre = (t==0) ? 0u : part[t-1];
    #pragma unroll
    for(int i=0;i<24;i++) rowptr[base+i] = pre + lpre[i];
    if(t==1023) rowptr[2*NROW] = part[1023];
}

__global__ void csr_scatter2(CB2 a){
    int ge = blockIdx.x*256 + threadIdx.x;
    if(ge >= 2*EHGT) return;
    int dir = ge >= EHGT;
    int e = ge - dir*EHGT;
    int r, el; edge_decode(e, r, el);
    int idx = dir*4 + r;
    int c = a.col[idx][el];
    int dst = dir*NROW + (a.dt[idx] ? (NI + c) : c);
    int src = a.row[idx][el];
    uint32_t p = a.rowptr[dst] + atomicAdd(&a.cnt[dst], 1u);
    uint32_t vmidx = (uint32_t)(r*NI + src);
    uint32_t hom = a.st[idx] ? (uint32_t)(NI + src) : (uint32_t)src;
    a.einfo[p] = vmidx | (hom << 16);
}

// ---------------- fused HGT edge phase: wave per dst, all 4 heads, online softmax ----------------
__global__ __launch_bounds__(256) void hgt_fused(const uint32_t* __restrict__ rowptr,
                                                 const uint32_t* __restrict__ einfo,
                                                 const float* __restrict__ q_i,
                                                 const float* __restrict__ q_d,
                                                 const float* __restrict__ ka,
                                                 const float* __restrict__ vm,
                                                 const float* __restrict__ prel,
                                                 u16* __restrict__ bagg_h,
                                                 u16* __restrict__ bagg_l){
    int wv = threadIdx.x >> 6, lane = threadIdx.x & 63;
    int rowi = blockIdx.x*4 + wv;
    uint32_t p0 = rowptr[rowi], p1 = rowptr[rowi+1];
    int h = lane >> 4;
    const float* qrow = (rowi < NI) ? (q_i + (size_t)rowi*DD) : (q_d + (size_t)(rowi-NI)*DD);
    float4 q4 = *(const float4*)(qrow + lane*4);
    float pr0 = prel[0*HH+h]*0.125f, pr1 = prel[1*HH+h]*0.125f;
    float pr2 = prel[2*HH+h]*0.125f, pr3 = prel[3*HH+h]*0.125f;
    float m = -INFINITY, den = 0.f;
    float4 o4 = {0.f,0.f,0.f,0.f};
    for(uint32_t p = p0; p < p1; p++){
        uint32_t vmidx = einfo[p] & 0xffffu;
        int r = vmidx >> 13;
        float4 k4 = *(const float4*)(ka + (size_t)vmidx*DD + lane*4);
        float4 v4 = *(const float4*)(vm + (size_t)vmidx*DD + lane*4);
        float d = q4.x*k4.x + q4.y*k4.y + q4.z*k4.z + q4.w*k4.w;
        d += __shfl_xor(d, 1); d += __shfl_xor(d, 2);
        d += __shfl_xor(d, 4); d += __shfl_xor(d, 8);
        float pf = (r==0) ? pr0 : (r==1) ? pr1 : (r==2) ? pr2 : pr3;
        float s = d * pf;
        float nm = fmaxf(m, s);
        float sc_ = expf(m - nm);
        float pe = expf(s - nm);
        den = den*sc_ + pe;
        o4.x = o4.x*sc_ + pe*v4.x;
        o4.y = o4.y*sc_ + pe*v4.y;
        o4.z = o4.z*sc_ + pe*v4.z;
        o4.w = o4.w*sc_ + pe*v4.w;
        m = nm;
    }
    float inv = 1.f/(den + 1e-16f);
    float vals[4] = {o4.x*inv, o4.y*inv, o4.z*inv, o4.w*inv};
    u16x4 h4, l4;
    #pragma unroll
    for(int j=0;j<4;j++){
        float g = gelu_f(vals[j]);
        u16 hh = f2b(g);
        h4[j] = hh;
        l4[j] = f2b(g - b2f(hh));
    }
    size_t ob = (size_t)rowi*DD + lane*4;
    *(u16x4*)(bagg_h + ob) = h4;
    *(u16x4*)(bagg_l + ob) = l4;
}

// ---------------- pooling ----------------
__global__ void pool_h2(const float* __restrict__ xi, const float* __restrict__ xd,
                        const float* __restrict__ w, float* __restrict__ h){
    int node = blockIdx.x*4 + (threadIdx.x>>6);
    int lane = threadIdx.x & 63;
    const float* xr = (node < NI) ? (xi + (size_t)node*DD) : (xd + (size_t)(node-NI)*DD);
    float s = 0.f;
    for(int j=lane;j<DD;j+=64) s += xr[j]*w[j];
    for(int m=32;m;m>>=1) s += __shfl_xor(s, m);
    if(lane==0) h[node] = s;
}

// GAT-style pooling score via fwd CSR + implicit self-loop; wave per dst node
__global__ __launch_bounds__(256) void pool_csr(const uint32_t* __restrict__ rowptr,
                                                const uint32_t* __restrict__ einfo,
                                                const float* __restrict__ h,
                                                const float* __restrict__ att,
                                                float* __restrict__ score){
    int w = blockIdx.x*4 + (threadIdx.x >> 6);
    int lane = threadIdx.x & 63;
    if(w >= NROW) return;
    uint32_t p0 = rowptr[w], p1 = rowptr[w+1];
    float a0 = att[0], a1 = att[1];
    float hn = h[w];
    float es = a0*hn + a1*hn;
    es = es >= 0.f ? es : 0.2f*es;
    float m = -INFINITY;
    for(uint32_t p = p0+lane; p < p1; p += 64){
        float hs = h[einfo[p] >> 16];
        float e = a0*hs + a1*hn;
        e = e >= 0.f ? e : 0.2f*e;
        m = fmaxf(m, e);
    }
    #pragma unroll
    for(int s=32;s;s>>=1) m = fmaxf(m, __shfl_xor(m, s));
    m = fmaxf(m, es);
    float lden = 0.f, lnum = 0.f;
    for(uint32_t p = p0+lane; p < p1; p += 64){
        float hs = h[einfo[p] >> 16];
        float e = a0*hs + a1*hn;
        e = e >= 0.f ? e : 0.2f*e;
        float a = expf(e - m);
        lden += a; lnum += a*hs;
    }
    #pragma unroll
    for(int s=32;s;s>>=1){ lden += __shfl_xor(lden, s); lnum += __shfl_xor(lnum, s); }
    float aself = expf(es - m);
    lden += aself; lnum += aself*hn;
    if(lane==0) score[w] = lnum/(lden + 1e-16f);
}

// top-768 of 1536 per graph via bitonic sort
__global__ __launch_bounds__(512) void topk_kernel(const float* __restrict__ score,
                                                   const float* __restrict__ bias,
                                                   int* __restrict__ sel_node,
                                                   float* __restrict__ sel_scale){
    __shared__ float skey[2048];
    __shared__ int   sval[2048];
    int b = blockIdx.x;
    float bv = bias[0];
    for(int p=threadIdx.x;p<2048;p+=512){
        if(p<1536){
            int node = (p<1024) ? (b*1024 + p) : (NI + b*512 + (p-1024));
            skey[p] = score[node] + bv;
            sval[p] = node;
        } else {
            skey[p] = -INFINITY;
            sval[p] = -1;
        }
    }
    for(int k=2;k<=2048;k<<=1){
        for(int j=k>>1;j>0;j>>=1){
            __syncthreads();
            for(int i=threadIdx.x;i<2048;i+=512){
                int ixj = i^j;
                if(ixj > i){
                    bool up = ((i & k) == 0);
                    float ki = skey[i], kj = skey[ixj];
                    if((ki < kj) == up){
                        skey[i]=kj; skey[ixj]=ki;
                        int t=sval[i]; sval[i]=sval[ixj]; sval[ixj]=t;
                    }
                }
            }
        }
    }
    __syncthreads();
    for(int j=threadIdx.x;j<KPOOL;j+=512){
        sel_node[b*KPOOL + j] = sval[j];
        sel_scale[b*KPOOL + j] = tanhf(skey[j]);
    }
}

__global__ void gather_xp(const int* __restrict__ sel, const float* __restrict__ scale,
                          const float* __restrict__ xi, const float* __restrict__ xd,
                          float* __restrict__ xp, u16* __restrict__ bh, u16* __restrict__ bl){
    int i = blockIdx.x*256 + threadIdx.x;
    int rowp = i >> 8, c = i & 255;
    int node = sel[rowp];
    float s = scale[rowp];
    float v = (node < NI) ? xi[(size_t)node*DD + c] : xd[(size_t)(node-NI)*DD + c];
    float x = v*s;
    xp[i] = x;
    u16 hh = f2b(x);
    bh[i] = hh;
    bl[i] = f2b(x - b2f(hh));
}

// ---------------- MFMA flash attention: block per (b,h,64 q rows), pre-split inputs ----------------
__global__ __launch_bounds__(256) void attn_mfma(const u16* __restrict__ Qh, const u16* __restrict__ Ql,
                                                 const u16* __restrict__ Kh, const u16* __restrict__ Kl,
                                                 const u16* __restrict__ Vh,
                                                 u16* __restrict__ aoh, u16* __restrict__ aol){
    __shared__ u16 KhS[64*64], KlS[64*64], VtS[64*64];
    char* KhB = (char*)KhS; char* KlB = (char*)KlS; char* VtB = (char*)VtS;
    int bh = blockIdx.y;
    int b = bh >> 2, h = bh & 3;
    int q0 = blockIdx.x * 64;
    int tid = threadIdx.x;
    int lane = tid & 63;
    int w = tid >> 6;
    int l15 = lane & 15, l4 = lane >> 4;
    size_t qrow = (size_t)(b*KPOOL + q0 + w*16 + l15);
    bf16x8 qh[2], ql[2];
    #pragma unroll
    for(int c=0;c<2;c++){
        qh[c] = *(const bf16x8*)(Qh + qrow*DD + h*64 + c*32 + l4*8);
        ql[c] = *(const bf16x8*)(Ql + qrow*DD + h*64 + c*32 + l4*8);
    }
    float mreg = -INFINITY, lreg = 0.f;
    f32x4 O[4] = {};
    for(int k0=0;k0<KPOOL;k0+=64){
        __syncthreads();
        {   // stage K hi/lo + V^T from pre-split bf16
            int row = tid >> 2, q4 = tid & 3;
            size_t gbase = ((size_t)(b*KPOOL + k0 + row))*DD + h*64 + q4*16;
            bf16x8 k0v = *(const bf16x8*)(Kh + gbase);
            bf16x8 k1v = *(const bf16x8*)(Kh + gbase + 8);
            bf16x8 kl0 = *(const bf16x8*)(Kl + gbase);
            bf16x8 kl1 = *(const bf16x8*)(Kl + gbase + 8);
            bf16x8 v0v = *(const bf16x8*)(Vh + gbase);
            bf16x8 v1v = *(const bf16x8*)(Vh + gbase + 8);
            int sw = (row&7)<<4;
            int colb = q4*32;
            *(bf16x8*)(KhB + row*128 + (colb ^ sw))        = k0v;
            *(bf16x8*)(KhB + row*128 + ((colb+16) ^ sw))   = k1v;
            *(bf16x8*)(KlB + row*128 + (colb ^ sw))        = kl0;
            *(bf16x8*)(KlB + row*128 + ((colb+16) ^ sw))   = kl1;
            #pragma unroll
            for(int j=0;j<8;j++){
                int dh0 = q4*16 + j;
                int dh1 = q4*16 + 8 + j;
                *(u16*)(VtB + dh0*128 + ((row*2) ^ ((dh0&7)<<4))) = (u16)(short)v0v[j];
                *(u16*)(VtB + dh1*128 + ((row*2) ^ ((dh1&7)<<4))) = (u16)(short)v1v[j];
            }
        }
        __syncthreads();
        // S^T tiles: mfma(A=K, B=Q)
        f32x4 s[4] = {};
        #pragma unroll
        for(int t=0;t<4;t++){
            int arow = t*16 + l15;
            int sw = (arow&7)<<4;
            const char* bh_ = KhB + arow*128;
            const char* bl_ = KlB + arow*128;
            bf16x8 kh0 = *(const bf16x8*)(bh_ + ((l4*16) ^ sw));
            bf16x8 kh1 = *(const bf16x8*)(bh_ + ((l4*16 + 64) ^ sw));
            bf16x8 kl0 = *(const bf16x8*)(bl_ + ((l4*16) ^ sw));
            bf16x8 kl1 = *(const bf16x8*)(bl_ + ((l4*16 + 64) ^ sw));
            s[t] = __builtin_amdgcn_mfma_f32_16x16x32_bf16(kh0, qh[0], s[t], 0,0,0);
            s[t] = __builtin_amdgcn_mfma_f32_16x16x32_bf16(kh1, qh[1], s[t], 0,0,0);
            s[t] = __builtin_amdgcn_mfma_f32_16x16x32_bf16(kh0, ql[0], s[t], 0,0,0);
            s[t] = __builtin_amdgcn_mfma_f32_16x16x32_bf16(kh1, ql[1], s[t], 0,0,0);
            s[t] = __builtin_amdgcn_mfma_f32_16x16x32_bf16(kl0, qh[0], s[t], 0,0,0);
            s[t] = __builtin_amdgcn_mfma_f32_16x16x32_bf16(kl1, qh[1], s[t], 0,0,0);
        }
        // online softmax
        float cm = -INFINITY;
        #pragma unroll
        for(int t=0;t<4;t++)
            #pragma unroll
            for(int r=0;r<4;r++){ s[t][r] *= 0.125f; cm = fmaxf(cm, s[t][r]); }
        cm = fmaxf(cm, __shfl_xor(cm,16));
        cm = fmaxf(cm, __shfl_xor(cm,32));
        float nm = fmaxf(mreg, cm);
        float es = expf(mreg - nm);
        float ps = 0.f;
        #pragma unroll
        for(int t=0;t<4;t++)
            #pragma unroll
            for(int r=0;r<4;r++){ float pv = expf(s[t][r] - nm); s[t][r] = pv; ps += pv; }
        ps += __shfl_xor(ps,16);
        ps += __shfl_xor(ps,32);
        lreg = lreg*es + ps;
        mreg = nm;
        #pragma unroll
        for(int d=0;d<4;d++){ O[d][0]*=es; O[d][1]*=es; O[d][2]*=es; O[d][3]*=es; }
        // O^T += mfma(A=V^T, B=P^T)
        #pragma unroll
        for(int c32=0;c32<2;c32++){
            bf16x8 pb;
            #pragma unroll
            for(int j=0;j<8;j++){
                int srcl = ((((lane>>4)*2 + (j>>2)) & 3) << 4) | l15;
                float v0 = __shfl(s[c32*2+0][j&3], srcl, 64);
                float v1 = __shfl(s[c32*2+1][j&3], srcl, 64);
                float v = (lane < 32) ? v0 : v1;
                pb[j] = (short)f2b(v);
            }
            #pragma unroll
            for(int dhb=0; dhb<4; dhb++){
                int vrow = dhb*16 + l15;
                bf16x8 va = *(const bf16x8*)(VtB + vrow*128 + ((c32*64 + l4*16) ^ ((vrow&7)<<4)));
                O[dhb] = __builtin_amdgcn_mfma_f32_16x16x32_bf16(va, pb, O[dhb], 0,0,0);
            }
        }
    }
    float inv = 1.f/lreg;
    #pragma unroll
    for(int dhb=0;dhb<4;dhb++)
        #pragma unroll
        for(int r=0;r<4;r++){
            float val = O[dhb][r]*inv;
            size_t o = qrow*DD + h*64 + dhb*16 + l4*4 + r;
            u16 hh = f2b(val);
            aoh[o] = hh;
            aol[o] = f2b(val - b2f(hh));
        }
}

// layernorm row kernel
__global__ __launch_bounds__(256) void ln_kernel(const float* __restrict__ xp, const float* __restrict__ o2,
                                                 const float* __restrict__ lg, const float* __restrict__ lb,
                                                 float* __restrict__ gatt){
    __shared__ float red[256];
    int r = blockIdx.x, c = threadIdx.x;
    float y = xp[(size_t)r*DD + c] + o2[(size_t)r*DD + c];
    red[c] = y; __syncthreads();
    for(int s=128;s;s>>=1){ if(c<s) red[c] += red[c+s]; __syncthreads(); }
    float mu = red[0]*(1.f/DD);
    __syncthreads();
    float d = y - mu;
    red[c] = d*d; __syncthreads();
    for(int s=128;s;s>>=1){ if(c<s) red[c] += red[c+s]; __syncthreads(); }
    float var = red[0]*(1.f/DD);
    gatt[(size_t)r*DD + c] = lg[c]*d/sqrtf(var+1e-5f) + lb[c];
}

__global__ void feat_reduce2(const float* __restrict__ xp, const float* __restrict__ gatt,
                             float* __restrict__ out){
    int b = blockIdx.x, c = threadIdx.x;
    int j0 = blockIdx.y*64;
    float s1=0.f, s2=0.f;
    for(int j=j0;j<j0+64;j++){
        size_t base = ((size_t)(b*KPOOL + j))*DD + c;
        s1 += xp[base];
        s2 += gatt[base];
    }
    atomicAdd(&out[b*512 + c], s1);
    atomicAdd(&out[b*512 + 256 + c], s2);
}

__global__ void cosine_kernel(const float* __restrict__ u, const float* __restrict__ v,
                              float* __restrict__ out){
    int b = blockIdx.x, t = threadIdx.x;
    float du=0.f, nu=0.f, nv=0.f;
    for(int j=t;j<512;j+=64){
        float a = u[b*512+j], bb = v[b*512+j];
        du += a*bb; nu += a*a; nv += bb*bb;
    }
    for(int m=32;m;m>>=1){
        du += __shfl_xor(du,m); nu += __shfl_xor(nu,m); nv += __shfl_xor(nv,m);
    }
    if(t==0) out[b] = du / (fmaxf(sqrtf(nu),1e-8f)*fmaxf(sqrtf(nv),1e-8f));
}

// =======================================================================
extern "C" void kernel_launch(void* const* d_in, const int* in_sizes, int n_in,
                              void* d_out, int out_size, void* d_ws, size_t ws_size,
                              hipStream_t stream){
    (void)in_sizes; (void)n_in; (void)out_size; (void)ws_size;
    const float* hgt_Wk   = (const float*)d_in[12];
    const float* hgt_Wq   = (const float*)d_in[13];
    const float* hgt_Wv   = (const float*)d_in[14];
    const float* hgt_Wo   = (const float*)d_in[15];
    const float* hgt_arel = (const float*)d_in[16];
    const float* hgt_mrel = (const float*)d_in[17];
    const float* hgt_prel = (const float*)d_in[18];
    const float* hgt_skip = (const float*)d_in[19];
    const float* pool_W   = (const float*)d_in[20];
    const float* pool_att = (const float*)d_in[21];
    const float* pool_bias= (const float*)d_in[22];
    const float* t_wq     = (const float*)d_in[23];
    const float* t_wk     = (const float*)d_in[24];
    const float* t_wv     = (const float*)d_in[25];
    const float* t_wo     = (const float*)d_in[26];
    const float* ln_g     = (const float*)d_in[27];
    const float* ln_b     = (const float*)d_in[28];
    float* out = (float*)d_out;

    char* base = (char*)d_ws;
    size_t off = 0;
    auto allocb = [&](size_t nbytes)->void*{
        void* p = (void*)(base + off);
        off += ((nbytes + 255) & ~(size_t)255);
        return p;
    };
    const size_t MAT = 65536;
    // ---- persistent ----
    u16* bwtk_h = (u16*)allocb(16*MAT*2); u16* bwtk_l = (u16*)allocb(16*MAT*2);
    u16* bwtv_h = (u16*)allocb(16*MAT*2); u16* bwtv_l = (u16*)allocb(16*MAT*2);
    u16* bwq_h  = (u16*)allocb(8*MAT*2);  u16* bwq_l  = (u16*)allocb(8*MAT*2);
    u16* bwo_h  = (u16*)allocb(8*MAT*2);  u16* bwo_l  = (u16*)allocb(8*MAT*2);
    u16* btw_h  = (u16*)allocb(4*MAT*2);  u16* btw_l  = (u16*)allocb(4*MAT*2);
    float* ubuf = (float*)allocb(BB*512*4);
    float* vbuf = (float*)allocb(BB*512*4);
    float* xa_i = (float*)allocb((size_t)NI*DD*4);
    float* xa_d = (float*)allocb((size_t)ND*DD*4);
    float* xb_i = (float*)allocb((size_t)NI*DD*4);
    float* xb_d = (float*)allocb((size_t)ND*DD*4);
    // ---- per-branch CSR ----
    uint32_t* ccnt   = (uint32_t*)allocb((size_t)2*NROW*4);
    uint32_t* rowptr = (uint32_t*)allocb((size_t)(2*NROW+1)*4);
    uint32_t* einfo  = (uint32_t*)allocb((size_t)2*EHGT*4);
    size_t region = off;
    // ---- conv scratch ----
    float* q_i  = (float*)allocb((size_t)NI*DD*4);
    float* q_d  = (float*)allocb((size_t)ND*DD*4);
    float* ka4  = (float*)allocb((size_t)4*NI*DD*4);
    float* vmb  = (float*)allocb((size_t)4*NI*DD*4);
    float* xacc_i= (float*)allocb((size_t)NI*DD*4);
    float* xacc_d= (float*)allocb((size_t)ND*DD*4);
    u16* bcur_h = (u16*)allocb((size_t)NROW*DD*2);
    u16* bcur_l = (u16*)allocb((size_t)NROW*DD*2);
    u16* bagg_h = (u16*)allocb((size_t)NROW*DD*2);
    u16* bagg_l = (u16*)allocb((size_t)NROW*DD*2);
    // ---- pooling/transformer overlay ----
    off = region;
    float* hvec = (float*)allocb(NROW*4);
    float* pscore = (float*)allocb(NROW*4);
    int* seln   = (int*)allocb(BB*KPOOL*4);
    float* sels = (float*)allocb(BB*KPOOL*4);
    float* xp   = (float*)allocb((size_t)BB*KPOOL*DD*4);
    float* o2   = (float*)allocb((size_t)BB*KPOOL*DD*4);
    float* gatt = (float*)allocb((size_t)BB*KPOOL*DD*4);
    u16* bxp_h = (u16*)allocb((size_t)BB*KPOOL*DD*2);
    u16* bxp_l = (u16*)allocb((size_t)BB*KPOOL*DD*2);
    u16* qbh = (u16*)allocb((size_t)BB*KPOOL*DD*2);
    u16* qbl = (u16*)allocb((size_t)BB*KPOOL*DD*2);
    u16* kbh = (u16*)allocb((size_t)BB*KPOOL*DD*2);
    u16* kbl = (u16*)allocb((size_t)BB*KPOOL*DD*2);
    u16* vbh = (u16*)allocb((size_t)BB*KPOOL*DD*2);
    u16* vbl = (u16*)allocb((size_t)BB*KPOOL*DD*2);
    u16* bao_h = (u16*)allocb((size_t)BB*KPOOL*DD*2);
    u16* bao_l = (u16*)allocb((size_t)BB*KPOOL*DD*2);

    const int st_tab[2][4] = {{0,1,0,0},{0,0,1,0}};
    const int dt_tab[2][4] = {{0,0,1,0},{0,1,0,0}};
    const int MR = BB*KPOOL;

    fill_u32<<<(2*BB*512+255)/256,256,0,stream>>>((uint32_t*)ubuf, 0u, 2*BB*512);
    float* wtkF = ka4;
    float* wtvF = ka4 + 16*MAT;
    combine_all<<<dim3(256,32),256,0,stream>>>(hgt_Wk, hgt_Wv, hgt_arel, hgt_mrel, wtkF, wtvF);
    WCArgs wc;
    wc.in[0]=wtkF;   wc.oh[0]=bwtk_h; wc.ol[0]=bwtk_l; wc.cnt[0]=16;
    wc.in[1]=wtvF;   wc.oh[1]=bwtv_h; wc.ol[1]=bwtv_l; wc.cnt[1]=16;
    wc.in[2]=hgt_Wq; wc.oh[2]=bwq_h;  wc.ol[2]=bwq_l;  wc.cnt[2]=8;
    wc.in[3]=hgt_Wo; wc.oh[3]=bwo_h;  wc.ol[3]=bwo_l;  wc.cnt[3]=8;
    wc.in[4]=t_wq;   wc.oh[4]=btw_h;          wc.ol[4]=btw_l;          wc.cnt[4]=1;
    wc.in[5]=t_wk;   wc.oh[5]=btw_h+1*MAT;    wc.ol[5]=btw_l+1*MAT;    wc.cnt[5]=1;
    wc.in[6]=t_wv;   wc.oh[6]=btw_h+2*MAT;    wc.ol[6]=btw_l+2*MAT;    wc.cnt[6]=1;
    wc.in[7]=t_wo;   wc.oh[7]=btw_h+3*MAT;    wc.ol[7]=btw_l+3*MAT;    wc.cnt[7]=1;
    wc.nr = 8;
    wcvt_split<<<dim3(256,52),256,0,stream>>>(wc);

    for(int bi=0;bi<2;bi++){
        int ib = bi*6;
        const float* x_inst = (const float*)d_in[ib+0];
        const float* x_data = (const float*)d_in[ib+1];
        const int* ecp = (const int*)d_in[ib+2];
        const int* eip = (const int*)d_in[ib+3];
        const int* eop = (const int*)d_in[ib+4];
        const int* ekp = (const int*)d_in[ib+5];
        const int* rows_f[4] = {ecp, eip, eop, ekp};
        const int* cols_f[4] = {ecp+EC, eip+EI, eop+EO, ekp+EK};

        // ---- CSR build (both dirs, one pass) ----
        CB2 cb;
        for(int r=0;r<4;r++){
            cb.row[r]   = rows_f[r]; cb.col[r]   = cols_f[r]; cb.dt[r]   = dt_tab[0][r]; cb.st[r]   = st_tab[0][r];
            cb.row[4+r] = cols_f[r]; cb.col[4+r] = rows_f[r]; cb.dt[4+r] = dt_tab[1][r]; cb.st[4+r] = st_tab[1][r];
        }
        cb.cnt = ccnt; cb.rowptr = rowptr; cb.einfo = einfo;
        fill_u32<<<(2*NROW+255)/256,256,0,stream>>>(ccnt, 0u, 2*NROW);
        csr_hist2<<<(2*EHGT+255)/256,256,0,stream>>>(cb);
        scan_rowptr2<<<1,1024,0,stream>>>(ccnt, rowptr);
        csr_scatter2<<<(2*EHGT+255)/256,256,0,stream>>>(cb);

        const float* cur_i = x_inst;
        const float* cur_d = x_data;
        cvt_split<<<((NROW*DD/4)+255)/256,256,0,stream>>>(cur_i, NI*DD, cur_d, ND*DD, bcur_h, bcur_l);
        for(int l=0;l<LL;l++){
            float* nxt_i = (l==0) ? xa_i : xb_i;
            float* nxt_d = (l==0) ? xa_d : xb_d;
            for(int dir=0;dir<2;dir++){
                int wb = l*2 + dir;

                // --- mega GEMM: Q(2) + KA(4) + VM(4) in one launch ---
                GArgs g1; int nb1 = 0, ndx = 0;
                auto addg = [&](int srctype, const u16* Bh, const u16* Bl, float* Cm, int M){
                    GDesc& d = g1.d[ndx];
                    size_t ao = srctype ? (size_t)NI*DD : 0;
                    d.Ah = bcur_h + ao; d.Al = bcur_l + ao;
                    d.Bh = Bh; d.Bl = Bl; d.C = Cm;
                    d.Oh = nullptr; d.Ol = nullptr; d.X = nullptr; d.Xacc = nullptr; d.skipp = nullptr;
                    d.mblks = M/128; d.mode = 0;
                    nb1 += M/128; ndx++;
                };
                addg(0, bwq_h + (size_t)(wb*2+0)*MAT, bwq_l + (size_t)(wb*2+0)*MAT, q_i, NI);
                addg(1, bwq_h + (size_t)(wb*2+1)*MAT, bwq_l + (size_t)(wb*2+1)*MAT, q_d, ND);
                for(int r=0;r<4;r++){
                    int st = st_tab[dir][r];
                    addg(st, bwtk_h + (size_t)(wb*4+r)*MAT, bwtk_l + (size_t)(wb*4+r)*MAT,
                         ka4 + (size_t)r*NI*DD, st ? ND : NI);
                }
                for(int r=0;r<4;r++){
                    int st = st_tab[dir][r];
                    addg(st, bwtv_h + (size_t)(wb*4+r)*MAT, bwtv_l + (size_t)(wb*4+r)*MAT,
                         vmb + (size_t)r*NI*DD, st ? ND : NI);
                }
                g1.nd = ndx;
                gemm_mfma<<<dim3(nb1,2),256,0,stream>>>(g1);

                // --- fused edge phase: scores + online softmax + gather + gelu + split ---
                hgt_fused<<<NROW/4,256,0,stream>>>(rowptr + (size_t)dir*NROW, einfo,
                    q_i, q_d, ka4, vmb, hgt_prel + (size_t)wb*4*HH, bagg_h, bagg_l);

                // --- Wo GEMMs with fused skip/relu epilogue ---
                GArgs g3; g3.nd = 2;
                for(int t=0;t<2;t++){
                    GDesc& d = g3.d[t];
                    size_t ao = t ? (size_t)NI*DD : 0;
                    d.Ah = bagg_h + ao; d.Al = bagg_l + ao;
                    d.Bh = bwo_h + (size_t)(wb*2+t)*MAT; d.Bl = bwo_l + (size_t)(wb*2+t)*MAT;
                    d.C = t ? nxt_d : nxt_i;
                    d.Oh = bcur_h + ao; d.Ol = bcur_l + ao;
                    d.X = t ? cur_d : cur_i;
                    d.Xacc = t ? xacc_d : xacc_i;
                    d.skipp = hgt_skip + wb*2 + t;
                    d.mblks = (t ? ND : NI)/128;
                    d.mode = dir ? 3 : 2;
                }
                gemm_mfma<<<dim3(NI/128 + ND/128,2),256,0,stream>>>(g3);
            }
            cur_i = nxt_i;
            cur_d = nxt_d;
        }

        // -------- SAGPooling (CSR-based, no atomics) --------
        pool_h2<<<NROW/4,256,0,stream>>>(cur_i, cur_d, pool_W, hvec);
        pool_csr<<<NROW/4,256,0,stream>>>(rowptr, einfo, hvec, pool_att, pscore);
        topk_kernel<<<BB,512,0,stream>>>(pscore, pool_bias, seln, sels);
        gather_xp<<<BB*KPOOL,256,0,stream>>>(seln, sels, cur_i, cur_d, xp, bxp_h, bxp_l);

        // -------- transformer --------
        GArgs g4; g4.nd = 3;
        for(int t=0;t<3;t++){
            GDesc& d = g4.d[t];
            d.Ah=bxp_h; d.Al=bxp_l;
            d.Bh=btw_h + (size_t)t*MAT; d.Bl=btw_l + (size_t)t*MAT;
            d.C = nullptr;
            d.Oh = (t==0)? qbh : (t==1)? kbh : vbh;
            d.Ol = (t==0)? qbl : (t==1)? kbl : vbl;
            d.X = nullptr; d.Xacc = nullptr; d.skipp = nullptr;
            d.mblks = MR/128; d.mode = 1;
        }
        gemm_mfma<<<dim3(3*(MR/128),2),256,0,stream>>>(g4);
        attn_mfma<<<dim3(KPOOL/64, BB*HH),256,0,stream>>>(qbh, qbl, kbh, kbl, vbh, bao_h, bao_l);
        GArgs g5; g5.nd = 1;
        {
            GDesc& d = g5.d[0];
            d.Ah=bao_h; d.Al=bao_l;
            d.Bh=btw_h + (size_t)3*MAT; d.Bl=btw_l + (size_t)3*MAT;
            d.C=o2; d.Oh=nullptr; d.Ol=nullptr; d.X=nullptr; d.Xacc=nullptr; d.skipp=nullptr;
            d.mblks=MR/128; d.mode=0;
        }
        gemm_mfma<<<dim3(MR/128,2),256,0,stream>>>(g5);
        ln_kernel<<<MR,256,0,stream>>>(xp, o2, ln_g, ln_b, gatt);
        feat_reduce2<<<dim3(BB,12),256,0,stream>>>(xp, gatt, bi ? vbuf : ubuf);
    }

    cosine_kernel<<<BB,64,0,stream>>>(ubuf, vbuf, out);
}

// Round 14
// 1182.805 us; speedup vs baseline: 1.6442x; 1.0825x over previous
//
#include <hip/hip_runtime.h>
#include <math.h>
#include <stdint.h>

#define LL 2
#define HH 4
#define DHH 64
#define DD 256
#define BB 8
#define NI 8192
#define ND 4096
#define NROW 12288
#define KPOOL 768
#define EC 65536
#define EI 32768
#define EO 32768
#define EK 8192
#define EHGT (EC+EI+EO+EK)

typedef unsigned short u16;
typedef short bf16x8 __attribute__((ext_vector_type(8)));
typedef float f32x4 __attribute__((ext_vector_type(4)));
typedef unsigned short u16x4 __attribute__((ext_vector_type(4)));

__device__ inline float gelu_f(float x){ return 0.5f*x*(1.f+erff(x*0.70710678118654752f)); }
__device__ inline u16 f2b(float x){ uint32_t u=__float_as_uint(x); return (u16)((u + 0x7fffu + ((u>>16)&1u))>>16); }
__device__ inline float b2f(u16 h){ return __uint_as_float(((uint32_t)h)<<16); }

// ---------------- generic fill ----------------
__global__ void fill_u32(uint32_t* p, uint32_t v, int n){
    int i = blockIdx.x*256 + threadIdx.x;
    if(i<n) p[i]=v;
}

// ---------------- activation split-convert ----------------
__global__ void cvt_split(const float* __restrict__ A, int nA, const float* __restrict__ B, int nB,
                          u16* __restrict__ oh, u16* __restrict__ ol){
    int i = (blockIdx.x*256 + threadIdx.x)*4;
    int tot = nA + nB;
    if(i >= tot) return;
    float4 v = (i < nA) ? *(const float4*)(A + i) : *(const float4*)(B + (i - nA));
    float vv[4] = {v.x, v.y, v.z, v.w};
    u16x4 h4, l4;
    #pragma unroll
    for(int j=0;j<4;j++){
        float x = vv[j];
        u16 h = f2b(x);
        h4[j] = h;
        l4[j] = f2b(x - b2f(h));
    }
    *(u16x4*)(oh + i) = h4;
    *(u16x4*)(ol + i) = l4;
}

// ---------------- weight transpose + split ----------------
struct WCArgs { const float* in[8]; u16* oh[8]; u16* ol[8]; int cnt[8]; int nr; };
__global__ void wcvt_split(WCArgs a){
    int mat = blockIdx.y, ri = 0;
    while(ri < a.nr-1 && mat >= a.cnt[ri]){ mat -= a.cnt[ri]; ri++; }
    const float* in = a.in[ri] + (size_t)mat*65536;
    u16* oh = a.oh[ri] + (size_t)mat*65536;
    u16* ol = a.ol[ri] + (size_t)mat*65536;
    int n = blockIdx.x, k = threadIdx.x;
    float x = in[(size_t)k*DD + n];
    u16 h = f2b(x);
    oh[n*DD + k] = h;
    ol[n*DD + k] = f2b(x - b2f(h));
}

// ---------------- MFMA batched GEMM with fused, LDS-restaged epilogues ----------------
// mode 0: C=f32   mode 1: Oh/Ol=split bf16   mode 4: Oh=plain bf16
// mode 2: Xacc = 0.5*(g*acc + (1-g)*X)
// mode 3: v=relu(Xacc + 0.5*(g*acc+(1-g)*X)); C=v; Oh/Ol=split(v)
struct GDesc { const u16* Ah; const u16* Al; const u16* Bh; const u16* Bl;
               float* C; u16* Oh; u16* Ol;
               const float* X; float* Xacc; const float* skipp;
               int mblks; int mode; };
struct GArgs { GDesc d[10]; int nd; };

__global__ __launch_bounds__(256) void gemm_mfma(GArgs ga){
    __shared__ u16 SBUF[2*128*64];
    char* Abuf = (char*)SBUF;
    char* Bbuf = (char*)(SBUF + 128*64);
    int mb = blockIdx.x, di = 0;
    while(di < ga.nd-1 && mb >= ga.d[di].mblks){ mb -= ga.d[di].mblks; di++; }
    GDesc g = ga.d[di];
    const int m0 = mb*128, n0 = blockIdx.y*128;
    const int tid = threadIdx.x;
    const int lane = tid & 63, wid = tid >> 6;
    const int wm = (wid>>1)*64, wn = (wid&1)*64;
    const int l15 = lane & 15, l4 = lane >> 4;
    const int srow = tid >> 1, hf = tid & 1;
    const int ssw = (srow&7)<<4;
    const int c0 = (hf*32) ^ ssw;
    const int c1 = (hf*32+16) ^ ssw;
    const int c2 = (64+hf*32) ^ ssw;
    const int c3 = (64+hf*32+16) ^ ssw;
    const int rbyte = srow*128;
    const u16* __restrict__ Aph = g.Ah + (size_t)(m0 + srow)*DD + hf*16;
    const u16* __restrict__ Apl = g.Al + (size_t)(m0 + srow)*DD + hf*16;
    const u16* __restrict__ Bph = g.Bh + (size_t)(n0 + srow)*DD + hf*16;
    const u16* __restrict__ Bpl = g.Bl + (size_t)(n0 + srow)*DD + hf*16;
    f32x4 acc[4][4] = {};
    bf16x8 r0 = *(const bf16x8*)(Aph);
    bf16x8 r1 = *(const bf16x8*)(Aph + 8);
    bf16x8 r2 = *(const bf16x8*)(Apl);
    bf16x8 r3 = *(const bf16x8*)(Apl + 8);
    bf16x8 r4 = *(const bf16x8*)(Bph);
    bf16x8 r5 = *(const bf16x8*)(Bph + 8);
    bf16x8 r6 = *(const bf16x8*)(Bpl);
    bf16x8 r7 = *(const bf16x8*)(Bpl + 8);
    #pragma unroll
    for(int k0=0;k0<DD;k0+=32){
        __syncthreads();
        *(bf16x8*)(Abuf + rbyte + c0) = r0; *(bf16x8*)(Abuf + rbyte + c1) = r1;
        *(bf16x8*)(Abuf + rbyte + c2) = r2; *(bf16x8*)(Abuf + rbyte + c3) = r3;
        *(bf16x8*)(Bbuf + rbyte + c0) = r4; *(bf16x8*)(Bbuf + rbyte + c1) = r5;
        *(bf16x8*)(Bbuf + rbyte + c2) = r6; *(bf16x8*)(Bbuf + rbyte + c3) = r7;
        __syncthreads();
        if(k0 + 32 < DD){
            int kn = k0 + 32;
            r0 = *(const bf16x8*)(Aph + kn);     r1 = *(const bf16x8*)(Aph + kn + 8);
            r2 = *(const bf16x8*)(Apl + kn);     r3 = *(const bf16x8*)(Apl + kn + 8);
            r4 = *(const bf16x8*)(Bph + kn);     r5 = *(const bf16x8*)(Bph + kn + 8);
            r6 = *(const bf16x8*)(Bpl + kn);     r7 = *(const bf16x8*)(Bpl + kn + 8);
        }
        bf16x8 afh[4], afl[4], bfh[4], bfl[4];
        #pragma unroll
        for(int i=0;i<4;i++){
            int ar = wm + i*16 + l15;
            int swa = (ar&7)<<4;
            int abase = ar*128;
            afh[i] = *(const bf16x8*)(Abuf + abase + ((l4*16) ^ swa));
            afl[i] = *(const bf16x8*)(Abuf + abase + ((64 + l4*16) ^ swa));
            int br = wn + i*16 + l15;
            int swb = (br&7)<<4;
            int bbase = br*128;
            bfh[i] = *(const bf16x8*)(Bbuf + bbase + ((l4*16) ^ swb));
            bfl[i] = *(const bf16x8*)(Bbuf + bbase + ((64 + l4*16) ^ swb));
        }
        #pragma unroll
        for(int i=0;i<4;i++)
            #pragma unroll
            for(int j=0;j<4;j++){
                acc[i][j] = __builtin_amdgcn_mfma_f32_16x16x32_bf16(afh[i], bfh[j], acc[i][j], 0,0,0);
                acc[i][j] = __builtin_amdgcn_mfma_f32_16x16x32_bf16(afh[i], bfl[j], acc[i][j], 0,0,0);
                acc[i][j] = __builtin_amdgcn_mfma_f32_16x16x32_bf16(afl[i], bfh[j], acc[i][j], 0,0,0);
            }
    }
    // ---- coalesced epilogue via LDS restage (two 64-row passes) ----
    const int mode = g.mode;
    float gg = 0.f;
    if(mode == 2 || mode == 3) gg = 1.f/(1.f + expf(-*g.skipp));
    float* LDSf = (float*)SBUF;
    const int lrow = tid >> 5;
    const int cc4 = (tid & 31)*4;
    #pragma unroll
    for(int half=0; half<2; half++){
        __syncthreads();
        if((wid>>1) == half){
            #pragma unroll
            for(int i=0;i<4;i++)
                #pragma unroll
                for(int j=0;j<4;j++)
                    #pragma unroll
                    for(int r=0;r<4;r++)
                        LDSf[(i*16 + l4*4 + r)*128 + wn + j*16 + l15] = acc[i][j][r];
        }
        __syncthreads();
        #pragma unroll
        for(int k=0;k<8;k++){
            int row = lrow + k*8;
            size_t o = (size_t)(m0 + half*64 + row)*DD + n0 + cc4;
            float4 v = *(const float4*)&LDSf[row*128 + cc4];
            float vv[4] = {v.x, v.y, v.z, v.w};
            if(mode==0){
                *(float4*)(g.C + o) = v;
            } else if(mode==4){
                u16x4 h4;
                #pragma unroll
                for(int j=0;j<4;j++) h4[j] = f2b(vv[j]);
                *(u16x4*)(g.Oh + o) = h4;
            } else if(mode==1){
                u16x4 h4, lo4;
                #pragma unroll
                for(int j=0;j<4;j++){
                    u16 hh = f2b(vv[j]); h4[j]=hh; lo4[j]=f2b(vv[j]-b2f(hh));
                }
                *(u16x4*)(g.Oh + o) = h4;
                *(u16x4*)(g.Ol + o) = lo4;
            } else if(mode==2){
                float4 x = *(const float4*)(g.X + o);
                float xx[4] = {x.x, x.y, x.z, x.w};
                float4 w;
                float* ww = (float*)&w;
                #pragma unroll
                for(int j=0;j<4;j++) ww[j] = 0.5f*(gg*vv[j] + (1.f-gg)*xx[j]);
                *(float4*)(g.Xacc + o) = w;
            } else {
                float4 x = *(const float4*)(g.X + o);
                float4 xa = *(const float4*)(g.Xacc + o);
                float xx[4] = {x.x, x.y, x.z, x.w};
                float aa[4] = {xa.x, xa.y, xa.z, xa.w};
                float4 cv;
                float* cvv = (float*)&cv;
                u16x4 h4, lo4;
                #pragma unroll
                for(int j=0;j<4;j++){
                    float v3 = aa[j] + 0.5f*(gg*vv[j] + (1.f-gg)*xx[j]);
                    v3 = v3 > 0.f ? v3 : 0.f;
                    cvv[j] = v3;
                    u16 hh = f2b(v3); h4[j]=hh; lo4[j]=f2b(v3-b2f(hh));
                }
                *(float4*)(g.C + o) = cv;
                *(u16x4*)(g.Oh + o) = h4;
                *(u16x4*)(g.Ol + o) = lo4;
            }
        }
    }
}

// ---------- combine ----------
__global__ void combine_all(const float* __restrict__ Wk, const float* __restrict__ Wv,
                            const float* __restrict__ Ra, const float* __restrict__ Rm,
                            float* __restrict__ wtk, float* __restrict__ wtv){
    const int st_tab[2][4] = {{0,1,0,0},{0,0,1,0}};
    int combo = blockIdx.y;
    int idx = combo >> 1, kv = combo & 1;
    int r = idx & 3, wb = idx >> 2, dir = wb & 1;
    int st = st_tab[dir][r];
    const float* W = (kv ? Wv : Wk) + (size_t)(wb*2 + st)*65536;
    const float* R = (kv ? Rm : Ra) + (size_t)idx*16384;
    float* o = (kv ? wtv : wtk) + (size_t)idx*65536;
    int d = blockIdx.x, c = threadIdx.x;
    int h = c >> 6, f = c & 63;
    const float* Wrow = W + d*DD + h*64;
    const float* Rh = R + h*4096 + f;
    float s = 0.f;
    #pragma unroll 8
    for(int k=0;k<64;k++) s += Wrow[k]*Rh[k*64];
    o[d*DD + c] = s;
}

// ---------------- CSR build (both directions in one pass) ----------------
__device__ inline void edge_decode(int e, int& r, int& el){
    if(e < EC){ r=0; el=e; }
    else if(e < EC+EI){ r=1; el=e-EC; }
    else if(e < EC+EI+EO){ r=2; el=e-(EC+EI); }
    else { r=3; el=e-(EC+EI+EO); }
}

struct CB2 {
    const int* row[8]; const int* col[8];
    int dt[8]; int st[8];
    uint32_t* cnt; uint32_t* rowptr; uint32_t* einfo;
};

__global__ void csr_hist2(CB2 a){
    int ge = blockIdx.x*256 + threadIdx.x;
    if(ge >= 2*EHGT) return;
    int dir = ge >= EHGT;
    int e = ge - dir*EHGT;
    int r, el; edge_decode(e, r, el);
    int idx = dir*4 + r;
    int c = a.col[idx][el];
    int dst = dir*NROW + (a.dt[idx] ? (NI + c) : c);
    atomicAdd(&a.cnt[dst], 1u);
}

__global__ __launch_bounds__(1024) void scan_rowptr2(uint32_t* cnt, uint32_t* rowptr){
    __shared__ uint32_t part[1024];
    int t = threadIdx.x;
    int base = t*24;
    uint32_t lpre[24];
    uint32_t sum = 0;
    #pragma unroll
    for(int i=0;i<24;i++){
        uint32_t c = cnt[base+i];
        lpre[i] = sum; sum += c;
        cnt[base+i] = 0;
    }
    part[t] = sum;
    __syncthreads();
    for(int offs=1; offs<1024; offs<<=1){
        uint32_t v = (t>=offs) ? part[t-offs] : 0u;
        __syncthreads();
        part[t] += v;
        __syncthreads();
    }
    uint32_t pre = (t==0) ? 0u : part[t-1];
    #pragma unroll
    for(int i=0;i<24;i++) rowptr[base+i] = pre + lpre[i];
    if(t==1023) rowptr[2*NROW] = part[1023];
}

__global__ void csr_scatter2(CB2 a){
    int ge = blockIdx.x*256 + threadIdx.x;
    if(ge >= 2*EHGT) return;
    int dir = ge >= EHGT;
    int e = ge - dir*EHGT;
    int r, el; edge_decode(e, r, el);
    int idx = dir*4 + r;
    int c = a.col[idx][el];
    int dst = dir*NROW + (a.dt[idx] ? (NI + c) : c);
    int src = a.row[idx][el];
    uint32_t p = a.rowptr[dst] + atomicAdd(&a.cnt[dst], 1u);
    uint32_t vmidx = (uint32_t)(r*NI + src);
    uint32_t hom = a.st[idx] ? (uint32_t)(NI + src) : (uint32_t)src;
    a.einfo[p] = vmidx | (hom << 16);
}

// ---------------- fused HGT edge phase: wave per dst, all 4 heads, online softmax ----------------
// ka/vm stored as plain bf16 (u16); per-lane uint2 load = 4 elems.
__global__ __launch_bounds__(256) void hgt_fused(const uint32_t* __restrict__ rowptr,
                                                 const uint32_t* __restrict__ einfo,
                                                 const float* __restrict__ q_i,
                                                 const float* __restrict__ q_d,
                                                 const u16* __restrict__ ka,
                                                 const u16* __restrict__ vm,
                                                 const float* __restrict__ prel,
                                                 u16* __restrict__ bagg_h,
                                                 u16* __restrict__ bagg_l){
    int wv = threadIdx.x >> 6, lane = threadIdx.x & 63;
    int rowi = blockIdx.x*4 + wv;
    uint32_t p0 = rowptr[rowi], p1 = rowptr[rowi+1];
    int h = lane >> 4;
    const float* qrow = (rowi < NI) ? (q_i + (size_t)rowi*DD) : (q_d + (size_t)(rowi-NI)*DD);
    float4 q4 = *(const float4*)(qrow + lane*4);
    float pr0 = prel[0*HH+h]*0.125f, pr1 = prel[1*HH+h]*0.125f;
    float pr2 = prel[2*HH+h]*0.125f, pr3 = prel[3*HH+h]*0.125f;
    float m = -INFINITY, den = 0.f;
    float4 o4 = {0.f,0.f,0.f,0.f};
    for(uint32_t p = p0; p < p1; p++){
        uint32_t vmidx = einfo[p] & 0xffffu;
        int r = vmidx >> 13;
        uint2 kr = *(const uint2*)(ka + (size_t)vmidx*DD + lane*4);
        uint2 vr = *(const uint2*)(vm + (size_t)vmidx*DD + lane*4);
        float k0 = __uint_as_float(kr.x << 16), k1 = __uint_as_float(kr.x & 0xffff0000u);
        float k2 = __uint_as_float(kr.y << 16), k3 = __uint_as_float(kr.y & 0xffff0000u);
        float v0 = __uint_as_float(vr.x << 16), v1 = __uint_as_float(vr.x & 0xffff0000u);
        float v2 = __uint_as_float(vr.y << 16), v3 = __uint_as_float(vr.y & 0xffff0000u);
        float d = q4.x*k0 + q4.y*k1 + q4.z*k2 + q4.w*k3;
        d += __shfl_xor(d, 1); d += __shfl_xor(d, 2);
        d += __shfl_xor(d, 4); d += __shfl_xor(d, 8);
        float pf = (r==0) ? pr0 : (r==1) ? pr1 : (r==2) ? pr2 : pr3;
        float s = d * pf;
        float nm = fmaxf(m, s);
        float sc_ = expf(m - nm);
        float pe = expf(s - nm);
        den = den*sc_ + pe;
        o4.x = o4.x*sc_ + pe*v0;
        o4.y = o4.y*sc_ + pe*v1;
        o4.z = o4.z*sc_ + pe*v2;
        o4.w = o4.w*sc_ + pe*v3;
        m = nm;
    }
    float inv = 1.f/(den + 1e-16f);
    float vals[4] = {o4.x*inv, o4.y*inv, o4.z*inv, o4.w*inv};
    u16x4 h4, l4;
    #pragma unroll
    for(int j=0;j<4;j++){
        float g = gelu_f(vals[j]);
        u16 hh = f2b(g);
        h4[j] = hh;
        l4[j] = f2b(g - b2f(hh));
    }
    size_t ob = (size_t)rowi*DD + lane*4;
    *(u16x4*)(bagg_h + ob) = h4;
    *(u16x4*)(bagg_l + ob) = l4;
}

// ---------------- pooling ----------------
__global__ void pool_h2(const float* __restrict__ xi, const float* __restrict__ xd,
                        const float* __restrict__ w, float* __restrict__ h){
    int node = blockIdx.x*4 + (threadIdx.x>>6);
    int lane = threadIdx.x & 63;
    const float* xr = (node < NI) ? (xi + (size_t)node*DD) : (xd + (size_t)(node-NI)*DD);
    float s = 0.f;
    for(int j=lane;j<DD;j+=64) s += xr[j]*w[j];
    for(int m=32;m;m>>=1) s += __shfl_xor(s, m);
    if(lane==0) h[node] = s;
}

// GAT-style pooling score via fwd CSR + implicit self-loop; wave per dst node
__global__ __launch_bounds__(256) void pool_csr(const uint32_t* __restrict__ rowptr,
                                                const uint32_t* __restrict__ einfo,
                                                const float* __restrict__ h,
                                                const float* __restrict__ att,
                                                float* __restrict__ score){
    int w = blockIdx.x*4 + (threadIdx.x >> 6);
    int lane = threadIdx.x & 63;
    if(w >= NROW) return;
    uint32_t p0 = rowptr[w], p1 = rowptr[w+1];
    float a0 = att[0], a1 = att[1];
    float hn = h[w];
    float es = a0*hn + a1*hn;
    es = es >= 0.f ? es : 0.2f*es;
    float m = -INFINITY;
    for(uint32_t p = p0+lane; p < p1; p += 64){
        float hs = h[einfo[p] >> 16];
        float e = a0*hs + a1*hn;
        e = e >= 0.f ? e : 0.2f*e;
        m = fmaxf(m, e);
    }
    #pragma unroll
    for(int s=32;s;s>>=1) m = fmaxf(m, __shfl_xor(m, s));
    m = fmaxf(m, es);
    float lden = 0.f, lnum = 0.f;
    for(uint32_t p = p0+lane; p < p1; p += 64){
        float hs = h[einfo[p] >> 16];
        float e = a0*hs + a1*hn;
        e = e >= 0.f ? e : 0.2f*e;
        float a = expf(e - m);
        lden += a; lnum += a*hs;
    }
    #pragma unroll
    for(int s=32;s;s>>=1){ lden += __shfl_xor(lden, s); lnum += __shfl_xor(lnum, s); }
    float aself = expf(es - m);
    lden += aself; lnum += aself*hn;
    if(lane==0) score[w] = lnum/(lden + 1e-16f);
}

// top-768 of 1536 per graph via bitonic sort
__global__ __launch_bounds__(512) void topk_kernel(const float* __restrict__ score,
                                                   const float* __restrict__ bias,
                                                   int* __restrict__ sel_node,
                                                   float* __restrict__ sel_scale){
    __shared__ float skey[2048];
    __shared__ int   sval[2048];
    int b = blockIdx.x;
    float bv = bias[0];
    for(int p=threadIdx.x;p<2048;p+=512){
        if(p<1536){
            int node = (p<1024) ? (b*1024 + p) : (NI + b*512 + (p-1024));
            skey[p] = score[node] + bv;
            sval[p] = node;
        } else {
            skey[p] = -INFINITY;
            sval[p] = -1;
        }
    }
    for(int k=2;k<=2048;k<<=1){
        for(int j=k>>1;j>0;j>>=1){
            __syncthreads();
            for(int i=threadIdx.x;i<2048;i+=512){
                int ixj = i^j;
                if(ixj > i){
                    bool up = ((i & k) == 0);
                    float ki = skey[i], kj = skey[ixj];
                    if((ki < kj) == up){
                        skey[i]=kj; skey[ixj]=ki;
                        int t=sval[i]; sval[i]=sval[ixj]; sval[ixj]=t;
                    }
                }
            }
        }
    }
    __syncthreads();
    for(int j=threadIdx.x;j<KPOOL;j+=512){
        sel_node[b*KPOOL + j] = sval[j];
        sel_scale[b*KPOOL + j] = tanhf(skey[j]);
    }
}

__global__ void gather_xp(const int* __restrict__ sel, const float* __restrict__ scale,
                          const float* __restrict__ xi, const float* __restrict__ xd,
                          float* __restrict__ xp, u16* __restrict__ bh, u16* __restrict__ bl){
    int i = blockIdx.x*256 + threadIdx.x;
    int rowp = i >> 8, c = i & 255;
    int node = sel[rowp];
    float s = scale[rowp];
    float v = (node < NI) ? xi[(size_t)node*DD + c] : xd[(size_t)(node-NI)*DD + c];
    float x = v*s;
    xp[i] = x;
    u16 hh = f2b(x);
    bh[i] = hh;
    bl[i] = f2b(x - b2f(hh));
}

// ---------------- MFMA flash attention: block per (b,h,64 q rows), pre-split inputs ----------------
__global__ __launch_bounds__(256) void attn_mfma(const u16* __restrict__ Qh, const u16* __restrict__ Ql,
                                                 const u16* __restrict__ Kh, const u16* __restrict__ Kl,
                                                 const u16* __restrict__ Vh,
                                                 u16* __restrict__ aoh, u16* __restrict__ aol){
    __shared__ u16 KhS[64*64], KlS[64*64], VtS[64*64];
    char* KhB = (char*)KhS; char* KlB = (char*)KlS; char* VtB = (char*)VtS;
    int bh = blockIdx.y;
    int b = bh >> 2, h = bh & 3;
    int q0 = blockIdx.x * 64;
    int tid = threadIdx.x;
    int lane = tid & 63;
    int w = tid >> 6;
    int l15 = lane & 15, l4 = lane >> 4;
    size_t qrow = (size_t)(b*KPOOL + q0 + w*16 + l15);
    bf16x8 qh[2], ql[2];
    #pragma unroll
    for(int c=0;c<2;c++){
        qh[c] = *(const bf16x8*)(Qh + qrow*DD + h*64 + c*32 + l4*8);
        ql[c] = *(const bf16x8*)(Ql + qrow*DD + h*64 + c*32 + l4*8);
    }
    float mreg = -INFINITY, lreg = 0.f;
    f32x4 O[4] = {};
    for(int k0=0;k0<KPOOL;k0+=64){
        __syncthreads();
        {   // stage K hi/lo + V^T from pre-split bf16
            int row = tid >> 2, q4 = tid & 3;
            size_t gbase = ((size_t)(b*KPOOL + k0 + row))*DD + h*64 + q4*16;
            bf16x8 k0v = *(const bf16x8*)(Kh + gbase);
            bf16x8 k1v = *(const bf16x8*)(Kh + gbase + 8);
            bf16x8 kl0 = *(const bf16x8*)(Kl + gbase);
            bf16x8 kl1 = *(const bf16x8*)(Kl + gbase + 8);
            bf16x8 v0v = *(const bf16x8*)(Vh + gbase);
            bf16x8 v1v = *(const bf16x8*)(Vh + gbase + 8);
            int sw = (row&7)<<4;
            int colb = q4*32;
            *(bf16x8*)(KhB + row*128 + (colb ^ sw))        = k0v;
            *(bf16x8*)(KhB + row*128 + ((colb+16) ^ sw))   = k1v;
            *(bf16x8*)(KlB + row*128 + (colb ^ sw))        = kl0;
            *(bf16x8*)(KlB + row*128 + ((colb+16) ^ sw))   = kl1;
            #pragma unroll
            for(int j=0;j<8;j++){
                int dh0 = q4*16 + j;
                int dh1 = q4*16 + 8 + j;
                *(u16*)(VtB + dh0*128 + ((row*2) ^ ((dh0&7)<<4))) = (u16)(short)v0v[j];
                *(u16*)(VtB + dh1*128 + ((row*2) ^ ((dh1&7)<<4))) = (u16)(short)v1v[j];
            }
        }
        __syncthreads();
        // S^T tiles: mfma(A=K, B=Q)
        f32x4 s[4] = {};
        #pragma unroll
        for(int t=0;t<4;t++){
            int arow = t*16 + l15;
            int sw = (arow&7)<<4;
            const char* bh_ = KhB + arow*128;
            const char* bl_ = KlB + arow*128;
            bf16x8 kh0 = *(const bf16x8*)(bh_ + ((l4*16) ^ sw));
            bf16x8 kh1 = *(const bf16x8*)(bh_ + ((l4*16 + 64) ^ sw));
            bf16x8 kl0 = *(const bf16x8*)(bl_ + ((l4*16) ^ sw));
            bf16x8 kl1 = *(const bf16x8*)(bl_ + ((l4*16 + 64) ^ sw));
            s[t] = __builtin_amdgcn_mfma_f32_16x16x32_bf16(kh0, qh[0], s[t], 0,0,0);
            s[t] = __builtin_amdgcn_mfma_f32_16x16x32_bf16(kh1, qh[1], s[t], 0,0,0);
            s[t] = __builtin_amdgcn_mfma_f32_16x16x32_bf16(kh0, ql[0], s[t], 0,0,0);
            s[t] = __builtin_amdgcn_mfma_f32_16x16x32_bf16(kh1, ql[1], s[t], 0,0,0);
            s[t] = __builtin_amdgcn_mfma_f32_16x16x32_bf16(kl0, qh[0], s[t], 0,0,0);
            s[t] = __builtin_amdgcn_mfma_f32_16x16x32_bf16(kl1, qh[1], s[t], 0,0,0);
        }
        // online softmax
        float cm = -INFINITY;
        #pragma unroll
        for(int t=0;t<4;t++)
            #pragma unroll
            for(int r=0;r<4;r++){ s[t][r] *= 0.125f; cm = fmaxf(cm, s[t][r]); }
        cm = fmaxf(cm, __shfl_xor(cm,16));
        cm = fmaxf(cm, __shfl_xor(cm,32));
        float nm = fmaxf(mreg, cm);
        float es = expf(mreg - nm);
        float ps = 0.f;
        #pragma unroll
        for(int t=0;t<4;t++)
            #pragma unroll
            for(int r=0;r<4;r++){ float pv = expf(s[t][r] - nm); s[t][r] = pv; ps += pv; }
        ps += __shfl_xor(ps,16);
        ps += __shfl_xor(ps,32);
        lreg = lreg*es + ps;
        mreg = nm;
        #pragma unroll
        for(int d=0;d<4;d++){ O[d][0]*=es; O[d][1]*=es; O[d][2]*=es; O[d][3]*=es; }
        // O^T += mfma(A=V^T, B=P^T)
        #pragma unroll
        for(int c32=0;c32<2;c32++){
            bf16x8 pb;
            #pragma unroll
            for(int j=0;j<8;j++){
                int srcl = ((((lane>>4)*2 + (j>>2)) & 3) << 4) | l15;
                float v0 = __shfl(s[c32*2+0][j&3], srcl, 64);
                float v1 = __shfl(s[c32*2+1][j&3], srcl, 64);
                float v = (lane < 32) ? v0 : v1;
                pb[j] = (short)f2b(v);
            }
            #pragma unroll
            for(int dhb=0; dhb<4; dhb++){
                int vrow = dhb*16 + l15;
                bf16x8 va = *(const bf16x8*)(VtB + vrow*128 + ((c32*64 + l4*16) ^ ((vrow&7)<<4)));
                O[dhb] = __builtin_amdgcn_mfma_f32_16x16x32_bf16(va, pb, O[dhb], 0,0,0);
            }
        }
    }
    float inv = 1.f/lreg;
    #pragma unroll
    for(int dhb=0;dhb<4;dhb++)
        #pragma unroll
        for(int r=0;r<4;r++){
            float val = O[dhb][r]*inv;
            size_t o = qrow*DD + h*64 + dhb*16 + l4*4 + r;
            u16 hh = f2b(val);
            aoh[o] = hh;
            aol[o] = f2b(val - b2f(hh));
        }
}

// layernorm row kernel
__global__ __launch_bounds__(256) void ln_kernel(const float* __restrict__ xp, const float* __restrict__ o2,
                                                 const float* __restrict__ lg, const float* __restrict__ lb,
                                                 float* __restrict__ gatt){
    __shared__ float red[256];
    int r = blockIdx.x, c = threadIdx.x;
    float y = xp[(size_t)r*DD + c] + o2[(size_t)r*DD + c];
    red[c] = y; __syncthreads();
    for(int s=128;s;s>>=1){ if(c<s) red[c] += red[c+s]; __syncthreads(); }
    float mu = red[0]*(1.f/DD);
    __syncthreads();
    float d = y - mu;
    red[c] = d*d; __syncthreads();
    for(int s=128;s;s>>=1){ if(c<s) red[c] += red[c+s]; __syncthreads(); }
    float var = red[0]*(1.f/DD);
    gatt[(size_t)r*DD + c] = lg[c]*d/sqrtf(var+1e-5f) + lb[c];
}

__global__ void feat_reduce2(const float* __restrict__ xp, const float* __restrict__ gatt,
                             float* __restrict__ out){
    int b = blockIdx.x, c = threadIdx.x;
    int j0 = blockIdx.y*64;
    float s1=0.f, s2=0.f;
    for(int j=j0;j<j0+64;j++){
        size_t base = ((size_t)(b*KPOOL + j))*DD + c;
        s1 += xp[base];
        s2 += gatt[base];
    }
    atomicAdd(&out[b*512 + c], s1);
    atomicAdd(&out[b*512 + 256 + c], s2);
}

__global__ void cosine_kernel(const float* __restrict__ u, const float* __restrict__ v,
                              float* __restrict__ out){
    int b = blockIdx.x, t = threadIdx.x;
    float du=0.f, nu=0.f, nv=0.f;
    for(int j=t;j<512;j+=64){
        float a = u[b*512+j], bb = v[b*512+j];
        du += a*bb; nu += a*a; nv += bb*bb;
    }
    for(int m=32;m;m>>=1){
        du += __shfl_xor(du,m); nu += __shfl_xor(nu,m); nv += __shfl_xor(nv,m);
    }
    if(t==0) out[b] = du / (fmaxf(sqrtf(nu),1e-8f)*fmaxf(sqrtf(nv),1e-8f));
}

// =======================================================================
extern "C" void kernel_launch(void* const* d_in, const int* in_sizes, int n_in,
                              void* d_out, int out_size, void* d_ws, size_t ws_size,
                              hipStream_t stream){
    (void)in_sizes; (void)n_in; (void)out_size; (void)ws_size;
    const float* hgt_Wk   = (const float*)d_in[12];
    const float* hgt_Wq   = (const float*)d_in[13];
    const float* hgt_Wv   = (const float*)d_in[14];
    const float* hgt_Wo   = (const float*)d_in[15];
    const float* hgt_arel = (const float*)d_in[16];
    const float* hgt_mrel = (const float*)d_in[17];
    const float* hgt_prel = (const float*)d_in[18];
    const float* hgt_skip = (const float*)d_in[19];
    const float* pool_W   = (const float*)d_in[20];
    const float* pool_att = (const float*)d_in[21];
    const float* pool_bias= (const float*)d_in[22];
    const float* t_wq     = (const float*)d_in[23];
    const float* t_wk     = (const float*)d_in[24];
    const float* t_wv     = (const float*)d_in[25];
    const float* t_wo     = (const float*)d_in[26];
    const float* ln_g     = (const float*)d_in[27];
    const float* ln_b     = (const float*)d_in[28];
    float* out = (float*)d_out;

    char* base = (char*)d_ws;
    size_t off = 0;
    auto allocb = [&](size_t nbytes)->void*{
        void* p = (void*)(base + off);
        off += ((nbytes + 255) & ~(size_t)255);
        return p;
    };
    const size_t MAT = 65536;
    // ---- persistent ----
    u16* bwtk_h = (u16*)allocb(16*MAT*2); u16* bwtk_l = (u16*)allocb(16*MAT*2);
    u16* bwtv_h = (u16*)allocb(16*MAT*2); u16* bwtv_l = (u16*)allocb(16*MAT*2);
    u16* bwq_h  = (u16*)allocb(8*MAT*2);  u16* bwq_l  = (u16*)allocb(8*MAT*2);
    u16* bwo_h  = (u16*)allocb(8*MAT*2);  u16* bwo_l  = (u16*)allocb(8*MAT*2);
    u16* btw_h  = (u16*)allocb(4*MAT*2);  u16* btw_l  = (u16*)allocb(4*MAT*2);
    float* ubuf = (float*)allocb(BB*512*4);
    float* vbuf = (float*)allocb(BB*512*4);
    float* xa_i = (float*)allocb((size_t)NI*DD*4);
    float* xa_d = (float*)allocb((size_t)ND*DD*4);
    float* xb_i = (float*)allocb((size_t)NI*DD*4);
    float* xb_d = (float*)allocb((size_t)ND*DD*4);
    // ---- per-branch CSR ----
    uint32_t* ccnt   = (uint32_t*)allocb((size_t)2*NROW*4);
    uint32_t* rowptr = (uint32_t*)allocb((size_t)(2*NROW+1)*4);
    uint32_t* einfo  = (uint32_t*)allocb((size_t)2*EHGT*4);
    size_t region = off;
    // ---- conv scratch ----
    float* q_i  = (float*)allocb((size_t)NI*DD*4);
    float* q_d  = (float*)allocb((size_t)ND*DD*4);
    u16* ka16 = (u16*)allocb((size_t)4*NI*DD*2);   // bf16 KA; also combine f32 temp (8.4MB < 16.8MB)
    u16* vm16 = (u16*)allocb((size_t)4*NI*DD*2);
    float* xacc_i= (float*)allocb((size_t)NI*DD*4);
    float* xacc_d= (float*)allocb((size_t)ND*DD*4);
    u16* bcur_h = (u16*)allocb((size_t)NROW*DD*2);
    u16* bcur_l = (u16*)allocb((size_t)NROW*DD*2);
    u16* bagg_h = (u16*)allocb((size_t)NROW*DD*2);
    u16* bagg_l = (u16*)allocb((size_t)NROW*DD*2);
    // ---- pooling/transformer overlay ----
    off = region;
    float* hvec = (float*)allocb(NROW*4);
    float* pscore = (float*)allocb(NROW*4);
    int* seln   = (int*)allocb(BB*KPOOL*4);
    float* sels = (float*)allocb(BB*KPOOL*4);
    float* xp   = (float*)allocb((size_t)BB*KPOOL*DD*4);
    float* o2   = (float*)allocb((size_t)BB*KPOOL*DD*4);
    float* gatt = (float*)allocb((size_t)BB*KPOOL*DD*4);
    u16* bxp_h = (u16*)allocb((size_t)BB*KPOOL*DD*2);
    u16* bxp_l = (u16*)allocb((size_t)BB*KPOOL*DD*2);
    u16* qbh = (u16*)allocb((size_t)BB*KPOOL*DD*2);
    u16* qbl = (u16*)allocb((size_t)BB*KPOOL*DD*2);
    u16* kbh = (u16*)allocb((size_t)BB*KPOOL*DD*2);
    u16* kbl = (u16*)allocb((size_t)BB*KPOOL*DD*2);
    u16* vbh = (u16*)allocb((size_t)BB*KPOOL*DD*2);
    u16* vbl = (u16*)allocb((size_t)BB*KPOOL*DD*2);
    u16* bao_h = (u16*)allocb((size_t)BB*KPOOL*DD*2);
    u16* bao_l = (u16*)allocb((size_t)BB*KPOOL*DD*2);

    const int st_tab[2][4] = {{0,1,0,0},{0,0,1,0}};
    const int dt_tab[2][4] = {{0,0,1,0},{0,1,0,0}};
    const int MR = BB*KPOOL;

    fill_u32<<<(2*BB*512+255)/256,256,0,stream>>>((uint32_t*)ubuf, 0u, 2*BB*512);
    float* wtkF = (float*)ka16;
    float* wtvF = (float*)ka16 + 16*MAT;
    combine_all<<<dim3(256,32),256,0,stream>>>(hgt_Wk, hgt_Wv, hgt_arel, hgt_mrel, wtkF, wtvF);
    WCArgs wc;
    wc.in[0]=wtkF;   wc.oh[0]=bwtk_h; wc.ol[0]=bwtk_l; wc.cnt[0]=16;
    wc.in[1]=wtvF;   wc.oh[1]=bwtv_h; wc.ol[1]=bwtv_l; wc.cnt[1]=16;
    wc.in[2]=hgt_Wq; wc.oh[2]=bwq_h;  wc.ol[2]=bwq_l;  wc.cnt[2]=8;
    wc.in[3]=hgt_Wo; wc.oh[3]=bwo_h;  wc.ol[3]=bwo_l;  wc.cnt[3]=8;
    wc.in[4]=t_wq;   wc.oh[4]=btw_h;          wc.ol[4]=btw_l;          wc.cnt[4]=1;
    wc.in[5]=t_wk;   wc.oh[5]=btw_h+1*MAT;    wc.ol[5]=btw_l+1*MAT;    wc.cnt[5]=1;
    wc.in[6]=t_wv;   wc.oh[6]=btw_h+2*MAT;    wc.ol[6]=btw_l+2*MAT;    wc.cnt[6]=1;
    wc.in[7]=t_wo;   wc.oh[7]=btw_h+3*MAT;    wc.ol[7]=btw_l+3*MAT;    wc.cnt[7]=1;
    wc.nr = 8;
    wcvt_split<<<dim3(256,52),256,0,stream>>>(wc);

    for(int bi=0;bi<2;bi++){
        int ib = bi*6;
        const float* x_inst = (const float*)d_in[ib+0];
        const float* x_data = (const float*)d_in[ib+1];
        const int* ecp = (const int*)d_in[ib+2];
        const int* eip = (const int*)d_in[ib+3];
        const int* eop = (const int*)d_in[ib+4];
        const int* ekp = (const int*)d_in[ib+5];
        const int* rows_f[4] = {ecp, eip, eop, ekp};
        const int* cols_f[4] = {ecp+EC, eip+EI, eop+EO, ekp+EK};

        // ---- CSR build (both dirs, one pass) ----
        CB2 cb;
        for(int r=0;r<4;r++){
            cb.row[r]   = rows_f[r]; cb.col[r]   = cols_f[r]; cb.dt[r]   = dt_tab[0][r]; cb.st[r]   = st_tab[0][r];
            cb.row[4+r] = cols_f[r]; cb.col[4+r] = rows_f[r]; cb.dt[4+r] = dt_tab[1][r]; cb.st[4+r] = st_tab[1][r];
        }
        cb.cnt = ccnt; cb.rowptr = rowptr; cb.einfo = einfo;
        fill_u32<<<(2*NROW+255)/256,256,0,stream>>>(ccnt, 0u, 2*NROW);
        csr_hist2<<<(2*EHGT+255)/256,256,0,stream>>>(cb);
        scan_rowptr2<<<1,1024,0,stream>>>(ccnt, rowptr);
        csr_scatter2<<<(2*EHGT+255)/256,256,0,stream>>>(cb);

        const float* cur_i = x_inst;
        const float* cur_d = x_data;
        cvt_split<<<((NROW*DD/4)+255)/256,256,0,stream>>>(cur_i, NI*DD, cur_d, ND*DD, bcur_h, bcur_l);
        for(int l=0;l<LL;l++){
            float* nxt_i = (l==0) ? xa_i : xb_i;
            float* nxt_d = (l==0) ? xa_d : xb_d;
            for(int dir=0;dir<2;dir++){
                int wb = l*2 + dir;

                // --- mega GEMM: Q(2, f32) + KA(4, bf16) + VM(4, bf16) in one launch ---
                GArgs g1; int nb1 = 0, ndx = 0;
                auto addg = [&](int srctype, const u16* Bh, const u16* Bl, float* Cm, u16* Om, int M, int mode){
                    GDesc& d = g1.d[ndx];
                    size_t ao = srctype ? (size_t)NI*DD : 0;
                    d.Ah = bcur_h + ao; d.Al = bcur_l + ao;
                    d.Bh = Bh; d.Bl = Bl; d.C = Cm;
                    d.Oh = Om; d.Ol = nullptr; d.X = nullptr; d.Xacc = nullptr; d.skipp = nullptr;
                    d.mblks = M/128; d.mode = mode;
                    nb1 += M/128; ndx++;
                };
                addg(0, bwq_h + (size_t)(wb*2+0)*MAT, bwq_l + (size_t)(wb*2+0)*MAT, q_i, nullptr, NI, 0);
                addg(1, bwq_h + (size_t)(wb*2+1)*MAT, bwq_l + (size_t)(wb*2+1)*MAT, q_d, nullptr, ND, 0);
                for(int r=0;r<4;r++){
                    int st = st_tab[dir][r];
                    addg(st, bwtk_h + (size_t)(wb*4+r)*MAT, bwtk_l + (size_t)(wb*4+r)*MAT,
                         nullptr, ka16 + (size_t)r*NI*DD, st ? ND : NI, 4);
                }
                for(int r=0;r<4;r++){
                    int st = st_tab[dir][r];
                    addg(st, bwtv_h + (size_t)(wb*4+r)*MAT, bwtv_l + (size_t)(wb*4+r)*MAT,
                         nullptr, vm16 + (size_t)r*NI*DD, st ? ND : NI, 4);
                }
                g1.nd = ndx;
                gemm_mfma<<<dim3(nb1,2),256,0,stream>>>(g1);

                // --- fused edge phase: scores + online softmax + gather + gelu + split ---
                hgt_fused<<<NROW/4,256,0,stream>>>(rowptr + (size_t)dir*NROW, einfo,
                    q_i, q_d, ka16, vm16, hgt_prel + (size_t)wb*4*HH, bagg_h, bagg_l);

                // --- Wo GEMMs with fused skip/relu epilogue ---
                GArgs g3; g3.nd = 2;
                for(int t=0;t<2;t++){
                    GDesc& d = g3.d[t];
                    size_t ao = t ? (size_t)NI*DD : 0;
                    d.Ah = bagg_h + ao; d.Al = bagg_l + ao;
                    d.Bh = bwo_h + (size_t)(wb*2+t)*MAT; d.Bl = bwo_l + (size_t)(wb*2+t)*MAT;
                    d.C = t ? nxt_d : nxt_i;
                    d.Oh = bcur_h + ao; d.Ol = bcur_l + ao;
                    d.X = t ? cur_d : cur_i;
                    d.Xacc = t ? xacc_d : xacc_i;
                    d.skipp = hgt_skip + wb*2 + t;
                    d.mblks = (t ? ND : NI)/128;
                    d.mode = dir ? 3 : 2;
                }
                gemm_mfma<<<dim3(NI/128 + ND/128,2),256,0,stream>>>(g3);
            }
            cur_i = nxt_i;
            cur_d = nxt_d;
        }

        // -------- SAGPooling (CSR-based, no atomics) --------
        pool_h2<<<NROW/4,256,0,stream>>>(cur_i, cur_d, pool_W, hvec);
        pool_csr<<<NROW/4,256,0,stream>>>(rowptr, einfo, hvec, pool_att, pscore);
        topk_kernel<<<BB,512,0,stream>>>(pscore, pool_bias, seln, sels);
        gather_xp<<<BB*KPOOL,256,0,stream>>>(seln, sels, cur_i, cur_d, xp, bxp_h, bxp_l);

        // -------- transformer --------
        GArgs g4; g4.nd = 3;
        for(int t=0;t<3;t++){
            GDesc& d = g4.d[t];
            d.Ah=bxp_h; d.Al=bxp_l;
            d.Bh=btw_h + (size_t)t*MAT; d.Bl=btw_l + (size_t)t*MAT;
            d.C = nullptr;
            d.Oh = (t==0)? qbh : (t==1)? kbh : vbh;
            d.Ol = (t==0)? qbl : (t==1)? kbl : vbl;
            d.X = nullptr; d.Xacc = nullptr; d.skipp = nullptr;
            d.mblks = MR/128; d.mode = 1;
        }
        gemm_mfma<<<dim3(3*(MR/128),2),256,0,stream>>>(g4);
        attn_mfma<<<dim3(KPOOL/64, BB*HH),256,0,stream>>>(qbh, qbl, kbh, kbl, vbh, bao_h, bao_l);
        GArgs g5; g5.nd = 1;
        {
            GDesc& d = g5.d[0];
            d.Ah=bao_h; d.Al=bao_l;
            d.Bh=btw_h + (size_t)3*MAT; d.Bl=btw_l + (size_t)3*MAT;
            d.C=o2; d.Oh=nullptr; d.Ol=nullptr; d.X=nullptr; d.Xacc=nullptr; d.skipp=nullptr;
            d.mblks=MR/128; d.mode=0;
        }
        gemm_mfma<<<dim3(MR/128,2),256,0,stream>>>(g5);
        ln_kernel<<<MR,256,0,stream>>>(xp, o2, ln_g, ln_b, gatt);
        feat_reduce2<<<dim3(BB,12),256,0,stream>>>(xp, gatt, bi ? vbuf : ubuf);
    }

    cosine_kernel<<<BB,64,0,stream>>>(ubuf, vbuf, out);
}

// Round 15
// 1068.869 us; speedup vs baseline: 1.8194x; 1.1066x over previous
//
#include <hip/hip_runtime.h>
#include <math.h>
#include <stdint.h>

#define LL 2
#define HH 4
#define DHH 64
#define DD 256
#define BB 8
#define NI 8192
#define ND 4096
#define NROW 12288
#define KPOOL 768
#define EC 65536
#define EI 32768
#define EO 32768
#define EK 8192
#define EHGT (EC+EI+EO+EK)

typedef unsigned short u16;
typedef short bf16x8 __attribute__((ext_vector_type(8)));
typedef float f32x4 __attribute__((ext_vector_type(4)));
typedef unsigned short u16x4 __attribute__((ext_vector_type(4)));

__device__ inline float gelu_f(float x){ return 0.5f*x*(1.f+erff(x*0.70710678118654752f)); }
__device__ inline u16 f2b(float x){ uint32_t u=__float_as_uint(x); return (u16)((u + 0x7fffu + ((u>>16)&1u))>>16); }
__device__ inline float b2f(u16 h){ return __uint_as_float(((uint32_t)h)<<16); }

// ---------------- generic fill ----------------
__global__ void fill_u32(uint32_t* p, uint32_t v, int n){
    int i = blockIdx.x*256 + threadIdx.x;
    if(i<n) p[i]=v;
}

// ---------------- activation split-convert ----------------
__global__ void cvt_split(const float* __restrict__ A, int nA, const float* __restrict__ B, int nB,
                          u16* __restrict__ oh, u16* __restrict__ ol){
    int i = (blockIdx.x*256 + threadIdx.x)*4;
    int tot = nA + nB;
    if(i >= tot) return;
    float4 v = (i < nA) ? *(const float4*)(A + i) : *(const float4*)(B + (i - nA));
    float vv[4] = {v.x, v.y, v.z, v.w};
    u16x4 h4, l4;
    #pragma unroll
    for(int j=0;j<4;j++){
        float x = vv[j];
        u16 h = f2b(x);
        h4[j] = h;
        l4[j] = f2b(x - b2f(h));
    }
    *(u16x4*)(oh + i) = h4;
    *(u16x4*)(ol + i) = l4;
}

// ---------------- weight transpose + split ----------------
struct WCArgs { const float* in[8]; u16* oh[8]; u16* ol[8]; int cnt[8]; int nr; };
__global__ void wcvt_split(WCArgs a){
    int mat = blockIdx.y, ri = 0;
    while(ri < a.nr-1 && mat >= a.cnt[ri]){ mat -= a.cnt[ri]; ri++; }
    const float* in = a.in[ri] + (size_t)mat*65536;
    u16* oh = a.oh[ri] + (size_t)mat*65536;
    u16* ol = a.ol[ri] + (size_t)mat*65536;
    int n = blockIdx.x, k = threadIdx.x;
    float x = in[(size_t)k*DD + n];
    u16 h = f2b(x);
    oh[n*DD + k] = h;
    ol[n*DD + k] = f2b(x - b2f(h));
}

// ---------------- MFMA batched GEMM with fused, LDS-restaged epilogues ----------------
// prec=0: split hi/lo (3 MFMA/step); prec=1: hi-only (1 MFMA/step, half staging)
// mode 0: C=f32   mode 1: Oh/Ol=split bf16   mode 4: Oh=plain bf16
// mode 2: Xacc = 0.5*(g*acc + (1-g)*X)
// mode 3: v=relu(Xacc + 0.5*(g*acc+(1-g)*X)); C=v; Oh/Ol=split(v)
struct GDesc { const u16* Ah; const u16* Al; const u16* Bh; const u16* Bl;
               float* C; u16* Oh; u16* Ol;
               const float* X; float* Xacc; const float* skipp;
               int mblks; int mode; int prec; };
struct GArgs { GDesc d[10]; int nd; };

__global__ __launch_bounds__(256) void gemm_mfma(GArgs ga){
    __shared__ u16 SBUF[2*128*64];
    char* Abuf = (char*)SBUF;
    char* Bbuf = (char*)(SBUF + 128*64);
    int mb = blockIdx.x, di = 0;
    while(di < ga.nd-1 && mb >= ga.d[di].mblks){ mb -= ga.d[di].mblks; di++; }
    GDesc g = ga.d[di];
    const int prec = g.prec;
    const int m0 = mb*128, n0 = blockIdx.y*128;
    const int tid = threadIdx.x;
    const int lane = tid & 63, wid = tid >> 6;
    const int wm = (wid>>1)*64, wn = (wid&1)*64;
    const int l15 = lane & 15, l4 = lane >> 4;
    const int srow = tid >> 1, hf = tid & 1;
    const int ssw = (srow&7)<<4;
    const int c0 = (hf*32) ^ ssw;
    const int c1 = (hf*32+16) ^ ssw;
    const int c2 = (64+hf*32) ^ ssw;
    const int c3 = (64+hf*32+16) ^ ssw;
    const int rbyte = srow*128;
    const u16* __restrict__ Aph = g.Ah + (size_t)(m0 + srow)*DD + hf*16;
    const u16* __restrict__ Apl = g.Al + (size_t)(m0 + srow)*DD + hf*16;
    const u16* __restrict__ Bph = g.Bh + (size_t)(n0 + srow)*DD + hf*16;
    const u16* __restrict__ Bpl = g.Bl + (size_t)(n0 + srow)*DD + hf*16;
    f32x4 acc[4][4] = {};
    bf16x8 r0, r1, r2, r3, r4, r5, r6, r7;
    r0 = *(const bf16x8*)(Aph);
    r1 = *(const bf16x8*)(Aph + 8);
    r4 = *(const bf16x8*)(Bph);
    r5 = *(const bf16x8*)(Bph + 8);
    if(!prec){
        r2 = *(const bf16x8*)(Apl);
        r3 = *(const bf16x8*)(Apl + 8);
        r6 = *(const bf16x8*)(Bpl);
        r7 = *(const bf16x8*)(Bpl + 8);
    }
    #pragma unroll
    for(int k0=0;k0<DD;k0+=32){
        __syncthreads();
        *(bf16x8*)(Abuf + rbyte + c0) = r0; *(bf16x8*)(Abuf + rbyte + c1) = r1;
        *(bf16x8*)(Bbuf + rbyte + c0) = r4; *(bf16x8*)(Bbuf + rbyte + c1) = r5;
        if(!prec){
            *(bf16x8*)(Abuf + rbyte + c2) = r2; *(bf16x8*)(Abuf + rbyte + c3) = r3;
            *(bf16x8*)(Bbuf + rbyte + c2) = r6; *(bf16x8*)(Bbuf + rbyte + c3) = r7;
        }
        __syncthreads();
        if(k0 + 32 < DD){
            int kn = k0 + 32;
            r0 = *(const bf16x8*)(Aph + kn);     r1 = *(const bf16x8*)(Aph + kn + 8);
            r4 = *(const bf16x8*)(Bph + kn);     r5 = *(const bf16x8*)(Bph + kn + 8);
            if(!prec){
                r2 = *(const bf16x8*)(Apl + kn); r3 = *(const bf16x8*)(Apl + kn + 8);
                r6 = *(const bf16x8*)(Bpl + kn); r7 = *(const bf16x8*)(Bpl + kn + 8);
            }
        }
        bf16x8 afh[4], bfh[4];
        #pragma unroll
        for(int i=0;i<4;i++){
            int ar = wm + i*16 + l15;
            int abase = ar*128;
            afh[i] = *(const bf16x8*)(Abuf + abase + ((l4*16) ^ ((ar&7)<<4)));
            int br = wn + i*16 + l15;
            int bbase = br*128;
            bfh[i] = *(const bf16x8*)(Bbuf + bbase + ((l4*16) ^ ((br&7)<<4)));
        }
        #pragma unroll
        for(int i=0;i<4;i++)
            #pragma unroll
            for(int j=0;j<4;j++)
                acc[i][j] = __builtin_amdgcn_mfma_f32_16x16x32_bf16(afh[i], bfh[j], acc[i][j], 0,0,0);
        if(!prec){
            bf16x8 afl[4], bfl[4];
            #pragma unroll
            for(int i=0;i<4;i++){
                int ar = wm + i*16 + l15;
                int abase = ar*128;
                afl[i] = *(const bf16x8*)(Abuf + abase + ((64 + l4*16) ^ ((ar&7)<<4)));
                int br = wn + i*16 + l15;
                int bbase = br*128;
                bfl[i] = *(const bf16x8*)(Bbuf + bbase + ((64 + l4*16) ^ ((br&7)<<4)));
            }
            #pragma unroll
            for(int i=0;i<4;i++)
                #pragma unroll
                for(int j=0;j<4;j++){
                    acc[i][j] = __builtin_amdgcn_mfma_f32_16x16x32_bf16(afh[i], bfl[j], acc[i][j], 0,0,0);
                    acc[i][j] = __builtin_amdgcn_mfma_f32_16x16x32_bf16(afl[i], bfh[j], acc[i][j], 0,0,0);
                }
        }
    }
    // ---- coalesced epilogue via LDS restage (two 64-row passes) ----
    const int mode = g.mode;
    float gg = 0.f;
    if(mode == 2 || mode == 3) gg = 1.f/(1.f + expf(-*g.skipp));
    float* LDSf = (float*)SBUF;
    const int lrow = tid >> 5;
    const int cc4 = (tid & 31)*4;
    #pragma unroll
    for(int half=0; half<2; half++){
        __syncthreads();
        if((wid>>1) == half){
            #pragma unroll
            for(int i=0;i<4;i++)
                #pragma unroll
                for(int j=0;j<4;j++)
                    #pragma unroll
                    for(int r=0;r<4;r++)
                        LDSf[(i*16 + l4*4 + r)*128 + wn + j*16 + l15] = acc[i][j][r];
        }
        __syncthreads();
        #pragma unroll
        for(int k=0;k<8;k++){
            int row = lrow + k*8;
            size_t o = (size_t)(m0 + half*64 + row)*DD + n0 + cc4;
            float4 v = *(const float4*)&LDSf[row*128 + cc4];
            float vv[4] = {v.x, v.y, v.z, v.w};
            if(mode==0){
                *(float4*)(g.C + o) = v;
            } else if(mode==4){
                u16x4 h4;
                #pragma unroll
                for(int j=0;j<4;j++) h4[j] = f2b(vv[j]);
                *(u16x4*)(g.Oh + o) = h4;
            } else if(mode==1){
                u16x4 h4, lo4;
                #pragma unroll
                for(int j=0;j<4;j++){
                    u16 hh = f2b(vv[j]); h4[j]=hh; lo4[j]=f2b(vv[j]-b2f(hh));
                }
                *(u16x4*)(g.Oh + o) = h4;
                *(u16x4*)(g.Ol + o) = lo4;
            } else if(mode==2){
                float4 x = *(const float4*)(g.X + o);
                float xx[4] = {x.x, x.y, x.z, x.w};
                float4 w;
                float* ww = (float*)&w;
                #pragma unroll
                for(int j=0;j<4;j++) ww[j] = 0.5f*(gg*vv[j] + (1.f-gg)*xx[j]);
                *(float4*)(g.Xacc + o) = w;
            } else {
                float4 x = *(const float4*)(g.X + o);
                float4 xa = *(const float4*)(g.Xacc + o);
                float xx[4] = {x.x, x.y, x.z, x.w};
                float aa[4] = {xa.x, xa.y, xa.z, xa.w};
                float4 cv;
                float* cvv = (float*)&cv;
                u16x4 h4, lo4;
                #pragma unroll
                for(int j=0;j<4;j++){
                    float v3 = aa[j] + 0.5f*(gg*vv[j] + (1.f-gg)*xx[j]);
                    v3 = v3 > 0.f ? v3 : 0.f;
                    cvv[j] = v3;
                    u16 hh = f2b(v3); h4[j]=hh; lo4[j]=f2b(v3-b2f(hh));
                }
                *(float4*)(g.C + o) = cv;
                *(u16x4*)(g.Oh + o) = h4;
                *(u16x4*)(g.Ol + o) = lo4;
            }
        }
    }
}

// ---------- combine ----------
__global__ void combine_all(const float* __restrict__ Wk, const float* __restrict__ Wv,
                            const float* __restrict__ Ra, const float* __restrict__ Rm,
                            float* __restrict__ wtk, float* __restrict__ wtv){
    const int st_tab[2][4] = {{0,1,0,0},{0,0,1,0}};
    int combo = blockIdx.y;
    int idx = combo >> 1, kv = combo & 1;
    int r = idx & 3, wb = idx >> 2, dir = wb & 1;
    int st = st_tab[dir][r];
    const float* W = (kv ? Wv : Wk) + (size_t)(wb*2 + st)*65536;
    const float* R = (kv ? Rm : Ra) + (size_t)idx*16384;
    float* o = (kv ? wtv : wtk) + (size_t)idx*65536;
    int d = blockIdx.x, c = threadIdx.x;
    int h = c >> 6, f = c & 63;
    const float* Wrow = W + d*DD + h*64;
    const float* Rh = R + h*4096 + f;
    float s = 0.f;
    #pragma unroll 8
    for(int k=0;k<64;k++) s += Wrow[k]*Rh[k*64];
    o[d*DD + c] = s;
}

// ---------------- CSR build (both directions in one pass) ----------------
__device__ inline void edge_decode(int e, int& r, int& el){
    if(e < EC){ r=0; el=e; }
    else if(e < EC+EI){ r=1; el=e-EC; }
    else if(e < EC+EI+EO){ r=2; el=e-(EC+EI); }
    else { r=3; el=e-(EC+EI+EO); }
}

struct CB2 {
    const int* row[8]; const int* col[8];
    int dt[8]; int st[8];
    uint32_t* cnt; uint32_t* rowptr; uint32_t* einfo;
};

__global__ void csr_hist2(CB2 a){
    int ge = blockIdx.x*256 + threadIdx.x;
    if(ge >= 2*EHGT) return;
    int dir = ge >= EHGT;
    int e = ge - dir*EHGT;
    int r, el; edge_decode(e, r, el);
    int idx = dir*4 + r;
    int c = a.col[idx][el];
    int dst = dir*NROW + (a.dt[idx] ? (NI + c) : c);
    atomicAdd(&a.cnt[dst], 1u);
}

__global__ __launch_bounds__(1024) void scan_rowptr2(uint32_t* cnt, uint32_t* rowptr){
    __shared__ uint32_t part[1024];
    int t = threadIdx.x;
    int base = t*24;
    uint32_t lpre[24];
    uint32_t sum = 0;
    #pragma unroll
    for(int i=0;i<24;i++){
        uint32_t c = cnt[base+i];
        lpre[i] = sum; sum += c;
        cnt[base+i] = 0;
    }
    part[t] = sum;
    __syncthreads();
    for(int offs=1; offs<1024; offs<<=1){
        uint32_t v = (t>=offs) ? part[t-offs] : 0u;
        __syncthreads();
        part[t] += v;
        __syncthreads();
    }
    uint32_t pre = (t==0) ? 0u : part[t-1];
    #pragma unroll
    for(int i=0;i<24;i++) rowptr[base+i] = pre + lpre[i];
    if(t==1023) rowptr[2*NROW] = part[1023];
}

__global__ void csr_scatter2(CB2 a){
    int ge = blockIdx.x*256 + threadIdx.x;
    if(ge >= 2*EHGT) return;
    int dir = ge >= EHGT;
    int e = ge - dir*EHGT;
    int r, el; edge_decode(e, r, el);
    int idx = dir*4 + r;
    int c = a.col[idx][el];
    int dst = dir*NROW + (a.dt[idx] ? (NI + c) : c);
    int src = a.row[idx][el];
    uint32_t p = a.rowptr[dst] + atomicAdd(&a.cnt[dst], 1u);
    uint32_t vmidx = (uint32_t)(r*NI + src);
    uint32_t hom = a.st[idx] ? (uint32_t)(NI + src) : (uint32_t)src;
    a.einfo[p] = vmidx | (hom << 16);
}

// ---------------- fused HGT edge phase: wave per dst, all 4 heads, online softmax ----------------
__global__ __launch_bounds__(256) void hgt_fused(const uint32_t* __restrict__ rowptr,
                                                 const uint32_t* __restrict__ einfo,
                                                 const float* __restrict__ q_i,
                                                 const float* __restrict__ q_d,
                                                 const u16* __restrict__ ka,
                                                 const u16* __restrict__ vm,
                                                 const float* __restrict__ prel,
                                                 u16* __restrict__ bagg_h,
                                                 u16* __restrict__ bagg_l){
    int wv = threadIdx.x >> 6, lane = threadIdx.x & 63;
    int rowi = blockIdx.x*4 + wv;
    uint32_t p0 = rowptr[rowi], p1 = rowptr[rowi+1];
    int h = lane >> 4;
    const float* qrow = (rowi < NI) ? (q_i + (size_t)rowi*DD) : (q_d + (size_t)(rowi-NI)*DD);
    float4 q4 = *(const float4*)(qrow + lane*4);
    float pr0 = prel[0*HH+h]*0.125f, pr1 = prel[1*HH+h]*0.125f;
    float pr2 = prel[2*HH+h]*0.125f, pr3 = prel[3*HH+h]*0.125f;
    float m = -INFINITY, den = 0.f;
    float4 o4 = {0.f,0.f,0.f,0.f};
    for(uint32_t p = p0; p < p1; p++){
        uint32_t vmidx = einfo[p] & 0xffffu;
        int r = vmidx >> 13;
        uint2 kr = *(const uint2*)(ka + (size_t)vmidx*DD + lane*4);
        uint2 vr = *(const uint2*)(vm + (size_t)vmidx*DD + lane*4);
        float k0 = __uint_as_float(kr.x << 16), k1 = __uint_as_float(kr.x & 0xffff0000u);
        float k2 = __uint_as_float(kr.y << 16), k3 = __uint_as_float(kr.y & 0xffff0000u);
        float v0 = __uint_as_float(vr.x << 16), v1 = __uint_as_float(vr.x & 0xffff0000u);
        float v2 = __uint_as_float(vr.y << 16), v3 = __uint_as_float(vr.y & 0xffff0000u);
        float d = q4.x*k0 + q4.y*k1 + q4.z*k2 + q4.w*k3;
        d += __shfl_xor(d, 1); d += __shfl_xor(d, 2);
        d += __shfl_xor(d, 4); d += __shfl_xor(d, 8);
        float pf = (r==0) ? pr0 : (r==1) ? pr1 : (r==2) ? pr2 : pr3;
        float s = d * pf;
        float nm = fmaxf(m, s);
        float sc_ = expf(m - nm);
        float pe = expf(s - nm);
        den = den*sc_ + pe;
        o4.x = o4.x*sc_ + pe*v0;
        o4.y = o4.y*sc_ + pe*v1;
        o4.z = o4.z*sc_ + pe*v2;
        o4.w = o4.w*sc_ + pe*v3;
        m = nm;
    }
    float inv = 1.f/(den + 1e-16f);
    float vals[4] = {o4.x*inv, o4.y*inv, o4.z*inv, o4.w*inv};
    u16x4 h4, l4;
    #pragma unroll
    for(int j=0;j<4;j++){
        float g = gelu_f(vals[j]);
        u16 hh = f2b(g);
        h4[j] = hh;
        l4[j] = f2b(g - b2f(hh));
    }
    size_t ob = (size_t)rowi*DD + lane*4;
    *(u16x4*)(bagg_h + ob) = h4;
    *(u16x4*)(bagg_l + ob) = l4;
}

// ---------------- pooling ----------------
__global__ void pool_h2(const float* __restrict__ xi, const float* __restrict__ xd,
                        const float* __restrict__ w, float* __restrict__ h){
    int node = blockIdx.x*4 + (threadIdx.x>>6);
    int lane = threadIdx.x & 63;
    const float* xr = (node < NI) ? (xi + (size_t)node*DD) : (xd + (size_t)(node-NI)*DD);
    float s = 0.f;
    for(int j=lane;j<DD;j+=64) s += xr[j]*w[j];
    for(int m=32;m;m>>=1) s += __shfl_xor(s, m);
    if(lane==0) h[node] = s;
}

// GAT-style pooling score via fwd CSR + implicit self-loop; wave per dst node
__global__ __launch_bounds__(256) void pool_csr(const uint32_t* __restrict__ rowptr,
                                                const uint32_t* __restrict__ einfo,
                                                const float* __restrict__ h,
                                                const float* __restrict__ att,
                                                float* __restrict__ score){
    int w = blockIdx.x*4 + (threadIdx.x >> 6);
    int lane = threadIdx.x & 63;
    if(w >= NROW) return;
    uint32_t p0 = rowptr[w], p1 = rowptr[w+1];
    float a0 = att[0], a1 = att[1];
    float hn = h[w];
    float es = a0*hn + a1*hn;
    es = es >= 0.f ? es : 0.2f*es;
    float m = -INFINITY;
    for(uint32_t p = p0+lane; p < p1; p += 64){
        float hs = h[einfo[p] >> 16];
        float e = a0*hs + a1*hn;
        e = e >= 0.f ? e : 0.2f*e;
        m = fmaxf(m, e);
    }
    #pragma unroll
    for(int s=32;s;s>>=1) m = fmaxf(m, __shfl_xor(m, s));
    m = fmaxf(m, es);
    float lden = 0.f, lnum = 0.f;
    for(uint32_t p = p0+lane; p < p1; p += 64){
        float hs = h[einfo[p] >> 16];
        float e = a0*hs + a1*hn;
        e = e >= 0.f ? e : 0.2f*e;
        float a = expf(e - m);
        lden += a; lnum += a*hs;
    }
    #pragma unroll
    for(int s=32;s;s>>=1){ lden += __shfl_xor(lden, s); lnum += __shfl_xor(lnum, s); }
    float aself = expf(es - m);
    lden += aself; lnum += aself*hn;
    if(lane==0) score[w] = lnum/(lden + 1e-16f);
}

// top-768 of 1536 per graph via bitonic sort
__global__ __launch_bounds__(512) void topk_kernel(const float* __restrict__ score,
                                                   const float* __restrict__ bias,
                                                   int* __restrict__ sel_node,
                                                   float* __restrict__ sel_scale){
    __shared__ float skey[2048];
    __shared__ int   sval[2048];
    int b = blockIdx.x;
    float bv = bias[0];
    for(int p=threadIdx.x;p<2048;p+=512){
        if(p<1536){
            int node = (p<1024) ? (b*1024 + p) : (NI + b*512 + (p-1024));
            skey[p] = score[node] + bv;
            sval[p] = node;
        } else {
            skey[p] = -INFINITY;
            sval[p] = -1;
        }
    }
    for(int k=2;k<=2048;k<<=1){
        for(int j=k>>1;j>0;j>>=1){
            __syncthreads();
            for(int i=threadIdx.x;i<2048;i+=512){
                int ixj = i^j;
                if(ixj > i){
                    bool up = ((i & k) == 0);
                    float ki = skey[i], kj = skey[ixj];
                    if((ki < kj) == up){
                        skey[i]=kj; skey[ixj]=ki;
                        int t=sval[i]; sval[i]=sval[ixj]; sval[ixj]=t;
                    }
                }
            }
        }
    }
    __syncthreads();
    for(int j=threadIdx.x;j<KPOOL;j+=512){
        sel_node[b*KPOOL + j] = sval[j];
        sel_scale[b*KPOOL + j] = tanhf(skey[j]);
    }
}

__global__ void gather_xp(const int* __restrict__ sel, const float* __restrict__ scale,
                          const float* __restrict__ xi, const float* __restrict__ xd,
                          float* __restrict__ xp, u16* __restrict__ bh, u16* __restrict__ bl){
    int i = blockIdx.x*256 + threadIdx.x;
    int rowp = i >> 8, c = i & 255;
    int node = sel[rowp];
    float s = scale[rowp];
    float v = (node < NI) ? xi[(size_t)node*DD + c] : xd[(size_t)(node-NI)*DD + c];
    float x = v*s;
    xp[i] = x;
    u16 hh = f2b(x);
    bh[i] = hh;
    bl[i] = f2b(x - b2f(hh));
}

// ---------------- MFMA flash attention: block per (b,h,64 q rows), pre-split inputs ----------------
__global__ __launch_bounds__(256) void attn_mfma(const u16* __restrict__ Qh, const u16* __restrict__ Ql,
                                                 const u16* __restrict__ Kh, const u16* __restrict__ Kl,
                                                 const u16* __restrict__ Vh,
                                                 u16* __restrict__ aoh, u16* __restrict__ aol){
    __shared__ u16 KhS[64*64], KlS[64*64], VtS[64*64];
    char* KhB = (char*)KhS; char* KlB = (char*)KlS; char* VtB = (char*)VtS;
    int bh = blockIdx.y;
    int b = bh >> 2, h = bh & 3;
    int q0 = blockIdx.x * 64;
    int tid = threadIdx.x;
    int lane = tid & 63;
    int w = tid >> 6;
    int l15 = lane & 15, l4 = lane >> 4;
    size_t qrow = (size_t)(b*KPOOL + q0 + w*16 + l15);
    bf16x8 qh[2], ql[2];
    #pragma unroll
    for(int c=0;c<2;c++){
        qh[c] = *(const bf16x8*)(Qh + qrow*DD + h*64 + c*32 + l4*8);
        ql[c] = *(const bf16x8*)(Ql + qrow*DD + h*64 + c*32 + l4*8);
    }
    float mreg = -INFINITY, lreg = 0.f;
    f32x4 O[4] = {};
    for(int k0=0;k0<KPOOL;k0+=64){
        __syncthreads();
        {   // stage K hi/lo + V^T from pre-split bf16
            int row = tid >> 2, q4 = tid & 3;
            size_t gbase = ((size_t)(b*KPOOL + k0 + row))*DD + h*64 + q4*16;
            bf16x8 k0v = *(const bf16x8*)(Kh + gbase);
            bf16x8 k1v = *(const bf16x8*)(Kh + gbase + 8);
            bf16x8 kl0 = *(const bf16x8*)(Kl + gbase);
            bf16x8 kl1 = *(const bf16x8*)(Kl + gbase + 8);
            bf16x8 v0v = *(const bf16x8*)(Vh + gbase);
            bf16x8 v1v = *(const bf16x8*)(Vh + gbase + 8);
            int sw = (row&7)<<4;
            int colb = q4*32;
            *(bf16x8*)(KhB + row*128 + (colb ^ sw))        = k0v;
            *(bf16x8*)(KhB + row*128 + ((colb+16) ^ sw))   = k1v;
            *(bf16x8*)(KlB + row*128 + (colb ^ sw))        = kl0;
            *(bf16x8*)(KlB + row*128 + ((colb+16) ^ sw))   = kl1;
            #pragma unroll
            for(int j=0;j<8;j++){
                int dh0 = q4*16 + j;
                int dh1 = q4*16 + 8 + j;
                *(u16*)(VtB + dh0*128 + ((row*2) ^ ((dh0&7)<<4))) = (u16)(short)v0v[j];
                *(u16*)(VtB + dh1*128 + ((row*2) ^ ((dh1&7)<<4))) = (u16)(short)v1v[j];
            }
        }
        __syncthreads();
        // S^T tiles: mfma(A=K, B=Q)
        f32x4 s[4] = {};
        #pragma unroll
        for(int t=0;t<4;t++){
            int arow = t*16 + l15;
            int sw = (arow&7)<<4;
            const char* bh_ = KhB + arow*128;
            const char* bl_ = KlB + arow*128;
            bf16x8 kh0 = *(const bf16x8*)(bh_ + ((l4*16) ^ sw));
            bf16x8 kh1 = *(const bf16x8*)(bh_ + ((l4*16 + 64) ^ sw));
            bf16x8 kl0 = *(const bf16x8*)(bl_ + ((l4*16) ^ sw));
            bf16x8 kl1 = *(const bf16x8*)(bl_ + ((l4*16 + 64) ^ sw));
            s[t] = __builtin_amdgcn_mfma_f32_16x16x32_bf16(kh0, qh[0], s[t], 0,0,0);
            s[t] = __builtin_amdgcn_mfma_f32_16x16x32_bf16(kh1, qh[1], s[t], 0,0,0);
            s[t] = __builtin_amdgcn_mfma_f32_16x16x32_bf16(kh0, ql[0], s[t], 0,0,0);
            s[t] = __builtin_amdgcn_mfma_f32_16x16x32_bf16(kh1, ql[1], s[t], 0,0,0);
            s[t] = __builtin_amdgcn_mfma_f32_16x16x32_bf16(kl0, qh[0], s[t], 0,0,0);
            s[t] = __builtin_amdgcn_mfma_f32_16x16x32_bf16(kl1, qh[1], s[t], 0,0,0);
        }
        // online softmax
        float cm = -INFINITY;
        #pragma unroll
        for(int t=0;t<4;t++)
            #pragma unroll
            for(int r=0;r<4;r++){ s[t][r] *= 0.125f; cm = fmaxf(cm, s[t][r]); }
        cm = fmaxf(cm, __shfl_xor(cm,16));
        cm = fmaxf(cm, __shfl_xor(cm,32));
        float nm = fmaxf(mreg, cm);
        float es = expf(mreg - nm);
        float ps = 0.f;
        #pragma unroll
        for(int t=0;t<4;t++)
            #pragma unroll
            for(int r=0;r<4;r++){ float pv = expf(s[t][r] - nm); s[t][r] = pv; ps += pv; }
        ps += __shfl_xor(ps,16);
        ps += __shfl_xor(ps,32);
        lreg = lreg*es + ps;
        mreg = nm;
        #pragma unroll
        for(int d=0;d<4;d++){ O[d][0]*=es; O[d][1]*=es; O[d][2]*=es; O[d][3]*=es; }
        // O^T += mfma(A=V^T, B=P^T)
        #pragma unroll
        for(int c32=0;c32<2;c32++){
            bf16x8 pb;
            #pragma unroll
            for(int j=0;j<8;j++){
                int srcl = ((((lane>>4)*2 + (j>>2)) & 3) << 4) | l15;
                float v0 = __shfl(s[c32*2+0][j&3], srcl, 64);
                float v1 = __shfl(s[c32*2+1][j&3], srcl, 64);
                float v = (lane < 32) ? v0 : v1;
                pb[j] = (short)f2b(v);
            }
            #pragma unroll
            for(int dhb=0; dhb<4; dhb++){
                int vrow = dhb*16 + l15;
                bf16x8 va = *(const bf16x8*)(VtB + vrow*128 + ((c32*64 + l4*16) ^ ((vrow&7)<<4)));
                O[dhb] = __builtin_amdgcn_mfma_f32_16x16x32_bf16(va, pb, O[dhb], 0,0,0);
            }
        }
    }
    float inv = 1.f/lreg;
    #pragma unroll
    for(int dhb=0;dhb<4;dhb++)
        #pragma unroll
        for(int r=0;r<4;r++){
            float val = O[dhb][r]*inv;
            size_t o = qrow*DD + h*64 + dhb*16 + l4*4 + r;
            u16 hh = f2b(val);
            aoh[o] = hh;
            aol[o] = f2b(val - b2f(hh));
        }
}

// layernorm row kernel
__global__ __launch_bounds__(256) void ln_kernel(const float* __restrict__ xp, const float* __restrict__ o2,
                                                 const float* __restrict__ lg, const float* __restrict__ lb,
                                                 float* __restrict__ gatt){
    __shared__ float red[256];
    int r = blockIdx.x, c = threadIdx.x;
    float y = xp[(size_t)r*DD + c] + o2[(size_t)r*DD + c];
    red[c] = y; __syncthreads();
    for(int s=128;s;s>>=1){ if(c<s) red[c] += red[c+s]; __syncthreads(); }
    float mu = red[0]*(1.f/DD);
    __syncthreads();
    float d = y - mu;
    red[c] = d*d; __syncthreads();
    for(int s=128;s;s>>=1){ if(c<s) red[c] += red[c+s]; __syncthreads(); }
    float var = red[0]*(1.f/DD);
    gatt[(size_t)r*DD + c] = lg[c]*d/sqrtf(var+1e-5f) + lb[c];
}

__global__ void feat_reduce2(const float* __restrict__ xp, const float* __restrict__ gatt,
                             float* __restrict__ out){
    int b = blockIdx.x, c = threadIdx.x;
    int j0 = blockIdx.y*64;
    float s1=0.f, s2=0.f;
    for(int j=j0;j<j0+64;j++){
        size_t base = ((size_t)(b*KPOOL + j))*DD + c;
        s1 += xp[base];
        s2 += gatt[base];
    }
    atomicAdd(&out[b*512 + c], s1);
    atomicAdd(&out[b*512 + 256 + c], s2);
}

__global__ void cosine_kernel(const float* __restrict__ u, const float* __restrict__ v,
                              float* __restrict__ out){
    int b = blockIdx.x, t = threadIdx.x;
    float du=0.f, nu=0.f, nv=0.f;
    for(int j=t;j<512;j+=64){
        float a = u[b*512+j], bb = v[b*512+j];
        du += a*bb; nu += a*a; nv += bb*bb;
    }
    for(int m=32;m;m>>=1){
        du += __shfl_xor(du,m); nu += __shfl_xor(nu,m); nv += __shfl_xor(nv,m);
    }
    if(t==0) out[b] = du / (fmaxf(sqrtf(nu),1e-8f)*fmaxf(sqrtf(nv),1e-8f));
}

// =======================================================================
extern "C" void kernel_launch(void* const* d_in, const int* in_sizes, int n_in,
                              void* d_out, int out_size, void* d_ws, size_t ws_size,
                              hipStream_t stream){
    (void)in_sizes; (void)n_in; (void)out_size; (void)ws_size;
    const float* hgt_Wk   = (const float*)d_in[12];
    const float* hgt_Wq   = (const float*)d_in[13];
    const float* hgt_Wv   = (const float*)d_in[14];
    const float* hgt_Wo   = (const float*)d_in[15];
    const float* hgt_arel = (const float*)d_in[16];
    const float* hgt_mrel = (const float*)d_in[17];
    const float* hgt_prel = (const float*)d_in[18];
    const float* hgt_skip = (const float*)d_in[19];
    const float* pool_W   = (const float*)d_in[20];
    const float* pool_att = (const float*)d_in[21];
    const float* pool_bias= (const float*)d_in[22];
    const float* t_wq     = (const float*)d_in[23];
    const float* t_wk     = (const float*)d_in[24];
    const float* t_wv     = (const float*)d_in[25];
    const float* t_wo     = (const float*)d_in[26];
    const float* ln_g     = (const float*)d_in[27];
    const float* ln_b     = (const float*)d_in[28];
    float* out = (float*)d_out;

    char* base = (char*)d_ws;
    size_t off = 0;
    auto allocb = [&](size_t nbytes)->void*{
        void* p = (void*)(base + off);
        off += ((nbytes + 255) & ~(size_t)255);
        return p;
    };
    const size_t MAT = 65536;
    // ---- persistent ----
    u16* bwtk_h = (u16*)allocb(16*MAT*2); u16* bwtk_l = (u16*)allocb(16*MAT*2);
    u16* bwtv_h = (u16*)allocb(16*MAT*2); u16* bwtv_l = (u16*)allocb(16*MAT*2);
    u16* bwq_h  = (u16*)allocb(8*MAT*2);  u16* bwq_l  = (u16*)allocb(8*MAT*2);
    u16* bwo_h  = (u16*)allocb(8*MAT*2);  u16* bwo_l  = (u16*)allocb(8*MAT*2);
    u16* btw_h  = (u16*)allocb(4*MAT*2);  u16* btw_l  = (u16*)allocb(4*MAT*2);
    float* ubuf = (float*)allocb(BB*512*4);
    float* vbuf = (float*)allocb(BB*512*4);
    float* xa_i = (float*)allocb((size_t)NI*DD*4);
    float* xa_d = (float*)allocb((size_t)ND*DD*4);
    float* xb_i = (float*)allocb((size_t)NI*DD*4);
    float* xb_d = (float*)allocb((size_t)ND*DD*4);
    // ---- per-branch CSR ----
    uint32_t* ccnt   = (uint32_t*)allocb((size_t)2*NROW*4);
    uint32_t* rowptr = (uint32_t*)allocb((size_t)(2*NROW+1)*4);
    uint32_t* einfo  = (uint32_t*)allocb((size_t)2*EHGT*4);
    size_t region = off;
    // ---- conv scratch ----
    float* q_i  = (float*)allocb((size_t)NI*DD*4);
    float* q_d  = (float*)allocb((size_t)ND*DD*4);
    u16* ka16 = (u16*)allocb((size_t)4*NI*DD*2);   // bf16 KA; also combine f32 temp
    u16* vm16 = (u16*)allocb((size_t)4*NI*DD*2);
    float* xacc_i= (float*)allocb((size_t)NI*DD*4);
    float* xacc_d= (float*)allocb((size_t)ND*DD*4);
    u16* bcur_h = (u16*)allocb((size_t)NROW*DD*2);
    u16* bcur_l = (u16*)allocb((size_t)NROW*DD*2);
    u16* bagg_h = (u16*)allocb((size_t)NROW*DD*2);
    u16* bagg_l = (u16*)allocb((size_t)NROW*DD*2);
    // ---- pooling/transformer overlay ----
    off = region;
    float* hvec = (float*)allocb(NROW*4);
    float* pscore = (float*)allocb(NROW*4);
    int* seln   = (int*)allocb(BB*KPOOL*4);
    float* sels = (float*)allocb(BB*KPOOL*4);
    float* xp   = (float*)allocb((size_t)BB*KPOOL*DD*4);
    float* o2   = (float*)allocb((size_t)BB*KPOOL*DD*4);
    float* gatt = (float*)allocb((size_t)BB*KPOOL*DD*4);
    u16* bxp_h = (u16*)allocb((size_t)BB*KPOOL*DD*2);
    u16* bxp_l = (u16*)allocb((size_t)BB*KPOOL*DD*2);
    u16* qbh = (u16*)allocb((size_t)BB*KPOOL*DD*2);
    u16* qbl = (u16*)allocb((size_t)BB*KPOOL*DD*2);
    u16* kbh = (u16*)allocb((size_t)BB*KPOOL*DD*2);
    u16* kbl = (u16*)allocb((size_t)BB*KPOOL*DD*2);
    u16* vbh = (u16*)allocb((size_t)BB*KPOOL*DD*2);
    u16* vbl = (u16*)allocb((size_t)BB*KPOOL*DD*2);
    u16* bao_h = (u16*)allocb((size_t)BB*KPOOL*DD*2);
    u16* bao_l = (u16*)allocb((size_t)BB*KPOOL*DD*2);

    const int st_tab[2][4] = {{0,1,0,0},{0,0,1,0}};
    const int dt_tab[2][4] = {{0,0,1,0},{0,1,0,0}};
    const int MR = BB*KPOOL;

    fill_u32<<<(2*BB*512+255)/256,256,0,stream>>>((uint32_t*)ubuf, 0u, 2*BB*512);
    float* wtkF = (float*)ka16;
    float* wtvF = (float*)ka16 + 16*MAT;
    combine_all<<<dim3(256,32),256,0,stream>>>(hgt_Wk, hgt_Wv, hgt_arel, hgt_mrel, wtkF, wtvF);
    WCArgs wc;
    wc.in[0]=wtkF;   wc.oh[0]=bwtk_h; wc.ol[0]=bwtk_l; wc.cnt[0]=16;
    wc.in[1]=wtvF;   wc.oh[1]=bwtv_h; wc.ol[1]=bwtv_l; wc.cnt[1]=16;
    wc.in[2]=hgt_Wq; wc.oh[2]=bwq_h;  wc.ol[2]=bwq_l;  wc.cnt[2]=8;
    wc.in[3]=hgt_Wo; wc.oh[3]=bwo_h;  wc.ol[3]=bwo_l;  wc.cnt[3]=8;
    wc.in[4]=t_wq;   wc.oh[4]=btw_h;          wc.ol[4]=btw_l;          wc.cnt[4]=1;
    wc.in[5]=t_wk;   wc.oh[5]=btw_h+1*MAT;    wc.ol[5]=btw_l+1*MAT;    wc.cnt[5]=1;
    wc.in[6]=t_wv;   wc.oh[6]=btw_h+2*MAT;    wc.ol[6]=btw_l+2*MAT;    wc.cnt[6]=1;
    wc.in[7]=t_wo;   wc.oh[7]=btw_h+3*MAT;    wc.ol[7]=btw_l+3*MAT;    wc.cnt[7]=1;
    wc.nr = 8;
    wcvt_split<<<dim3(256,52),256,0,stream>>>(wc);

    for(int bi=0;bi<2;bi++){
        int ib = bi*6;
        const float* x_inst = (const float*)d_in[ib+0];
        const float* x_data = (const float*)d_in[ib+1];
        const int* ecp = (const int*)d_in[ib+2];
        const int* eip = (const int*)d_in[ib+3];
        const int* eop = (const int*)d_in[ib+4];
        const int* ekp = (const int*)d_in[ib+5];
        const int* rows_f[4] = {ecp, eip, eop, ekp};
        const int* cols_f[4] = {ecp+EC, eip+EI, eop+EO, ekp+EK};

        // ---- CSR build (both dirs, one pass) ----
        CB2 cb;
        for(int r=0;r<4;r++){
            cb.row[r]   = rows_f[r]; cb.col[r]   = cols_f[r]; cb.dt[r]   = dt_tab[0][r]; cb.st[r]   = st_tab[0][r];
            cb.row[4+r] = cols_f[r]; cb.col[4+r] = rows_f[r]; cb.dt[4+r] = dt_tab[1][r]; cb.st[4+r] = st_tab[1][r];
        }
        cb.cnt = ccnt; cb.rowptr = rowptr; cb.einfo = einfo;
        fill_u32<<<(2*NROW+255)/256,256,0,stream>>>(ccnt, 0u, 2*NROW);
        csr_hist2<<<(2*EHGT+255)/256,256,0,stream>>>(cb);
        scan_rowptr2<<<1,1024,0,stream>>>(ccnt, rowptr);
        csr_scatter2<<<(2*EHGT+255)/256,256,0,stream>>>(cb);

        const float* cur_i = x_inst;
        const float* cur_d = x_data;
        cvt_split<<<((NROW*DD/4)+255)/256,256,0,stream>>>(cur_i, NI*DD, cur_d, ND*DD, bcur_h, bcur_l);
        for(int l=0;l<LL;l++){
            float* nxt_i = (l==0) ? xa_i : xb_i;
            float* nxt_d = (l==0) ? xa_d : xb_d;
            for(int dir=0;dir<2;dir++){
                int wb = l*2 + dir;

                // --- mega GEMM: Q(2, f32, split) + KA(4, bf16, prec=1) + VM(4, bf16, prec=1) ---
                GArgs g1; int nb1 = 0, ndx = 0;
                auto addg = [&](int srctype, const u16* Bh, const u16* Bl, float* Cm, u16* Om, int M, int mode, int prec){
                    GDesc& d = g1.d[ndx];
                    size_t ao = srctype ? (size_t)NI*DD : 0;
                    d.Ah = bcur_h + ao; d.Al = bcur_l + ao;
                    d.Bh = Bh; d.Bl = Bl; d.C = Cm;
                    d.Oh = Om; d.Ol = nullptr; d.X = nullptr; d.Xacc = nullptr; d.skipp = nullptr;
                    d.mblks = M/128; d.mode = mode; d.prec = prec;
                    nb1 += M/128; ndx++;
                };
                addg(0, bwq_h + (size_t)(wb*2+0)*MAT, bwq_l + (size_t)(wb*2+0)*MAT, q_i, nullptr, NI, 0, 0);
                addg(1, bwq_h + (size_t)(wb*2+1)*MAT, bwq_l + (size_t)(wb*2+1)*MAT, q_d, nullptr, ND, 0, 0);
                for(int r=0;r<4;r++){
                    int st = st_tab[dir][r];
                    addg(st, bwtk_h + (size_t)(wb*4+r)*MAT, bwtk_l + (size_t)(wb*4+r)*MAT,
                         nullptr, ka16 + (size_t)r*NI*DD, st ? ND : NI, 4, 1);
                }
                for(int r=0;r<4;r++){
                    int st = st_tab[dir][r];
                    addg(st, bwtv_h + (size_t)(wb*4+r)*MAT, bwtv_l + (size_t)(wb*4+r)*MAT,
                         nullptr, vm16 + (size_t)r*NI*DD, st ? ND : NI, 4, 1);
                }
                g1.nd = ndx;
                gemm_mfma<<<dim3(nb1,2),256,0,stream>>>(g1);

                // --- fused edge phase ---
                hgt_fused<<<NROW/4,256,0,stream>>>(rowptr + (size_t)dir*NROW, einfo,
                    q_i, q_d, ka16, vm16, hgt_prel + (size_t)wb*4*HH, bagg_h, bagg_l);

                // --- Wo GEMMs with fused skip/relu epilogue (split) ---
                GArgs g3; g3.nd = 2;
                for(int t=0;t<2;t++){
                    GDesc& d = g3.d[t];
                    size_t ao = t ? (size_t)NI*DD : 0;
                    d.Ah = bagg_h + ao; d.Al = bagg_l + ao;
                    d.Bh = bwo_h + (size_t)(wb*2+t)*MAT; d.Bl = bwo_l + (size_t)(wb*2+t)*MAT;
                    d.C = t ? nxt_d : nxt_i;
                    d.Oh = bcur_h + ao; d.Ol = bcur_l + ao;
                    d.X = t ? cur_d : cur_i;
                    d.Xacc = t ? xacc_d : xacc_i;
                    d.skipp = hgt_skip + wb*2 + t;
                    d.mblks = (t ? ND : NI)/128;
                    d.mode = dir ? 3 : 2;
                    d.prec = 0;
                }
                gemm_mfma<<<dim3(NI/128 + ND/128,2),256,0,stream>>>(g3);
            }
            cur_i = nxt_i;
            cur_d = nxt_d;
        }

        // -------- SAGPooling (CSR-based, no atomics) --------
        pool_h2<<<NROW/4,256,0,stream>>>(cur_i, cur_d, pool_W, hvec);
        pool_csr<<<NROW/4,256,0,stream>>>(rowptr, einfo, hvec, pool_att, pscore);
        topk_kernel<<<BB,512,0,stream>>>(pscore, pool_bias, seln, sels);
        gather_xp<<<BB*KPOOL,256,0,stream>>>(seln, sels, cur_i, cur_d, xp, bxp_h, bxp_l);

        // -------- transformer --------
        GArgs g4; g4.nd = 3;
        for(int t=0;t<3;t++){
            GDesc& d = g4.d[t];
            d.Ah=bxp_h; d.Al=bxp_l;
            d.Bh=btw_h + (size_t)t*MAT; d.Bl=btw_l + (size_t)t*MAT;
            d.C = nullptr;
            d.Oh = (t==0)? qbh : (t==1)? kbh : vbh;
            d.Ol = (t==0)? qbl : (t==1)? kbl : vbl;
            d.X = nullptr; d.Xacc = nullptr; d.skipp = nullptr;
            d.mblks = MR/128; d.mode = 1; d.prec = 0;
        }
        gemm_mfma<<<dim3(3*(MR/128),2),256,0,stream>>>(g4);
        attn_mfma<<<dim3(KPOOL/64, BB*HH),256,0,stream>>>(qbh, qbl, kbh, kbl, vbh, bao_h, bao_l);
        GArgs g5; g5.nd = 1;
        {
            GDesc& d = g5.d[0];
            d.Ah=bao_h; d.Al=bao_l;
            d.Bh=btw_h + (size_t)3*MAT; d.Bl=btw_l + (size_t)3*MAT;
            d.C=o2; d.Oh=nullptr; d.Ol=nullptr; d.X=nullptr; d.Xacc=nullptr; d.skipp=nullptr;
            d.mblks=MR/128; d.mode=0; d.prec=0;
        }
        gemm_mfma<<<dim3(MR/128,2),256,0,stream>>>(g5);
        ln_kernel<<<MR,256,0,stream>>>(xp, o2, ln_g, ln_b, gatt);
        feat_reduce2<<<dim3(BB,12),256,0,stream>>>(xp, gatt, bi ? vbuf : ubuf);
    }

    cosine_kernel<<<BB,64,0,stream>>>(ubuf, vbuf, out);
}

// Round 16
// 1061.549 us; speedup vs baseline: 1.8320x; 1.0069x over previous
//
#include <hip/hip_runtime.h>
#include <math.h>
#include <stdint.h>

#define LL 2
#define HH 4
#define DHH 64
#define DD 256
#define BB 8
#define NI 8192
#define ND 4096
#define NROW 12288
#define KPOOL 768
#define EC 65536
#define EI 32768
#define EO 32768
#define EK 8192
#define EHGT (EC+EI+EO+EK)

typedef unsigned short u16;
typedef short bf16x8 __attribute__((ext_vector_type(8)));
typedef float f32x4 __attribute__((ext_vector_type(4)));
typedef unsigned short u16x4 __attribute__((ext_vector_type(4)));

__device__ inline float gelu_f(float x){ return 0.5f*x*(1.f+erff(x*0.70710678118654752f)); }
__device__ inline u16 f2b(float x){ uint32_t u=__float_as_uint(x); return (u16)((u + 0x7fffu + ((u>>16)&1u))>>16); }
__device__ inline float b2f(u16 h){ return __uint_as_float(((uint32_t)h)<<16); }

// ---------------- generic fill ----------------
__global__ void fill_u32(uint32_t* p, uint32_t v, int n){
    int i = blockIdx.x*256 + threadIdx.x;
    if(i<n) p[i]=v;
}

// ---------------- activation split-convert ----------------
__global__ void cvt_split(const float* __restrict__ A, int nA, const float* __restrict__ B, int nB,
                          u16* __restrict__ oh, u16* __restrict__ ol){
    int i = (blockIdx.x*256 + threadIdx.x)*4;
    int tot = nA + nB;
    if(i >= tot) return;
    float4 v = (i < nA) ? *(const float4*)(A + i) : *(const float4*)(B + (i - nA));
    float vv[4] = {v.x, v.y, v.z, v.w};
    u16x4 h4, l4;
    #pragma unroll
    for(int j=0;j<4;j++){
        float x = vv[j];
        u16 h = f2b(x);
        h4[j] = h;
        l4[j] = f2b(x - b2f(h));
    }
    *(u16x4*)(oh + i) = h4;
    *(u16x4*)(ol + i) = l4;
}

// ---------------- weight transpose + split ----------------
struct WCArgs { const float* in[8]; u16* oh[8]; u16* ol[8]; int cnt[8]; int nr; };
__global__ void wcvt_split(WCArgs a){
    int mat = blockIdx.y, ri = 0;
    while(ri < a.nr-1 && mat >= a.cnt[ri]){ mat -= a.cnt[ri]; ri++; }
    const float* in = a.in[ri] + (size_t)mat*65536;
    u16* oh = a.oh[ri] + (size_t)mat*65536;
    u16* ol = a.ol[ri] + (size_t)mat*65536;
    int n = blockIdx.x, k = threadIdx.x;
    float x = in[(size_t)k*DD + n];
    u16 h = f2b(x);
    oh[n*DD + k] = h;
    ol[n*DD + k] = f2b(x - b2f(h));
}

// ---------------- MFMA batched GEMM with fused, LDS-restaged epilogues ----------------
// prec=0: split hi/lo (3 MFMA/step); prec=1: hi-only (1 MFMA/step, half staging)
// mode 0: C=f32   mode 1: Oh/Ol=split bf16   mode 4: Oh=plain bf16
// mode 2: Xacc = 0.5*(g*acc + (1-g)*X)
// mode 3: v=relu(Xacc + 0.5*(g*acc+(1-g)*X)); C=v; Oh/Ol=split(v)
struct GDesc { const u16* Ah; const u16* Al; const u16* Bh; const u16* Bl;
               float* C; u16* Oh; u16* Ol;
               const float* X; float* Xacc; const float* skipp;
               int mblks; int mode; int prec; };
struct GArgs { GDesc d[10]; int nd; };

__global__ __launch_bounds__(256) void gemm_mfma(GArgs ga){
    __shared__ u16 SBUF[2*128*64];
    char* Abuf = (char*)SBUF;
    char* Bbuf = (char*)(SBUF + 128*64);
    int mb = blockIdx.x, di = 0;
    while(di < ga.nd-1 && mb >= ga.d[di].mblks){ mb -= ga.d[di].mblks; di++; }
    GDesc g = ga.d[di];
    const int prec = g.prec;
    const int m0 = mb*128, n0 = blockIdx.y*128;
    const int tid = threadIdx.x;
    const int lane = tid & 63, wid = tid >> 6;
    const int wm = (wid>>1)*64, wn = (wid&1)*64;
    const int l15 = lane & 15, l4 = lane >> 4;
    const int srow = tid >> 1, hf = tid & 1;
    const int ssw = (srow&7)<<4;
    const int c0 = (hf*32) ^ ssw;
    const int c1 = (hf*32+16) ^ ssw;
    const int c2 = (64+hf*32) ^ ssw;
    const int c3 = (64+hf*32+16) ^ ssw;
    const int rbyte = srow*128;
    const u16* __restrict__ Aph = g.Ah + (size_t)(m0 + srow)*DD + hf*16;
    const u16* __restrict__ Apl = g.Al + (size_t)(m0 + srow)*DD + hf*16;
    const u16* __restrict__ Bph = g.Bh + (size_t)(n0 + srow)*DD + hf*16;
    const u16* __restrict__ Bpl = g.Bl + (size_t)(n0 + srow)*DD + hf*16;
    f32x4 acc[4][4] = {};
    bf16x8 r0, r1, r2, r3, r4, r5, r6, r7;
    r0 = *(const bf16x8*)(Aph);
    r1 = *(const bf16x8*)(Aph + 8);
    r4 = *(const bf16x8*)(Bph);
    r5 = *(const bf16x8*)(Bph + 8);
    if(!prec){
        r2 = *(const bf16x8*)(Apl);
        r3 = *(const bf16x8*)(Apl + 8);
        r6 = *(const bf16x8*)(Bpl);
        r7 = *(const bf16x8*)(Bpl + 8);
    }
    #pragma unroll
    for(int k0=0;k0<DD;k0+=32){
        __syncthreads();
        *(bf16x8*)(Abuf + rbyte + c0) = r0; *(bf16x8*)(Abuf + rbyte + c1) = r1;
        *(bf16x8*)(Bbuf + rbyte + c0) = r4; *(bf16x8*)(Bbuf + rbyte + c1) = r5;
        if(!prec){
            *(bf16x8*)(Abuf + rbyte + c2) = r2; *(bf16x8*)(Abuf + rbyte + c3) = r3;
            *(bf16x8*)(Bbuf + rbyte + c2) = r6; *(bf16x8*)(Bbuf + rbyte + c3) = r7;
        }
        __syncthreads();
        if(k0 + 32 < DD){
            int kn = k0 + 32;
            r0 = *(const bf16x8*)(Aph + kn);     r1 = *(const bf16x8*)(Aph + kn + 8);
            r4 = *(const bf16x8*)(Bph + kn);     r5 = *(const bf16x8*)(Bph + kn + 8);
            if(!prec){
                r2 = *(const bf16x8*)(Apl + kn); r3 = *(const bf16x8*)(Apl + kn + 8);
                r6 = *(const bf16x8*)(Bpl + kn); r7 = *(const bf16x8*)(Bpl + kn + 8);
            }
        }
        bf16x8 afh[4], bfh[4];
        #pragma unroll
        for(int i=0;i<4;i++){
            int ar = wm + i*16 + l15;
            int abase = ar*128;
            afh[i] = *(const bf16x8*)(Abuf + abase + ((l4*16) ^ ((ar&7)<<4)));
            int br = wn + i*16 + l15;
            int bbase = br*128;
            bfh[i] = *(const bf16x8*)(Bbuf + bbase + ((l4*16) ^ ((br&7)<<4)));
        }
        #pragma unroll
        for(int i=0;i<4;i++)
            #pragma unroll
            for(int j=0;j<4;j++)
                acc[i][j] = __builtin_amdgcn_mfma_f32_16x16x32_bf16(afh[i], bfh[j], acc[i][j], 0,0,0);
        if(!prec){
            bf16x8 afl[4], bfl[4];
            #pragma unroll
            for(int i=0;i<4;i++){
                int ar = wm + i*16 + l15;
                int abase = ar*128;
                afl[i] = *(const bf16x8*)(Abuf + abase + ((64 + l4*16) ^ ((ar&7)<<4)));
                int br = wn + i*16 + l15;
                int bbase = br*128;
                bfl[i] = *(const bf16x8*)(Bbuf + bbase + ((64 + l4*16) ^ ((br&7)<<4)));
            }
            #pragma unroll
            for(int i=0;i<4;i++)
                #pragma unroll
                for(int j=0;j<4;j++){
                    acc[i][j] = __builtin_amdgcn_mfma_f32_16x16x32_bf16(afh[i], bfl[j], acc[i][j], 0,0,0);
                    acc[i][j] = __builtin_amdgcn_mfma_f32_16x16x32_bf16(afl[i], bfh[j], acc[i][j], 0,0,0);
                }
        }
    }
    // ---- coalesced epilogue via LDS restage (two 64-row passes) ----
    const int mode = g.mode;
    float gg = 0.f;
    if(mode == 2 || mode == 3) gg = 1.f/(1.f + expf(-*g.skipp));
    float* LDSf = (float*)SBUF;
    const int lrow = tid >> 5;
    const int cc4 = (tid & 31)*4;
    #pragma unroll
    for(int half=0; half<2; half++){
        __syncthreads();
        if((wid>>1) == half){
            #pragma unroll
            for(int i=0;i<4;i++)
                #pragma unroll
                for(int j=0;j<4;j++)
                    #pragma unroll
                    for(int r=0;r<4;r++)
                        LDSf[(i*16 + l4*4 + r)*128 + wn + j*16 + l15] = acc[i][j][r];
        }
        __syncthreads();
        #pragma unroll
        for(int k=0;k<8;k++){
            int row = lrow + k*8;
            size_t o = (size_t)(m0 + half*64 + row)*DD + n0 + cc4;
            float4 v = *(const float4*)&LDSf[row*128 + cc4];
            float vv[4] = {v.x, v.y, v.z, v.w};
            if(mode==0){
                *(float4*)(g.C + o) = v;
            } else if(mode==4){
                u16x4 h4;
                #pragma unroll
                for(int j=0;j<4;j++) h4[j] = f2b(vv[j]);
                *(u16x4*)(g.Oh + o) = h4;
            } else if(mode==1){
                u16x4 h4, lo4;
                #pragma unroll
                for(int j=0;j<4;j++){
                    u16 hh = f2b(vv[j]); h4[j]=hh; lo4[j]=f2b(vv[j]-b2f(hh));
                }
                *(u16x4*)(g.Oh + o) = h4;
                *(u16x4*)(g.Ol + o) = lo4;
            } else if(mode==2){
                float4 x = *(const float4*)(g.X + o);
                float xx[4] = {x.x, x.y, x.z, x.w};
                float4 w;
                float* ww = (float*)&w;
                #pragma unroll
                for(int j=0;j<4;j++) ww[j] = 0.5f*(gg*vv[j] + (1.f-gg)*xx[j]);
                *(float4*)(g.Xacc + o) = w;
            } else {
                float4 x = *(const float4*)(g.X + o);
                float4 xa = *(const float4*)(g.Xacc + o);
                float xx[4] = {x.x, x.y, x.z, x.w};
                float aa[4] = {xa.x, xa.y, xa.z, xa.w};
                float4 cv;
                float* cvv = (float*)&cv;
                u16x4 h4, lo4;
                #pragma unroll
                for(int j=0;j<4;j++){
                    float v3 = aa[j] + 0.5f*(gg*vv[j] + (1.f-gg)*xx[j]);
                    v3 = v3 > 0.f ? v3 : 0.f;
                    cvv[j] = v3;
                    u16 hh = f2b(v3); h4[j]=hh; lo4[j]=f2b(v3-b2f(hh));
                }
                *(float4*)(g.C + o) = cv;
                *(u16x4*)(g.Oh + o) = h4;
                *(u16x4*)(g.Ol + o) = lo4;
            }
        }
    }
}

// ---------- combine ----------
__global__ void combine_all(const float* __restrict__ Wk, const float* __restrict__ Wv,
                            const float* __restrict__ Ra, const float* __restrict__ Rm,
                            float* __restrict__ wtk, float* __restrict__ wtv){
    const int st_tab[2][4] = {{0,1,0,0},{0,0,1,0}};
    int combo = blockIdx.y;
    int idx = combo >> 1, kv = combo & 1;
    int r = idx & 3, wb = idx >> 2, dir = wb & 1;
    int st = st_tab[dir][r];
    const float* W = (kv ? Wv : Wk) + (size_t)(wb*2 + st)*65536;
    const float* R = (kv ? Rm : Ra) + (size_t)idx*16384;
    float* o = (kv ? wtv : wtk) + (size_t)idx*65536;
    int d = blockIdx.x, c = threadIdx.x;
    int h = c >> 6, f = c & 63;
    const float* Wrow = W + d*DD + h*64;
    const float* Rh = R + h*4096 + f;
    float s = 0.f;
    #pragma unroll 8
    for(int k=0;k<64;k++) s += Wrow[k]*Rh[k*64];
    o[d*DD + c] = s;
}

// ---------------- CSR build (both directions in one pass) ----------------
__device__ inline void edge_decode(int e, int& r, int& el){
    if(e < EC){ r=0; el=e; }
    else if(e < EC+EI){ r=1; el=e-EC; }
    else if(e < EC+EI+EO){ r=2; el=e-(EC+EI); }
    else { r=3; el=e-(EC+EI+EO); }
}

struct CB2 {
    const int* row[8]; const int* col[8];
    int dt[8]; int st[8];
    uint32_t* cnt; uint32_t* rowptr; uint32_t* einfo;
};

__global__ void csr_hist2(CB2 a){
    int ge = blockIdx.x*256 + threadIdx.x;
    if(ge >= 2*EHGT) return;
    int dir = ge >= EHGT;
    int e = ge - dir*EHGT;
    int r, el; edge_decode(e, r, el);
    int idx = dir*4 + r;
    int c = a.col[idx][el];
    int dst = dir*NROW + (a.dt[idx] ? (NI + c) : c);
    atomicAdd(&a.cnt[dst], 1u);
}

__global__ __launch_bounds__(1024) void scan_rowptr2(uint32_t* cnt, uint32_t* rowptr){
    __shared__ uint32_t part[1024];
    int t = threadIdx.x;
    int base = t*24;
    uint32_t lpre[24];
    uint32_t sum = 0;
    #pragma unroll
    for(int i=0;i<24;i++){
        uint32_t c = cnt[base+i];
        lpre[i] = sum; sum += c;
        cnt[base+i] = 0;
    }
    part[t] = sum;
    __syncthreads();
    for(int offs=1; offs<1024; offs<<=1){
        uint32_t v = (t>=offs) ? part[t-offs] : 0u;
        __syncthreads();
        part[t] += v;
        __syncthreads();
    }
    uint32_t pre = (t==0) ? 0u : part[t-1];
    #pragma unroll
    for(int i=0;i<24;i++) rowptr[base+i] = pre + lpre[i];
    if(t==1023) rowptr[2*NROW] = part[1023];
}

__global__ void csr_scatter2(CB2 a){
    int ge = blockIdx.x*256 + threadIdx.x;
    if(ge >= 2*EHGT) return;
    int dir = ge >= EHGT;
    int e = ge - dir*EHGT;
    int r, el; edge_decode(e, r, el);
    int idx = dir*4 + r;
    int c = a.col[idx][el];
    int dst = dir*NROW + (a.dt[idx] ? (NI + c) : c);
    int src = a.row[idx][el];
    uint32_t p = a.rowptr[dst] + atomicAdd(&a.cnt[dst], 1u);
    uint32_t vmidx = (uint32_t)(r*NI + src);
    uint32_t hom = a.st[idx] ? (uint32_t)(NI + src) : (uint32_t)src;
    a.einfo[p] = vmidx | (hom << 16);
}

// ---------------- fused HGT edge phase: wave per dst, all 4 heads, online softmax ----------------
__global__ __launch_bounds__(256) void hgt_fused(const uint32_t* __restrict__ rowptr,
                                                 const uint32_t* __restrict__ einfo,
                                                 const float* __restrict__ q_i,
                                                 const float* __restrict__ q_d,
                                                 const u16* __restrict__ ka,
                                                 const u16* __restrict__ vm,
                                                 const float* __restrict__ prel,
                                                 u16* __restrict__ bagg_h,
                                                 u16* __restrict__ bagg_l){
    int wv = threadIdx.x >> 6, lane = threadIdx.x & 63;
    int rowi = blockIdx.x*4 + wv;
    uint32_t p0 = rowptr[rowi], p1 = rowptr[rowi+1];
    int h = lane >> 4;
    const float* qrow = (rowi < NI) ? (q_i + (size_t)rowi*DD) : (q_d + (size_t)(rowi-NI)*DD);
    float4 q4 = *(const float4*)(qrow + lane*4);
    float pr0 = prel[0*HH+h]*0.125f, pr1 = prel[1*HH+h]*0.125f;
    float pr2 = prel[2*HH+h]*0.125f, pr3 = prel[3*HH+h]*0.125f;
    float m = -INFINITY, den = 0.f;
    float4 o4 = {0.f,0.f,0.f,0.f};
    for(uint32_t p = p0; p < p1; p++){
        uint32_t vmidx = einfo[p] & 0xffffu;
        int r = vmidx >> 13;
        uint2 kr = *(const uint2*)(ka + (size_t)vmidx*DD + lane*4);
        uint2 vr = *(const uint2*)(vm + (size_t)vmidx*DD + lane*4);
        float k0 = __uint_as_float(kr.x << 16), k1 = __uint_as_float(kr.x & 0xffff0000u);
        float k2 = __uint_as_float(kr.y << 16), k3 = __uint_as_float(kr.y & 0xffff0000u);
        float v0 = __uint_as_float(vr.x << 16), v1 = __uint_as_float(vr.x & 0xffff0000u);
        float v2 = __uint_as_float(vr.y << 16), v3 = __uint_as_float(vr.y & 0xffff0000u);
        float d = q4.x*k0 + q4.y*k1 + q4.z*k2 + q4.w*k3;
        d += __shfl_xor(d, 1); d += __shfl_xor(d, 2);
        d += __shfl_xor(d, 4); d += __shfl_xor(d, 8);
        float pf = (r==0) ? pr0 : (r==1) ? pr1 : (r==2) ? pr2 : pr3;
        float s = d * pf;
        float nm = fmaxf(m, s);
        float sc_ = expf(m - nm);
        float pe = expf(s - nm);
        den = den*sc_ + pe;
        o4.x = o4.x*sc_ + pe*v0;
        o4.y = o4.y*sc_ + pe*v1;
        o4.z = o4.z*sc_ + pe*v2;
        o4.w = o4.w*sc_ + pe*v3;
        m = nm;
    }
    float inv = 1.f/(den + 1e-16f);
    float vals[4] = {o4.x*inv, o4.y*inv, o4.z*inv, o4.w*inv};
    u16x4 h4, l4;
    #pragma unroll
    for(int j=0;j<4;j++){
        float g = gelu_f(vals[j]);
        u16 hh = f2b(g);
        h4[j] = hh;
        l4[j] = f2b(g - b2f(hh));
    }
    size_t ob = (size_t)rowi*DD + lane*4;
    *(u16x4*)(bagg_h + ob) = h4;
    *(u16x4*)(bagg_l + ob) = l4;
}

// ---------------- pooling ----------------
__global__ void pool_h2(const float* __restrict__ xi, const float* __restrict__ xd,
                        const float* __restrict__ w, float* __restrict__ h){
    int node = blockIdx.x*4 + (threadIdx.x>>6);
    int lane = threadIdx.x & 63;
    const float* xr = (node < NI) ? (xi + (size_t)node*DD) : (xd + (size_t)(node-NI)*DD);
    float s = 0.f;
    for(int j=lane;j<DD;j+=64) s += xr[j]*w[j];
    for(int m=32;m;m>>=1) s += __shfl_xor(s, m);
    if(lane==0) h[node] = s;
}

// GAT-style pooling score via fwd CSR + implicit self-loop; wave per dst node
__global__ __launch_bounds__(256) void pool_csr(const uint32_t* __restrict__ rowptr,
                                                const uint32_t* __restrict__ einfo,
                                                const float* __restrict__ h,
                                                const float* __restrict__ att,
                                                float* __restrict__ score){
    int w = blockIdx.x*4 + (threadIdx.x >> 6);
    int lane = threadIdx.x & 63;
    if(w >= NROW) return;
    uint32_t p0 = rowptr[w], p1 = rowptr[w+1];
    float a0 = att[0], a1 = att[1];
    float hn = h[w];
    float es = a0*hn + a1*hn;
    es = es >= 0.f ? es : 0.2f*es;
    float m = -INFINITY;
    for(uint32_t p = p0+lane; p < p1; p += 64){
        float hs = h[einfo[p] >> 16];
        float e = a0*hs + a1*hn;
        e = e >= 0.f ? e : 0.2f*e;
        m = fmaxf(m, e);
    }
    #pragma unroll
    for(int s=32;s;s>>=1) m = fmaxf(m, __shfl_xor(m, s));
    m = fmaxf(m, es);
    float lden = 0.f, lnum = 0.f;
    for(uint32_t p = p0+lane; p < p1; p += 64){
        float hs = h[einfo[p] >> 16];
        float e = a0*hs + a1*hn;
        e = e >= 0.f ? e : 0.2f*e;
        float a = expf(e - m);
        lden += a; lnum += a*hs;
    }
    #pragma unroll
    for(int s=32;s;s>>=1){ lden += __shfl_xor(lden, s); lnum += __shfl_xor(lnum, s); }
    float aself = expf(es - m);
    lden += aself; lnum += aself*hn;
    if(lane==0) score[w] = lnum/(lden + 1e-16f);
}

// ---------------- top-768 of 1536 per graph via exact rank selection ----------------
// grid (6, BB), 256 thr. rank(i) = #{j: k_j>k_i or (k_j==k_i and j<i)}; rank<KPOOL -> out[rank].
// Reproduces jax.lax.top_k order (descending, ties by index) exactly.
__global__ __launch_bounds__(256) void topk_rank(const float* __restrict__ score,
                                                 const float* __restrict__ bias,
                                                 int* __restrict__ sel_node,
                                                 float* __restrict__ sel_scale){
    __shared__ float keys[1536];
    int b = blockIdx.y;
    for(int t=threadIdx.x; t<1536; t+=256){
        int node = (t<1024) ? (b*1024 + t) : (NI + b*512 + (t-1024));
        keys[t] = score[node];
    }
    __syncthreads();
    int i = blockIdx.x*256 + threadIdx.x;
    float ki = keys[i];
    int rank = 0;
    #pragma unroll 8
    for(int j=0;j<1536;j++){
        float kj = keys[j];
        rank += (kj > ki) || (kj == ki && j < i);
    }
    if(rank < KPOOL){
        int node = (i<1024) ? (b*1024 + i) : (NI + b*512 + (i-1024));
        sel_node[b*KPOOL + rank] = node;
        sel_scale[b*KPOOL + rank] = tanhf(ki + bias[0]);
    }
}

__global__ void gather_xp(const int* __restrict__ sel, const float* __restrict__ scale,
                          const float* __restrict__ xi, const float* __restrict__ xd,
                          float* __restrict__ xp, u16* __restrict__ bh, u16* __restrict__ bl){
    int i = blockIdx.x*256 + threadIdx.x;
    int rowp = i >> 8, c = i & 255;
    int node = sel[rowp];
    float s = scale[rowp];
    float v = (node < NI) ? xi[(size_t)node*DD + c] : xd[(size_t)(node-NI)*DD + c];
    float x = v*s;
    xp[i] = x;
    u16 hh = f2b(x);
    bh[i] = hh;
    bl[i] = f2b(x - b2f(hh));
}

// ---------------- MFMA flash attention: block per (b,h,64 q rows), pre-split inputs ----------------
__global__ __launch_bounds__(256) void attn_mfma(const u16* __restrict__ Qh, const u16* __restrict__ Ql,
                                                 const u16* __restrict__ Kh, const u16* __restrict__ Kl,
                                                 const u16* __restrict__ Vh,
                                                 u16* __restrict__ aoh, u16* __restrict__ aol){
    __shared__ u16 KhS[64*64], KlS[64*64], VtS[64*64];
    char* KhB = (char*)KhS; char* KlB = (char*)KlS; char* VtB = (char*)VtS;
    int bh = blockIdx.y;
    int b = bh >> 2, h = bh & 3;
    int q0 = blockIdx.x * 64;
    int tid = threadIdx.x;
    int lane = tid & 63;
    int w = tid >> 6;
    int l15 = lane & 15, l4 = lane >> 4;
    size_t qrow = (size_t)(b*KPOOL + q0 + w*16 + l15);
    bf16x8 qh[2], ql[2];
    #pragma unroll
    for(int c=0;c<2;c++){
        qh[c] = *(const bf16x8*)(Qh + qrow*DD + h*64 + c*32 + l4*8);
        ql[c] = *(const bf16x8*)(Ql + qrow*DD + h*64 + c*32 + l4*8);
    }
    float mreg = -INFINITY, lreg = 0.f;
    f32x4 O[4] = {};
    for(int k0=0;k0<KPOOL;k0+=64){
        __syncthreads();
        {   // stage K hi/lo + V^T from pre-split bf16
            int row = tid >> 2, q4 = tid & 3;
            size_t gbase = ((size_t)(b*KPOOL + k0 + row))*DD + h*64 + q4*16;
            bf16x8 k0v = *(const bf16x8*)(Kh + gbase);
            bf16x8 k1v = *(const bf16x8*)(Kh + gbase + 8);
            bf16x8 kl0 = *(const bf16x8*)(Kl + gbase);
            bf16x8 kl1 = *(const bf16x8*)(Kl + gbase + 8);
            bf16x8 v0v = *(const bf16x8*)(Vh + gbase);
            bf16x8 v1v = *(const bf16x8*)(Vh + gbase + 8);
            int sw = (row&7)<<4;
            int colb = q4*32;
            *(bf16x8*)(KhB + row*128 + (colb ^ sw))        = k0v;
            *(bf16x8*)(KhB + row*128 + ((colb+16) ^ sw))   = k1v;
            *(bf16x8*)(KlB + row*128 + (colb ^ sw))        = kl0;
            *(bf16x8*)(KlB + row*128 + ((colb+16) ^ sw))   = kl1;
            #pragma unroll
            for(int j=0;j<8;j++){
                int dh0 = q4*16 + j;
                int dh1 = q4*16 + 8 + j;
                *(u16*)(VtB + dh0*128 + ((row*2) ^ ((dh0&7)<<4))) = (u16)(short)v0v[j];
                *(u16*)(VtB + dh1*128 + ((row*2) ^ ((dh1&7)<<4))) = (u16)(short)v1v[j];
            }
        }
        __syncthreads();
        // S^T tiles: mfma(A=K, B=Q)
        f32x4 s[4] = {};
        #pragma unroll
        for(int t=0;t<4;t++){
            int arow = t*16 + l15;
            int sw = (arow&7)<<4;
            const char* bh_ = KhB + arow*128;
            const char* bl_ = KlB + arow*128;
            bf16x8 kh0 = *(const bf16x8*)(bh_ + ((l4*16) ^ sw));
            bf16x8 kh1 = *(const bf16x8*)(bh_ + ((l4*16 + 64) ^ sw));
            bf16x8 kl0 = *(const bf16x8*)(bl_ + ((l4*16) ^ sw));
            bf16x8 kl1 = *(const bf16x8*)(bl_ + ((l4*16 + 64) ^ sw));
            s[t] = __builtin_amdgcn_mfma_f32_16x16x32_bf16(kh0, qh[0], s[t], 0,0,0);
            s[t] = __builtin_amdgcn_mfma_f32_16x16x32_bf16(kh1, qh[1], s[t], 0,0,0);
            s[t] = __builtin_amdgcn_mfma_f32_16x16x32_bf16(kh0, ql[0], s[t], 0,0,0);
            s[t] = __builtin_amdgcn_mfma_f32_16x16x32_bf16(kh1, ql[1], s[t], 0,0,0);
            s[t] = __builtin_amdgcn_mfma_f32_16x16x32_bf16(kl0, qh[0], s[t], 0,0,0);
            s[t] = __builtin_amdgcn_mfma_f32_16x16x32_bf16(kl1, qh[1], s[t], 0,0,0);
        }
        // online softmax
        float cm = -INFINITY;
        #pragma unroll
        for(int t=0;t<4;t++)
            #pragma unroll
            for(int r=0;r<4;r++){ s[t][r] *= 0.125f; cm = fmaxf(cm, s[t][r]); }
        cm = fmaxf(cm, __shfl_xor(cm,16));
        cm = fmaxf(cm, __shfl_xor(cm,32));
        float nm = fmaxf(mreg, cm);
        float es = expf(mreg - nm);
        float ps = 0.f;
        #pragma unroll
        for(int t=0;t<4;t++)
            #pragma unroll
            for(int r=0;r<4;r++){ float pv = expf(s[t][r] - nm); s[t][r] = pv; ps += pv; }
        ps += __shfl_xor(ps,16);
        ps += __shfl_xor(ps,32);
        lreg = lreg*es + ps;
        mreg = nm;
        #pragma unroll
        for(int d=0;d<4;d++){ O[d][0]*=es; O[d][1]*=es; O[d][2]*=es; O[d][3]*=es; }
        // O^T += mfma(A=V^T, B=P^T)
        #pragma unroll
        for(int c32=0;c32<2;c32++){
            bf16x8 pb;
            #pragma unroll
            for(int j=0;j<8;j++){
                int srcl = ((((lane>>4)*2 + (j>>2)) & 3) << 4) | l15;
                float v0 = __shfl(s[c32*2+0][j&3], srcl, 64);
                float v1 = __shfl(s[c32*2+1][j&3], srcl, 64);
                float v = (lane < 32) ? v0 : v1;
                pb[j] = (short)f2b(v);
            }
            #pragma unroll
            for(int dhb=0; dhb<4; dhb++){
                int vrow = dhb*16 + l15;
                bf16x8 va = *(const bf16x8*)(VtB + vrow*128 + ((c32*64 + l4*16) ^ ((vrow&7)<<4)));
                O[dhb] = __builtin_amdgcn_mfma_f32_16x16x32_bf16(va, pb, O[dhb], 0,0,0);
            }
        }
    }
    float inv = 1.f/lreg;
    #pragma unroll
    for(int dhb=0;dhb<4;dhb++)
        #pragma unroll
        for(int r=0;r<4;r++){
            float val = O[dhb][r]*inv;
            size_t o = qrow*DD + h*64 + dhb*16 + l4*4 + r;
            u16 hh = f2b(val);
            aoh[o] = hh;
            aol[o] = f2b(val - b2f(hh));
        }
}

// layernorm row kernel
__global__ __launch_bounds__(256) void ln_kernel(const float* __restrict__ xp, const float* __restrict__ o2,
                                                 const float* __restrict__ lg, const float* __restrict__ lb,
                                                 float* __restrict__ gatt){
    __shared__ float red[256];
    int r = blockIdx.x, c = threadIdx.x;
    float y = xp[(size_t)r*DD + c] + o2[(size_t)r*DD + c];
    red[c] = y; __syncthreads();
    for(int s=128;s;s>>=1){ if(c<s) red[c] += red[c+s]; __syncthreads(); }
    float mu = red[0]*(1.f/DD);
    __syncthreads();
    float d = y - mu;
    red[c] = d*d; __syncthreads();
    for(int s=128;s;s>>=1){ if(c<s) red[c] += red[c+s]; __syncthreads(); }
    float var = red[0]*(1.f/DD);
    gatt[(size_t)r*DD + c] = lg[c]*d/sqrtf(var+1e-5f) + lb[c];
}

__global__ void feat_reduce2(const float* __restrict__ xp, const float* __restrict__ gatt,
                             float* __restrict__ out){
    int b = blockIdx.x, c = threadIdx.x;
    int j0 = blockIdx.y*64;
    float s1=0.f, s2=0.f;
    for(int j=j0;j<j0+64;j++){
        size_t base = ((size_t)(b*KPOOL + j))*DD + c;
        s1 += xp[base];
        s2 += gatt[base];
    }
    atomicAdd(&out[b*512 + c], s1);
    atomicAdd(&out[b*512 + 256 + c], s2);
}

__global__ void cosine_kernel(const float* __restrict__ u, const float* __restrict__ v,
                              float* __restrict__ out){
    int b = blockIdx.x, t = threadIdx.x;
    float du=0.f, nu=0.f, nv=0.f;
    for(int j=t;j<512;j+=64){
        float a = u[b*512+j], bb = v[b*512+j];
        du += a*bb; nu += a*a; nv += bb*bb;
    }
    for(int m=32;m;m>>=1){
        du += __shfl_xor(du,m); nu += __shfl_xor(nu,m); nv += __shfl_xor(nv,m);
    }
    if(t==0) out[b] = du / (fmaxf(sqrtf(nu),1e-8f)*fmaxf(sqrtf(nv),1e-8f));
}

// =======================================================================
extern "C" void kernel_launch(void* const* d_in, const int* in_sizes, int n_in,
                              void* d_out, int out_size, void* d_ws, size_t ws_size,
                              hipStream_t stream){
    (void)in_sizes; (void)n_in; (void)out_size; (void)ws_size;
    const float* hgt_Wk   = (const float*)d_in[12];
    const float* hgt_Wq   = (const float*)d_in[13];
    const float* hgt_Wv   = (const float*)d_in[14];
    const float* hgt_Wo   = (const float*)d_in[15];
    const float* hgt_arel = (const float*)d_in[16];
    const float* hgt_mrel = (const float*)d_in[17];
    const float* hgt_prel = (const float*)d_in[18];
    const float* hgt_skip = (const float*)d_in[19];
    const float* pool_W   = (const float*)d_in[20];
    const float* pool_att = (const float*)d_in[21];
    const float* pool_bias= (const float*)d_in[22];
    const float* t_wq     = (const float*)d_in[23];
    const float* t_wk     = (const float*)d_in[24];
    const float* t_wv     = (const float*)d_in[25];
    const float* t_wo     = (const float*)d_in[26];
    const float* ln_g     = (const float*)d_in[27];
    const float* ln_b     = (const float*)d_in[28];
    float* out = (float*)d_out;

    char* base = (char*)d_ws;
    size_t off = 0;
    auto allocb = [&](size_t nbytes)->void*{
        void* p = (void*)(base + off);
        off += ((nbytes + 255) & ~(size_t)255);
        return p;
    };
    const size_t MAT = 65536;
    // ---- persistent ----
    u16* bwtk_h = (u16*)allocb(16*MAT*2); u16* bwtk_l = (u16*)allocb(16*MAT*2);
    u16* bwtv_h = (u16*)allocb(16*MAT*2); u16* bwtv_l = (u16*)allocb(16*MAT*2);
    u16* bwq_h  = (u16*)allocb(8*MAT*2);  u16* bwq_l  = (u16*)allocb(8*MAT*2);
    u16* bwo_h  = (u16*)allocb(8*MAT*2);  u16* bwo_l  = (u16*)allocb(8*MAT*2);
    u16* btw_h  = (u16*)allocb(4*MAT*2);  u16* btw_l  = (u16*)allocb(4*MAT*2);
    float* ubuf = (float*)allocb(BB*512*4);
    float* vbuf = (float*)allocb(BB*512*4);
    float* xa_i = (float*)allocb((size_t)NI*DD*4);
    float* xa_d = (float*)allocb((size_t)ND*DD*4);
    float* xb_i = (float*)allocb((size_t)NI*DD*4);
    float* xb_d = (float*)allocb((size_t)ND*DD*4);
    // ---- per-branch CSR ----
    uint32_t* ccnt   = (uint32_t*)allocb((size_t)2*NROW*4);
    uint32_t* rowptr = (uint32_t*)allocb((size_t)(2*NROW+1)*4);
    uint32_t* einfo  = (uint32_t*)allocb((size_t)2*EHGT*4);
    size_t region = off;
    // ---- conv scratch ----
    float* q_i  = (float*)allocb((size_t)NI*DD*4);
    float* q_d  = (float*)allocb((size_t)ND*DD*4);
    u16* ka16 = (u16*)allocb((size_t)4*NI*DD*2);   // bf16 KA; also combine f32 temp
    u16* vm16 = (u16*)allocb((size_t)4*NI*DD*2);
    float* xacc_i= (float*)allocb((size_t)NI*DD*4);
    float* xacc_d= (float*)allocb((size_t)ND*DD*4);
    u16* bcur_h = (u16*)allocb((size_t)NROW*DD*2);
    u16* bcur_l = (u16*)allocb((size_t)NROW*DD*2);
    u16* bagg_h = (u16*)allocb((size_t)NROW*DD*2);
    u16* bagg_l = (u16*)allocb((size_t)NROW*DD*2);
    // ---- pooling/transformer overlay ----
    off = region;
    float* hvec = (float*)allocb(NROW*4);
    float* pscore = (float*)allocb(NROW*4);
    int* seln   = (int*)allocb(BB*KPOOL*4);
    float* sels = (float*)allocb(BB*KPOOL*4);
    float* xp   = (float*)allocb((size_t)BB*KPOOL*DD*4);
    float* o2   = (float*)allocb((size_t)BB*KPOOL*DD*4);
    float* gatt = (float*)allocb((size_t)BB*KPOOL*DD*4);
    u16* bxp_h = (u16*)allocb((size_t)BB*KPOOL*DD*2);
    u16* bxp_l = (u16*)allocb((size_t)BB*KPOOL*DD*2);
    u16* qbh = (u16*)allocb((size_t)BB*KPOOL*DD*2);
    u16* qbl = (u16*)allocb((size_t)BB*KPOOL*DD*2);
    u16* kbh = (u16*)allocb((size_t)BB*KPOOL*DD*2);
    u16* kbl = (u16*)allocb((size_t)BB*KPOOL*DD*2);
    u16* vbh = (u16*)allocb((size_t)BB*KPOOL*DD*2);
    u16* vbl = (u16*)allocb((size_t)BB*KPOOL*DD*2);
    u16* bao_h = (u16*)allocb((size_t)BB*KPOOL*DD*2);
    u16* bao_l = (u16*)allocb((size_t)BB*KPOOL*DD*2);

    const int st_tab[2][4] = {{0,1,0,0},{0,0,1,0}};
    const int dt_tab[2][4] = {{0,0,1,0},{0,1,0,0}};
    const int MR = BB*KPOOL;

    fill_u32<<<(2*BB*512+255)/256,256,0,stream>>>((uint32_t*)ubuf, 0u, 2*BB*512);
    float* wtkF = (float*)ka16;
    float* wtvF = (float*)ka16 + 16*MAT;
    combine_all<<<dim3(256,32),256,0,stream>>>(hgt_Wk, hgt_Wv, hgt_arel, hgt_mrel, wtkF, wtvF);
    WCArgs wc;
    wc.in[0]=wtkF;   wc.oh[0]=bwtk_h; wc.ol[0]=bwtk_l; wc.cnt[0]=16;
    wc.in[1]=wtvF;   wc.oh[1]=bwtv_h; wc.ol[1]=bwtv_l; wc.cnt[1]=16;
    wc.in[2]=hgt_Wq; wc.oh[2]=bwq_h;  wc.ol[2]=bwq_l;  wc.cnt[2]=8;
    wc.in[3]=hgt_Wo; wc.oh[3]=bwo_h;  wc.ol[3]=bwo_l;  wc.cnt[3]=8;
    wc.in[4]=t_wq;   wc.oh[4]=btw_h;          wc.ol[4]=btw_l;          wc.cnt[4]=1;
    wc.in[5]=t_wk;   wc.oh[5]=btw_h+1*MAT;    wc.ol[5]=btw_l+1*MAT;    wc.cnt[5]=1;
    wc.in[6]=t_wv;   wc.oh[6]=btw_h+2*MAT;    wc.ol[6]=btw_l+2*MAT;    wc.cnt[6]=1;
    wc.in[7]=t_wo;   wc.oh[7]=btw_h+3*MAT;    wc.ol[7]=btw_l+3*MAT;    wc.cnt[7]=1;
    wc.nr = 8;
    wcvt_split<<<dim3(256,52),256,0,stream>>>(wc);

    for(int bi=0;bi<2;bi++){
        int ib = bi*6;
        const float* x_inst = (const float*)d_in[ib+0];
        const float* x_data = (const float*)d_in[ib+1];
        const int* ecp = (const int*)d_in[ib+2];
        const int* eip = (const int*)d_in[ib+3];
        const int* eop = (const int*)d_in[ib+4];
        const int* ekp = (const int*)d_in[ib+5];
        const int* rows_f[4] = {ecp, eip, eop, ekp};
        const int* cols_f[4] = {ecp+EC, eip+EI, eop+EO, ekp+EK};

        // ---- CSR build (both dirs, one pass) ----
        CB2 cb;
        for(int r=0;r<4;r++){
            cb.row[r]   = rows_f[r]; cb.col[r]   = cols_f[r]; cb.dt[r]   = dt_tab[0][r]; cb.st[r]   = st_tab[0][r];
            cb.row[4+r] = cols_f[r]; cb.col[4+r] = rows_f[r]; cb.dt[4+r] = dt_tab[1][r]; cb.st[4+r] = st_tab[1][r];
        }
        cb.cnt = ccnt; cb.rowptr = rowptr; cb.einfo = einfo;
        fill_u32<<<(2*NROW+255)/256,256,0,stream>>>(ccnt, 0u, 2*NROW);
        csr_hist2<<<(2*EHGT+255)/256,256,0,stream>>>(cb);
        scan_rowptr2<<<1,1024,0,stream>>>(ccnt, rowptr);
        csr_scatter2<<<(2*EHGT+255)/256,256,0,stream>>>(cb);

        const float* cur_i = x_inst;
        const float* cur_d = x_data;
        cvt_split<<<((NROW*DD/4)+255)/256,256,0,stream>>>(cur_i, NI*DD, cur_d, ND*DD, bcur_h, bcur_l);
        for(int l=0;l<LL;l++){
            float* nxt_i = (l==0) ? xa_i : xb_i;
            float* nxt_d = (l==0) ? xa_d : xb_d;
            for(int dir=0;dir<2;dir++){
                int wb = l*2 + dir;

                // --- mega GEMM: Q(2, f32, split) + KA(4, bf16, prec=1) + VM(4, bf16, prec=1) ---
                GArgs g1; int nb1 = 0, ndx = 0;
                auto addg = [&](int srctype, const u16* Bh, const u16* Bl, float* Cm, u16* Om, int M, int mode, int prec){
                    GDesc& d = g1.d[ndx];
                    size_t ao = srctype ? (size_t)NI*DD : 0;
                    d.Ah = bcur_h + ao; d.Al = bcur_l + ao;
                    d.Bh = Bh; d.Bl = Bl; d.C = Cm;
                    d.Oh = Om; d.Ol = nullptr; d.X = nullptr; d.Xacc = nullptr; d.skipp = nullptr;
                    d.mblks = M/128; d.mode = mode; d.prec = prec;
                    nb1 += M/128; ndx++;
                };
                addg(0, bwq_h + (size_t)(wb*2+0)*MAT, bwq_l + (size_t)(wb*2+0)*MAT, q_i, nullptr, NI, 0, 0);
                addg(1, bwq_h + (size_t)(wb*2+1)*MAT, bwq_l + (size_t)(wb*2+1)*MAT, q_d, nullptr, ND, 0, 0);
                for(int r=0;r<4;r++){
                    int st = st_tab[dir][r];
                    addg(st, bwtk_h + (size_t)(wb*4+r)*MAT, bwtk_l + (size_t)(wb*4+r)*MAT,
                         nullptr, ka16 + (size_t)r*NI*DD, st ? ND : NI, 4, 1);
                }
                for(int r=0;r<4;r++){
                    int st = st_tab[dir][r];
                    addg(st, bwtv_h + (size_t)(wb*4+r)*MAT, bwtv_l + (size_t)(wb*4+r)*MAT,
                         nullptr, vm16 + (size_t)r*NI*DD, st ? ND : NI, 4, 1);
                }
                g1.nd = ndx;
                gemm_mfma<<<dim3(nb1,2),256,0,stream>>>(g1);

                // --- fused edge phase ---
                hgt_fused<<<NROW/4,256,0,stream>>>(rowptr + (size_t)dir*NROW, einfo,
                    q_i, q_d, ka16, vm16, hgt_prel + (size_t)wb*4*HH, bagg_h, bagg_l);

                // --- Wo GEMMs with fused skip/relu epilogue (split) ---
                GArgs g3; g3.nd = 2;
                for(int t=0;t<2;t++){
                    GDesc& d = g3.d[t];
                    size_t ao = t ? (size_t)NI*DD : 0;
                    d.Ah = bagg_h + ao; d.Al = bagg_l + ao;
                    d.Bh = bwo_h + (size_t)(wb*2+t)*MAT; d.Bl = bwo_l + (size_t)(wb*2+t)*MAT;
                    d.C = t ? nxt_d : nxt_i;
                    d.Oh = bcur_h + ao; d.Ol = bcur_l + ao;
                    d.X = t ? cur_d : cur_i;
                    d.Xacc = t ? xacc_d : xacc_i;
                    d.skipp = hgt_skip + wb*2 + t;
                    d.mblks = (t ? ND : NI)/128;
                    d.mode = dir ? 3 : 2;
                    d.prec = 0;
                }
                gemm_mfma<<<dim3(NI/128 + ND/128,2),256,0,stream>>>(g3);
            }
            cur_i = nxt_i;
            cur_d = nxt_d;
        }

        // -------- SAGPooling (CSR-based, no atomics) --------
        pool_h2<<<NROW/4,256,0,stream>>>(cur_i, cur_d, pool_W, hvec);
        pool_csr<<<NROW/4,256,0,stream>>>(rowptr, einfo, hvec, pool_att, pscore);
        topk_rank<<<dim3(6,BB),256,0,stream>>>(pscore, pool_bias, seln, sels);
        gather_xp<<<BB*KPOOL,256,0,stream>>>(seln, sels, cur_i, cur_d, xp, bxp_h, bxp_l);

        // -------- transformer --------
        GArgs g4; g4.nd = 3;
        for(int t=0;t<3;t++){
            GDesc& d = g4.d[t];
            d.Ah=bxp_h; d.Al=bxp_l;
            d.Bh=btw_h + (size_t)t*MAT; d.Bl=btw_l + (size_t)t*MAT;
            d.C = nullptr;
            d.Oh = (t==0)? qbh : (t==1)? kbh : vbh;
            d.Ol = (t==0)? qbl : (t==1)? kbl : vbl;
            d.X = nullptr; d.Xacc = nullptr; d.skipp = nullptr;
            d.mblks = MR/128; d.mode = 1; d.prec = 0;
        }
        gemm_mfma<<<dim3(3*(MR/128),2),256,0,stream>>>(g4);
        attn_mfma<<<dim3(KPOOL/64, BB*HH),256,0,stream>>>(qbh, qbl, kbh, kbl, vbh, bao_h, bao_l);
        GArgs g5; g5.nd = 1;
        {
            GDesc& d = g5.d[0];
            d.Ah=bao_h; d.Al=bao_l;
            d.Bh=btw_h + (size_t)3*MAT; d.Bl=btw_l + (size_t)3*MAT;
            d.C=o2; d.Oh=nullptr; d.Ol=nullptr; d.X=nullptr; d.Xacc=nullptr; d.skipp=nullptr;
            d.mblks=MR/128; d.mode=0; d.prec=0;
        }
        gemm_mfma<<<dim3(MR/128,2),256,0,stream>>>(g5);
        ln_kernel<<<MR,256,0,stream>>>(xp, o2, ln_g, ln_b, gatt);
        feat_reduce2<<<dim3(BB,12),256,0,stream>>>(xp, gatt, bi ? vbuf : ubuf);
    }

    cosine_kernel<<<BB,64,0,stream>>>(ubuf, vbuf, out);
}

// Round 17
// 1047.240 us; speedup vs baseline: 1.8570x; 1.0137x over previous
//
#include <hip/hip_runtime.h>
#include <math.h>
#include <stdint.h>

#define LL 2
#define HH 4
#define DHH 64
#define DD 256
#define BB 8
#define NI 8192
#define ND 4096
#define NROW 12288
#define KPOOL 768
#define EC 65536
#define EI 32768
#define EO 32768
#define EK 8192
#define EHGT (EC+EI+EO+EK)

typedef unsigned short u16;
typedef short bf16x8 __attribute__((ext_vector_type(8)));
typedef float f32x4 __attribute__((ext_vector_type(4)));
typedef unsigned short u16x4 __attribute__((ext_vector_type(4)));

__device__ inline float gelu_f(float x){ return 0.5f*x*(1.f+erff(x*0.70710678118654752f)); }
__device__ inline u16 f2b(float x){ uint32_t u=__float_as_uint(x); return (u16)((u + 0x7fffu + ((u>>16)&1u))>>16); }
__device__ inline float b2f(u16 h){ return __uint_as_float(((uint32_t)h)<<16); }

// ---------------- generic fill ----------------
__global__ void fill_u32(uint32_t* p, uint32_t v, int n){
    int i = blockIdx.x*256 + threadIdx.x;
    if(i<n) p[i]=v;
}

// ---------------- activation split-convert ----------------
__global__ void cvt_split(const float* __restrict__ A, int nA, const float* __restrict__ B, int nB,
                          u16* __restrict__ oh, u16* __restrict__ ol){
    int i = (blockIdx.x*256 + threadIdx.x)*4;
    int tot = nA + nB;
    if(i >= tot) return;
    float4 v = (i < nA) ? *(const float4*)(A + i) : *(const float4*)(B + (i - nA));
    float vv[4] = {v.x, v.y, v.z, v.w};
    u16x4 h4, l4;
    #pragma unroll
    for(int j=0;j<4;j++){
        float x = vv[j];
        u16 h = f2b(x);
        h4[j] = h;
        l4[j] = f2b(x - b2f(h));
    }
    *(u16x4*)(oh + i) = h4;
    *(u16x4*)(ol + i) = l4;
}

// ---------------- weight transpose + split ----------------
struct WCArgs { const float* in[8]; u16* oh[8]; u16* ol[8]; int cnt[8]; int nr; };
__global__ void wcvt_split(WCArgs a){
    int mat = blockIdx.y, ri = 0;
    while(ri < a.nr-1 && mat >= a.cnt[ri]){ mat -= a.cnt[ri]; ri++; }
    const float* in = a.in[ri] + (size_t)mat*65536;
    u16* oh = a.oh[ri] + (size_t)mat*65536;
    u16* ol = a.ol[ri] + (size_t)mat*65536;
    int n = blockIdx.x, k = threadIdx.x;
    float x = in[(size_t)k*DD + n];
    u16 h = f2b(x);
    oh[n*DD + k] = h;
    ol[n*DD + k] = f2b(x - b2f(h));
}

// ---------------- MFMA batched GEMM with fused, LDS-restaged epilogues ----------------
// prec=0: split hi/lo (3 MFMA/step); prec=1: hi-only (1 MFMA/step, half staging)
// mode 0: C=f32   mode 1: Oh/Ol=split bf16   mode 4: Oh=plain bf16
// mode 2: Xacc = 0.5*(g*acc + (1-g)*X)
// mode 3: v=relu(Xacc + 0.5*(g*acc+(1-g)*X)); C=v; Oh/Ol=split(v)
struct GDesc { const u16* Ah; const u16* Al; const u16* Bh; const u16* Bl;
               float* C; u16* Oh; u16* Ol;
               const float* X; float* Xacc; const float* skipp;
               int mblks; int mode; int prec; };
struct GArgs { GDesc d[10]; int nd; };

__global__ __launch_bounds__(256) void gemm_mfma(GArgs ga){
    __shared__ u16 SBUF[2*128*64];
    char* Abuf = (char*)SBUF;
    char* Bbuf = (char*)(SBUF + 128*64);
    int mb = blockIdx.x, di = 0;
    while(di < ga.nd-1 && mb >= ga.d[di].mblks){ mb -= ga.d[di].mblks; di++; }
    GDesc g = ga.d[di];
    const int prec = g.prec;
    const int m0 = mb*128, n0 = blockIdx.y*128;
    const int tid = threadIdx.x;
    const int lane = tid & 63, wid = tid >> 6;
    const int wm = (wid>>1)*64, wn = (wid&1)*64;
    const int l15 = lane & 15, l4 = lane >> 4;
    const int srow = tid >> 1, hf = tid & 1;
    const int ssw = (srow&7)<<4;
    const int c0 = (hf*32) ^ ssw;
    const int c1 = (hf*32+16) ^ ssw;
    const int c2 = (64+hf*32) ^ ssw;
    const int c3 = (64+hf*32+16) ^ ssw;
    const int rbyte = srow*128;
    const u16* __restrict__ Aph = g.Ah + (size_t)(m0 + srow)*DD + hf*16;
    const u16* __restrict__ Apl = g.Al + (size_t)(m0 + srow)*DD + hf*16;
    const u16* __restrict__ Bph = g.Bh + (size_t)(n0 + srow)*DD + hf*16;
    const u16* __restrict__ Bpl = g.Bl + (size_t)(n0 + srow)*DD + hf*16;
    f32x4 acc[4][4] = {};
    bf16x8 r0, r1, r2, r3, r4, r5, r6, r7;
    r0 = *(const bf16x8*)(Aph);
    r1 = *(const bf16x8*)(Aph + 8);
    r4 = *(const bf16x8*)(Bph);
    r5 = *(const bf16x8*)(Bph + 8);
    if(!prec){
        r2 = *(const bf16x8*)(Apl);
        r3 = *(const bf16x8*)(Apl + 8);
        r6 = *(const bf16x8*)(Bpl);
        r7 = *(const bf16x8*)(Bpl + 8);
    }
    #pragma unroll
    for(int k0=0;k0<DD;k0+=32){
        __syncthreads();
        *(bf16x8*)(Abuf + rbyte + c0) = r0; *(bf16x8*)(Abuf + rbyte + c1) = r1;
        *(bf16x8*)(Bbuf + rbyte + c0) = r4; *(bf16x8*)(Bbuf + rbyte + c1) = r5;
        if(!prec){
            *(bf16x8*)(Abuf + rbyte + c2) = r2; *(bf16x8*)(Abuf + rbyte + c3) = r3;
            *(bf16x8*)(Bbuf + rbyte + c2) = r6; *(bf16x8*)(Bbuf + rbyte + c3) = r7;
        }
        __syncthreads();
        if(k0 + 32 < DD){
            int kn = k0 + 32;
            r0 = *(const bf16x8*)(Aph + kn);     r1 = *(const bf16x8*)(Aph + kn + 8);
            r4 = *(const bf16x8*)(Bph + kn);     r5 = *(const bf16x8*)(Bph + kn + 8);
            if(!prec){
                r2 = *(const bf16x8*)(Apl + kn); r3 = *(const bf16x8*)(Apl + kn + 8);
                r6 = *(const bf16x8*)(Bpl + kn); r7 = *(const bf16x8*)(Bpl + kn + 8);
            }
        }
        bf16x8 afh[4], bfh[4];
        #pragma unroll
        for(int i=0;i<4;i++){
            int ar = wm + i*16 + l15;
            int abase = ar*128;
            afh[i] = *(const bf16x8*)(Abuf + abase + ((l4*16) ^ ((ar&7)<<4)));
            int br = wn + i*16 + l15;
            int bbase = br*128;
            bfh[i] = *(const bf16x8*)(Bbuf + bbase + ((l4*16) ^ ((br&7)<<4)));
        }
        #pragma unroll
        for(int i=0;i<4;i++)
            #pragma unroll
            for(int j=0;j<4;j++)
                acc[i][j] = __builtin_amdgcn_mfma_f32_16x16x32_bf16(afh[i], bfh[j], acc[i][j], 0,0,0);
        if(!prec){
            bf16x8 afl[4], bfl[4];
            #pragma unroll
            for(int i=0;i<4;i++){
                int ar = wm + i*16 + l15;
                int abase = ar*128;
                afl[i] = *(const bf16x8*)(Abuf + abase + ((64 + l4*16) ^ ((ar&7)<<4)));
                int br = wn + i*16 + l15;
                int bbase = br*128;
                bfl[i] = *(const bf16x8*)(Bbuf + bbase + ((64 + l4*16) ^ ((br&7)<<4)));
            }
            #pragma unroll
            for(int i=0;i<4;i++)
                #pragma unroll
                for(int j=0;j<4;j++){
                    acc[i][j] = __builtin_amdgcn_mfma_f32_16x16x32_bf16(afh[i], bfl[j], acc[i][j], 0,0,0);
                    acc[i][j] = __builtin_amdgcn_mfma_f32_16x16x32_bf16(afl[i], bfh[j], acc[i][j], 0,0,0);
                }
        }
    }
    // ---- coalesced epilogue via LDS restage (two 64-row passes) ----
    const int mode = g.mode;
    float gg = 0.f;
    if(mode == 2 || mode == 3) gg = 1.f/(1.f + expf(-*g.skipp));
    float* LDSf = (float*)SBUF;
    const int lrow = tid >> 5;
    const int cc4 = (tid & 31)*4;
    #pragma unroll
    for(int half=0; half<2; half++){
        __syncthreads();
        if((wid>>1) == half){
            #pragma unroll
            for(int i=0;i<4;i++)
                #pragma unroll
                for(int j=0;j<4;j++)
                    #pragma unroll
                    for(int r=0;r<4;r++)
                        LDSf[(i*16 + l4*4 + r)*128 + wn + j*16 + l15] = acc[i][j][r];
        }
        __syncthreads();
        #pragma unroll
        for(int k=0;k<8;k++){
            int row = lrow + k*8;
            size_t o = (size_t)(m0 + half*64 + row)*DD + n0 + cc4;
            float4 v = *(const float4*)&LDSf[row*128 + cc4];
            float vv[4] = {v.x, v.y, v.z, v.w};
            if(mode==0){
                *(float4*)(g.C + o) = v;
            } else if(mode==4){
                u16x4 h4;
                #pragma unroll
                for(int j=0;j<4;j++) h4[j] = f2b(vv[j]);
                *(u16x4*)(g.Oh + o) = h4;
            } else if(mode==1){
                u16x4 h4, lo4;
                #pragma unroll
                for(int j=0;j<4;j++){
                    u16 hh = f2b(vv[j]); h4[j]=hh; lo4[j]=f2b(vv[j]-b2f(hh));
                }
                *(u16x4*)(g.Oh + o) = h4;
                *(u16x4*)(g.Ol + o) = lo4;
            } else if(mode==2){
                float4 x = *(const float4*)(g.X + o);
                float xx[4] = {x.x, x.y, x.z, x.w};
                float4 w;
                float* ww = (float*)&w;
                #pragma unroll
                for(int j=0;j<4;j++) ww[j] = 0.5f*(gg*vv[j] + (1.f-gg)*xx[j]);
                *(float4*)(g.Xacc + o) = w;
            } else {
                float4 x = *(const float4*)(g.X + o);
                float4 xa = *(const float4*)(g.Xacc + o);
                float xx[4] = {x.x, x.y, x.z, x.w};
                float aa[4] = {xa.x, xa.y, xa.z, xa.w};
                float4 cv;
                float* cvv = (float*)&cv;
                u16x4 h4, lo4;
                #pragma unroll
                for(int j=0;j<4;j++){
                    float v3 = aa[j] + 0.5f*(gg*vv[j] + (1.f-gg)*xx[j]);
                    v3 = v3 > 0.f ? v3 : 0.f;
                    cvv[j] = v3;
                    u16 hh = f2b(v3); h4[j]=hh; lo4[j]=f2b(v3-b2f(hh));
                }
                *(float4*)(g.C + o) = cv;
                *(u16x4*)(g.Oh + o) = h4;
                *(u16x4*)(g.Ol + o) = lo4;
            }
        }
    }
}

// ---------- combine ----------
__global__ void combine_all(const float* __restrict__ Wk, const float* __restrict__ Wv,
                            const float* __restrict__ Ra, const float* __restrict__ Rm,
                            float* __restrict__ wtk, float* __restrict__ wtv){
    const int st_tab[2][4] = {{0,1,0,0},{0,0,1,0}};
    int combo = blockIdx.y;
    int idx = combo >> 1, kv = combo & 1;
    int r = idx & 3, wb = idx >> 2, dir = wb & 1;
    int st = st_tab[dir][r];
    const float* W = (kv ? Wv : Wk) + (size_t)(wb*2 + st)*65536;
    const float* R = (kv ? Rm : Ra) + (size_t)idx*16384;
    float* o = (kv ? wtv : wtk) + (size_t)idx*65536;
    int d = blockIdx.x, c = threadIdx.x;
    int h = c >> 6, f = c & 63;
    const float* Wrow = W + d*DD + h*64;
    const float* Rh = R + h*4096 + f;
    float s = 0.f;
    #pragma unroll 8
    for(int k=0;k<64;k++) s += Wrow[k]*Rh[k*64];
    o[d*DD + c] = s;
}

// ---------------- CSR build (both directions in one pass) ----------------
__device__ inline void edge_decode(int e, int& r, int& el){
    if(e < EC){ r=0; el=e; }
    else if(e < EC+EI){ r=1; el=e-EC; }
    else if(e < EC+EI+EO){ r=2; el=e-(EC+EI); }
    else { r=3; el=e-(EC+EI+EO); }
}

struct CB2 {
    const int* row[8]; const int* col[8];
    int dt[8]; int st[8];
    uint32_t* cnt; uint32_t* rowptr; uint32_t* einfo;
};

__global__ void csr_hist2(CB2 a){
    int ge = blockIdx.x*256 + threadIdx.x;
    if(ge >= 2*EHGT) return;
    int dir = ge >= EHGT;
    int e = ge - dir*EHGT;
    int r, el; edge_decode(e, r, el);
    int idx = dir*4 + r;
    int c = a.col[idx][el];
    int dst = dir*NROW + (a.dt[idx] ? (NI + c) : c);
    atomicAdd(&a.cnt[dst], 1u);
}

__global__ __launch_bounds__(1024) void scan_rowptr2(uint32_t* cnt, uint32_t* rowptr){
    __shared__ uint32_t part[1024];
    int t = threadIdx.x;
    int base = t*24;
    uint32_t lpre[24];
    uint32_t sum = 0;
    #pragma unroll
    for(int i=0;i<24;i++){
        uint32_t c = cnt[base+i];
        lpre[i] = sum; sum += c;
        cnt[base+i] = 0;
    }
    part[t] = sum;
    __syncthreads();
    for(int offs=1; offs<1024; offs<<=1){
        uint32_t v = (t>=offs) ? part[t-offs] : 0u;
        __syncthreads();
        part[t] += v;
        __syncthreads();
    }
    uint32_t pre = (t==0) ? 0u : part[t-1];
    #pragma unroll
    for(int i=0;i<24;i++) rowptr[base+i] = pre + lpre[i];
    if(t==1023) rowptr[2*NROW] = part[1023];
}

__global__ void csr_scatter2(CB2 a){
    int ge = blockIdx.x*256 + threadIdx.x;
    if(ge >= 2*EHGT) return;
    int dir = ge >= EHGT;
    int e = ge - dir*EHGT;
    int r, el; edge_decode(e, r, el);
    int idx = dir*4 + r;
    int c = a.col[idx][el];
    int dst = dir*NROW + (a.dt[idx] ? (NI + c) : c);
    int src = a.row[idx][el];
    uint32_t p = a.rowptr[dst] + atomicAdd(&a.cnt[dst], 1u);
    uint32_t vmidx = (uint32_t)(r*NI + src);
    uint32_t hom = a.st[idx] ? (uint32_t)(NI + src) : (uint32_t)src;
    a.einfo[p] = vmidx | (hom << 16);
}

// ---------------- fused HGT edge phase: wave per dst, all 4 heads, online softmax ----------------
__global__ __launch_bounds__(256) void hgt_fused(const uint32_t* __restrict__ rowptr,
                                                 const uint32_t* __restrict__ einfo,
                                                 const float* __restrict__ q_i,
                                                 const float* __restrict__ q_d,
                                                 const u16* __restrict__ ka,
                                                 const u16* __restrict__ vm,
                                                 const float* __restrict__ prel,
                                                 u16* __restrict__ bagg_h,
                                                 u16* __restrict__ bagg_l){
    int wv = threadIdx.x >> 6, lane = threadIdx.x & 63;
    int rowi = blockIdx.x*4 + wv;
    uint32_t p0 = rowptr[rowi], p1 = rowptr[rowi+1];
    int h = lane >> 4;
    const float* qrow = (rowi < NI) ? (q_i + (size_t)rowi*DD) : (q_d + (size_t)(rowi-NI)*DD);
    float4 q4 = *(const float4*)(qrow + lane*4);
    float pr0 = prel[0*HH+h]*0.125f, pr1 = prel[1*HH+h]*0.125f;
    float pr2 = prel[2*HH+h]*0.125f, pr3 = prel[3*HH+h]*0.125f;
    float m = -INFINITY, den = 0.f;
    float4 o4 = {0.f,0.f,0.f,0.f};
    for(uint32_t p = p0; p < p1; p++){
        uint32_t vmidx = einfo[p] & 0xffffu;
        int r = vmidx >> 13;
        uint2 kr = *(const uint2*)(ka + (size_t)vmidx*DD + lane*4);
        uint2 vr = *(const uint2*)(vm + (size_t)vmidx*DD + lane*4);
        float k0 = __uint_as_float(kr.x << 16), k1 = __uint_as_float(kr.x & 0xffff0000u);
        float k2 = __uint_as_float(kr.y << 16), k3 = __uint_as_float(kr.y & 0xffff0000u);
        float v0 = __uint_as_float(vr.x << 16), v1 = __uint_as_float(vr.x & 0xffff0000u);
        float v2 = __uint_as_float(vr.y << 16), v3 = __uint_as_float(vr.y & 0xffff0000u);
        float d = q4.x*k0 + q4.y*k1 + q4.z*k2 + q4.w*k3;
        d += __shfl_xor(d, 1); d += __shfl_xor(d, 2);
        d += __shfl_xor(d, 4); d += __shfl_xor(d, 8);
        float pf = (r==0) ? pr0 : (r==1) ? pr1 : (r==2) ? pr2 : pr3;
        float s = d * pf;
        float nm = fmaxf(m, s);
        float sc_ = expf(m - nm);
        float pe = expf(s - nm);
        den = den*sc_ + pe;
        o4.x = o4.x*sc_ + pe*v0;
        o4.y = o4.y*sc_ + pe*v1;
        o4.z = o4.z*sc_ + pe*v2;
        o4.w = o4.w*sc_ + pe*v3;
        m = nm;
    }
    float inv = 1.f/(den + 1e-16f);
    float vals[4] = {o4.x*inv, o4.y*inv, o4.z*inv, o4.w*inv};
    u16x4 h4, l4;
    #pragma unroll
    for(int j=0;j<4;j++){
        float g = gelu_f(vals[j]);
        u16 hh = f2b(g);
        h4[j] = hh;
        l4[j] = f2b(g - b2f(hh));
    }
    size_t ob = (size_t)rowi*DD + lane*4;
    *(u16x4*)(bagg_h + ob) = h4;
    *(u16x4*)(bagg_l + ob) = l4;
}

// ---------------- pooling ----------------
__global__ void pool_h2(const float* __restrict__ xi, const float* __restrict__ xd,
                        const float* __restrict__ w, float* __restrict__ h){
    int node = blockIdx.x*4 + (threadIdx.x>>6);
    int lane = threadIdx.x & 63;
    const float* xr = (node < NI) ? (xi + (size_t)node*DD) : (xd + (size_t)(node-NI)*DD);
    float s = 0.f;
    for(int j=lane;j<DD;j+=64) s += xr[j]*w[j];
    for(int m=32;m;m>>=1) s += __shfl_xor(s, m);
    if(lane==0) h[node] = s;
}

// GAT-style pooling score via fwd CSR + implicit self-loop; wave per dst node
__global__ __launch_bounds__(256) void pool_csr(const uint32_t* __restrict__ rowptr,
                                                const uint32_t* __restrict__ einfo,
                                                const float* __restrict__ h,
                                                const float* __restrict__ att,
                                                float* __restrict__ score){
    int w = blockIdx.x*4 + (threadIdx.x >> 6);
    int lane = threadIdx.x & 63;
    if(w >= NROW) return;
    uint32_t p0 = rowptr[w], p1 = rowptr[w+1];
    float a0 = att[0], a1 = att[1];
    float hn = h[w];
    float es = a0*hn + a1*hn;
    es = es >= 0.f ? es : 0.2f*es;
    float m = -INFINITY;
    for(uint32_t p = p0+lane; p < p1; p += 64){
        float hs = h[einfo[p] >> 16];
        float e = a0*hs + a1*hn;
        e = e >= 0.f ? e : 0.2f*e;
        m = fmaxf(m, e);
    }
    #pragma unroll
    for(int s=32;s;s>>=1) m = fmaxf(m, __shfl_xor(m, s));
    m = fmaxf(m, es);
    float lden = 0.f, lnum = 0.f;
    for(uint32_t p = p0+lane; p < p1; p += 64){
        float hs = h[einfo[p] >> 16];
        float e = a0*hs + a1*hn;
        e = e >= 0.f ? e : 0.2f*e;
        float a = expf(e - m);
        lden += a; lnum += a*hs;
    }
    #pragma unroll
    for(int s=32;s;s>>=1){ lden += __shfl_xor(lden, s); lnum += __shfl_xor(lnum, s); }
    float aself = expf(es - m);
    lden += aself; lnum += aself*hn;
    if(lane==0) score[w] = lnum/(lden + 1e-16f);
}

// ---------------- top-768 of 1536 per graph via exact rank selection ----------------
__global__ __launch_bounds__(256) void topk_rank(const float* __restrict__ score,
                                                 const float* __restrict__ bias,
                                                 int* __restrict__ sel_node,
                                                 float* __restrict__ sel_scale){
    __shared__ float keys[1536];
    int b = blockIdx.y;
    for(int t=threadIdx.x; t<1536; t+=256){
        int node = (t<1024) ? (b*1024 + t) : (NI + b*512 + (t-1024));
        keys[t] = score[node];
    }
    __syncthreads();
    int i = blockIdx.x*256 + threadIdx.x;
    float ki = keys[i];
    int rank = 0;
    #pragma unroll 8
    for(int j=0;j<1536;j++){
        float kj = keys[j];
        rank += (kj > ki) || (kj == ki && j < i);
    }
    if(rank < KPOOL){
        int node = (i<1024) ? (b*1024 + i) : (NI + b*512 + (i-1024));
        sel_node[b*KPOOL + rank] = node;
        sel_scale[b*KPOOL + rank] = tanhf(ki + bias[0]);
    }
}

__global__ void gather_xp(const int* __restrict__ sel, const float* __restrict__ scale,
                          const float* __restrict__ xi, const float* __restrict__ xd,
                          float* __restrict__ xp, u16* __restrict__ bh, u16* __restrict__ bl){
    int i = blockIdx.x*256 + threadIdx.x;
    int rowp = i >> 8, c = i & 255;
    int node = sel[rowp];
    float s = scale[rowp];
    float v = (node < NI) ? xi[(size_t)node*DD + c] : xd[(size_t)(node-NI)*DD + c];
    float x = v*s;
    xp[i] = x;
    u16 hh = f2b(x);
    bh[i] = hh;
    bl[i] = f2b(x - b2f(hh));
}

// ---------------- MFMA flash attention: block per (bh, 64 q rows), plain-bf16 QKV ----------------
// grid (BB*HH, KPOOL/64): gridDim.x = 32 ≡ 0 mod 8, so XCD = bh % 8 for all q-tiles
// of the same (b,h) -> K/V stays in one XCD's L2.
__global__ __launch_bounds__(256) void attn_mfma(const u16* __restrict__ Qh,
                                                 const u16* __restrict__ Kh,
                                                 const u16* __restrict__ Vh,
                                                 u16* __restrict__ aoh, u16* __restrict__ aol){
    __shared__ u16 KhS[64*64], VtS[64*64];
    char* KhB = (char*)KhS; char* VtB = (char*)VtS;
    int bh = blockIdx.x;
    int b = bh >> 2, h = bh & 3;
    int q0 = blockIdx.y * 64;
    int tid = threadIdx.x;
    int lane = tid & 63;
    int w = tid >> 6;
    int l15 = lane & 15, l4 = lane >> 4;
    size_t qrow = (size_t)(b*KPOOL + q0 + w*16 + l15);
    bf16x8 qh[2];
    #pragma unroll
    for(int c=0;c<2;c++)
        qh[c] = *(const bf16x8*)(Qh + qrow*DD + h*64 + c*32 + l4*8);
    float mreg = -INFINITY, lreg = 0.f;
    f32x4 O[4] = {};
    for(int k0=0;k0<KPOOL;k0+=64){
        __syncthreads();
        {   // stage K (vectorized, swizzled) + V^T (row-pair packed u32 stores)
            int row = tid >> 2, q4 = tid & 3;
            size_t gbase = ((size_t)(b*KPOOL + k0 + row))*DD + h*64 + q4*16;
            bf16x8 k0v = *(const bf16x8*)(Kh + gbase);
            bf16x8 k1v = *(const bf16x8*)(Kh + gbase + 8);
            int sw = (row&7)<<4;
            int colb = q4*32;
            *(bf16x8*)(KhB + row*128 + (colb ^ sw))      = k0v;
            *(bf16x8*)(KhB + row*128 + ((colb+16) ^ sw)) = k1v;
            int row0 = (tid >> 3)*2, dhg = (tid & 7)*8;
            size_t vbase = ((size_t)(b*KPOOL + k0 + row0))*DD + h*64 + dhg;
            bf16x8 va = *(const bf16x8*)(Vh + vbase);
            bf16x8 vb = *(const bf16x8*)(Vh + vbase + DD);
            #pragma unroll
            for(int j=0;j<8;j++){
                int dh = dhg + j;
                uint32_t pk = (uint32_t)(u16)(short)va[j] | ((uint32_t)(u16)(short)vb[j] << 16);
                *(uint32_t*)(VtB + dh*128 + ((row0*2) ^ ((dh&7)<<4))) = pk;
            }
        }
        __syncthreads();
        // S^T tiles: mfma(A=K, B=Q)  (plain bf16: 2 MFMA per tile)
        f32x4 s[4] = {};
        #pragma unroll
        for(int t=0;t<4;t++){
            int arow = t*16 + l15;
            int sw = (arow&7)<<4;
            const char* bh_ = KhB + arow*128;
            bf16x8 kh0 = *(const bf16x8*)(bh_ + ((l4*16) ^ sw));
            bf16x8 kh1 = *(const bf16x8*)(bh_ + ((l4*16 + 64) ^ sw));
            s[t] = __builtin_amdgcn_mfma_f32_16x16x32_bf16(kh0, qh[0], s[t], 0,0,0);
            s[t] = __builtin_amdgcn_mfma_f32_16x16x32_bf16(kh1, qh[1], s[t], 0,0,0);
        }
        // online softmax
        float cm = -INFINITY;
        #pragma unroll
        for(int t=0;t<4;t++)
            #pragma unroll
            for(int r=0;r<4;r++){ s[t][r] *= 0.125f; cm = fmaxf(cm, s[t][r]); }
        cm = fmaxf(cm, __shfl_xor(cm,16));
        cm = fmaxf(cm, __shfl_xor(cm,32));
        float nm = fmaxf(mreg, cm);
        float es = expf(mreg - nm);
        float ps = 0.f;
        #pragma unroll
        for(int t=0;t<4;t++)
            #pragma unroll
            for(int r=0;r<4;r++){ float pv = expf(s[t][r] - nm); s[t][r] = pv; ps += pv; }
        ps += __shfl_xor(ps,16);
        ps += __shfl_xor(ps,32);
        lreg = lreg*es + ps;
        mreg = nm;
        #pragma unroll
        for(int d=0;d<4;d++){ O[d][0]*=es; O[d][1]*=es; O[d][2]*=es; O[d][3]*=es; }
        // O^T += mfma(A=V^T, B=P^T)
        #pragma unroll
        for(int c32=0;c32<2;c32++){
            bf16x8 pb;
            #pragma unroll
            for(int j=0;j<8;j++){
                int srcl = ((((lane>>4)*2 + (j>>2)) & 3) << 4) | l15;
                float v0 = __shfl(s[c32*2+0][j&3], srcl, 64);
                float v1 = __shfl(s[c32*2+1][j&3], srcl, 64);
                float v = (lane < 32) ? v0 : v1;
                pb[j] = (short)f2b(v);
            }
            #pragma unroll
            for(int dhb=0; dhb<4; dhb++){
                int vrow = dhb*16 + l15;
                bf16x8 va = *(const bf16x8*)(VtB + vrow*128 + ((c32*64 + l4*16) ^ ((vrow&7)<<4)));
                O[dhb] = __builtin_amdgcn_mfma_f32_16x16x32_bf16(va, pb, O[dhb], 0,0,0);
            }
        }
    }
    float inv = 1.f/lreg;
    #pragma unroll
    for(int dhb=0;dhb<4;dhb++)
        #pragma unroll
        for(int r=0;r<4;r++){
            float val = O[dhb][r]*inv;
            size_t o = qrow*DD + h*64 + dhb*16 + l4*4 + r;
            u16 hh = f2b(val);
            aoh[o] = hh;
            aol[o] = f2b(val - b2f(hh));
        }
}

// layernorm row kernel
__global__ __launch_bounds__(256) void ln_kernel(const float* __restrict__ xp, const float* __restrict__ o2,
                                                 const float* __restrict__ lg, const float* __restrict__ lb,
                                                 float* __restrict__ gatt){
    __shared__ float red[256];
    int r = blockIdx.x, c = threadIdx.x;
    float y = xp[(size_t)r*DD + c] + o2[(size_t)r*DD + c];
    red[c] = y; __syncthreads();
    for(int s=128;s;s>>=1){ if(c<s) red[c] += red[c+s]; __syncthreads(); }
    float mu = red[0]*(1.f/DD);
    __syncthreads();
    float d = y - mu;
    red[c] = d*d; __syncthreads();
    for(int s=128;s;s>>=1){ if(c<s) red[c] += red[c+s]; __syncthreads(); }
    float var = red[0]*(1.f/DD);
    gatt[(size_t)r*DD + c] = lg[c]*d/sqrtf(var+1e-5f) + lb[c];
}

__global__ void feat_reduce2(const float* __restrict__ xp, const float* __restrict__ gatt,
                             float* __restrict__ out){
    int b = blockIdx.x, c = threadIdx.x;
    int j0 = blockIdx.y*64;
    float s1=0.f, s2=0.f;
    for(int j=j0;j<j0+64;j++){
        size_t base = ((size_t)(b*KPOOL + j))*DD + c;
        s1 += xp[base];
        s2 += gatt[base];
    }
    atomicAdd(&out[b*512 + c], s1);
    atomicAdd(&out[b*512 + 256 + c], s2);
}

__global__ void cosine_kernel(const float* __restrict__ u, const float* __restrict__ v,
                              float* __restrict__ out){
    int b = blockIdx.x, t = threadIdx.x;
    float du=0.f, nu=0.f, nv=0.f;
    for(int j=t;j<512;j+=64){
        float a = u[b*512+j], bb = v[b*512+j];
        du += a*bb; nu += a*a; nv += bb*bb;
    }
    for(int m=32;m;m>>=1){
        du += __shfl_xor(du,m); nu += __shfl_xor(nu,m); nv += __shfl_xor(nv,m);
    }
    if(t==0) out[b] = du / (fmaxf(sqrtf(nu),1e-8f)*fmaxf(sqrtf(nv),1e-8f));
}

// =======================================================================
extern "C" void kernel_launch(void* const* d_in, const int* in_sizes, int n_in,
                              void* d_out, int out_size, void* d_ws, size_t ws_size,
                              hipStream_t stream){
    (void)in_sizes; (void)n_in; (void)out_size; (void)ws_size;
    const float* hgt_Wk   = (const float*)d_in[12];
    const float* hgt_Wq   = (const float*)d_in[13];
    const float* hgt_Wv   = (const float*)d_in[14];
    const float* hgt_Wo   = (const float*)d_in[15];
    const float* hgt_arel = (const float*)d_in[16];
    const float* hgt_mrel = (const float*)d_in[17];
    const float* hgt_prel = (const float*)d_in[18];
    const float* hgt_skip = (const float*)d_in[19];
    const float* pool_W   = (const float*)d_in[20];
    const float* pool_att = (const float*)d_in[21];
    const float* pool_bias= (const float*)d_in[22];
    const float* t_wq     = (const float*)d_in[23];
    const float* t_wk     = (const float*)d_in[24];
    const float* t_wv     = (const float*)d_in[25];
    const float* t_wo     = (const float*)d_in[26];
    const float* ln_g     = (const float*)d_in[27];
    const float* ln_b     = (const float*)d_in[28];
    float* out = (float*)d_out;

    char* base = (char*)d_ws;
    size_t off = 0;
    auto allocb = [&](size_t nbytes)->void*{
        void* p = (void*)(base + off);
        off += ((nbytes + 255) & ~(size_t)255);
        return p;
    };
    const size_t MAT = 65536;
    // ---- persistent ----
    u16* bwtk_h = (u16*)allocb(16*MAT*2); u16* bwtk_l = (u16*)allocb(16*MAT*2);
    u16* bwtv_h = (u16*)allocb(16*MAT*2); u16* bwtv_l = (u16*)allocb(16*MAT*2);
    u16* bwq_h  = (u16*)allocb(8*MAT*2);  u16* bwq_l  = (u16*)allocb(8*MAT*2);
    u16* bwo_h  = (u16*)allocb(8*MAT*2);  u16* bwo_l  = (u16*)allocb(8*MAT*2);
    u16* btw_h  = (u16*)allocb(4*MAT*2);  u16* btw_l  = (u16*)allocb(4*MAT*2);
    float* ubuf = (float*)allocb(BB*512*4);
    float* vbuf = (float*)allocb(BB*512*4);
    float* xa_i = (float*)allocb((size_t)NI*DD*4);
    float* xa_d = (float*)allocb((size_t)ND*DD*4);
    float* xb_i = (float*)allocb((size_t)NI*DD*4);
    float* xb_d = (float*)allocb((size_t)ND*DD*4);
    // ---- per-branch CSR ----
    uint32_t* ccnt   = (uint32_t*)allocb((size_t)2*NROW*4);
    uint32_t* rowptr = (uint32_t*)allocb((size_t)(2*NROW+1)*4);
    uint32_t* einfo  = (uint32_t*)allocb((size_t)2*EHGT*4);
    size_t region = off;
    // ---- conv scratch ----
    float* q_i  = (float*)allocb((size_t)NI*DD*4);
    float* q_d  = (float*)allocb((size_t)ND*DD*4);
    u16* ka16 = (u16*)allocb((size_t)4*NI*DD*2);   // bf16 KA; also combine f32 temp
    u16* vm16 = (u16*)allocb((size_t)4*NI*DD*2);
    float* xacc_i= (float*)allocb((size_t)NI*DD*4);
    float* xacc_d= (float*)allocb((size_t)ND*DD*4);
    u16* bcur_h = (u16*)allocb((size_t)NROW*DD*2);
    u16* bcur_l = (u16*)allocb((size_t)NROW*DD*2);
    u16* bagg_h = (u16*)allocb((size_t)NROW*DD*2);
    u16* bagg_l = (u16*)allocb((size_t)NROW*DD*2);
    // ---- pooling/transformer overlay ----
    off = region;
    float* hvec = (float*)allocb(NROW*4);
    float* pscore = (float*)allocb(NROW*4);
    int* seln   = (int*)allocb(BB*KPOOL*4);
    float* sels = (float*)allocb(BB*KPOOL*4);
    float* xp   = (float*)allocb((size_t)BB*KPOOL*DD*4);
    float* o2   = (float*)allocb((size_t)BB*KPOOL*DD*4);
    float* gatt = (float*)allocb((size_t)BB*KPOOL*DD*4);
    u16* bxp_h = (u16*)allocb((size_t)BB*KPOOL*DD*2);
    u16* bxp_l = (u16*)allocb((size_t)BB*KPOOL*DD*2);
    u16* qbh = (u16*)allocb((size_t)BB*KPOOL*DD*2);
    u16* kbh = (u16*)allocb((size_t)BB*KPOOL*DD*2);
    u16* vbh = (u16*)allocb((size_t)BB*KPOOL*DD*2);
    u16* bao_h = (u16*)allocb((size_t)BB*KPOOL*DD*2);
    u16* bao_l = (u16*)allocb((size_t)BB*KPOOL*DD*2);

    const int st_tab[2][4] = {{0,1,0,0},{0,0,1,0}};
    const int dt_tab[2][4] = {{0,0,1,0},{0,1,0,0}};
    const int MR = BB*KPOOL;

    fill_u32<<<(2*BB*512+255)/256,256,0,stream>>>((uint32_t*)ubuf, 0u, 2*BB*512);
    float* wtkF = (float*)ka16;
    float* wtvF = (float*)ka16 + 16*MAT;
    combine_all<<<dim3(256,32),256,0,stream>>>(hgt_Wk, hgt_Wv, hgt_arel, hgt_mrel, wtkF, wtvF);
    WCArgs wc;
    wc.in[0]=wtkF;   wc.oh[0]=bwtk_h; wc.ol[0]=bwtk_l; wc.cnt[0]=16;
    wc.in[1]=wtvF;   wc.oh[1]=bwtv_h; wc.ol[1]=bwtv_l; wc.cnt[1]=16;
    wc.in[2]=hgt_Wq; wc.oh[2]=bwq_h;  wc.ol[2]=bwq_l;  wc.cnt[2]=8;
    wc.in[3]=hgt_Wo; wc.oh[3]=bwo_h;  wc.ol[3]=bwo_l;  wc.cnt[3]=8;
    wc.in[4]=t_wq;   wc.oh[4]=btw_h;          wc.ol[4]=btw_l;          wc.cnt[4]=1;
    wc.in[5]=t_wk;   wc.oh[5]=btw_h+1*MAT;    wc.ol[5]=btw_l+1*MAT;    wc.cnt[5]=1;
    wc.in[6]=t_wv;   wc.oh[6]=btw_h+2*MAT;    wc.ol[6]=btw_l+2*MAT;    wc.cnt[6]=1;
    wc.in[7]=t_wo;   wc.oh[7]=btw_h+3*MAT;    wc.ol[7]=btw_l+3*MAT;    wc.cnt[7]=1;
    wc.nr = 8;
    wcvt_split<<<dim3(256,52),256,0,stream>>>(wc);

    for(int bi=0;bi<2;bi++){
        int ib = bi*6;
        const float* x_inst = (const float*)d_in[ib+0];
        const float* x_data = (const float*)d_in[ib+1];
        const int* ecp = (const int*)d_in[ib+2];
        const int* eip = (const int*)d_in[ib+3];
        const int* eop = (const int*)d_in[ib+4];
        const int* ekp = (const int*)d_in[ib+5];
        const int* rows_f[4] = {ecp, eip, eop, ekp};
        const int* cols_f[4] = {ecp+EC, eip+EI, eop+EO, ekp+EK};

        // ---- CSR build (both dirs, one pass) ----
        CB2 cb;
        for(int r=0;r<4;r++){
            cb.row[r]   = rows_f[r]; cb.col[r]   = cols_f[r]; cb.dt[r]   = dt_tab[0][r]; cb.st[r]   = st_tab[0][r];
            cb.row[4+r] = cols_f[r]; cb.col[4+r] = rows_f[r]; cb.dt[4+r] = dt_tab[1][r]; cb.st[4+r] = st_tab[1][r];
        }
        cb.cnt = ccnt; cb.rowptr = rowptr; cb.einfo = einfo;
        fill_u32<<<(2*NROW+255)/256,256,0,stream>>>(ccnt, 0u, 2*NROW);
        csr_hist2<<<(2*EHGT+255)/256,256,0,stream>>>(cb);
        scan_rowptr2<<<1,1024,0,stream>>>(ccnt, rowptr);
        csr_scatter2<<<(2*EHGT+255)/256,256,0,stream>>>(cb);

        const float* cur_i = x_inst;
        const float* cur_d = x_data;
        cvt_split<<<((NROW*DD/4)+255)/256,256,0,stream>>>(cur_i, NI*DD, cur_d, ND*DD, bcur_h, bcur_l);
        for(int l=0;l<LL;l++){
            float* nxt_i = (l==0) ? xa_i : xb_i;
            float* nxt_d = (l==0) ? xa_d : xb_d;
            for(int dir=0;dir<2;dir++){
                int wb = l*2 + dir;

                // --- mega GEMM: Q(2, f32, split) + KA(4, bf16, prec=1) + VM(4, bf16, prec=1) ---
                GArgs g1; int nb1 = 0, ndx = 0;
                auto addg = [&](int srctype, const u16* Bh, const u16* Bl, float* Cm, u16* Om, int M, int mode, int prec){
                    GDesc& d = g1.d[ndx];
                    size_t ao = srctype ? (size_t)NI*DD : 0;
                    d.Ah = bcur_h + ao; d.Al = bcur_l + ao;
                    d.Bh = Bh; d.Bl = Bl; d.C = Cm;
                    d.Oh = Om; d.Ol = nullptr; d.X = nullptr; d.Xacc = nullptr; d.skipp = nullptr;
                    d.mblks = M/128; d.mode = mode; d.prec = prec;
                    nb1 += M/128; ndx++;
                };
                addg(0, bwq_h + (size_t)(wb*2+0)*MAT, bwq_l + (size_t)(wb*2+0)*MAT, q_i, nullptr, NI, 0, 0);
                addg(1, bwq_h + (size_t)(wb*2+1)*MAT, bwq_l + (size_t)(wb*2+1)*MAT, q_d, nullptr, ND, 0, 0);
                for(int r=0;r<4;r++){
                    int st = st_tab[dir][r];
                    addg(st, bwtk_h + (size_t)(wb*4+r)*MAT, bwtk_l + (size_t)(wb*4+r)*MAT,
                         nullptr, ka16 + (size_t)r*NI*DD, st ? ND : NI, 4, 1);
                }
                for(int r=0;r<4;r++){
                    int st = st_tab[dir][r];
                    addg(st, bwtv_h + (size_t)(wb*4+r)*MAT, bwtv_l + (size_t)(wb*4+r)*MAT,
                         nullptr, vm16 + (size_t)r*NI*DD, st ? ND : NI, 4, 1);
                }
                g1.nd = ndx;
                gemm_mfma<<<dim3(nb1,2),256,0,stream>>>(g1);

                // --- fused edge phase ---
                hgt_fused<<<NROW/4,256,0,stream>>>(rowptr + (size_t)dir*NROW, einfo,
                    q_i, q_d, ka16, vm16, hgt_prel + (size_t)wb*4*HH, bagg_h, bagg_l);

                // --- Wo GEMMs with fused skip/relu epilogue (split) ---
                GArgs g3; g3.nd = 2;
                for(int t=0;t<2;t++){
                    GDesc& d = g3.d[t];
                    size_t ao = t ? (size_t)NI*DD : 0;
                    d.Ah = bagg_h + ao; d.Al = bagg_l + ao;
                    d.Bh = bwo_h + (size_t)(wb*2+t)*MAT; d.Bl = bwo_l + (size_t)(wb*2+t)*MAT;
                    d.C = t ? nxt_d : nxt_i;
                    d.Oh = bcur_h + ao; d.Ol = bcur_l + ao;
                    d.X = t ? cur_d : cur_i;
                    d.Xacc = t ? xacc_d : xacc_i;
                    d.skipp = hgt_skip + wb*2 + t;
                    d.mblks = (t ? ND : NI)/128;
                    d.mode = dir ? 3 : 2;
                    d.prec = 0;
                }
                gemm_mfma<<<dim3(NI/128 + ND/128,2),256,0,stream>>>(g3);
            }
            cur_i = nxt_i;
            cur_d = nxt_d;
        }

        // -------- SAGPooling (CSR-based, no atomics) --------
        pool_h2<<<NROW/4,256,0,stream>>>(cur_i, cur_d, pool_W, hvec);
        pool_csr<<<NROW/4,256,0,stream>>>(rowptr, einfo, hvec, pool_att, pscore);
        topk_rank<<<dim3(6,BB),256,0,stream>>>(pscore, pool_bias, seln, sels);
        gather_xp<<<BB*KPOOL,256,0,stream>>>(seln, sels, cur_i, cur_d, xp, bxp_h, bxp_l);

        // -------- transformer --------
        GArgs g4; g4.nd = 3;
        for(int t=0;t<3;t++){
            GDesc& d = g4.d[t];
            d.Ah=bxp_h; d.Al=bxp_l;
            d.Bh=btw_h + (size_t)t*MAT; d.Bl=btw_l + (size_t)t*MAT;
            d.C = nullptr;
            d.Oh = (t==0)? qbh : (t==1)? kbh : vbh;
            d.Ol = nullptr;
            d.X = nullptr; d.Xacc = nullptr; d.skipp = nullptr;
            d.mblks = MR/128; d.mode = 4; d.prec = 0;
        }
        gemm_mfma<<<dim3(3*(MR/128),2),256,0,stream>>>(g4);
        attn_mfma<<<dim3(BB*HH, KPOOL/64),256,0,stream>>>(qbh, kbh, vbh, bao_h, bao_l);
        GArgs g5; g5.nd = 1;
        {
            GDesc& d = g5.d[0];
            d.Ah=bao_h; d.Al=bao_l;
            d.Bh=btw_h + (size_t)3*MAT; d.Bl=btw_l + (size_t)3*MAT;
            d.C=o2; d.Oh=nullptr; d.Ol=nullptr; d.X=nullptr; d.Xacc=nullptr; d.skipp=nullptr;
            d.mblks=MR/128; d.mode=0; d.prec=0;
        }
        gemm_mfma<<<dim3(MR/128,2),256,0,stream>>>(g5);
        ln_kernel<<<MR,256,0,stream>>>(xp, o2, ln_g, ln_b, gatt);
        feat_reduce2<<<dim3(BB,12),256,0,stream>>>(xp, gatt, bi ? vbuf : ubuf);
    }

    cosine_kernel<<<BB,64,0,stream>>>(ubuf, vbuf, out);
}

// Round 18
// 1045.828 us; speedup vs baseline: 1.8595x; 1.0013x over previous
//
#include <hip/hip_runtime.h>
#include <math.h>
#include <stdint.h>

#define LL 2
#define HH 4
#define DHH 64
#define DD 256
#define BB 8
#define NI 8192
#define ND 4096
#define NROW 12288
#define KPOOL 768
#define EC 65536
#define EI 32768
#define EO 32768
#define EK 8192
#define EHGT (EC+EI+EO+EK)

typedef unsigned short u16;
typedef short bf16x8 __attribute__((ext_vector_type(8)));
typedef float f32x4 __attribute__((ext_vector_type(4)));
typedef unsigned short u16x4 __attribute__((ext_vector_type(4)));

__device__ inline float gelu_f(float x){ return 0.5f*x*(1.f+erff(x*0.70710678118654752f)); }
__device__ inline u16 f2b(float x){ uint32_t u=__float_as_uint(x); return (u16)((u + 0x7fffu + ((u>>16)&1u))>>16); }
__device__ inline float b2f(u16 h){ return __uint_as_float(((uint32_t)h)<<16); }

// ---------------- generic fill ----------------
__global__ void fill_u32(uint32_t* p, uint32_t v, int n){
    int i = blockIdx.x*256 + threadIdx.x;
    if(i<n) p[i]=v;
}

// ---------------- activation split-convert ----------------
__global__ void cvt_split(const float* __restrict__ A, int nA, const float* __restrict__ B, int nB,
                          u16* __restrict__ oh, u16* __restrict__ ol){
    int i = (blockIdx.x*256 + threadIdx.x)*4;
    int tot = nA + nB;
    if(i >= tot) return;
    float4 v = (i < nA) ? *(const float4*)(A + i) : *(const float4*)(B + (i - nA));
    float vv[4] = {v.x, v.y, v.z, v.w};
    u16x4 h4, l4;
    #pragma unroll
    for(int j=0;j<4;j++){
        float x = vv[j];
        u16 h = f2b(x);
        h4[j] = h;
        l4[j] = f2b(x - b2f(h));
    }
    *(u16x4*)(oh + i) = h4;
    *(u16x4*)(ol + i) = l4;
}

// ---------------- weight transpose + split ----------------
struct WCArgs { const float* in[8]; u16* oh[8]; u16* ol[8]; int cnt[8]; int nr; };
__global__ void wcvt_split(WCArgs a){
    int mat = blockIdx.y, ri = 0;
    while(ri < a.nr-1 && mat >= a.cnt[ri]){ mat -= a.cnt[ri]; ri++; }
    const float* in = a.in[ri] + (size_t)mat*65536;
    u16* oh = a.oh[ri] + (size_t)mat*65536;
    u16* ol = a.ol[ri] + (size_t)mat*65536;
    int n = blockIdx.x, k = threadIdx.x;
    float x = in[(size_t)k*DD + n];
    u16 h = f2b(x);
    oh[n*DD + k] = h;
    ol[n*DD + k] = f2b(x - b2f(h));
}

// ---------------- MFMA batched GEMM with fused, LDS-restaged epilogues ----------------
// prec=0: split hi/lo (3 MFMA/step); prec=1: hi-only (1 MFMA/step, half staging)
// mode 0: C=f32   mode 1: Oh/Ol=split bf16   mode 4: Oh=plain bf16
// mode 2: Xacc = 0.5*(g*acc + (1-g)*X)
// mode 3: v=relu(Xacc + 0.5*(g*acc+(1-g)*X)); C=v; Oh/Ol=split(v)
struct GDesc { const u16* Ah; const u16* Al; const u16* Bh; const u16* Bl;
               float* C; u16* Oh; u16* Ol;
               const float* X; float* Xacc; const float* skipp;
               int mblks; int mode; int prec; };
struct GArgs { GDesc d[10]; int nd; };

__global__ __launch_bounds__(256) void gemm_mfma(GArgs ga){
    __shared__ u16 SBUF[2*128*64];
    char* Abuf = (char*)SBUF;
    char* Bbuf = (char*)(SBUF + 128*64);
    int mb = blockIdx.x, di = 0;
    while(di < ga.nd-1 && mb >= ga.d[di].mblks){ mb -= ga.d[di].mblks; di++; }
    GDesc g = ga.d[di];
    const int prec = g.prec;
    const int m0 = mb*128, n0 = blockIdx.y*128;
    const int tid = threadIdx.x;
    const int lane = tid & 63, wid = tid >> 6;
    const int wm = (wid>>1)*64, wn = (wid&1)*64;
    const int l15 = lane & 15, l4 = lane >> 4;
    const int srow = tid >> 1, hf = tid & 1;
    const int ssw = (srow&7)<<4;
    const int c0 = (hf*32) ^ ssw;
    const int c1 = (hf*32+16) ^ ssw;
    const int c2 = (64+hf*32) ^ ssw;
    const int c3 = (64+hf*32+16) ^ ssw;
    const int rbyte = srow*128;
    const u16* __restrict__ Aph = g.Ah + (size_t)(m0 + srow)*DD + hf*16;
    const u16* __restrict__ Apl = g.Al + (size_t)(m0 + srow)*DD + hf*16;
    const u16* __restrict__ Bph = g.Bh + (size_t)(n0 + srow)*DD + hf*16;
    const u16* __restrict__ Bpl = g.Bl + (size_t)(n0 + srow)*DD + hf*16;
    f32x4 acc[4][4] = {};
    bf16x8 r0, r1, r2, r3, r4, r5, r6, r7;
    r0 = *(const bf16x8*)(Aph);
    r1 = *(const bf16x8*)(Aph + 8);
    r4 = *(const bf16x8*)(Bph);
    r5 = *(const bf16x8*)(Bph + 8);
    if(!prec){
        r2 = *(const bf16x8*)(Apl);
        r3 = *(const bf16x8*)(Apl + 8);
        r6 = *(const bf16x8*)(Bpl);
        r7 = *(const bf16x8*)(Bpl + 8);
    }
    #pragma unroll
    for(int k0=0;k0<DD;k0+=32){
        __syncthreads();
        *(bf16x8*)(Abuf + rbyte + c0) = r0; *(bf16x8*)(Abuf + rbyte + c1) = r1;
        *(bf16x8*)(Bbuf + rbyte + c0) = r4; *(bf16x8*)(Bbuf + rbyte + c1) = r5;
        if(!prec){
            *(bf16x8*)(Abuf + rbyte + c2) = r2; *(bf16x8*)(Abuf + rbyte + c3) = r3;
            *(bf16x8*)(Bbuf + rbyte + c2) = r6; *(bf16x8*)(Bbuf + rbyte + c3) = r7;
        }
        __syncthreads();
        if(k0 + 32 < DD){
            int kn = k0 + 32;
            r0 = *(const bf16x8*)(Aph + kn);     r1 = *(const bf16x8*)(Aph + kn + 8);
            r4 = *(const bf16x8*)(Bph + kn);     r5 = *(const bf16x8*)(Bph + kn + 8);
            if(!prec){
                r2 = *(const bf16x8*)(Apl + kn); r3 = *(const bf16x8*)(Apl + kn + 8);
                r6 = *(const bf16x8*)(Bpl + kn); r7 = *(const bf16x8*)(Bpl + kn + 8);
            }
        }
        bf16x8 afh[4], bfh[4];
        #pragma unroll
        for(int i=0;i<4;i++){
            int ar = wm + i*16 + l15;
            int abase = ar*128;
            afh[i] = *(const bf16x8*)(Abuf + abase + ((l4*16) ^ ((ar&7)<<4)));
            int br = wn + i*16 + l15;
            int bbase = br*128;
            bfh[i] = *(const bf16x8*)(Bbuf + bbase + ((l4*16) ^ ((br&7)<<4)));
        }
        #pragma unroll
        for(int i=0;i<4;i++)
            #pragma unroll
            for(int j=0;j<4;j++)
                acc[i][j] = __builtin_amdgcn_mfma_f32_16x16x32_bf16(afh[i], bfh[j], acc[i][j], 0,0,0);
        if(!prec){
            bf16x8 afl[4], bfl[4];
            #pragma unroll
            for(int i=0;i<4;i++){
                int ar = wm + i*16 + l15;
                int abase = ar*128;
                afl[i] = *(const bf16x8*)(Abuf + abase + ((64 + l4*16) ^ ((ar&7)<<4)));
                int br = wn + i*16 + l15;
                int bbase = br*128;
                bfl[i] = *(const bf16x8*)(Bbuf + bbase + ((64 + l4*16) ^ ((br&7)<<4)));
            }
            #pragma unroll
            for(int i=0;i<4;i++)
                #pragma unroll
                for(int j=0;j<4;j++){
                    acc[i][j] = __builtin_amdgcn_mfma_f32_16x16x32_bf16(afh[i], bfl[j], acc[i][j], 0,0,0);
                    acc[i][j] = __builtin_amdgcn_mfma_f32_16x16x32_bf16(afl[i], bfh[j], acc[i][j], 0,0,0);
                }
        }
    }
    // ---- coalesced epilogue via LDS restage (two 64-row passes) ----
    const int mode = g.mode;
    float gg = 0.f;
    if(mode == 2 || mode == 3) gg = 1.f/(1.f + expf(-*g.skipp));
    float* LDSf = (float*)SBUF;
    const int lrow = tid >> 5;
    const int cc4 = (tid & 31)*4;
    #pragma unroll
    for(int half=0; half<2; half++){
        __syncthreads();
        if((wid>>1) == half){
            #pragma unroll
            for(int i=0;i<4;i++)
                #pragma unroll
                for(int j=0;j<4;j++)
                    #pragma unroll
                    for(int r=0;r<4;r++)
                        LDSf[(i*16 + l4*4 + r)*128 + wn + j*16 + l15] = acc[i][j][r];
        }
        __syncthreads();
        #pragma unroll
        for(int k=0;k<8;k++){
            int row = lrow + k*8;
            size_t o = (size_t)(m0 + half*64 + row)*DD + n0 + cc4;
            float4 v = *(const float4*)&LDSf[row*128 + cc4];
            float vv[4] = {v.x, v.y, v.z, v.w};
            if(mode==0){
                *(float4*)(g.C + o) = v;
            } else if(mode==4){
                u16x4 h4;
                #pragma unroll
                for(int j=0;j<4;j++) h4[j] = f2b(vv[j]);
                *(u16x4*)(g.Oh + o) = h4;
            } else if(mode==1){
                u16x4 h4, lo4;
                #pragma unroll
                for(int j=0;j<4;j++){
                    u16 hh = f2b(vv[j]); h4[j]=hh; lo4[j]=f2b(vv[j]-b2f(hh));
                }
                *(u16x4*)(g.Oh + o) = h4;
                *(u16x4*)(g.Ol + o) = lo4;
            } else if(mode==2){
                float4 x = *(const float4*)(g.X + o);
                float xx[4] = {x.x, x.y, x.z, x.w};
                float4 w;
                float* ww = (float*)&w;
                #pragma unroll
                for(int j=0;j<4;j++) ww[j] = 0.5f*(gg*vv[j] + (1.f-gg)*xx[j]);
                *(float4*)(g.Xacc + o) = w;
            } else {
                float4 x = *(const float4*)(g.X + o);
                float4 xa = *(const float4*)(g.Xacc + o);
                float xx[4] = {x.x, x.y, x.z, x.w};
                float aa[4] = {xa.x, xa.y, xa.z, xa.w};
                float4 cv;
                float* cvv = (float*)&cv;
                u16x4 h4, lo4;
                #pragma unroll
                for(int j=0;j<4;j++){
                    float v3 = aa[j] + 0.5f*(gg*vv[j] + (1.f-gg)*xx[j]);
                    v3 = v3 > 0.f ? v3 : 0.f;
                    cvv[j] = v3;
                    u16 hh = f2b(v3); h4[j]=hh; lo4[j]=f2b(v3-b2f(hh));
                }
                *(float4*)(g.C + o) = cv;
                *(u16x4*)(g.Oh + o) = h4;
                *(u16x4*)(g.Ol + o) = lo4;
            }
        }
    }
}

// ---------- combine ----------
__global__ void combine_all(const float* __restrict__ Wk, const float* __restrict__ Wv,
                            const float* __restrict__ Ra, const float* __restrict__ Rm,
                            float* __restrict__ wtk, float* __restrict__ wtv){
    const int st_tab[2][4] = {{0,1,0,0},{0,0,1,0}};
    int combo = blockIdx.y;
    int idx = combo >> 1, kv = combo & 1;
    int r = idx & 3, wb = idx >> 2, dir = wb & 1;
    int st = st_tab[dir][r];
    const float* W = (kv ? Wv : Wk) + (size_t)(wb*2 + st)*65536;
    const float* R = (kv ? Rm : Ra) + (size_t)idx*16384;
    float* o = (kv ? wtv : wtk) + (size_t)idx*65536;
    int d = blockIdx.x, c = threadIdx.x;
    int h = c >> 6, f = c & 63;
    const float* Wrow = W + d*DD + h*64;
    const float* Rh = R + h*4096 + f;
    float s = 0.f;
    #pragma unroll 8
    for(int k=0;k<64;k++) s += Wrow[k]*Rh[k*64];
    o[d*DD + c] = s;
}

// ---------------- CSR build (both directions in one pass) ----------------
__device__ inline void edge_decode(int e, int& r, int& el){
    if(e < EC){ r=0; el=e; }
    else if(e < EC+EI){ r=1; el=e-EC; }
    else if(e < EC+EI+EO){ r=2; el=e-(EC+EI); }
    else { r=3; el=e-(EC+EI+EO); }
}

struct CB2 {
    const int* row[8]; const int* col[8];
    int dt[8]; int st[8];
    uint32_t* cnt; uint32_t* rowptr; uint32_t* einfo;
};

__global__ void csr_hist2(CB2 a){
    int ge = blockIdx.x*256 + threadIdx.x;
    if(ge >= 2*EHGT) return;
    int dir = ge >= EHGT;
    int e = ge - dir*EHGT;
    int r, el; edge_decode(e, r, el);
    int idx = dir*4 + r;
    int c = a.col[idx][el];
    int dst = dir*NROW + (a.dt[idx] ? (NI + c) : c);
    atomicAdd(&a.cnt[dst], 1u);
}

__global__ __launch_bounds__(1024) void scan_rowptr2(uint32_t* cnt, uint32_t* rowptr){
    __shared__ uint32_t part[1024];
    int t = threadIdx.x;
    int base = t*24;
    uint32_t lpre[24];
    uint32_t sum = 0;
    #pragma unroll
    for(int i=0;i<24;i++){
        uint32_t c = cnt[base+i];
        lpre[i] = sum; sum += c;
        cnt[base+i] = 0;
    }
    part[t] = sum;
    __syncthreads();
    for(int offs=1; offs<1024; offs<<=1){
        uint32_t v = (t>=offs) ? part[t-offs] : 0u;
        __syncthreads();
        part[t] += v;
        __syncthreads();
    }
    uint32_t pre = (t==0) ? 0u : part[t-1];
    #pragma unroll
    for(int i=0;i<24;i++) rowptr[base+i] = pre + lpre[i];
    if(t==1023) rowptr[2*NROW] = part[1023];
}

__global__ void csr_scatter2(CB2 a){
    int ge = blockIdx.x*256 + threadIdx.x;
    if(ge >= 2*EHGT) return;
    int dir = ge >= EHGT;
    int e = ge - dir*EHGT;
    int r, el; edge_decode(e, r, el);
    int idx = dir*4 + r;
    int c = a.col[idx][el];
    int dst = dir*NROW + (a.dt[idx] ? (NI + c) : c);
    int src = a.row[idx][el];
    uint32_t p = a.rowptr[dst] + atomicAdd(&a.cnt[dst], 1u);
    uint32_t vmidx = (uint32_t)(r*NI + src);
    uint32_t hom = a.st[idx] ? (uint32_t)(NI + src) : (uint32_t)src;
    a.einfo[p] = vmidx | (hom << 16);
}

// ---------------- fused HGT edge phase: wave per dst, all 4 heads, online softmax ----------------
__global__ __launch_bounds__(256) void hgt_fused(const uint32_t* __restrict__ rowptr,
                                                 const uint32_t* __restrict__ einfo,
                                                 const float* __restrict__ q_i,
                                                 const float* __restrict__ q_d,
                                                 const u16* __restrict__ ka,
                                                 const u16* __restrict__ vm,
                                                 const float* __restrict__ prel,
                                                 u16* __restrict__ bagg_h,
                                                 u16* __restrict__ bagg_l){
    int wv = threadIdx.x >> 6, lane = threadIdx.x & 63;
    int rowi = blockIdx.x*4 + wv;
    uint32_t p0 = rowptr[rowi], p1 = rowptr[rowi+1];
    int h = lane >> 4;
    const float* qrow = (rowi < NI) ? (q_i + (size_t)rowi*DD) : (q_d + (size_t)(rowi-NI)*DD);
    float4 q4 = *(const float4*)(qrow + lane*4);
    float pr0 = prel[0*HH+h]*0.125f, pr1 = prel[1*HH+h]*0.125f;
    float pr2 = prel[2*HH+h]*0.125f, pr3 = prel[3*HH+h]*0.125f;
    float m = -INFINITY, den = 0.f;
    float4 o4 = {0.f,0.f,0.f,0.f};
    for(uint32_t p = p0; p < p1; p++){
        uint32_t vmidx = einfo[p] & 0xffffu;
        int r = vmidx >> 13;
        uint2 kr = *(const uint2*)(ka + (size_t)vmidx*DD + lane*4);
        uint2 vr = *(const uint2*)(vm + (size_t)vmidx*DD + lane*4);
        float k0 = __uint_as_float(kr.x << 16), k1 = __uint_as_float(kr.x & 0xffff0000u);
        float k2 = __uint_as_float(kr.y << 16), k3 = __uint_as_float(kr.y & 0xffff0000u);
        float v0 = __uint_as_float(vr.x << 16), v1 = __uint_as_float(vr.x & 0xffff0000u);
        float v2 = __uint_as_float(vr.y << 16), v3 = __uint_as_float(vr.y & 0xffff0000u);
        float d = q4.x*k0 + q4.y*k1 + q4.z*k2 + q4.w*k3;
        d += __shfl_xor(d, 1); d += __shfl_xor(d, 2);
        d += __shfl_xor(d, 4); d += __shfl_xor(d, 8);
        float pf = (r==0) ? pr0 : (r==1) ? pr1 : (r==2) ? pr2 : pr3;
        float s = d * pf;
        float nm = fmaxf(m, s);
        float sc_ = expf(m - nm);
        float pe = expf(s - nm);
        den = den*sc_ + pe;
        o4.x = o4.x*sc_ + pe*v0;
        o4.y = o4.y*sc_ + pe*v1;
        o4.z = o4.z*sc_ + pe*v2;
        o4.w = o4.w*sc_ + pe*v3;
        m = nm;
    }
    float inv = 1.f/(den + 1e-16f);
    float vals[4] = {o4.x*inv, o4.y*inv, o4.z*inv, o4.w*inv};
    u16x4 h4, l4;
    #pragma unroll
    for(int j=0;j<4;j++){
        float g = gelu_f(vals[j]);
        u16 hh = f2b(g);
        h4[j] = hh;
        l4[j] = f2b(g - b2f(hh));
    }
    size_t ob = (size_t)rowi*DD + lane*4;
    *(u16x4*)(bagg_h + ob) = h4;
    *(u16x4*)(bagg_l + ob) = l4;
}

// ---------------- pooling ----------------
__global__ void pool_h2(const float* __restrict__ xi, const float* __restrict__ xd,
                        const float* __restrict__ w, float* __restrict__ h){
    int node = blockIdx.x*4 + (threadIdx.x>>6);
    int lane = threadIdx.x & 63;
    const float* xr = (node < NI) ? (xi + (size_t)node*DD) : (xd + (size_t)(node-NI)*DD);
    float s = 0.f;
    for(int j=lane;j<DD;j+=64) s += xr[j]*w[j];
    for(int m=32;m;m>>=1) s += __shfl_xor(s, m);
    if(lane==0) h[node] = s;
}

// GAT-style pooling score via fwd CSR + implicit self-loop; wave per dst node
__global__ __launch_bounds__(256) void pool_csr(const uint32_t* __restrict__ rowptr,
                                                const uint32_t* __restrict__ einfo,
                                                const float* __restrict__ h,
                                                const float* __restrict__ att,
                                                float* __restrict__ score){
    int w = blockIdx.x*4 + (threadIdx.x >> 6);
    int lane = threadIdx.x & 63;
    if(w >= NROW) return;
    uint32_t p0 = rowptr[w], p1 = rowptr[w+1];
    float a0 = att[0], a1 = att[1];
    float hn = h[w];
    float es = a0*hn + a1*hn;
    es = es >= 0.f ? es : 0.2f*es;
    float m = -INFINITY;
    for(uint32_t p = p0+lane; p < p1; p += 64){
        float hs = h[einfo[p] >> 16];
        float e = a0*hs + a1*hn;
        e = e >= 0.f ? e : 0.2f*e;
        m = fmaxf(m, e);
    }
    #pragma unroll
    for(int s=32;s;s>>=1) m = fmaxf(m, __shfl_xor(m, s));
    m = fmaxf(m, es);
    float lden = 0.f, lnum = 0.f;
    for(uint32_t p = p0+lane; p < p1; p += 64){
        float hs = h[einfo[p] >> 16];
        float e = a0*hs + a1*hn;
        e = e >= 0.f ? e : 0.2f*e;
        float a = expf(e - m);
        lden += a; lnum += a*hs;
    }
    #pragma unroll
    for(int s=32;s;s>>=1){ lden += __shfl_xor(lden, s); lnum += __shfl_xor(lnum, s); }
    float aself = expf(es - m);
    lden += aself; lnum += aself*hn;
    if(lane==0) score[w] = lnum/(lden + 1e-16f);
}

// ---------------- top-768 of 1536 per graph via exact rank selection ----------------
// float4 LDS reads + 4 independent rank accumulators (latency-hiding ILP).
// rank(i) = #{j: k_j>k_i or (k_j==k_i and j<i)}; rank<KPOOL -> out[rank].
__global__ __launch_bounds__(256) void topk_rank(const float* __restrict__ score,
                                                 const float* __restrict__ bias,
                                                 int* __restrict__ sel_node,
                                                 float* __restrict__ sel_scale){
    __shared__ float keys[1536];
    int b = blockIdx.y;
    for(int t=threadIdx.x; t<1536; t+=256){
        int node = (t<1024) ? (b*1024 + t) : (NI + b*512 + (t-1024));
        keys[t] = score[node];
    }
    __syncthreads();
    int i = blockIdx.x*256 + threadIdx.x;
    float ki = keys[i];
    int r0=0, r1=0, r2=0, r3=0;
    #pragma unroll 4
    for(int j=0;j<1536;j+=4){
        float4 k4 = *(const float4*)&keys[j];
        r0 += (k4.x > ki) || (k4.x == ki && (j+0) < i);
        r1 += (k4.y > ki) || (k4.y == ki && (j+1) < i);
        r2 += (k4.z > ki) || (k4.z == ki && (j+2) < i);
        r3 += (k4.w > ki) || (k4.w == ki && (j+3) < i);
    }
    int rank = r0 + r1 + r2 + r3;
    if(rank < KPOOL){
        int node = (i<1024) ? (b*1024 + i) : (NI + b*512 + (i-1024));
        sel_node[b*KPOOL + rank] = node;
        sel_scale[b*KPOOL + rank] = tanhf(ki + bias[0]);
    }
}

__global__ void gather_xp(const int* __restrict__ sel, const float* __restrict__ scale,
                          const float* __restrict__ xi, const float* __restrict__ xd,
                          float* __restrict__ xp, u16* __restrict__ bh, u16* __restrict__ bl){
    int i = blockIdx.x*256 + threadIdx.x;
    int rowp = i >> 8, c = i & 255;
    int node = sel[rowp];
    float s = scale[rowp];
    float v = (node < NI) ? xi[(size_t)node*DD + c] : xd[(size_t)(node-NI)*DD + c];
    float x = v*s;
    xp[i] = x;
    u16 hh = f2b(x);
    bh[i] = hh;
    bl[i] = f2b(x - b2f(hh));
}

// ---------------- MFMA flash attention: block per (bh, 64 q rows), plain-bf16 QKV ----------------
__global__ __launch_bounds__(256) void attn_mfma(const u16* __restrict__ Qh,
                                                 const u16* __restrict__ Kh,
                                                 const u16* __restrict__ Vh,
                                                 u16* __restrict__ aoh, u16* __restrict__ aol){
    __shared__ u16 KhS[64*64], VtS[64*64];
    char* KhB = (char*)KhS; char* VtB = (char*)VtS;
    int bh = blockIdx.x;
    int b = bh >> 2, h = bh & 3;
    int q0 = blockIdx.y * 64;
    int tid = threadIdx.x;
    int lane = tid & 63;
    int w = tid >> 6;
    int l15 = lane & 15, l4 = lane >> 4;
    size_t qrow = (size_t)(b*KPOOL + q0 + w*16 + l15);
    bf16x8 qh[2];
    #pragma unroll
    for(int c=0;c<2;c++)
        qh[c] = *(const bf16x8*)(Qh + qrow*DD + h*64 + c*32 + l4*8);
    float mreg = -INFINITY, lreg = 0.f;
    f32x4 O[4] = {};
    for(int k0=0;k0<KPOOL;k0+=64){
        __syncthreads();
        {   // stage K (vectorized, swizzled) + V^T (row-pair packed u32 stores)
            int row = tid >> 2, q4 = tid & 3;
            size_t gbase = ((size_t)(b*KPOOL + k0 + row))*DD + h*64 + q4*16;
            bf16x8 k0v = *(const bf16x8*)(Kh + gbase);
            bf16x8 k1v = *(const bf16x8*)(Kh + gbase + 8);
            int sw = (row&7)<<4;
            int colb = q4*32;
            *(bf16x8*)(KhB + row*128 + (colb ^ sw))      = k0v;
            *(bf16x8*)(KhB + row*128 + ((colb+16) ^ sw)) = k1v;
            int row0 = (tid >> 3)*2, dhg = (tid & 7)*8;
            size_t vbase = ((size_t)(b*KPOOL + k0 + row0))*DD + h*64 + dhg;
            bf16x8 va = *(const bf16x8*)(Vh + vbase);
            bf16x8 vb = *(const bf16x8*)(Vh + vbase + DD);
            #pragma unroll
            for(int j=0;j<8;j++){
                int dh = dhg + j;
                uint32_t pk = (uint32_t)(u16)(short)va[j] | ((uint32_t)(u16)(short)vb[j] << 16);
                *(uint32_t*)(VtB + dh*128 + ((row0*2) ^ ((dh&7)<<4))) = pk;
            }
        }
        __syncthreads();
        // S^T tiles: mfma(A=K, B=Q)  (plain bf16: 2 MFMA per tile)
        f32x4 s[4] = {};
        #pragma unroll
        for(int t=0;t<4;t++){
            int arow = t*16 + l15;
            int sw = (arow&7)<<4;
            const char* bh_ = KhB + arow*128;
            bf16x8 kh0 = *(const bf16x8*)(bh_ + ((l4*16) ^ sw));
            bf16x8 kh1 = *(const bf16x8*)(bh_ + ((l4*16 + 64) ^ sw));
            s[t] = __builtin_amdgcn_mfma_f32_16x16x32_bf16(kh0, qh[0], s[t], 0,0,0);
            s[t] = __builtin_amdgcn_mfma_f32_16x16x32_bf16(kh1, qh[1], s[t], 0,0,0);
        }
        // online softmax
        float cm = -INFINITY;
        #pragma unroll
        for(int t=0;t<4;t++)
            #pragma unroll
            for(int r=0;r<4;r++){ s[t][r] *= 0.125f; cm = fmaxf(cm, s[t][r]); }
        cm = fmaxf(cm, __shfl_xor(cm,16));
        cm = fmaxf(cm, __shfl_xor(cm,32));
        float nm = fmaxf(mreg, cm);
        float es = expf(mreg - nm);
        float ps = 0.f;
        #pragma unroll
        for(int t=0;t<4;t++)
            #pragma unroll
            for(int r=0;r<4;r++){ float pv = expf(s[t][r] - nm); s[t][r] = pv; ps += pv; }
        ps += __shfl_xor(ps,16);
        ps += __shfl_xor(ps,32);
        lreg = lreg*es + ps;
        mreg = nm;
        #pragma unroll
        for(int d=0;d<4;d++){ O[d][0]*=es; O[d][1]*=es; O[d][2]*=es; O[d][3]*=es; }
        // O^T += mfma(A=V^T, B=P^T)
        #pragma unroll
        for(int c32=0;c32<2;c32++){
            bf16x8 pb;
            #pragma unroll
            for(int j=0;j<8;j++){
                int srcl = ((((lane>>4)*2 + (j>>2)) & 3) << 4) | l15;
                float v0 = __shfl(s[c32*2+0][j&3], srcl, 64);
                float v1 = __shfl(s[c32*2+1][j&3], srcl, 64);
                float v = (lane < 32) ? v0 : v1;
                pb[j] = (short)f2b(v);
            }
            #pragma unroll
            for(int dhb=0; dhb<4; dhb++){
                int vrow = dhb*16 + l15;
                bf16x8 va = *(const bf16x8*)(VtB + vrow*128 + ((c32*64 + l4*16) ^ ((vrow&7)<<4)));
                O[dhb] = __builtin_amdgcn_mfma_f32_16x16x32_bf16(va, pb, O[dhb], 0,0,0);
            }
        }
    }
    float inv = 1.f/lreg;
    #pragma unroll
    for(int dhb=0;dhb<4;dhb++)
        #pragma unroll
        for(int r=0;r<4;r++){
            float val = O[dhb][r]*inv;
            size_t o = qrow*DD + h*64 + dhb*16 + l4*4 + r;
            u16 hh = f2b(val);
            aoh[o] = hh;
            aol[o] = f2b(val - b2f(hh));
        }
}

// layernorm row kernel
__global__ __launch_bounds__(256) void ln_kernel(const float* __restrict__ xp, const float* __restrict__ o2,
                                                 const float* __restrict__ lg, const float* __restrict__ lb,
                                                 float* __restrict__ gatt){
    __shared__ float red[256];
    int r = blockIdx.x, c = threadIdx.x;
    float y = xp[(size_t)r*DD + c] + o2[(size_t)r*DD + c];
    red[c] = y; __syncthreads();
    for(int s=128;s;s>>=1){ if(c<s) red[c] += red[c+s]; __syncthreads(); }
    float mu = red[0]*(1.f/DD);
    __syncthreads();
    float d = y - mu;
    red[c] = d*d; __syncthreads();
    for(int s=128;s;s>>=1){ if(c<s) red[c] += red[c+s]; __syncthreads(); }
    float var = red[0]*(1.f/DD);
    gatt[(size_t)r*DD + c] = lg[c]*d/sqrtf(var+1e-5f) + lb[c];
}

__global__ void feat_reduce2(const float* __restrict__ xp, const float* __restrict__ gatt,
                             float* __restrict__ out){
    int b = blockIdx.x, c = threadIdx.x;
    int j0 = blockIdx.y*64;
    float s1=0.f, s2=0.f;
    for(int j=j0;j<j0+64;j++){
        size_t base = ((size_t)(b*KPOOL + j))*DD + c;
        s1 += xp[base];
        s2 += gatt[base];
    }
    atomicAdd(&out[b*512 + c], s1);
    atomicAdd(&out[b*512 + 256 + c], s2);
}

__global__ void cosine_kernel(const float* __restrict__ u, const float* __restrict__ v,
                              float* __restrict__ out){
    int b = blockIdx.x, t = threadIdx.x;
    float du=0.f, nu=0.f, nv=0.f;
    for(int j=t;j<512;j+=64){
        float a = u[b*512+j], bb = v[b*512+j];
        du += a*bb; nu += a*a; nv += bb*bb;
    }
    for(int m=32;m;m>>=1){
        du += __shfl_xor(du,m); nu += __shfl_xor(nu,m); nv += __shfl_xor(nv,m);
    }
    if(t==0) out[b] = du / (fmaxf(sqrtf(nu),1e-8f)*fmaxf(sqrtf(nv),1e-8f));
}

// =======================================================================
extern "C" void kernel_launch(void* const* d_in, const int* in_sizes, int n_in,
                              void* d_out, int out_size, void* d_ws, size_t ws_size,
                              hipStream_t stream){
    (void)in_sizes; (void)n_in; (void)out_size; (void)ws_size;
    const float* hgt_Wk   = (const float*)d_in[12];
    const float* hgt_Wq   = (const float*)d_in[13];
    const float* hgt_Wv   = (const float*)d_in[14];
    const float* hgt_Wo   = (const float*)d_in[15];
    const float* hgt_arel = (const float*)d_in[16];
    const float* hgt_mrel = (const float*)d_in[17];
    const float* hgt_prel = (const float*)d_in[18];
    const float* hgt_skip = (const float*)d_in[19];
    const float* pool_W   = (const float*)d_in[20];
    const float* pool_att = (const float*)d_in[21];
    const float* pool_bias= (const float*)d_in[22];
    const float* t_wq     = (const float*)d_in[23];
    const float* t_wk     = (const float*)d_in[24];
    const float* t_wv     = (const float*)d_in[25];
    const float* t_wo     = (const float*)d_in[26];
    const float* ln_g     = (const float*)d_in[27];
    const float* ln_b     = (const float*)d_in[28];
    float* out = (float*)d_out;

    char* base = (char*)d_ws;
    size_t off = 0;
    auto allocb = [&](size_t nbytes)->void*{
        void* p = (void*)(base + off);
        off += ((nbytes + 255) & ~(size_t)255);
        return p;
    };
    const size_t MAT = 65536;
    // ---- persistent ----
    u16* bwtk_h = (u16*)allocb(16*MAT*2); u16* bwtk_l = (u16*)allocb(16*MAT*2);
    u16* bwtv_h = (u16*)allocb(16*MAT*2); u16* bwtv_l = (u16*)allocb(16*MAT*2);
    u16* bwq_h  = (u16*)allocb(8*MAT*2);  u16* bwq_l  = (u16*)allocb(8*MAT*2);
    u16* bwo_h  = (u16*)allocb(8*MAT*2);  u16* bwo_l  = (u16*)allocb(8*MAT*2);
    u16* btw_h  = (u16*)allocb(4*MAT*2);  u16* btw_l  = (u16*)allocb(4*MAT*2);
    float* ubuf = (float*)allocb(BB*512*4);
    float* vbuf = (float*)allocb(BB*512*4);
    float* xa_i = (float*)allocb((size_t)NI*DD*4);
    float* xa_d = (float*)allocb((size_t)ND*DD*4);
    float* xb_i = (float*)allocb((size_t)NI*DD*4);
    float* xb_d = (float*)allocb((size_t)ND*DD*4);
    // ---- per-branch CSR ----
    uint32_t* ccnt   = (uint32_t*)allocb((size_t)2*NROW*4);
    uint32_t* rowptr = (uint32_t*)allocb((size_t)(2*NROW+1)*4);
    uint32_t* einfo  = (uint32_t*)allocb((size_t)2*EHGT*4);
    size_t region = off;
    // ---- conv scratch ----
    float* q_i  = (float*)allocb((size_t)NI*DD*4);
    float* q_d  = (float*)allocb((size_t)ND*DD*4);
    u16* ka16 = (u16*)allocb((size_t)4*NI*DD*2);   // bf16 KA; also combine f32 temp
    u16* vm16 = (u16*)allocb((size_t)4*NI*DD*2);
    float* xacc_i= (float*)allocb((size_t)NI*DD*4);
    float* xacc_d= (float*)allocb((size_t)ND*DD*4);
    u16* bcur_h = (u16*)allocb((size_t)NROW*DD*2);
    u16* bcur_l = (u16*)allocb((size_t)NROW*DD*2);
    u16* bagg_h = (u16*)allocb((size_t)NROW*DD*2);
    u16* bagg_l = (u16*)allocb((size_t)NROW*DD*2);
    // ---- pooling/transformer overlay ----
    off = region;
    float* hvec = (float*)allocb(NROW*4);
    float* pscore = (float*)allocb(NROW*4);
    int* seln   = (int*)allocb(BB*KPOOL*4);
    float* sels = (float*)allocb(BB*KPOOL*4);
    float* xp   = (float*)allocb((size_t)BB*KPOOL*DD*4);
    float* o2   = (float*)allocb((size_t)BB*KPOOL*DD*4);
    float* gatt = (float*)allocb((size_t)BB*KPOOL*DD*4);
    u16* bxp_h = (u16*)allocb((size_t)BB*KPOOL*DD*2);
    u16* bxp_l = (u16*)allocb((size_t)BB*KPOOL*DD*2);
    u16* qbh = (u16*)allocb((size_t)BB*KPOOL*DD*2);
    u16* kbh = (u16*)allocb((size_t)BB*KPOOL*DD*2);
    u16* vbh = (u16*)allocb((size_t)BB*KPOOL*DD*2);
    u16* bao_h = (u16*)allocb((size_t)BB*KPOOL*DD*2);
    u16* bao_l = (u16*)allocb((size_t)BB*KPOOL*DD*2);

    const int st_tab[2][4] = {{0,1,0,0},{0,0,1,0}};
    const int dt_tab[2][4] = {{0,0,1,0},{0,1,0,0}};
    const int MR = BB*KPOOL;

    fill_u32<<<(2*BB*512+255)/256,256,0,stream>>>((uint32_t*)ubuf, 0u, 2*BB*512);
    float* wtkF = (float*)ka16;
    float* wtvF = (float*)ka16 + 16*MAT;
    combine_all<<<dim3(256,32),256,0,stream>>>(hgt_Wk, hgt_Wv, hgt_arel, hgt_mrel, wtkF, wtvF);
    WCArgs wc;
    wc.in[0]=wtkF;   wc.oh[0]=bwtk_h; wc.ol[0]=bwtk_l; wc.cnt[0]=16;
    wc.in[1]=wtvF;   wc.oh[1]=bwtv_h; wc.ol[1]=bwtv_l; wc.cnt[1]=16;
    wc.in[2]=hgt_Wq; wc.oh[2]=bwq_h;  wc.ol[2]=bwq_l;  wc.cnt[2]=8;
    wc.in[3]=hgt_Wo; wc.oh[3]=bwo_h;  wc.ol[3]=bwo_l;  wc.cnt[3]=8;
    wc.in[4]=t_wq;   wc.oh[4]=btw_h;          wc.ol[4]=btw_l;          wc.cnt[4]=1;
    wc.in[5]=t_wk;   wc.oh[5]=btw_h+1*MAT;    wc.ol[5]=btw_l+1*MAT;    wc.cnt[5]=1;
    wc.in[6]=t_wv;   wc.oh[6]=btw_h+2*MAT;    wc.ol[6]=btw_l+2*MAT;    wc.cnt[6]=1;
    wc.in[7]=t_wo;   wc.oh[7]=btw_h+3*MAT;    wc.ol[7]=btw_l+3*MAT;    wc.cnt[7]=1;
    wc.nr = 8;
    wcvt_split<<<dim3(256,52),256,0,stream>>>(wc);

    for(int bi=0;bi<2;bi++){
        int ib = bi*6;
        const float* x_inst = (const float*)d_in[ib+0];
        const float* x_data = (const float*)d_in[ib+1];
        const int* ecp = (const int*)d_in[ib+2];
        const int* eip = (const int*)d_in[ib+3];
        const int* eop = (const int*)d_in[ib+4];
        const int* ekp = (const int*)d_in[ib+5];
        const int* rows_f[4] = {ecp, eip, eop, ekp};
        const int* cols_f[4] = {ecp+EC, eip+EI, eop+EO, ekp+EK};

        // ---- CSR build (both dirs, one pass) ----
        CB2 cb;
        for(int r=0;r<4;r++){
            cb.row[r]   = rows_f[r]; cb.col[r]   = cols_f[r]; cb.dt[r]   = dt_tab[0][r]; cb.st[r]   = st_tab[0][r];
            cb.row[4+r] = cols_f[r]; cb.col[4+r] = rows_f[r]; cb.dt[4+r] = dt_tab[1][r]; cb.st[4+r] = st_tab[1][r];
        }
        cb.cnt = ccnt; cb.rowptr = rowptr; cb.einfo = einfo;
        fill_u32<<<(2*NROW+255)/256,256,0,stream>>>(ccnt, 0u, 2*NROW);
        csr_hist2<<<(2*EHGT+255)/256,256,0,stream>>>(cb);
        scan_rowptr2<<<1,1024,0,stream>>>(ccnt, rowptr);
        csr_scatter2<<<(2*EHGT+255)/256,256,0,stream>>>(cb);

        const float* cur_i = x_inst;
        const float* cur_d = x_data;
        cvt_split<<<((NROW*DD/4)+255)/256,256,0,stream>>>(cur_i, NI*DD, cur_d, ND*DD, bcur_h, bcur_l);
        for(int l=0;l<LL;l++){
            float* nxt_i = (l==0) ? xa_i : xb_i;
            float* nxt_d = (l==0) ? xa_d : xb_d;
            for(int dir=0;dir<2;dir++){
                int wb = l*2 + dir;

                // --- mega GEMM: Q(2, f32, split) + KA(4, bf16, prec=1) + VM(4, bf16, prec=1) ---
                GArgs g1; int nb1 = 0, ndx = 0;
                auto addg = [&](int srctype, const u16* Bh, const u16* Bl, float* Cm, u16* Om, int M, int mode, int prec){
                    GDesc& d = g1.d[ndx];
                    size_t ao = srctype ? (size_t)NI*DD : 0;
                    d.Ah = bcur_h + ao; d.Al = bcur_l + ao;
                    d.Bh = Bh; d.Bl = Bl; d.C = Cm;
                    d.Oh = Om; d.Ol = nullptr; d.X = nullptr; d.Xacc = nullptr; d.skipp = nullptr;
                    d.mblks = M/128; d.mode = mode; d.prec = prec;
                    nb1 += M/128; ndx++;
                };
                addg(0, bwq_h + (size_t)(wb*2+0)*MAT, bwq_l + (size_t)(wb*2+0)*MAT, q_i, nullptr, NI, 0, 0);
                addg(1, bwq_h + (size_t)(wb*2+1)*MAT, bwq_l + (size_t)(wb*2+1)*MAT, q_d, nullptr, ND, 0, 0);
                for(int r=0;r<4;r++){
                    int st = st_tab[dir][r];
                    addg(st, bwtk_h + (size_t)(wb*4+r)*MAT, bwtk_l + (size_t)(wb*4+r)*MAT,
                         nullptr, ka16 + (size_t)r*NI*DD, st ? ND : NI, 4, 1);
                }
                for(int r=0;r<4;r++){
                    int st = st_tab[dir][r];
                    addg(st, bwtv_h + (size_t)(wb*4+r)*MAT, bwtv_l + (size_t)(wb*4+r)*MAT,
                         nullptr, vm16 + (size_t)r*NI*DD, st ? ND : NI, 4, 1);
                }
                g1.nd = ndx;
                gemm_mfma<<<dim3(nb1,2),256,0,stream>>>(g1);

                // --- fused edge phase ---
                hgt_fused<<<NROW/4,256,0,stream>>>(rowptr + (size_t)dir*NROW, einfo,
                    q_i, q_d, ka16, vm16, hgt_prel + (size_t)wb*4*HH, bagg_h, bagg_l);

                // --- Wo GEMMs with fused skip/relu epilogue (split) ---
                GArgs g3; g3.nd = 2;
                for(int t=0;t<2;t++){
                    GDesc& d = g3.d[t];
                    size_t ao = t ? (size_t)NI*DD : 0;
                    d.Ah = bagg_h + ao; d.Al = bagg_l + ao;
                    d.Bh = bwo_h + (size_t)(wb*2+t)*MAT; d.Bl = bwo_l + (size_t)(wb*2+t)*MAT;
                    d.C = t ? nxt_d : nxt_i;
                    d.Oh = bcur_h + ao; d.Ol = bcur_l + ao;
                    d.X = t ? cur_d : cur_i;
                    d.Xacc = t ? xacc_d : xacc_i;
                    d.skipp = hgt_skip + wb*2 + t;
                    d.mblks = (t ? ND : NI)/128;
                    d.mode = dir ? 3 : 2;
                    d.prec = 0;
                }
                gemm_mfma<<<dim3(NI/128 + ND/128,2),256,0,stream>>>(g3);
            }
            cur_i = nxt_i;
            cur_d = nxt_d;
        }

        // -------- SAGPooling (CSR-based, no atomics) --------
        pool_h2<<<NROW/4,256,0,stream>>>(cur_i, cur_d, pool_W, hvec);
        pool_csr<<<NROW/4,256,0,stream>>>(rowptr, einfo, hvec, pool_att, pscore);
        topk_rank<<<dim3(6,BB),256,0,stream>>>(pscore, pool_bias, seln, sels);
        gather_xp<<<BB*KPOOL,256,0,stream>>>(seln, sels, cur_i, cur_d, xp, bxp_h, bxp_l);

        // -------- transformer --------
        GArgs g4; g4.nd = 3;
        for(int t=0;t<3;t++){
            GDesc& d = g4.d[t];
            d.Ah=bxp_h; d.Al=bxp_l;
            d.Bh=btw_h + (size_t)t*MAT; d.Bl=btw_l + (size_t)t*MAT;
            d.C = nullptr;
            d.Oh = (t==0)? qbh : (t==1)? kbh : vbh;
            d.Ol = nullptr;
            d.X = nullptr; d.Xacc = nullptr; d.skipp = nullptr;
            d.mblks = MR/128; d.mode = 4; d.prec = 0;
        }
        gemm_mfma<<<dim3(3*(MR/128),2),256,0,stream>>>(g4);
        attn_mfma<<<dim3(BB*HH, KPOOL/64),256,0,stream>>>(qbh, kbh, vbh, bao_h, bao_l);
        GArgs g5; g5.nd = 1;
        {
            GDesc& d = g5.d[0];
            d.Ah=bao_h; d.Al=bao_l;
            d.Bh=btw_h + (size_t)3*MAT; d.Bl=btw_l + (size_t)3*MAT;
            d.C=o2; d.Oh=nullptr; d.Ol=nullptr; d.X=nullptr; d.Xacc=nullptr; d.skipp=nullptr;
            d.mblks=MR/128; d.mode=0; d.prec=0;
        }
        gemm_mfma<<<dim3(MR/128,2),256,0,stream>>>(g5);
        ln_kernel<<<MR,256,0,stream>>>(xp, o2, ln_g, ln_b, gatt);
        feat_reduce2<<<dim3(BB,12),256,0,stream>>>(xp, gatt, bi ? vbuf : ubuf);
    }

    cosine_kernel<<<BB,64,0,stream>>>(ubuf, vbuf, out);
}